// Round 9
// baseline (553.193 us; speedup 1.0000x reference)
//
#include <hip/hip_runtime.h>

// ---------- helpers ----------
__device__ __forceinline__ unsigned short f2bf(float f) {
  unsigned u = __builtin_bit_cast(unsigned, f);
  u = u + 0x7fffu + ((u >> 16) & 1u);      // RNE
  return (unsigned short)(u >> 16);
}
__device__ __forceinline__ float bf2f(unsigned short u) {
  return __builtin_bit_cast(float, ((unsigned)u) << 16);
}

typedef __bf16 bf16x8 __attribute__((ext_vector_type(8)));
typedef float  f32x4  __attribute__((ext_vector_type(4)));
typedef unsigned short u16x8 __attribute__((ext_vector_type(8)));

#define GLD16(gp, lp) __builtin_amdgcn_global_load_lds( \
    (const __attribute__((address_space(1))) unsigned int*)(gp), \
    (__attribute__((address_space(3))) unsigned int*)(lp), 16, 0, 0)

// ---------- rmsnorm (+ optional residual) ----------
template<int HAS_DELTA, int WRITE_SUM, int WRITE_N32>
__global__ __launch_bounds__(256) void resrms_k(const float* __restrict__ xin,
    const float* __restrict__ delta, float* __restrict__ xsum,
    unsigned short* __restrict__ nbf, float* __restrict__ nf32) {
  int row = blockIdx.x, tid = threadIdx.x;
  size_t base = ((size_t)row << 10) + ((size_t)tid << 2);
  float4 v = *(const float4*)(xin + base);
  if (HAS_DELTA) {
    float4 d = *(const float4*)(delta + base);
    v.x += d.x; v.y += d.y; v.z += d.z; v.w += d.w;
  }
  if (WRITE_SUM) *(float4*)(xsum + base) = v;
  float ss = v.x*v.x + v.y*v.y + v.z*v.z + v.w*v.w;
  #pragma unroll
  for (int off = 32; off; off >>= 1) ss += __shfl_xor(ss, off);
  __shared__ float ws4[4];
  if ((tid & 63) == 0) ws4[tid >> 6] = ss;
  __syncthreads();
  float tot = ws4[0] + ws4[1] + ws4[2] + ws4[3];
  float sc = rsqrtf(tot * (1.0f / 1024.0f) + 1e-5f);
  *(ushort4*)(nbf + base) = make_ushort4(f2bf(v.x*sc), f2bf(v.y*sc), f2bf(v.z*sc), f2bf(v.w*sc));
  if (WRITE_N32) {
    float4 n; n.x = v.x*sc; n.y = v.y*sc; n.z = v.z*sc; n.w = v.w*sc;
    *(float4*)(nf32 + base) = n;
  }
}

// ---------- transpose+convert: W[K][ldw] f32 -> Wt[Npad][K] bf16 ----------
__global__ void transp_k(const float* __restrict__ W, unsigned short* __restrict__ Wt,
                         int K, int Ncols, int Npad, int col_off, int ldw) {
  __shared__ float t[32][33];
  int n0 = blockIdx.x << 5, k0 = blockIdx.y << 5;
  int tx = threadIdx.x, ty = threadIdx.y;
  #pragma unroll
  for (int rr = 0; rr < 32; rr += 8) {
    int k = k0 + rr + ty, n = n0 + tx;
    t[rr + ty][tx] = (n < Ncols) ? W[(size_t)k * ldw + col_off + n] : 0.f;
  }
  __syncthreads();
  #pragma unroll
  for (int rr = 0; rr < 32; rr += 8) {
    int nrow = n0 + rr + ty;
    Wt[(size_t)nrow * K + k0 + tx] = f2bf(t[tx][rr + ty]);
  }
}

// ---------- 8-phase 256x256 bf16 MFMA GEMM (m201-style): C = A[M][K] * Bt[N][K]^T ----------
// 512 thr = 8 waves (2M x 4N), wave tile 128x64, acc 8x4. BK=64.
// LDS 128KB: 2 bufs x {A: 2 halves x 128x64, B: same}. Chunk swizzle pc = c ^ (r&7), both sides.
// Per phase: {ds_read 0/4/8/12 || stage 1 half-tile} -> barrier -> lgkmcnt(0) -> 16 MFMA -> barrier.
// vmcnt(4) only at phases 4/8 (counted, never drains mid-loop). Stage plan per iter (tiles t,t+1):
// ph1:A0(t+1) ph2:A1(t+1) ph3:B0(t+2) ph4:B1(t+2) ph5:A0(t+2) ph6:A1(t+2) ph7:B0(t+3) ph8:B1(t+3)
template<int EPI>   // 0=f32, 1=bf16, 2=erf->bf16
__global__ __launch_bounds__(512, 2) void gemm8_k(const unsigned short* __restrict__ A,
    const unsigned short* __restrict__ Bt, void* __restrict__ Cout,
    int M, int N, int K, int ntx) {
  __shared__ unsigned short lds[2 * 32768];   // 128 KiB
  const int tid = threadIdx.x;
  const int w = tid >> 6, lane = tid & 63;
  const int fr = lane & 15, g = lane >> 4;
  const int wmi = w >> 2, wni = w & 3;
  // XCD bijective swizzle + 2D stripe
  const int nwg = gridDim.x;
  const int nty = nwg / ntx;
  const int l = (blockIdx.x & 7) * (nwg >> 3) + (blockIdx.x >> 3);
  const int S = ((ntx & 3) == 0) ? 4 : (((ntx & 1) == 0) ? 2 : 1);
  const int sw = S * nty;
  const int s_ = l / sw, r_ = l - s_ * sw;
  const int bx = s_ * S + (r_ % S);
  const int by = r_ / S;
  const int m0 = by << 8, n0 = bx << 8;

  f32x4 acc[8][4];
  #pragma unroll
  for (int i = 0; i < 8; ++i)
    #pragma unroll
    for (int j = 0; j < 4; ++j) acc[i][j] = (f32x4){0.f, 0.f, 0.f, 0.f};

  // staging source (inverse-swizzled): slot = tid (+512 for 2nd load); row r0 (+64), phys chunk pc
  const int r0 = tid >> 3, pc = tid & 7;
  const int lc = pc ^ (r0 & 7);              // same for r0+64
  const unsigned short* Abase = A + (size_t)(m0 + r0) * K + (lc << 3);
  const unsigned short* Bbase = Bt + (size_t)(n0 + r0) * K + (lc << 3);
  const size_t aK64 = (size_t)64 * K, aK128 = (size_t)128 * K;

#define STG_A(h_, kt_, bb_) { \
    const unsigned short* s0_ = Abase + (size_t)(h_) * aK128 + ((size_t)(kt_) << 6); \
    unsigned short* d0_ = lds + (bb_) * 32768 + (h_) * 8192 + (w << 9); \
    GLD16(s0_, d0_); GLD16(s0_ + aK64, d0_ + 4096); }
#define STG_B(h_, kt_, bb_) { \
    const unsigned short* s0_ = Bbase + (size_t)(h_) * aK128 + ((size_t)(kt_) << 6); \
    unsigned short* d0_ = lds + (bb_) * 32768 + 16384 + (h_) * 8192 + (w << 9); \
    GLD16(s0_, d0_); GLD16(s0_ + aK64, d0_ + 4096); }

  bf16x8 Areg[4][2], Breg[4][2];
#define LDA(mh_, bb_) { \
    _Pragma("unroll") for (int mf = 0; mf < 4; ++mf) \
    _Pragma("unroll") for (int kk = 0; kk < 2; ++kk) { \
      int r = ((mh_) << 6) + (mf << 4) + fr; \
      Areg[mf][kk] = *(const bf16x8*)&lds[(bb_) * 32768 + wmi * 8192 + (r << 6) + ((((kk << 2) + g) ^ (r & 7)) << 3)]; } }
#define LDB(nh_, bb_) { \
    _Pragma("unroll") for (int nf2 = 0; nf2 < 2; ++nf2) \
    _Pragma("unroll") for (int kk = 0; kk < 2; ++kk) { \
      int nf = ((nh_) << 1) + nf2; \
      int r = ((wni & 1) << 6) + (nf << 4) + fr; \
      Breg[nf][kk] = *(const bf16x8*)&lds[(bb_) * 32768 + 16384 + (wni >> 1) * 8192 + (r << 6) + ((((kk << 2) + g) ^ (r & 7)) << 3)]; } }
#define MM(mh_, nh_) { \
    __builtin_amdgcn_s_setprio(1); \
    _Pragma("unroll") for (int mf = 0; mf < 4; ++mf) \
    _Pragma("unroll") for (int nf2 = 0; nf2 < 2; ++nf2) \
    _Pragma("unroll") for (int kk = 0; kk < 2; ++kk) \
      acc[((mh_) << 2) + mf][((nh_) << 1) + nf2] = __builtin_amdgcn_mfma_f32_16x16x32_bf16( \
          Areg[mf][kk], Breg[((nh_) << 1) + nf2][kk], acc[((mh_) << 2) + mf][((nh_) << 1) + nf2], 0, 0, 0); \
    __builtin_amdgcn_s_setprio(0); }
#define BAR_LG \
    __builtin_amdgcn_s_barrier(); \
    asm volatile("s_waitcnt lgkmcnt(0)" ::: "memory"); \
    __builtin_amdgcn_sched_barrier(0);
#define ENDBAR \
    __builtin_amdgcn_s_barrier(); \
    __builtin_amdgcn_sched_barrier(0);

  // prologue: B(0), A(0), B(1); wait oldest 8 (A0,B0), leave B(1) in flight
  STG_B(0, 0, 0) STG_B(1, 0, 0) STG_A(0, 0, 0) STG_A(1, 0, 0) STG_B(0, 1, 1) STG_B(1, 1, 1)
  asm volatile("s_waitcnt vmcnt(4)" ::: "memory");
  __builtin_amdgcn_s_barrier();
  __builtin_amdgcn_sched_barrier(0);

  const int NITER = K >> 7;   // 2 K-tiles (BK=64) per iter
  for (int it = 0; it < NITER; ++it) {
    const int t = it << 1;
    const bool lastI = (it == NITER - 1);
    // ---- tile t (buf0) ----
    LDA(0, 0) LDB(0, 0)                 // ph1: 12 reads
    STG_A(0, t + 1, 1)
    BAR_LG MM(0, 0) ENDBAR
    LDB(1, 0)                           // ph2: 4 reads
    STG_A(1, t + 1, 1)
    BAR_LG MM(0, 1) ENDBAR
    LDA(1, 0)                           // ph3: 8 reads
    if (!lastI) STG_B(0, t + 2, 0)
    BAR_LG MM(1, 0) ENDBAR
    if (!lastI) STG_B(1, t + 2, 0)      // ph4: 0 reads
    BAR_LG MM(1, 1)
    if (!lastI) { asm volatile("s_waitcnt vmcnt(4)" ::: "memory"); }
    else        { asm volatile("s_waitcnt vmcnt(0)" ::: "memory"); }
    ENDBAR
    // ---- tile t+1 (buf1) ----
    LDA(0, 1) LDB(0, 1)                 // ph5
    if (!lastI) STG_A(0, t + 2, 0)
    BAR_LG MM(0, 0) ENDBAR
    LDB(1, 1)                           // ph6
    if (!lastI) STG_A(1, t + 2, 0)
    BAR_LG MM(0, 1) ENDBAR
    LDA(1, 1)                           // ph7
    if (!lastI) STG_B(0, t + 3, 1)
    BAR_LG MM(1, 0) ENDBAR
    if (!lastI) STG_B(1, t + 3, 1)      // ph8
    BAR_LG MM(1, 1)
    if (!lastI) { asm volatile("s_waitcnt vmcnt(4)" ::: "memory"); }
    else        { asm volatile("s_waitcnt vmcnt(0)" ::: "memory"); }
    ENDBAR
  }
#undef STG_A
#undef STG_B
#undef LDA
#undef LDB
#undef MM
#undef BAR_LG
#undef ENDBAR

  // ---- epilogue: 4 slabs of 64 rows via LDS, contiguous 16B stores ----
  asm volatile("s_waitcnt vmcnt(0)" ::: "memory");
  __syncthreads();
  float (*eps)[260] = (float(*)[260])lds;   // 64 x 260 x 4B = 65 KB
  const int er = tid >> 3, ec0 = (tid & 7) << 5;
  #pragma unroll
  for (int slab = 0; slab < 4; ++slab) {
    if (wmi == (slab >> 1)) {
      const int mhs = slab & 1;
      #pragma unroll
      for (int mf = 0; mf < 4; ++mf)
        #pragma unroll
        for (int nf = 0; nf < 4; ++nf)
          #pragma unroll
          for (int rr = 0; rr < 4; ++rr)
            eps[(mf << 4) + (g << 2) + rr][(wni << 6) + (nf << 4) + fr] = acc[(mhs << 2) + mf][nf][rr];
    }
    __syncthreads();
    const int grow = m0 + (slab << 6) + er;
    if (EPI == 0) {
      float* orow = (float*)Cout + (size_t)grow * N + n0 + ec0;
      #pragma unroll
      for (int u = 0; u < 8; ++u) {
        int col = n0 + ec0 + (u << 2);
        if (col < N) {
          float4 v; v.x = eps[er][ec0 + (u << 2)]; v.y = eps[er][ec0 + (u << 2) + 1];
          v.z = eps[er][ec0 + (u << 2) + 2]; v.w = eps[er][ec0 + (u << 2) + 3];
          *(float4*)(orow + (u << 2)) = v;
        }
      }
    } else {
      unsigned short* orow = (unsigned short*)Cout + (size_t)grow * N + n0 + ec0;
      #pragma unroll
      for (int u = 0; u < 4; ++u) {
        int col = n0 + ec0 + (u << 3);
        if (col < N) {
          u16x8 pk;
          #pragma unroll
          for (int e = 0; e < 8; ++e) {
            float v = eps[er][ec0 + (u << 3) + e];
            if (EPI == 2) v = 0.5f * (1.0f + erff((v - 0.70710678f) * 2.5066283f));
            pk[e] = f2bf(v);
          }
          *(u16x8*)(orow + (u << 3)) = pk;
        }
      }
    }
    __syncthreads();
  }
}

// ---------- bf16 MFMA GEMM (m97-class, 3 blk/CU) ----------
// EPI: 0=f32, 1=bf16, 2=erf->bf16, 3=fused final: out = Ex + sigmoid(acc)*Ev (f32)
template<int EPI>
__global__ __launch_bounds__(256, 3) void gemm4_k(const unsigned short* __restrict__ A,
    const unsigned short* __restrict__ Bt, void* __restrict__ Cout,
    int M, int N, int K, int ntx, const float* __restrict__ Ex, const float* __restrict__ Ev) {
  __shared__ char smem[49152];
  unsigned short* lds = (unsigned short*)smem;
  const int tid = threadIdx.x;
  const int w = tid >> 6, lane = tid & 63;
  const int fr = lane & 15, g = lane >> 4;
  const int nwg = gridDim.x;
  const int nty = nwg / ntx;
  const int l = (blockIdx.x & 7) * (nwg >> 3) + (blockIdx.x >> 3);
  const int S = ((ntx & 3) == 0) ? 4 : (((ntx & 1) == 0) ? 2 : 1);
  const int sw = S * nty;
  const int s = l / sw, r_ = l - s * sw;
  const int bx = s * S + (r_ % S);
  const int by = r_ / S;
  const int m0 = by << 7, n0 = bx << 7;
  const int wm = (w >> 1) << 6, wn = (w & 1) << 6;

  f32x4 acc[4][4];
  #pragma unroll
  for (int i = 0; i < 4; ++i)
    #pragma unroll
    for (int j = 0; j < 4; ++j) acc[i][j] = (f32x4){0.f, 0.f, 0.f, 0.f};

  const int r0s = tid >> 2, pc0 = tid & 3;
  const int lc0 = pc0 ^ ((r0s >> 1) & 3);
  const int r1s = r0s + 64;
  const int lc1 = pc0 ^ ((r1s >> 1) & 3);
  const unsigned short* a0 = A + (size_t)(m0 + r0s) * K + (lc0 << 3);
  const unsigned short* a1 = A + (size_t)(m0 + r1s) * K + (lc1 << 3);
  const unsigned short* b0 = Bt + (size_t)(n0 + r0s) * K + (lc0 << 3);
  const unsigned short* b1 = Bt + (size_t)(n0 + r1s) * K + (lc1 << 3);
  const int wofs = w << 9;

#define STAGE4(kt_, bb_) { \
    unsigned short* d_ = lds + (bb_) * 8192 + wofs; \
    GLD16(a0 + ((kt_) << 5), d_); \
    GLD16(a1 + ((kt_) << 5), d_ + 2048); \
    GLD16(b0 + ((kt_) << 5), d_ + 4096); \
    GLD16(b1 + ((kt_) << 5), d_ + 6144); }

  const int NT = K >> 5;
  STAGE4(0, 0)
  STAGE4(1, 1)
  asm volatile("s_waitcnt vmcnt(4)" ::: "memory");
  __builtin_amdgcn_s_barrier();
  __builtin_amdgcn_sched_barrier(0);

  int cb = 0;
  for (int t = 0; t < NT; ++t) {
    const unsigned short* bufp = lds + cb * 8192;
    int sb = cb + 2; if (sb >= 3) sb -= 3;
    const int have2 = (t + 2 < NT);
    if (have2) STAGE4(t + 2, sb)
    bf16x8 af[4], bv[4];
    #pragma unroll
    for (int i = 0; i < 4; ++i) {
      int r = wm + (i << 4) + fr;
      af[i] = *(const bf16x8*)&bufp[(r << 5) + (((g ^ (r >> 1)) & 3) << 3)];
    }
    #pragma unroll
    for (int j = 0; j < 4; ++j) {
      int r = wn + (j << 4) + fr;
      bv[j] = *(const bf16x8*)&bufp[4096 + (r << 5) + (((g ^ (r >> 1)) & 3) << 3)];
    }
    __builtin_amdgcn_s_setprio(1);
    #pragma unroll
    for (int i = 0; i < 4; ++i)
      #pragma unroll
      for (int j = 0; j < 4; ++j)
        acc[i][j] = __builtin_amdgcn_mfma_f32_16x16x32_bf16(af[i], bv[j], acc[i][j], 0, 0, 0);
    __builtin_amdgcn_s_setprio(0);
    if (t + 1 < NT) {
      if (have2) { asm volatile("s_waitcnt vmcnt(4)" ::: "memory"); }
      else       { asm volatile("s_waitcnt vmcnt(0)" ::: "memory"); }
      __builtin_amdgcn_s_barrier();
      __builtin_amdgcn_sched_barrier(0);
    }
    cb = cb + 1; if (cb >= 3) cb -= 3;
  }
#undef STAGE4

  float (*eps)[132] = (float(*)[132])smem;
  const int rin = g << 2;
  const int er = tid >> 2, ec0 = (tid & 3) << 5;
  #pragma unroll
  for (int rh = 0; rh < 2; ++rh) {
    __syncthreads();
    if ((wm >> 6) == rh) {
      #pragma unroll
      for (int i = 0; i < 4; ++i)
        #pragma unroll
        for (int j = 0; j < 4; ++j)
          #pragma unroll
          for (int rr = 0; rr < 4; ++rr)
            eps[(i << 4) + rin + rr][wn + (j << 4) + fr] = acc[i][j][rr];
    }
    __syncthreads();
    int grow = m0 + (rh << 6) + er;
    if (EPI == 0 || EPI == 3) {
      float* orow = (float*)Cout + (size_t)grow * N + n0 + ec0;
      #pragma unroll
      for (int u = 0; u < 8; ++u) {
        int col = n0 + ec0 + (u << 2);
        if (col < N) {
          float4 v; v.x = eps[er][ec0 + (u<<2)]; v.y = eps[er][ec0 + (u<<2) + 1];
          v.z = eps[er][ec0 + (u<<2) + 2]; v.w = eps[er][ec0 + (u<<2) + 3];
          if (EPI == 3) {
            size_t o = (size_t)grow * N + n0 + ec0 + (u << 2);
            float4 xv = *(const float4*)(Ex + o);
            float4 vv = *(const float4*)(Ev + o);
            v.x = xv.x + vv.x / (1.f + __expf(-v.x));
            v.y = xv.y + vv.y / (1.f + __expf(-v.y));
            v.z = xv.z + vv.z / (1.f + __expf(-v.z));
            v.w = xv.w + vv.w / (1.f + __expf(-v.w));
          }
          *(float4*)(orow + (u << 2)) = v;
        }
      }
    } else {
      unsigned short* orow = (unsigned short*)Cout + (size_t)grow * N + n0 + ec0;
      #pragma unroll
      for (int u = 0; u < 4; ++u) {
        int col = n0 + ec0 + (u << 3);
        if (col < N) {
          u16x8 pk;
          #pragma unroll
          for (int e = 0; e < 8; ++e) {
            float v = eps[er][ec0 + (u << 3) + e];
            if (EPI == 2) v = 0.5f * (1.0f + erff((v - 0.70710678f) * 2.5066283f));
            pk[e] = f2bf(v);
          }
          *(u16x8*)(orow + (u << 3)) = pk;
        }
      }
    }
  }
}

// ---------- causal depthwise conv(4) + silu, with fused dt/softplus ----------
__global__ __launch_bounds__(256) void convk(const float* __restrict__ zxr,
    const float* __restrict__ conv_w, const float* __restrict__ conv_b,
    const float* __restrict__ dt_bias, float* __restrict__ xbc,
    float* __restrict__ dtb) {
  int i = blockIdx.x * 256 + threadIdx.x;     // 4*1024*2176
  if (i >= 4 * 1024 * 2176) return;
  int c = i % 2176; int bt = i / 2176; int t = bt & 1023;
  const float* col = zxr + (size_t)bt * 2208 + c;
  float acc = conv_b[c];
  float w0 = conv_w[c * 4 + 0], w1 = conv_w[c * 4 + 1], w2 = conv_w[c * 4 + 2], w3 = conv_w[c * 4 + 3];
  if (t >= 3) acc = fmaf(col[-3 * 2208], w0, acc);
  if (t >= 2) acc = fmaf(col[-2 * 2208], w1, acc);
  if (t >= 1) acc = fmaf(col[-1 * 2208], w2, acc);
  acc = fmaf(col[0], w3, acc);
  xbc[(size_t)bt * 2176 + c] = acc / (1.f + __expf(-acc));
  if (c < 32) {
    float v = zxr[(size_t)bt * 2208 + 2176 + c] + dt_bias[c];
    dtb[bt * 32 + c] = (v > 20.f) ? v : log1pf(__expf(v));
  }
}

// ---------- SSD chunked scan, stage 1 ----------
__global__ __launch_bounds__(256) void ssd1_k(const float* __restrict__ xbc,
    const float* __restrict__ dtb, const float* __restrict__ A_log,
    float* __restrict__ ydin, float* __restrict__ dhbuf, float* __restrict__ labuf) {
  __shared__ unsigned short Cs[64][68];
  __shared__ unsigned short Bsm[64][68];
  __shared__ unsigned short XT[64][68];
  __shared__ unsigned short BT[64][68];
  __shared__ unsigned short Ms[64][68];
  __shared__ float laS[64], dtS[64];
  const int id = blockIdx.x;
  const int h = id & 31, b = (id >> 5) & 3, c = id >> 7;
  const int tid = threadIdx.x, w = tid >> 6, lane = tid & 63;
  const int fr = lane & 15, g = lane >> 4;
  const size_t rowbase = (size_t)((b << 10) + (c << 6));

  {
    int r = tid >> 2, c0 = (tid & 3) << 4;
    const float* src = xbc + (rowbase + r) * 2176;
    #pragma unroll
    for (int i = 0; i < 4; ++i) {
      float4 v = *(const float4*)(src + 2112 + c0 + 4 * i);
      *(ushort4*)&Cs[r][c0 + 4 * i] = make_ushort4(f2bf(v.x), f2bf(v.y), f2bf(v.z), f2bf(v.w));
      float4 u = *(const float4*)(src + 2048 + c0 + 4 * i);
      *(ushort4*)&Bsm[r][c0 + 4 * i] = make_ushort4(f2bf(u.x), f2bf(u.y), f2bf(u.z), f2bf(u.w));
    }
  }
  {
    int r0 = (tid & 15) << 2, d0 = (tid >> 4) << 2;
    const float* src = xbc + (rowbase + r0) * 2176 + (h << 6) + d0;
    float4 v0 = *(const float4*)(src);
    float4 v1 = *(const float4*)(src + 2176);
    float4 v2 = *(const float4*)(src + 4352);
    float4 v3 = *(const float4*)(src + 6528);
    *(ushort4*)&XT[d0 + 0][r0] = make_ushort4(f2bf(v0.x), f2bf(v1.x), f2bf(v2.x), f2bf(v3.x));
    *(ushort4*)&XT[d0 + 1][r0] = make_ushort4(f2bf(v0.y), f2bf(v1.y), f2bf(v2.y), f2bf(v3.y));
    *(ushort4*)&XT[d0 + 2][r0] = make_ushort4(f2bf(v0.z), f2bf(v1.z), f2bf(v2.z), f2bf(v3.z));
    *(ushort4*)&XT[d0 + 3][r0] = make_ushort4(f2bf(v0.w), f2bf(v1.w), f2bf(v2.w), f2bf(v3.w));
  }
  if (w == 0) {
    float Ah = -__expf(A_log[h]);
    float dtv = dtb[(rowbase + lane) * 32 + h];
    float v = dtv * Ah;
    #pragma unroll
    for (int off = 1; off < 64; off <<= 1) {
      float u = __shfl_up(v, off);
      if (lane >= off) v += u;
    }
    laS[lane] = v; dtS[lane] = dtv;
    labuf[(size_t)((((b << 4) | c) << 5 | h) << 6) + lane] = v;
  }
  __syncthreads();

  const int wr = w >> 1, wc = w & 1;
  f32x4 gf[2][2];
  #pragma unroll
  for (int i = 0; i < 2; ++i)
    #pragma unroll
    for (int j = 0; j < 2; ++j) gf[i][j] = (f32x4){0.f, 0.f, 0.f, 0.f};
  {
    int r0 = (tid & 15) << 2, d0 = (tid >> 4) << 2;
    const float* src = xbc + (rowbase + r0) * 2176 + 2048 + d0;
    float la63 = laS[63];
    float4 v0 = *(const float4*)(src);
    float4 v1 = *(const float4*)(src + 2176);
    float4 v2 = *(const float4*)(src + 4352);
    float4 v3 = *(const float4*)(src + 6528);
    float w0 = __expf(la63 - laS[r0 + 0]) * dtS[r0 + 0];
    float w1 = __expf(la63 - laS[r0 + 1]) * dtS[r0 + 1];
    float w2 = __expf(la63 - laS[r0 + 2]) * dtS[r0 + 2];
    float w3 = __expf(la63 - laS[r0 + 3]) * dtS[r0 + 3];
    *(ushort4*)&BT[d0 + 0][r0] = make_ushort4(f2bf(v0.x*w0), f2bf(v1.x*w1), f2bf(v2.x*w2), f2bf(v3.x*w3));
    *(ushort4*)&BT[d0 + 1][r0] = make_ushort4(f2bf(v0.y*w0), f2bf(v1.y*w1), f2bf(v2.y*w2), f2bf(v3.y*w3));
    *(ushort4*)&BT[d0 + 2][r0] = make_ushort4(f2bf(v0.z*w0), f2bf(v1.z*w1), f2bf(v2.z*w2), f2bf(v3.z*w3));
    *(ushort4*)&BT[d0 + 3][r0] = make_ushort4(f2bf(v0.w*w0), f2bf(v1.w*w1), f2bf(v2.w*w2), f2bf(v3.w*w3));
  }
  #pragma unroll
  for (int ks = 0; ks < 2; ++ks) {
    bf16x8 ca[2], bb[2];
    #pragma unroll
    for (int i = 0; i < 2; ++i) ca[i] = *(const bf16x8*)&Cs[(wr << 5) + (i << 4) + fr][(ks << 5) + (g << 3)];
    #pragma unroll
    for (int j = 0; j < 2; ++j) bb[j] = *(const bf16x8*)&Bsm[(wc << 5) + (j << 4) + fr][(ks << 5) + (g << 3)];
    #pragma unroll
    for (int i = 0; i < 2; ++i)
      #pragma unroll
      for (int j = 0; j < 2; ++j)
        gf[i][j] = __builtin_amdgcn_mfma_f32_16x16x32_bf16(ca[i], bb[j], gf[i][j], 0, 0, 0);
  }
  #pragma unroll
  for (int i = 0; i < 2; ++i) {
    #pragma unroll
    for (int j = 0; j < 2; ++j) {
      int s = (wc << 5) + (j << 4) + fr;
      float la_s = laS[s], dt_s = dtS[s];
      #pragma unroll
      for (int rr = 0; rr < 4; ++rr) {
        int t = (wr << 5) + (i << 4) + (g << 2) + rr;
        float e = __expf(fminf(laS[t] - la_s, 0.f));
        float val = (s <= t) ? gf[i][j][rr] * e * dt_s : 0.f;
        Ms[t][s] = f2bf(val);
      }
    }
  }
  __syncthreads();

  f32x4 yf[2][2], hf[2][2];
  #pragma unroll
  for (int i = 0; i < 2; ++i)
    #pragma unroll
    for (int j = 0; j < 2; ++j) { yf[i][j] = (f32x4){0.f,0.f,0.f,0.f}; hf[i][j] = (f32x4){0.f,0.f,0.f,0.f}; }
  #pragma unroll
  for (int ks = 0; ks < 2; ++ks) {
    bf16x8 ma[2], ba[2], xb[2];
    #pragma unroll
    for (int i = 0; i < 2; ++i) {
      ma[i] = *(const bf16x8*)&Ms[(wr << 5) + (i << 4) + fr][(ks << 5) + (g << 3)];
      ba[i] = *(const bf16x8*)&BT[(wr << 5) + (i << 4) + fr][(ks << 5) + (g << 3)];
    }
    #pragma unroll
    for (int j = 0; j < 2; ++j) xb[j] = *(const bf16x8*)&XT[(wc << 5) + (j << 4) + fr][(ks << 5) + (g << 3)];
    #pragma unroll
    for (int i = 0; i < 2; ++i)
      #pragma unroll
      for (int j = 0; j < 2; ++j) {
        yf[i][j] = __builtin_amdgcn_mfma_f32_16x16x32_bf16(ma[i], xb[j], yf[i][j], 0, 0, 0);
        hf[i][j] = __builtin_amdgcn_mfma_f32_16x16x32_bf16(ba[i], xb[j], hf[i][j], 0, 0, 0);
      }
  }
  float* dhb = dhbuf + ((size_t)(((c << 2) + b) * 32 + h) << 12);
  #pragma unroll
  for (int i = 0; i < 2; ++i) {
    #pragma unroll
    for (int j = 0; j < 2; ++j) {
      int p = (wc << 5) + (j << 4) + fr;
      #pragma unroll
      for (int rr = 0; rr < 4; ++rr) {
        int t = (wr << 5) + (i << 4) + (g << 2) + rr;
        ydin[((rowbase + t) << 11) + (h << 6) + p] = yf[i][j][rr];
        dhb[(t << 6) + p] = hf[i][j][rr];
      }
    }
  }
}

// ---------- SSD stage 2 ----------
__global__ __launch_bounds__(256) void ssd2_k(const float* __restrict__ dhbuf,
    const float* __restrict__ labuf, float* __restrict__ hseq) {
  int idx = blockIdx.x * 256 + threadIdx.x;
  int np = idx & 4095;
  int h = (idx >> 12) & 31, b = idx >> 17;
  float carry = 0.f;
  #pragma unroll
  for (int c = 0; c < 16; ++c) {
    size_t o = ((size_t)(((c << 2) + b) * 32 + h) << 12) + np;
    hseq[o] = carry;
    float ec = __expf(labuf[(size_t)((((b << 4) | c) << 5 | h) << 6) + 63]);
    carry = fmaf(ec, carry, dhbuf[o]);
  }
}

// ---------- SSD stage 3 ----------
__global__ __launch_bounds__(256) void ssd3_k(const float* __restrict__ xbc,
    const float* __restrict__ hseq, const float* __restrict__ labuf,
    const float* __restrict__ Dv, float* __restrict__ ydin) {
  __shared__ unsigned short Cs[64][68];
  __shared__ unsigned short HT[64][68];
  __shared__ float laS[64];
  const int id = blockIdx.x;
  const int h = id & 31, b = (id >> 5) & 3, c = id >> 7;
  const int tid = threadIdx.x, w = tid >> 6, lane = tid & 63;
  const int fr = lane & 15, g = lane >> 4;
  const size_t rowbase = (size_t)((b << 10) + (c << 6));
  {
    int r = tid >> 2, c0 = (tid & 3) << 4;
    const float* src = xbc + (rowbase + r) * 2176 + 2112 + c0;
    #pragma unroll
    for (int i = 0; i < 4; ++i) {
      float4 v = *(const float4*)(src + 4 * i);
      *(ushort4*)&Cs[r][c0 + 4 * i] = make_ushort4(f2bf(v.x), f2bf(v.y), f2bf(v.z), f2bf(v.w));
    }
  }
  {
    const float* hb = hseq + ((size_t)(((c << 2) + b) * 32 + h) << 12);
    int n0 = (tid & 15) << 2, p0 = (tid >> 4) << 2;
    float4 v0 = *(const float4*)(hb + ((n0 + 0) << 6) + p0);
    float4 v1 = *(const float4*)(hb + ((n0 + 1) << 6) + p0);
    float4 v2 = *(const float4*)(hb + ((n0 + 2) << 6) + p0);
    float4 v3 = *(const float4*)(hb + ((n0 + 3) << 6) + p0);
    *(ushort4*)&HT[p0 + 0][n0] = make_ushort4(f2bf(v0.x), f2bf(v1.x), f2bf(v2.x), f2bf(v3.x));
    *(ushort4*)&HT[p0 + 1][n0] = make_ushort4(f2bf(v0.y), f2bf(v1.y), f2bf(v2.y), f2bf(v3.y));
    *(ushort4*)&HT[p0 + 2][n0] = make_ushort4(f2bf(v0.z), f2bf(v1.z), f2bf(v2.z), f2bf(v3.z));
    *(ushort4*)&HT[p0 + 3][n0] = make_ushort4(f2bf(v0.w), f2bf(v1.w), f2bf(v2.w), f2bf(v3.w));
  }
  if (tid < 64) laS[tid] = labuf[(size_t)((((b << 4) | c) << 5 | h) << 6) + tid];
  __syncthreads();
  const int wr = w >> 1, wc = w & 1;
  f32x4 yf[2][2];
  #pragma unroll
  for (int i = 0; i < 2; ++i)
    #pragma unroll
    for (int j = 0; j < 2; ++j) yf[i][j] = (f32x4){0.f, 0.f, 0.f, 0.f};
  #pragma unroll
  for (int ks = 0; ks < 2; ++ks) {
    bf16x8 ca[2], hv[2];
    #pragma unroll
    for (int i = 0; i < 2; ++i) ca[i] = *(const bf16x8*)&Cs[(wr << 5) + (i << 4) + fr][(ks << 5) + (g << 3)];
    #pragma unroll
    for (int j = 0; j < 2; ++j) hv[j] = *(const bf16x8*)&HT[(wc << 5) + (j << 4) + fr][(ks << 5) + (g << 3)];
    #pragma unroll
    for (int i = 0; i < 2; ++i)
      #pragma unroll
      for (int j = 0; j < 2; ++j)
        yf[i][j] = __builtin_amdgcn_mfma_f32_16x16x32_bf16(ca[i], hv[j], yf[i][j], 0, 0, 0);
  }
  float Dh = Dv[h];
  #pragma unroll
  for (int i = 0; i < 2; ++i) {
    #pragma unroll
    for (int j = 0; j < 2; ++j) {
      int p = (wc << 5) + (j << 4) + fr;
      #pragma unroll
      for (int rr = 0; rr < 4; ++rr) {
        int t = (wr << 5) + (i << 4) + (g << 2) + rr;
        size_t yo = ((rowbase + t) << 11) + (h << 6) + p;
        float xv = xbc[(rowbase + t) * 2176 + (h << 6) + p];
        ydin[yo] = ydin[yo] + __expf(laS[t]) * yf[i][j][rr] + Dh * xv;
      }
    }
  }
}

// ---------- g = ydin * silu(z); rmsnorm(2048) * mnorm_w -> bf16 ----------
__global__ __launch_bounds__(256) void gnormk(const float* __restrict__ ydin,
    const unsigned short* __restrict__ zbf, const float* __restrict__ mw,
    unsigned short* __restrict__ gbf) {
  int row = blockIdx.x, tid = threadIdx.x;
  size_t base = ((size_t)row << 11) + ((size_t)tid << 3);
  float4 y0 = *(const float4*)(ydin + base);
  float4 y1 = *(const float4*)(ydin + base + 4);
  ushort4 z0 = *(const ushort4*)(zbf + base);
  ushort4 z1 = *(const ushort4*)(zbf + base + 4);
  float g[8];
  {
    float z;
    z = bf2f(z0.x); g[0] = y0.x * (z / (1.f + __expf(-z)));
    z = bf2f(z0.y); g[1] = y0.y * (z / (1.f + __expf(-z)));
    z = bf2f(z0.z); g[2] = y0.z * (z / (1.f + __expf(-z)));
    z = bf2f(z0.w); g[3] = y0.w * (z / (1.f + __expf(-z)));
    z = bf2f(z1.x); g[4] = y1.x * (z / (1.f + __expf(-z)));
    z = bf2f(z1.y); g[5] = y1.y * (z / (1.f + __expf(-z)));
    z = bf2f(z1.z); g[6] = y1.z * (z / (1.f + __expf(-z)));
    z = bf2f(z1.w); g[7] = y1.w * (z / (1.f + __expf(-z)));
  }
  float ss = 0.f;
  #pragma unroll
  for (int k = 0; k < 8; ++k) ss += g[k] * g[k];
  #pragma unroll
  for (int off = 32; off; off >>= 1) ss += __shfl_xor(ss, off);
  __shared__ float ws4[4];
  if ((tid & 63) == 0) ws4[tid >> 6] = ss;
  __syncthreads();
  float tot = ws4[0] + ws4[1] + ws4[2] + ws4[3];
  float sc = rsqrtf(tot * (1.f / 2048.f) + 1e-5f);
  int c0 = tid << 3;
  float4 m0 = *(const float4*)(mw + c0);
  float4 m1 = *(const float4*)(mw + c0 + 4);
  *(ushort4*)(gbf + base)     = make_ushort4(f2bf(g[0]*sc*m0.x), f2bf(g[1]*sc*m0.y), f2bf(g[2]*sc*m0.z), f2bf(g[3]*sc*m0.w));
  *(ushort4*)(gbf + base + 4) = make_ushort4(f2bf(g[4]*sc*m1.x), f2bf(g[5]*sc*m1.y), f2bf(g[6]*sc*m1.z), f2bf(g[7]*sc*m1.w));
}

// ---------- MQA causal attention (MFMA flash), bf16 in/out ----------
__global__ __launch_bounds__(256) void attnk(const unsigned short* __restrict__ qkv,
                                             unsigned short* __restrict__ ybf) {
  __shared__ unsigned short Qs[64][72];
  __shared__ unsigned short Ks[64][72];
  __shared__ unsigned short VT[64][72];
  __shared__ unsigned short Ps[4][16][72];
  const int id = blockIdx.x;
  const int b = id & 3, h = (id >> 2) & 15, qt = id >> 6;
  const int t0 = qt << 6;
  const int tid = threadIdx.x, w = tid >> 6, lane = tid & 63;
  const int fr = lane & 15, g = lane >> 4;
  {
    int r = tid >> 2, d0 = (tid & 3) << 4;
    const unsigned short* src = qkv + ((size_t)((b << 10) | (t0 + r))) * 1152 + (h << 6) + d0;
    *(uint4*)&Qs[r][d0]     = *(const uint4*)(src);
    *(uint4*)&Qs[r][d0 + 8] = *(const uint4*)(src + 8);
  }
  __syncthreads();
  bf16x8 afQ0 = *(const bf16x8*)&Qs[(w << 4) + fr][g << 3];
  bf16x8 afQ1 = *(const bf16x8*)&Qs[(w << 4) + fr][32 + (g << 3)];
  f32x4 acc_o[4];
  #pragma unroll
  for (int i = 0; i < 4; ++i) acc_o[i] = (f32x4){0.f, 0.f, 0.f, 0.f};
  float m[4] = {-1e30f, -1e30f, -1e30f, -1e30f};
  float l[4] = {0.f, 0.f, 0.f, 0.f};
  const int qrow = t0 + (w << 4) + (g << 2);
  for (int kt = 0; kt <= qt; ++kt) {
    const int s0 = kt << 6;
    __syncthreads();
    {
      int r = tid >> 2, d0 = (tid & 3) << 4;
      const unsigned short* src = qkv + ((size_t)((b << 10) | (s0 + r))) * 1152 + 1024 + d0;
      *(uint4*)&Ks[r][d0]     = *(const uint4*)(src);
      *(uint4*)&Ks[r][d0 + 8] = *(const uint4*)(src + 8);
    }
    {
      int r0 = (tid & 15) << 2, d0 = (tid >> 4) << 2;
      const unsigned short* src = qkv + ((size_t)((b << 10) | (s0 + r0))) * 1152 + 1088 + d0;
      ushort4 v0 = *(const ushort4*)(src);
      ushort4 v1 = *(const ushort4*)(src + 1152);
      ushort4 v2 = *(const ushort4*)(src + 2304);
      ushort4 v3 = *(const ushort4*)(src + 3456);
      *(ushort4*)&VT[d0 + 0][r0] = make_ushort4(v0.x, v1.x, v2.x, v3.x);
      *(ushort4*)&VT[d0 + 1][r0] = make_ushort4(v0.y, v1.y, v2.y, v3.y);
      *(ushort4*)&VT[d0 + 2][r0] = make_ushort4(v0.z, v1.z, v2.z, v3.z);
      *(ushort4*)&VT[d0 + 3][r0] = make_ushort4(v0.w, v1.w, v2.w, v3.w);
    }
    __syncthreads();
    f32x4 s4[4];
    #pragma unroll
    for (int jt = 0; jt < 4; ++jt) {
      bf16x8 b0 = *(const bf16x8*)&Ks[(jt << 4) + fr][g << 3];
      bf16x8 b1 = *(const bf16x8*)&Ks[(jt << 4) + fr][32 + (g << 3)];
      f32x4 z4 = (f32x4){0.f, 0.f, 0.f, 0.f};
      z4 = __builtin_amdgcn_mfma_f32_16x16x32_bf16(afQ0, b0, z4, 0, 0, 0);
      z4 = __builtin_amdgcn_mfma_f32_16x16x32_bf16(afQ1, b1, z4, 0, 0, 0);
      s4[jt] = z4 * 0.125f;
    }
    if (kt == qt) {
      #pragma unroll
      for (int jt = 0; jt < 4; ++jt) {
        int key = s0 + (jt << 4) + fr;
        #pragma unroll
        for (int r = 0; r < 4; ++r)
          if (key > qrow + r) s4[jt][r] = -1e30f;
      }
    }
    #pragma unroll
    for (int r = 0; r < 4; ++r) {
      float mt = fmaxf(fmaxf(s4[0][r], s4[1][r]), fmaxf(s4[2][r], s4[3][r]));
      #pragma unroll
      for (int off = 8; off; off >>= 1) mt = fmaxf(mt, __shfl_xor(mt, off));
      float mn = fmaxf(m[r], mt);
      float scl = __expf(m[r] - mn);
      m[r] = mn;
      float ps = 0.f;
      #pragma unroll
      for (int jt = 0; jt < 4; ++jt) {
        float p = __expf(s4[jt][r] - mn);
        ps += p;
        Ps[w][(g << 2) + r][(jt << 4) + fr] = f2bf(p);
      }
      #pragma unroll
      for (int off = 8; off; off >>= 1) ps += __shfl_xor(ps, off);
      l[r] = l[r] * scl + ps;
      acc_o[0][r] *= scl; acc_o[1][r] *= scl; acc_o[2][r] *= scl; acc_o[3][r] *= scl;
    }
    #pragma unroll
    for (int ks = 0; ks < 2; ++ks) {
      bf16x8 ap = *(const bf16x8*)&Ps[w][fr][(ks << 5) + (g << 3)];
      #pragma unroll
      for (int dt = 0; dt < 4; ++dt) {
        bf16x8 bv = *(const bf16x8*)&VT[(dt << 4) + fr][(ks << 5) + (g << 3)];
        acc_o[dt] = __builtin_amdgcn_mfma_f32_16x16x32_bf16(ap, bv, acc_o[dt], 0, 0, 0);
      }
    }
  }
  #pragma unroll
  for (int dt = 0; dt < 4; ++dt) {
    #pragma unroll
    for (int r = 0; r < 4; ++r) {
      float o = acc_o[dt][r] / l[r];
      int t = t0 + (w << 4) + (g << 2) + r;
      ybf[(((size_t)((b << 10) | t)) << 10) + (h << 6) + (dt << 4) + fr] = f2bf(o);
    }
  }
}

// ---------- cmix token-shift mix -> xk, xr (bf16) ----------
__global__ __launch_bounds__(256) void mixk(const float* __restrict__ xn3,
    const float* __restrict__ tmk, const float* __restrict__ tmr,
    unsigned short* __restrict__ xkbf, unsigned short* __restrict__ xrbf) {
  int idx4 = blockIdx.x * 256 + threadIdx.x;
  int col = (idx4 & 255) << 2;
  int row = idx4 >> 8;
  int t = row & 1023;
  size_t off = ((size_t)idx4) << 2;
  float4 cur = *(const float4*)(xn3 + off);
  float4 prev = make_float4(0.f, 0.f, 0.f, 0.f);
  if (t > 0) prev = *(const float4*)(xn3 + off - 1024);
  float4 tk = *(const float4*)(tmk + col);
  float4 tr = *(const float4*)(tmr + col);
  float dx = prev.x - cur.x, dy = prev.y - cur.y, dz = prev.z - cur.z, dw = prev.w - cur.w;
  *(ushort4*)(xkbf + off) = make_ushort4(
      f2bf(cur.x + dx * tk.x), f2bf(cur.y + dy * tk.y), f2bf(cur.z + dz * tk.z), f2bf(cur.w + dw * tk.w));
  *(ushort4*)(xrbf + off) = make_ushort4(
      f2bf(cur.x + dx * tr.x), f2bf(cur.y + dy * tr.y), f2bf(cur.z + dz * tr.z), f2bf(cur.w + dw * tr.w));
}

// ---------- host launcher ----------
extern "C" void kernel_launch(void* const* d_in, const int* in_sizes, int n_in,
                              void* d_out, int out_size, void* d_ws, size_t ws_size,
                              hipStream_t stream) {
  (void)in_sizes; (void)n_in; (void)out_size;
  const float* x        = (const float*)d_in[0];
  const float* in_proj  = (const float*)d_in[1];
  const float* conv_w   = (const float*)d_in[2];
  const float* conv_b   = (const float*)d_in[3];
  const float* dt_bias  = (const float*)d_in[4];
  const float* A_log    = (const float*)d_in[5];
  const float* Dvec     = (const float*)d_in[6];
  const float* mnorm_w  = (const float*)d_in[7];
  const float* out_proj = (const float*)d_in[8];
  const float* attn_w   = (const float*)d_in[9];
  const float* proj_w   = (const float*)d_in[10];
  const float* tmk      = (const float*)d_in[11];
  const float* tmr      = (const float*)d_in[12];
  const float* key_w    = (const float*)d_in[13];
  const float* recept_w = (const float*)d_in[14];
  const float* value_w  = (const float*)d_in[15];
  float* out = (float*)d_out;

  if (ws_size < 199229440ull) return;

  char* ws = (char*)d_ws;
  unsigned short* Wt   = (unsigned short*)(ws + 0);
  unsigned short* Abf  = (unsigned short*)(ws + 8912896ull);
  unsigned short* Abf2 = (unsigned short*)(ws + 42467328ull);
  float* bigF = (float*)(ws + 59244544ull);
  float* big1 = (float*)(ws + 95420416ull);
  float* big2 = (float*)(ws + 131072000ull);
  float* x1   = (float*)(ws + 164626432ull);
  float* xn3  = (float*)(ws + 181403648ull);
  float* dtb  = (float*)(ws + 198180864ull);
  float* labuf= (float*)(ws + 198705152ull);
  unsigned short* zbf  = Abf2;
  unsigned short* xkbf = Abf2;
  unsigned short* xrbf = Abf2 + 4194304;
  float* dhbuf = bigF;
  float* hseq  = (float*)Abf;
  unsigned short* qkvbf = (unsigned short*)big1;

  dim3 b256(256);
  dim3 b512(512);
  dim3 tb(32, 8);

  // ===== Phase A: mamba2 =====
  resrms_k<0, 0, 0><<<4096, b256, 0, stream>>>(x, nullptr, nullptr, Abf, nullptr);
  transp_k<<<dim3(64, 32), tb, 0, stream>>>(in_proj, Wt, 1024, 2048, 2048, 0, 4256);
  gemm8_k<1><<<128, b512, 0, stream>>>(Abf, Wt, zbf, 4096, 2048, 1024, 8);               // z (bf16)
  transp_k<<<dim3(72, 32), tb, 0, stream>>>(in_proj, Wt, 1024, 2208, 2304, 2048, 4256);
  gemm8_k<0><<<144, b512, 0, stream>>>(Abf, Wt, bigF, 4096, 2208, 1024, 9);              // xBC+dt (f32)
  convk<<<34816, b256, 0, stream>>>(bigF, conv_w, conv_b, dt_bias, big1, dtb);           // xbc_act + dt
  ssd1_k<<<2048, b256, 0, stream>>>(big1, dtb, A_log, big2, dhbuf, labuf);               // Y_intra, dh, la
  ssd2_k<<<2048, b256, 0, stream>>>(dhbuf, labuf, hseq);                                 // chunk states
  ssd3_k<<<2048, b256, 0, stream>>>(big1, hseq, labuf, Dvec, big2);                      // ydin final
  gnormk<<<4096, b256, 0, stream>>>(big2, zbf, mnorm_w, Abf);                            // g (bf16)
  transp_k<<<dim3(32, 64), tb, 0, stream>>>(out_proj, Wt, 2048, 1024, 1024, 0, 1024);
  gemm4_k<0><<<256, b256, 0, stream>>>(Abf, Wt, big1, 4096, 1024, 2048, 8, nullptr, nullptr);   // mo
  resrms_k<1, 1, 0><<<4096, b256, 0, stream>>>(x, big1, x1, Abf, nullptr);               // x1, xn2

  // ===== Phase B: mqa =====
  transp_k<<<dim3(36, 32), tb, 0, stream>>>(attn_w, Wt, 1024, 1152, 1152, 0, 1152);
  gemm4_k<1><<<288, b256, 0, stream>>>(Abf, Wt, qkvbf, 4096, 1152, 1024, 9, nullptr, nullptr);  // qkv (bf16)
  attnk<<<1024, b256, 0, stream>>>(qkvbf, Abf);                                          // atty (bf16)
  transp_k<<<dim3(32, 32), tb, 0, stream>>>(proj_w, Wt, 1024, 1024, 1024, 0, 1024);
  gemm4_k<0><<<256, b256, 0, stream>>>(Abf, Wt, big2, 4096, 1024, 1024, 8, nullptr, nullptr);   // po
  resrms_k<1, 1, 1><<<4096, b256, 0, stream>>>(x1, big2, x1, Abf, xn3);                  // x2 (in x1), xn3

  // ===== Phase C: cmix =====
  mixk<<<4096, b256, 0, stream>>>(xn3, tmk, tmr, xkbf, xrbf);
  transp_k<<<dim3(128, 32), tb, 0, stream>>>(key_w, Wt, 1024, 4096, 4096, 0, 4096);
  gemm8_k<2><<<256, b512, 0, stream>>>(xkbf, Wt, Abf, 4096, 4096, 1024, 16);             // kact (bf16)
  transp_k<<<dim3(32, 128), tb, 0, stream>>>(value_w, Wt, 4096, 1024, 1024, 0, 1024);
  gemm4_k<0><<<256, b256, 0, stream>>>(Abf, Wt, big2, 4096, 1024, 4096, 8, nullptr, nullptr);   // vout
  transp_k<<<dim3(32, 32), tb, 0, stream>>>(recept_w, Wt, 1024, 1024, 1024, 0, 1024);
  gemm4_k<3><<<256, b256, 0, stream>>>(xrbf, Wt, out, 4096, 1024, 1024, 8, x1, big2);    // out = x2 + sig(rraw)*vout
}

// Round 10
// 540.726 us; speedup vs baseline: 1.0231x; 1.0231x over previous
//
#include <hip/hip_runtime.h>

// ---------- helpers ----------
__device__ __forceinline__ unsigned short f2bf(float f) {
  unsigned u = __builtin_bit_cast(unsigned, f);
  u = u + 0x7fffu + ((u >> 16) & 1u);      // RNE
  return (unsigned short)(u >> 16);
}
__device__ __forceinline__ float bf2f(unsigned short u) {
  return __builtin_bit_cast(float, ((unsigned)u) << 16);
}

typedef __bf16 bf16x8 __attribute__((ext_vector_type(8)));
typedef float  f32x4  __attribute__((ext_vector_type(4)));
typedef unsigned short u16x8 __attribute__((ext_vector_type(8)));

#define GLD16(gp, lp) __builtin_amdgcn_global_load_lds( \
    (const __attribute__((address_space(1))) unsigned int*)(gp), \
    (__attribute__((address_space(3))) unsigned int*)(lp), 16, 0, 0)

// ---------- rmsnorm (+ optional residual) ----------
template<int HAS_DELTA, int WRITE_SUM, int WRITE_N32>
__global__ __launch_bounds__(256) void resrms_k(const float* __restrict__ xin,
    const float* __restrict__ delta, float* __restrict__ xsum,
    unsigned short* __restrict__ nbf, float* __restrict__ nf32) {
  int row = blockIdx.x, tid = threadIdx.x;
  size_t base = ((size_t)row << 10) + ((size_t)tid << 2);
  float4 v = *(const float4*)(xin + base);
  if (HAS_DELTA) {
    float4 d = *(const float4*)(delta + base);
    v.x += d.x; v.y += d.y; v.z += d.z; v.w += d.w;
  }
  if (WRITE_SUM) *(float4*)(xsum + base) = v;
  float ss = v.x*v.x + v.y*v.y + v.z*v.z + v.w*v.w;
  #pragma unroll
  for (int off = 32; off; off >>= 1) ss += __shfl_xor(ss, off);
  __shared__ float ws4[4];
  if ((tid & 63) == 0) ws4[tid >> 6] = ss;
  __syncthreads();
  float tot = ws4[0] + ws4[1] + ws4[2] + ws4[3];
  float sc = rsqrtf(tot * (1.0f / 1024.0f) + 1e-5f);
  *(ushort4*)(nbf + base) = make_ushort4(f2bf(v.x*sc), f2bf(v.y*sc), f2bf(v.z*sc), f2bf(v.w*sc));
  if (WRITE_N32) {
    float4 n; n.x = v.x*sc; n.y = v.y*sc; n.z = v.z*sc; n.w = v.w*sc;
    *(float4*)(nf32 + base) = n;
  }
}

// ---------- transpose+convert: W[K][ldw] f32 -> Wt[Npad][K] bf16 ----------
__global__ void transp_k(const float* __restrict__ W, unsigned short* __restrict__ Wt,
                         int K, int Ncols, int Npad, int col_off, int ldw) {
  __shared__ float t[32][33];
  int n0 = blockIdx.x << 5, k0 = blockIdx.y << 5;
  int tx = threadIdx.x, ty = threadIdx.y;
  #pragma unroll
  for (int rr = 0; rr < 32; rr += 8) {
    int k = k0 + rr + ty, n = n0 + tx;
    t[rr + ty][tx] = (n < Ncols) ? W[(size_t)k * ldw + col_off + n] : 0.f;
  }
  __syncthreads();
  #pragma unroll
  for (int rr = 0; rr < 32; rr += 8) {
    int nrow = n0 + rr + ty;
    Wt[(size_t)nrow * K + k0 + tx] = f2bf(t[tx][rr + ty]);
  }
}

// ---------- 8-phase 256x256 bf16 MFMA GEMM (only for grids >= 256) ----------
template<int EPI>   // 0=f32, 1=bf16, 2=erf->bf16
__global__ __launch_bounds__(512, 2) void gemm8_k(const unsigned short* __restrict__ A,
    const unsigned short* __restrict__ Bt, void* __restrict__ Cout,
    int M, int N, int K, int ntx) {
  __shared__ unsigned short lds[2 * 32768];   // 128 KiB
  const int tid = threadIdx.x;
  const int w = tid >> 6, lane = tid & 63;
  const int fr = lane & 15, g = lane >> 4;
  const int wmi = w >> 2, wni = w & 3;
  const int nwg = gridDim.x;
  const int nty = nwg / ntx;
  const int l = (blockIdx.x & 7) * (nwg >> 3) + (blockIdx.x >> 3);
  const int S = ((ntx & 3) == 0) ? 4 : (((ntx & 1) == 0) ? 2 : 1);
  const int sw = S * nty;
  const int s_ = l / sw, r_ = l - s_ * sw;
  const int bx = s_ * S + (r_ % S);
  const int by = r_ / S;
  const int m0 = by << 8, n0 = bx << 8;

  f32x4 acc[8][4];
  #pragma unroll
  for (int i = 0; i < 8; ++i)
    #pragma unroll
    for (int j = 0; j < 4; ++j) acc[i][j] = (f32x4){0.f, 0.f, 0.f, 0.f};

  const int r0 = tid >> 3, pc = tid & 7;
  const int lc = pc ^ (r0 & 7);
  const unsigned short* Abase = A + (size_t)(m0 + r0) * K + (lc << 3);
  const unsigned short* Bbase = Bt + (size_t)(n0 + r0) * K + (lc << 3);
  const size_t aK64 = (size_t)64 * K, aK128 = (size_t)128 * K;

#define STG_A(h_, kt_, bb_) { \
    const unsigned short* s0_ = Abase + (size_t)(h_) * aK128 + ((size_t)(kt_) << 6); \
    unsigned short* d0_ = lds + (bb_) * 32768 + (h_) * 8192 + (w << 9); \
    GLD16(s0_, d0_); GLD16(s0_ + aK64, d0_ + 4096); }
#define STG_B(h_, kt_, bb_) { \
    const unsigned short* s0_ = Bbase + (size_t)(h_) * aK128 + ((size_t)(kt_) << 6); \
    unsigned short* d0_ = lds + (bb_) * 32768 + 16384 + (h_) * 8192 + (w << 9); \
    GLD16(s0_, d0_); GLD16(s0_ + aK64, d0_ + 4096); }

  bf16x8 Areg[4][2], Breg[4][2];
#define LDA(mh_, bb_) { \
    _Pragma("unroll") for (int mf = 0; mf < 4; ++mf) \
    _Pragma("unroll") for (int kk = 0; kk < 2; ++kk) { \
      int r = ((mh_) << 6) + (mf << 4) + fr; \
      Areg[mf][kk] = *(const bf16x8*)&lds[(bb_) * 32768 + wmi * 8192 + (r << 6) + ((((kk << 2) + g) ^ (r & 7)) << 3)]; } }
#define LDB(nh_, bb_) { \
    _Pragma("unroll") for (int nf2 = 0; nf2 < 2; ++nf2) \
    _Pragma("unroll") for (int kk = 0; kk < 2; ++kk) { \
      int nf = ((nh_) << 1) + nf2; \
      int r = ((wni & 1) << 6) + (nf << 4) + fr; \
      Breg[nf][kk] = *(const bf16x8*)&lds[(bb_) * 32768 + 16384 + (wni >> 1) * 8192 + (r << 6) + ((((kk << 2) + g) ^ (r & 7)) << 3)]; } }
#define MM(mh_, nh_) { \
    __builtin_amdgcn_s_setprio(1); \
    _Pragma("unroll") for (int mf = 0; mf < 4; ++mf) \
    _Pragma("unroll") for (int nf2 = 0; nf2 < 2; ++nf2) \
    _Pragma("unroll") for (int kk = 0; kk < 2; ++kk) \
      acc[((mh_) << 2) + mf][((nh_) << 1) + nf2] = __builtin_amdgcn_mfma_f32_16x16x32_bf16( \
          Areg[mf][kk], Breg[((nh_) << 1) + nf2][kk], acc[((mh_) << 2) + mf][((nh_) << 1) + nf2], 0, 0, 0); \
    __builtin_amdgcn_s_setprio(0); }
#define BAR_LG \
    __builtin_amdgcn_s_barrier(); \
    asm volatile("s_waitcnt lgkmcnt(0)" ::: "memory"); \
    __builtin_amdgcn_sched_barrier(0);
#define ENDBAR \
    __builtin_amdgcn_s_barrier(); \
    __builtin_amdgcn_sched_barrier(0);

  STG_B(0, 0, 0) STG_B(1, 0, 0) STG_A(0, 0, 0) STG_A(1, 0, 0) STG_B(0, 1, 1) STG_B(1, 1, 1)
  asm volatile("s_waitcnt vmcnt(4)" ::: "memory");
  __builtin_amdgcn_s_barrier();
  __builtin_amdgcn_sched_barrier(0);

  const int NITER = K >> 7;
  for (int it = 0; it < NITER; ++it) {
    const int t = it << 1;
    const bool lastI = (it == NITER - 1);
    LDA(0, 0) LDB(0, 0)
    STG_A(0, t + 1, 1)
    BAR_LG MM(0, 0) ENDBAR
    LDB(1, 0)
    STG_A(1, t + 1, 1)
    BAR_LG MM(0, 1) ENDBAR
    LDA(1, 0)
    if (!lastI) STG_B(0, t + 2, 0)
    BAR_LG MM(1, 0) ENDBAR
    if (!lastI) STG_B(1, t + 2, 0)
    BAR_LG MM(1, 1)
    if (!lastI) { asm volatile("s_waitcnt vmcnt(4)" ::: "memory"); }
    else        { asm volatile("s_waitcnt vmcnt(0)" ::: "memory"); }
    ENDBAR
    LDA(0, 1) LDB(0, 1)
    if (!lastI) STG_A(0, t + 2, 0)
    BAR_LG MM(0, 0) ENDBAR
    LDB(1, 1)
    if (!lastI) STG_A(1, t + 2, 0)
    BAR_LG MM(0, 1) ENDBAR
    LDA(1, 1)
    if (!lastI) STG_B(0, t + 3, 1)
    BAR_LG MM(1, 0) ENDBAR
    if (!lastI) STG_B(1, t + 3, 1)
    BAR_LG MM(1, 1)
    if (!lastI) { asm volatile("s_waitcnt vmcnt(4)" ::: "memory"); }
    else        { asm volatile("s_waitcnt vmcnt(0)" ::: "memory"); }
    ENDBAR
  }
#undef STG_A
#undef STG_B
#undef LDA
#undef LDB
#undef MM
#undef BAR_LG
#undef ENDBAR

  asm volatile("s_waitcnt vmcnt(0)" ::: "memory");
  __syncthreads();
  float (*eps)[260] = (float(*)[260])lds;
  const int er = tid >> 3, ec0 = (tid & 7) << 5;
  #pragma unroll
  for (int slab = 0; slab < 4; ++slab) {
    if (wmi == (slab >> 1)) {
      const int mhs = slab & 1;
      #pragma unroll
      for (int mf = 0; mf < 4; ++mf)
        #pragma unroll
        for (int nf = 0; nf < 4; ++nf)
          #pragma unroll
          for (int rr = 0; rr < 4; ++rr)
            eps[(mf << 4) + (g << 2) + rr][(wni << 6) + (nf << 4) + fr] = acc[(mhs << 2) + mf][nf][rr];
    }
    __syncthreads();
    const int grow = m0 + (slab << 6) + er;
    if (EPI == 0) {
      float* orow = (float*)Cout + (size_t)grow * N + n0 + ec0;
      #pragma unroll
      for (int u = 0; u < 8; ++u) {
        int col = n0 + ec0 + (u << 2);
        if (col < N) {
          float4 v; v.x = eps[er][ec0 + (u << 2)]; v.y = eps[er][ec0 + (u << 2) + 1];
          v.z = eps[er][ec0 + (u << 2) + 2]; v.w = eps[er][ec0 + (u << 2) + 3];
          *(float4*)(orow + (u << 2)) = v;
        }
      }
    } else {
      unsigned short* orow = (unsigned short*)Cout + (size_t)grow * N + n0 + ec0;
      #pragma unroll
      for (int u = 0; u < 4; ++u) {
        int col = n0 + ec0 + (u << 3);
        if (col < N) {
          u16x8 pk;
          #pragma unroll
          for (int e = 0; e < 8; ++e) {
            float v = eps[er][ec0 + (u << 3) + e];
            if (EPI == 2) v = 0.5f * (1.0f + erff((v - 0.70710678f) * 2.5066283f));
            pk[e] = f2bf(v);
          }
          *(u16x8*)(orow + (u << 3)) = pk;
        }
      }
    }
    __syncthreads();
  }
}

// ---------- bf16 MFMA GEMM (m97-class, 3 blk/CU) ----------
// EPI: 0=f32, 1=bf16, 2=erf->bf16, 3=fused final: out = Ex + sigmoid(acc)*Ev (f32)
template<int EPI>
__global__ __launch_bounds__(256, 3) void gemm4_k(const unsigned short* __restrict__ A,
    const unsigned short* __restrict__ Bt, void* __restrict__ Cout,
    int M, int N, int K, int ntx, const float* __restrict__ Ex, const float* __restrict__ Ev) {
  __shared__ char smem[49152];
  unsigned short* lds = (unsigned short*)smem;
  const int tid = threadIdx.x;
  const int w = tid >> 6, lane = tid & 63;
  const int fr = lane & 15, g = lane >> 4;
  const int nwg = gridDim.x;
  const int nty = nwg / ntx;
  const int l = (blockIdx.x & 7) * (nwg >> 3) + (blockIdx.x >> 3);
  const int S = ((ntx & 3) == 0) ? 4 : (((ntx & 1) == 0) ? 2 : 1);
  const int sw = S * nty;
  const int s = l / sw, r_ = l - s * sw;
  const int bx = s * S + (r_ % S);
  const int by = r_ / S;
  const int m0 = by << 7, n0 = bx << 7;
  const int wm = (w >> 1) << 6, wn = (w & 1) << 6;

  f32x4 acc[4][4];
  #pragma unroll
  for (int i = 0; i < 4; ++i)
    #pragma unroll
    for (int j = 0; j < 4; ++j) acc[i][j] = (f32x4){0.f, 0.f, 0.f, 0.f};

  const int r0s = tid >> 2, pc0 = tid & 3;
  const int lc0 = pc0 ^ ((r0s >> 1) & 3);
  const int r1s = r0s + 64;
  const int lc1 = pc0 ^ ((r1s >> 1) & 3);
  const unsigned short* a0 = A + (size_t)(m0 + r0s) * K + (lc0 << 3);
  const unsigned short* a1 = A + (size_t)(m0 + r1s) * K + (lc1 << 3);
  const unsigned short* b0 = Bt + (size_t)(n0 + r0s) * K + (lc0 << 3);
  const unsigned short* b1 = Bt + (size_t)(n0 + r1s) * K + (lc1 << 3);
  const int wofs = w << 9;

#define STAGE4(kt_, bb_) { \
    unsigned short* d_ = lds + (bb_) * 8192 + wofs; \
    GLD16(a0 + ((kt_) << 5), d_); \
    GLD16(a1 + ((kt_) << 5), d_ + 2048); \
    GLD16(b0 + ((kt_) << 5), d_ + 4096); \
    GLD16(b1 + ((kt_) << 5), d_ + 6144); }

  const int NT = K >> 5;
  STAGE4(0, 0)
  STAGE4(1, 1)
  asm volatile("s_waitcnt vmcnt(4)" ::: "memory");
  __builtin_amdgcn_s_barrier();
  __builtin_amdgcn_sched_barrier(0);

  int cb = 0;
  for (int t = 0; t < NT; ++t) {
    const unsigned short* bufp = lds + cb * 8192;
    int sb = cb + 2; if (sb >= 3) sb -= 3;
    const int have2 = (t + 2 < NT);
    if (have2) STAGE4(t + 2, sb)
    bf16x8 af[4], bv[4];
    #pragma unroll
    for (int i = 0; i < 4; ++i) {
      int r = wm + (i << 4) + fr;
      af[i] = *(const bf16x8*)&bufp[(r << 5) + (((g ^ (r >> 1)) & 3) << 3)];
    }
    #pragma unroll
    for (int j = 0; j < 4; ++j) {
      int r = wn + (j << 4) + fr;
      bv[j] = *(const bf16x8*)&bufp[4096 + (r << 5) + (((g ^ (r >> 1)) & 3) << 3)];
    }
    __builtin_amdgcn_s_setprio(1);
    #pragma unroll
    for (int i = 0; i < 4; ++i)
      #pragma unroll
      for (int j = 0; j < 4; ++j)
        acc[i][j] = __builtin_amdgcn_mfma_f32_16x16x32_bf16(af[i], bv[j], acc[i][j], 0, 0, 0);
    __builtin_amdgcn_s_setprio(0);
    if (t + 1 < NT) {
      if (have2) { asm volatile("s_waitcnt vmcnt(4)" ::: "memory"); }
      else       { asm volatile("s_waitcnt vmcnt(0)" ::: "memory"); }
      __builtin_amdgcn_s_barrier();
      __builtin_amdgcn_sched_barrier(0);
    }
    cb = cb + 1; if (cb >= 3) cb -= 3;
  }
#undef STAGE4

  float (*eps)[132] = (float(*)[132])smem;
  const int rin = g << 2;
  const int er = tid >> 2, ec0 = (tid & 3) << 5;
  #pragma unroll
  for (int rh = 0; rh < 2; ++rh) {
    __syncthreads();
    if ((wm >> 6) == rh) {
      #pragma unroll
      for (int i = 0; i < 4; ++i)
        #pragma unroll
        for (int j = 0; j < 4; ++j)
          #pragma unroll
          for (int rr = 0; rr < 4; ++rr)
            eps[(i << 4) + rin + rr][wn + (j << 4) + fr] = acc[i][j][rr];
    }
    __syncthreads();
    int grow = m0 + (rh << 6) + er;
    if (EPI == 0 || EPI == 3) {
      float* orow = (float*)Cout + (size_t)grow * N + n0 + ec0;
      #pragma unroll
      for (int u = 0; u < 8; ++u) {
        int col = n0 + ec0 + (u << 2);
        if (col < N) {
          float4 v; v.x = eps[er][ec0 + (u<<2)]; v.y = eps[er][ec0 + (u<<2) + 1];
          v.z = eps[er][ec0 + (u<<2) + 2]; v.w = eps[er][ec0 + (u<<2) + 3];
          if (EPI == 3) {
            size_t o = (size_t)grow * N + n0 + ec0 + (u << 2);
            float4 xv = *(const float4*)(Ex + o);
            float4 vv = *(const float4*)(Ev + o);
            v.x = xv.x + vv.x / (1.f + __expf(-v.x));
            v.y = xv.y + vv.y / (1.f + __expf(-v.y));
            v.z = xv.z + vv.z / (1.f + __expf(-v.z));
            v.w = xv.w + vv.w / (1.f + __expf(-v.w));
          }
          *(float4*)(orow + (u << 2)) = v;
        }
      }
    } else {
      unsigned short* orow = (unsigned short*)Cout + (size_t)grow * N + n0 + ec0;
      #pragma unroll
      for (int u = 0; u < 4; ++u) {
        int col = n0 + ec0 + (u << 3);
        if (col < N) {
          u16x8 pk;
          #pragma unroll
          for (int e = 0; e < 8; ++e) {
            float v = eps[er][ec0 + (u << 3) + e];
            if (EPI == 2) v = 0.5f * (1.0f + erff((v - 0.70710678f) * 2.5066283f));
            pk[e] = f2bf(v);
          }
          *(u16x8*)(orow + (u << 3)) = pk;
        }
      }
    }
  }
}

// ---------- causal depthwise conv(4) + silu, with fused dt/softplus ----------
__global__ __launch_bounds__(256) void convk(const float* __restrict__ zxr,
    const float* __restrict__ conv_w, const float* __restrict__ conv_b,
    const float* __restrict__ dt_bias, float* __restrict__ xbc,
    float* __restrict__ dtb) {
  int i = blockIdx.x * 256 + threadIdx.x;     // 4*1024*2176
  if (i >= 4 * 1024 * 2176) return;
  int c = i % 2176; int bt = i / 2176; int t = bt & 1023;
  const float* col = zxr + (size_t)bt * 2208 + c;
  float acc = conv_b[c];
  float w0 = conv_w[c * 4 + 0], w1 = conv_w[c * 4 + 1], w2 = conv_w[c * 4 + 2], w3 = conv_w[c * 4 + 3];
  if (t >= 3) acc = fmaf(col[-3 * 2208], w0, acc);
  if (t >= 2) acc = fmaf(col[-2 * 2208], w1, acc);
  if (t >= 1) acc = fmaf(col[-1 * 2208], w2, acc);
  acc = fmaf(col[0], w3, acc);
  xbc[(size_t)bt * 2176 + c] = acc / (1.f + __expf(-acc));
  if (c < 32) {
    float v = zxr[(size_t)bt * 2208 + 2176 + c] + dt_bias[c];
    dtb[bt * 32 + c] = (v > 20.f) ? v : log1pf(__expf(v));
  }
}

// ---------- SSD chunked scan, stage 1 ----------
__global__ __launch_bounds__(256) void ssd1_k(const float* __restrict__ xbc,
    const float* __restrict__ dtb, const float* __restrict__ A_log,
    float* __restrict__ ydin, float* __restrict__ dhbuf, float* __restrict__ labuf) {
  __shared__ unsigned short Cs[64][68];
  __shared__ unsigned short Bsm[64][68];
  __shared__ unsigned short XT[64][68];
  __shared__ unsigned short BT[64][68];
  __shared__ unsigned short Ms[64][68];
  __shared__ float laS[64], dtS[64];
  const int id = blockIdx.x;
  const int h = id & 31, b = (id >> 5) & 3, c = id >> 7;
  const int tid = threadIdx.x, w = tid >> 6, lane = tid & 63;
  const int fr = lane & 15, g = lane >> 4;
  const size_t rowbase = (size_t)((b << 10) + (c << 6));

  {
    int r = tid >> 2, c0 = (tid & 3) << 4;
    const float* src = xbc + (rowbase + r) * 2176;
    #pragma unroll
    for (int i = 0; i < 4; ++i) {
      float4 v = *(const float4*)(src + 2112 + c0 + 4 * i);
      *(ushort4*)&Cs[r][c0 + 4 * i] = make_ushort4(f2bf(v.x), f2bf(v.y), f2bf(v.z), f2bf(v.w));
      float4 u = *(const float4*)(src + 2048 + c0 + 4 * i);
      *(ushort4*)&Bsm[r][c0 + 4 * i] = make_ushort4(f2bf(u.x), f2bf(u.y), f2bf(u.z), f2bf(u.w));
    }
  }
  {
    int r0 = (tid & 15) << 2, d0 = (tid >> 4) << 2;
    const float* src = xbc + (rowbase + r0) * 2176 + (h << 6) + d0;
    float4 v0 = *(const float4*)(src);
    float4 v1 = *(const float4*)(src + 2176);
    float4 v2 = *(const float4*)(src + 4352);
    float4 v3 = *(const float4*)(src + 6528);
    *(ushort4*)&XT[d0 + 0][r0] = make_ushort4(f2bf(v0.x), f2bf(v1.x), f2bf(v2.x), f2bf(v3.x));
    *(ushort4*)&XT[d0 + 1][r0] = make_ushort4(f2bf(v0.y), f2bf(v1.y), f2bf(v2.y), f2bf(v3.y));
    *(ushort4*)&XT[d0 + 2][r0] = make_ushort4(f2bf(v0.z), f2bf(v1.z), f2bf(v2.z), f2bf(v3.z));
    *(ushort4*)&XT[d0 + 3][r0] = make_ushort4(f2bf(v0.w), f2bf(v1.w), f2bf(v2.w), f2bf(v3.w));
  }
  if (w == 0) {
    float Ah = -__expf(A_log[h]);
    float dtv = dtb[(rowbase + lane) * 32 + h];
    float v = dtv * Ah;
    #pragma unroll
    for (int off = 1; off < 64; off <<= 1) {
      float u = __shfl_up(v, off);
      if (lane >= off) v += u;
    }
    laS[lane] = v; dtS[lane] = dtv;
    labuf[(size_t)((((b << 4) | c) << 5 | h) << 6) + lane] = v;
  }
  __syncthreads();

  const int wr = w >> 1, wc = w & 1;
  f32x4 gf[2][2];
  #pragma unroll
  for (int i = 0; i < 2; ++i)
    #pragma unroll
    for (int j = 0; j < 2; ++j) gf[i][j] = (f32x4){0.f, 0.f, 0.f, 0.f};
  {
    int r0 = (tid & 15) << 2, d0 = (tid >> 4) << 2;
    const float* src = xbc + (rowbase + r0) * 2176 + 2048 + d0;
    float la63 = laS[63];
    float4 v0 = *(const float4*)(src);
    float4 v1 = *(const float4*)(src + 2176);
    float4 v2 = *(const float4*)(src + 4352);
    float4 v3 = *(const float4*)(src + 6528);
    float w0 = __expf(la63 - laS[r0 + 0]) * dtS[r0 + 0];
    float w1 = __expf(la63 - laS[r0 + 1]) * dtS[r0 + 1];
    float w2 = __expf(la63 - laS[r0 + 2]) * dtS[r0 + 2];
    float w3 = __expf(la63 - laS[r0 + 3]) * dtS[r0 + 3];
    *(ushort4*)&BT[d0 + 0][r0] = make_ushort4(f2bf(v0.x*w0), f2bf(v1.x*w1), f2bf(v2.x*w2), f2bf(v3.x*w3));
    *(ushort4*)&BT[d0 + 1][r0] = make_ushort4(f2bf(v0.y*w0), f2bf(v1.y*w1), f2bf(v2.y*w2), f2bf(v3.y*w3));
    *(ushort4*)&BT[d0 + 2][r0] = make_ushort4(f2bf(v0.z*w0), f2bf(v1.z*w1), f2bf(v2.z*w2), f2bf(v3.z*w3));
    *(ushort4*)&BT[d0 + 3][r0] = make_ushort4(f2bf(v0.w*w0), f2bf(v1.w*w1), f2bf(v2.w*w2), f2bf(v3.w*w3));
  }
  #pragma unroll
  for (int ks = 0; ks < 2; ++ks) {
    bf16x8 ca[2], bb[2];
    #pragma unroll
    for (int i = 0; i < 2; ++i) ca[i] = *(const bf16x8*)&Cs[(wr << 5) + (i << 4) + fr][(ks << 5) + (g << 3)];
    #pragma unroll
    for (int j = 0; j < 2; ++j) bb[j] = *(const bf16x8*)&Bsm[(wc << 5) + (j << 4) + fr][(ks << 5) + (g << 3)];
    #pragma unroll
    for (int i = 0; i < 2; ++i)
      #pragma unroll
      for (int j = 0; j < 2; ++j)
        gf[i][j] = __builtin_amdgcn_mfma_f32_16x16x32_bf16(ca[i], bb[j], gf[i][j], 0, 0, 0);
  }
  #pragma unroll
  for (int i = 0; i < 2; ++i) {
    #pragma unroll
    for (int j = 0; j < 2; ++j) {
      int s = (wc << 5) + (j << 4) + fr;
      float la_s = laS[s], dt_s = dtS[s];
      #pragma unroll
      for (int rr = 0; rr < 4; ++rr) {
        int t = (wr << 5) + (i << 4) + (g << 2) + rr;
        float e = __expf(fminf(laS[t] - la_s, 0.f));
        float val = (s <= t) ? gf[i][j][rr] * e * dt_s : 0.f;
        Ms[t][s] = f2bf(val);
      }
    }
  }
  __syncthreads();

  f32x4 yf[2][2], hf[2][2];
  #pragma unroll
  for (int i = 0; i < 2; ++i)
    #pragma unroll
    for (int j = 0; j < 2; ++j) { yf[i][j] = (f32x4){0.f,0.f,0.f,0.f}; hf[i][j] = (f32x4){0.f,0.f,0.f,0.f}; }
  #pragma unroll
  for (int ks = 0; ks < 2; ++ks) {
    bf16x8 ma[2], ba[2], xb[2];
    #pragma unroll
    for (int i = 0; i < 2; ++i) {
      ma[i] = *(const bf16x8*)&Ms[(wr << 5) + (i << 4) + fr][(ks << 5) + (g << 3)];
      ba[i] = *(const bf16x8*)&BT[(wr << 5) + (i << 4) + fr][(ks << 5) + (g << 3)];
    }
    #pragma unroll
    for (int j = 0; j < 2; ++j) xb[j] = *(const bf16x8*)&XT[(wc << 5) + (j << 4) + fr][(ks << 5) + (g << 3)];
    #pragma unroll
    for (int i = 0; i < 2; ++i)
      #pragma unroll
      for (int j = 0; j < 2; ++j) {
        yf[i][j] = __builtin_amdgcn_mfma_f32_16x16x32_bf16(ma[i], xb[j], yf[i][j], 0, 0, 0);
        hf[i][j] = __builtin_amdgcn_mfma_f32_16x16x32_bf16(ba[i], xb[j], hf[i][j], 0, 0, 0);
      }
  }
  float* dhb = dhbuf + ((size_t)(((c << 2) + b) * 32 + h) << 12);
  #pragma unroll
  for (int i = 0; i < 2; ++i) {
    #pragma unroll
    for (int j = 0; j < 2; ++j) {
      int p = (wc << 5) + (j << 4) + fr;
      #pragma unroll
      for (int rr = 0; rr < 4; ++rr) {
        int t = (wr << 5) + (i << 4) + (g << 2) + rr;
        ydin[((rowbase + t) << 11) + (h << 6) + p] = yf[i][j][rr];
        dhb[(t << 6) + p] = hf[i][j][rr];
      }
    }
  }
}

// ---------- SSD stage 2 ----------
__global__ __launch_bounds__(256) void ssd2_k(const float* __restrict__ dhbuf,
    const float* __restrict__ labuf, float* __restrict__ hseq) {
  int idx = blockIdx.x * 256 + threadIdx.x;
  int np = idx & 4095;
  int h = (idx >> 12) & 31, b = idx >> 17;
  float carry = 0.f;
  #pragma unroll
  for (int c = 0; c < 16; ++c) {
    size_t o = ((size_t)(((c << 2) + b) * 32 + h) << 12) + np;
    hseq[o] = carry;
    float ec = __expf(labuf[(size_t)((((b << 4) | c) << 5 | h) << 6) + 63]);
    carry = fmaf(ec, carry, dhbuf[o]);
  }
}

// ---------- SSD stage 3 ----------
__global__ __launch_bounds__(256) void ssd3_k(const float* __restrict__ xbc,
    const float* __restrict__ hseq, const float* __restrict__ labuf,
    const float* __restrict__ Dv, float* __restrict__ ydin) {
  __shared__ unsigned short Cs[64][68];
  __shared__ unsigned short HT[64][68];
  __shared__ float laS[64];
  const int id = blockIdx.x;
  const int h = id & 31, b = (id >> 5) & 3, c = id >> 7;
  const int tid = threadIdx.x, w = tid >> 6, lane = tid & 63;
  const int fr = lane & 15, g = lane >> 4;
  const size_t rowbase = (size_t)((b << 10) + (c << 6));
  {
    int r = tid >> 2, c0 = (tid & 3) << 4;
    const float* src = xbc + (rowbase + r) * 2176 + 2112 + c0;
    #pragma unroll
    for (int i = 0; i < 4; ++i) {
      float4 v = *(const float4*)(src + 4 * i);
      *(ushort4*)&Cs[r][c0 + 4 * i] = make_ushort4(f2bf(v.x), f2bf(v.y), f2bf(v.z), f2bf(v.w));
    }
  }
  {
    const float* hb = hseq + ((size_t)(((c << 2) + b) * 32 + h) << 12);
    int n0 = (tid & 15) << 2, p0 = (tid >> 4) << 2;
    float4 v0 = *(const float4*)(hb + ((n0 + 0) << 6) + p0);
    float4 v1 = *(const float4*)(hb + ((n0 + 1) << 6) + p0);
    float4 v2 = *(const float4*)(hb + ((n0 + 2) << 6) + p0);
    float4 v3 = *(const float4*)(hb + ((n0 + 3) << 6) + p0);
    *(ushort4*)&HT[p0 + 0][n0] = make_ushort4(f2bf(v0.x), f2bf(v1.x), f2bf(v2.x), f2bf(v3.x));
    *(ushort4*)&HT[p0 + 1][n0] = make_ushort4(f2bf(v0.y), f2bf(v1.y), f2bf(v2.y), f2bf(v3.y));
    *(ushort4*)&HT[p0 + 2][n0] = make_ushort4(f2bf(v0.z), f2bf(v1.z), f2bf(v2.z), f2bf(v3.z));
    *(ushort4*)&HT[p0 + 3][n0] = make_ushort4(f2bf(v0.w), f2bf(v1.w), f2bf(v2.w), f2bf(v3.w));
  }
  if (tid < 64) laS[tid] = labuf[(size_t)((((b << 4) | c) << 5 | h) << 6) + tid];
  __syncthreads();
  const int wr = w >> 1, wc = w & 1;
  f32x4 yf[2][2];
  #pragma unroll
  for (int i = 0; i < 2; ++i)
    #pragma unroll
    for (int j = 0; j < 2; ++j) yf[i][j] = (f32x4){0.f, 0.f, 0.f, 0.f};
  #pragma unroll
  for (int ks = 0; ks < 2; ++ks) {
    bf16x8 ca[2], hv[2];
    #pragma unroll
    for (int i = 0; i < 2; ++i) ca[i] = *(const bf16x8*)&Cs[(wr << 5) + (i << 4) + fr][(ks << 5) + (g << 3)];
    #pragma unroll
    for (int j = 0; j < 2; ++j) hv[j] = *(const bf16x8*)&HT[(wc << 5) + (j << 4) + fr][(ks << 5) + (g << 3)];
    #pragma unroll
    for (int i = 0; i < 2; ++i)
      #pragma unroll
      for (int j = 0; j < 2; ++j)
        yf[i][j] = __builtin_amdgcn_mfma_f32_16x16x32_bf16(ca[i], hv[j], yf[i][j], 0, 0, 0);
  }
  float Dh = Dv[h];
  #pragma unroll
  for (int i = 0; i < 2; ++i) {
    #pragma unroll
    for (int j = 0; j < 2; ++j) {
      int p = (wc << 5) + (j << 4) + fr;
      #pragma unroll
      for (int rr = 0; rr < 4; ++rr) {
        int t = (wr << 5) + (i << 4) + (g << 2) + rr;
        size_t yo = ((rowbase + t) << 11) + (h << 6) + p;
        float xv = xbc[(rowbase + t) * 2176 + (h << 6) + p];
        ydin[yo] = ydin[yo] + __expf(laS[t]) * yf[i][j][rr] + Dh * xv;
      }
    }
  }
}

// ---------- g = ydin * silu(z); rmsnorm(2048) * mnorm_w -> bf16 ----------
__global__ __launch_bounds__(256) void gnormk(const float* __restrict__ ydin,
    const unsigned short* __restrict__ zbf, const float* __restrict__ mw,
    unsigned short* __restrict__ gbf) {
  int row = blockIdx.x, tid = threadIdx.x;
  size_t base = ((size_t)row << 11) + ((size_t)tid << 3);
  float4 y0 = *(const float4*)(ydin + base);
  float4 y1 = *(const float4*)(ydin + base + 4);
  ushort4 z0 = *(const ushort4*)(zbf + base);
  ushort4 z1 = *(const ushort4*)(zbf + base + 4);
  float g[8];
  {
    float z;
    z = bf2f(z0.x); g[0] = y0.x * (z / (1.f + __expf(-z)));
    z = bf2f(z0.y); g[1] = y0.y * (z / (1.f + __expf(-z)));
    z = bf2f(z0.z); g[2] = y0.z * (z / (1.f + __expf(-z)));
    z = bf2f(z0.w); g[3] = y0.w * (z / (1.f + __expf(-z)));
    z = bf2f(z1.x); g[4] = y1.x * (z / (1.f + __expf(-z)));
    z = bf2f(z1.y); g[5] = y1.y * (z / (1.f + __expf(-z)));
    z = bf2f(z1.z); g[6] = y1.z * (z / (1.f + __expf(-z)));
    z = bf2f(z1.w); g[7] = y1.w * (z / (1.f + __expf(-z)));
  }
  float ss = 0.f;
  #pragma unroll
  for (int k = 0; k < 8; ++k) ss += g[k] * g[k];
  #pragma unroll
  for (int off = 32; off; off >>= 1) ss += __shfl_xor(ss, off);
  __shared__ float ws4[4];
  if ((tid & 63) == 0) ws4[tid >> 6] = ss;
  __syncthreads();
  float tot = ws4[0] + ws4[1] + ws4[2] + ws4[3];
  float sc = rsqrtf(tot * (1.f / 2048.f) + 1e-5f);
  int c0 = tid << 3;
  float4 m0 = *(const float4*)(mw + c0);
  float4 m1 = *(const float4*)(mw + c0 + 4);
  *(ushort4*)(gbf + base)     = make_ushort4(f2bf(g[0]*sc*m0.x), f2bf(g[1]*sc*m0.y), f2bf(g[2]*sc*m0.z), f2bf(g[3]*sc*m0.w));
  *(ushort4*)(gbf + base + 4) = make_ushort4(f2bf(g[4]*sc*m1.x), f2bf(g[5]*sc*m1.y), f2bf(g[6]*sc*m1.z), f2bf(g[7]*sc*m1.w));
}

// ---------- MQA causal attention (MFMA flash), bf16 in/out ----------
__global__ __launch_bounds__(256) void attnk(const unsigned short* __restrict__ qkv,
                                             unsigned short* __restrict__ ybf) {
  __shared__ unsigned short Qs[64][72];
  __shared__ unsigned short Ks[64][72];
  __shared__ unsigned short VT[64][72];
  __shared__ unsigned short Ps[4][16][72];
  const int id = blockIdx.x;
  const int b = id & 3, h = (id >> 2) & 15, qt = id >> 6;
  const int t0 = qt << 6;
  const int tid = threadIdx.x, w = tid >> 6, lane = tid & 63;
  const int fr = lane & 15, g = lane >> 4;
  {
    int r = tid >> 2, d0 = (tid & 3) << 4;
    const unsigned short* src = qkv + ((size_t)((b << 10) | (t0 + r))) * 1152 + (h << 6) + d0;
    *(uint4*)&Qs[r][d0]     = *(const uint4*)(src);
    *(uint4*)&Qs[r][d0 + 8] = *(const uint4*)(src + 8);
  }
  __syncthreads();
  bf16x8 afQ0 = *(const bf16x8*)&Qs[(w << 4) + fr][g << 3];
  bf16x8 afQ1 = *(const bf16x8*)&Qs[(w << 4) + fr][32 + (g << 3)];
  f32x4 acc_o[4];
  #pragma unroll
  for (int i = 0; i < 4; ++i) acc_o[i] = (f32x4){0.f, 0.f, 0.f, 0.f};
  float m[4] = {-1e30f, -1e30f, -1e30f, -1e30f};
  float l[4] = {0.f, 0.f, 0.f, 0.f};
  const int qrow = t0 + (w << 4) + (g << 2);
  for (int kt = 0; kt <= qt; ++kt) {
    const int s0 = kt << 6;
    __syncthreads();
    {
      int r = tid >> 2, d0 = (tid & 3) << 4;
      const unsigned short* src = qkv + ((size_t)((b << 10) | (s0 + r))) * 1152 + 1024 + d0;
      *(uint4*)&Ks[r][d0]     = *(const uint4*)(src);
      *(uint4*)&Ks[r][d0 + 8] = *(const uint4*)(src + 8);
    }
    {
      int r0 = (tid & 15) << 2, d0 = (tid >> 4) << 2;
      const unsigned short* src = qkv + ((size_t)((b << 10) | (s0 + r0))) * 1152 + 1088 + d0;
      ushort4 v0 = *(const ushort4*)(src);
      ushort4 v1 = *(const ushort4*)(src + 1152);
      ushort4 v2 = *(const ushort4*)(src + 2304);
      ushort4 v3 = *(const ushort4*)(src + 3456);
      *(ushort4*)&VT[d0 + 0][r0] = make_ushort4(v0.x, v1.x, v2.x, v3.x);
      *(ushort4*)&VT[d0 + 1][r0] = make_ushort4(v0.y, v1.y, v2.y, v3.y);
      *(ushort4*)&VT[d0 + 2][r0] = make_ushort4(v0.z, v1.z, v2.z, v3.z);
      *(ushort4*)&VT[d0 + 3][r0] = make_ushort4(v0.w, v1.w, v2.w, v3.w);
    }
    __syncthreads();
    f32x4 s4[4];
    #pragma unroll
    for (int jt = 0; jt < 4; ++jt) {
      bf16x8 b0 = *(const bf16x8*)&Ks[(jt << 4) + fr][g << 3];
      bf16x8 b1 = *(const bf16x8*)&Ks[(jt << 4) + fr][32 + (g << 3)];
      f32x4 z4 = (f32x4){0.f, 0.f, 0.f, 0.f};
      z4 = __builtin_amdgcn_mfma_f32_16x16x32_bf16(afQ0, b0, z4, 0, 0, 0);
      z4 = __builtin_amdgcn_mfma_f32_16x16x32_bf16(afQ1, b1, z4, 0, 0, 0);
      s4[jt] = z4 * 0.125f;
    }
    if (kt == qt) {
      #pragma unroll
      for (int jt = 0; jt < 4; ++jt) {
        int key = s0 + (jt << 4) + fr;
        #pragma unroll
        for (int r = 0; r < 4; ++r)
          if (key > qrow + r) s4[jt][r] = -1e30f;
      }
    }
    #pragma unroll
    for (int r = 0; r < 4; ++r) {
      float mt = fmaxf(fmaxf(s4[0][r], s4[1][r]), fmaxf(s4[2][r], s4[3][r]));
      #pragma unroll
      for (int off = 8; off; off >>= 1) mt = fmaxf(mt, __shfl_xor(mt, off));
      float mn = fmaxf(m[r], mt);
      float scl = __expf(m[r] - mn);
      m[r] = mn;
      float ps = 0.f;
      #pragma unroll
      for (int jt = 0; jt < 4; ++jt) {
        float p = __expf(s4[jt][r] - mn);
        ps += p;
        Ps[w][(g << 2) + r][(jt << 4) + fr] = f2bf(p);
      }
      #pragma unroll
      for (int off = 8; off; off >>= 1) ps += __shfl_xor(ps, off);
      l[r] = l[r] * scl + ps;
      acc_o[0][r] *= scl; acc_o[1][r] *= scl; acc_o[2][r] *= scl; acc_o[3][r] *= scl;
    }
    #pragma unroll
    for (int ks = 0; ks < 2; ++ks) {
      bf16x8 ap = *(const bf16x8*)&Ps[w][fr][(ks << 5) + (g << 3)];
      #pragma unroll
      for (int dt = 0; dt < 4; ++dt) {
        bf16x8 bv = *(const bf16x8*)&VT[(dt << 4) + fr][(ks << 5) + (g << 3)];
        acc_o[dt] = __builtin_amdgcn_mfma_f32_16x16x32_bf16(ap, bv, acc_o[dt], 0, 0, 0);
      }
    }
  }
  #pragma unroll
  for (int dt = 0; dt < 4; ++dt) {
    #pragma unroll
    for (int r = 0; r < 4; ++r) {
      float o = acc_o[dt][r] / l[r];
      int t = t0 + (w << 4) + (g << 2) + r;
      ybf[(((size_t)((b << 10) | t)) << 10) + (h << 6) + (dt << 4) + fr] = f2bf(o);
    }
  }
}

// ---------- cmix token-shift mix -> xk, xr (bf16) ----------
__global__ __launch_bounds__(256) void mixk(const float* __restrict__ xn3,
    const float* __restrict__ tmk, const float* __restrict__ tmr,
    unsigned short* __restrict__ xkbf, unsigned short* __restrict__ xrbf) {
  int idx4 = blockIdx.x * 256 + threadIdx.x;
  int col = (idx4 & 255) << 2;
  int row = idx4 >> 8;
  int t = row & 1023;
  size_t off = ((size_t)idx4) << 2;
  float4 cur = *(const float4*)(xn3 + off);
  float4 prev = make_float4(0.f, 0.f, 0.f, 0.f);
  if (t > 0) prev = *(const float4*)(xn3 + off - 1024);
  float4 tk = *(const float4*)(tmk + col);
  float4 tr = *(const float4*)(tmr + col);
  float dx = prev.x - cur.x, dy = prev.y - cur.y, dz = prev.z - cur.z, dw = prev.w - cur.w;
  *(ushort4*)(xkbf + off) = make_ushort4(
      f2bf(cur.x + dx * tk.x), f2bf(cur.y + dy * tk.y), f2bf(cur.z + dz * tk.z), f2bf(cur.w + dw * tk.w));
  *(ushort4*)(xrbf + off) = make_ushort4(
      f2bf(cur.x + dx * tr.x), f2bf(cur.y + dy * tr.y), f2bf(cur.z + dz * tr.z), f2bf(cur.w + dw * tr.w));
}

// ---------- host launcher ----------
extern "C" void kernel_launch(void* const* d_in, const int* in_sizes, int n_in,
                              void* d_out, int out_size, void* d_ws, size_t ws_size,
                              hipStream_t stream) {
  (void)in_sizes; (void)n_in; (void)out_size;
  const float* x        = (const float*)d_in[0];
  const float* in_proj  = (const float*)d_in[1];
  const float* conv_w   = (const float*)d_in[2];
  const float* conv_b   = (const float*)d_in[3];
  const float* dt_bias  = (const float*)d_in[4];
  const float* A_log    = (const float*)d_in[5];
  const float* Dvec     = (const float*)d_in[6];
  const float* mnorm_w  = (const float*)d_in[7];
  const float* out_proj = (const float*)d_in[8];
  const float* attn_w   = (const float*)d_in[9];
  const float* proj_w   = (const float*)d_in[10];
  const float* tmk      = (const float*)d_in[11];
  const float* tmr      = (const float*)d_in[12];
  const float* key_w    = (const float*)d_in[13];
  const float* recept_w = (const float*)d_in[14];
  const float* value_w  = (const float*)d_in[15];
  float* out = (float*)d_out;

  if (ws_size < 199229440ull) return;

  char* ws = (char*)d_ws;
  unsigned short* Wt   = (unsigned short*)(ws + 0);
  unsigned short* Abf  = (unsigned short*)(ws + 8912896ull);
  unsigned short* Abf2 = (unsigned short*)(ws + 42467328ull);
  float* bigF = (float*)(ws + 59244544ull);
  float* big1 = (float*)(ws + 95420416ull);
  float* big2 = (float*)(ws + 131072000ull);
  float* x1   = (float*)(ws + 164626432ull);
  float* xn3  = (float*)(ws + 181403648ull);
  float* dtb  = (float*)(ws + 198180864ull);
  float* labuf= (float*)(ws + 198705152ull);
  unsigned short* zbf  = Abf2;
  unsigned short* xkbf = Abf2;
  unsigned short* xrbf = Abf2 + 4194304;
  float* dhbuf = bigF;
  float* hseq  = (float*)Abf;
  unsigned short* qkvbf = (unsigned short*)big1;

  dim3 b256(256);
  dim3 b512(512);
  dim3 tb(32, 8);

  // ===== Phase A: mamba2 =====
  resrms_k<0, 0, 0><<<4096, b256, 0, stream>>>(x, nullptr, nullptr, Abf, nullptr);
  transp_k<<<dim3(64, 32), tb, 0, stream>>>(in_proj, Wt, 1024, 2048, 2048, 0, 4256);
  gemm4_k<1><<<512, b256, 0, stream>>>(Abf, Wt, zbf, 4096, 2048, 1024, 16, nullptr, nullptr);   // z (bf16)
  transp_k<<<dim3(72, 32), tb, 0, stream>>>(in_proj, Wt, 1024, 2208, 2304, 2048, 4256);
  gemm4_k<0><<<576, b256, 0, stream>>>(Abf, Wt, bigF, 4096, 2208, 1024, 18, nullptr, nullptr);  // xBC+dt (f32)
  convk<<<34816, b256, 0, stream>>>(bigF, conv_w, conv_b, dt_bias, big1, dtb);           // xbc_act + dt
  ssd1_k<<<2048, b256, 0, stream>>>(big1, dtb, A_log, big2, dhbuf, labuf);               // Y_intra, dh, la
  ssd2_k<<<2048, b256, 0, stream>>>(dhbuf, labuf, hseq);                                 // chunk states
  ssd3_k<<<2048, b256, 0, stream>>>(big1, hseq, labuf, Dvec, big2);                      // ydin final
  gnormk<<<4096, b256, 0, stream>>>(big2, zbf, mnorm_w, Abf);                            // g (bf16)
  transp_k<<<dim3(32, 64), tb, 0, stream>>>(out_proj, Wt, 2048, 1024, 1024, 0, 1024);
  gemm4_k<0><<<256, b256, 0, stream>>>(Abf, Wt, big1, 4096, 1024, 2048, 8, nullptr, nullptr);   // mo
  resrms_k<1, 1, 0><<<4096, b256, 0, stream>>>(x, big1, x1, Abf, nullptr);               // x1, xn2

  // ===== Phase B: mqa =====
  transp_k<<<dim3(36, 32), tb, 0, stream>>>(attn_w, Wt, 1024, 1152, 1152, 0, 1152);
  gemm4_k<1><<<288, b256, 0, stream>>>(Abf, Wt, qkvbf, 4096, 1152, 1024, 9, nullptr, nullptr);  // qkv (bf16)
  attnk<<<1024, b256, 0, stream>>>(qkvbf, Abf);                                          // atty (bf16)
  transp_k<<<dim3(32, 32), tb, 0, stream>>>(proj_w, Wt, 1024, 1024, 1024, 0, 1024);
  gemm4_k<0><<<256, b256, 0, stream>>>(Abf, Wt, big2, 4096, 1024, 1024, 8, nullptr, nullptr);   // po
  resrms_k<1, 1, 1><<<4096, b256, 0, stream>>>(x1, big2, x1, Abf, xn3);                  // x2 (in x1), xn3

  // ===== Phase C: cmix =====
  mixk<<<4096, b256, 0, stream>>>(xn3, tmk, tmr, xkbf, xrbf);
  transp_k<<<dim3(128, 32), tb, 0, stream>>>(key_w, Wt, 1024, 4096, 4096, 0, 4096);
  gemm8_k<2><<<256, b512, 0, stream>>>(xkbf, Wt, Abf, 4096, 4096, 1024, 16);             // kact (bf16, 1 blk/CU)
  transp_k<<<dim3(32, 128), tb, 0, stream>>>(value_w, Wt, 4096, 1024, 1024, 0, 1024);
  gemm4_k<0><<<256, b256, 0, stream>>>(Abf, Wt, big2, 4096, 1024, 4096, 8, nullptr, nullptr);   // vout
  transp_k<<<dim3(32, 32), tb, 0, stream>>>(recept_w, Wt, 1024, 1024, 1024, 0, 1024);
  gemm4_k<3><<<256, b256, 0, stream>>>(xrbf, Wt, out, 4096, 1024, 1024, 8, x1, big2);    // out = x2 + sig(rraw)*vout
}

// Round 11
// 532.798 us; speedup vs baseline: 1.0383x; 1.0149x over previous
//
#include <hip/hip_runtime.h>

// ---------- helpers ----------
__device__ __forceinline__ unsigned short f2bf(float f) {
  unsigned u = __builtin_bit_cast(unsigned, f);
  u = u + 0x7fffu + ((u >> 16) & 1u);      // RNE
  return (unsigned short)(u >> 16);
}
__device__ __forceinline__ float bf2f(unsigned short u) {
  return __builtin_bit_cast(float, ((unsigned)u) << 16);
}

typedef __bf16 bf16x8 __attribute__((ext_vector_type(8)));
typedef float  f32x4  __attribute__((ext_vector_type(4)));
typedef unsigned short u16x8 __attribute__((ext_vector_type(8)));

#define GLD16(gp, lp) __builtin_amdgcn_global_load_lds( \
    (const __attribute__((address_space(1))) unsigned int*)(gp), \
    (__attribute__((address_space(3))) unsigned int*)(lp), 16, 0, 0)

// ---------- rmsnorm (+ optional residual) ----------
template<int HAS_DELTA, int WRITE_SUM, int WRITE_N32>
__global__ __launch_bounds__(256) void resrms_k(const float* __restrict__ xin,
    const float* __restrict__ delta, float* __restrict__ xsum,
    unsigned short* __restrict__ nbf, float* __restrict__ nf32) {
  int row = blockIdx.x, tid = threadIdx.x;
  size_t base = ((size_t)row << 10) + ((size_t)tid << 2);
  float4 v = *(const float4*)(xin + base);
  if (HAS_DELTA) {
    float4 d = *(const float4*)(delta + base);
    v.x += d.x; v.y += d.y; v.z += d.z; v.w += d.w;
  }
  if (WRITE_SUM) *(float4*)(xsum + base) = v;
  float ss = v.x*v.x + v.y*v.y + v.z*v.z + v.w*v.w;
  #pragma unroll
  for (int off = 32; off; off >>= 1) ss += __shfl_xor(ss, off);
  __shared__ float ws4[4];
  if ((tid & 63) == 0) ws4[tid >> 6] = ss;
  __syncthreads();
  float tot = ws4[0] + ws4[1] + ws4[2] + ws4[3];
  float sc = rsqrtf(tot * (1.0f / 1024.0f) + 1e-5f);
  *(ushort4*)(nbf + base) = make_ushort4(f2bf(v.x*sc), f2bf(v.y*sc), f2bf(v.z*sc), f2bf(v.w*sc));
  if (WRITE_N32) {
    float4 n; n.x = v.x*sc; n.y = v.y*sc; n.z = v.z*sc; n.w = v.w*sc;
    *(float4*)(nf32 + base) = n;
  }
}

// ---------- transpose+convert: W[K][ldw] f32 -> Wt[Npad][K] bf16 ----------
__global__ void transp_k(const float* __restrict__ W, unsigned short* __restrict__ Wt,
                         int K, int Ncols, int Npad, int col_off, int ldw) {
  __shared__ float t[32][33];
  int n0 = blockIdx.x << 5, k0 = blockIdx.y << 5;
  int tx = threadIdx.x, ty = threadIdx.y;
  #pragma unroll
  for (int rr = 0; rr < 32; rr += 8) {
    int k = k0 + rr + ty, n = n0 + tx;
    t[rr + ty][tx] = (n < Ncols) ? W[(size_t)k * ldw + col_off + n] : 0.f;
  }
  __syncthreads();
  #pragma unroll
  for (int rr = 0; rr < 32; rr += 8) {
    int nrow = n0 + rr + ty;
    Wt[(size_t)nrow * K + k0 + tx] = f2bf(t[tx][rr + ty]);
  }
}

// ---------- 8-phase 256x256 bf16 MFMA GEMM (only for grids >= 256; used for kact) ----------
template<int EPI>   // 0=f32, 1=bf16, 2=erf->bf16
__global__ __launch_bounds__(512, 2) void gemm8_k(const unsigned short* __restrict__ A,
    const unsigned short* __restrict__ Bt, void* __restrict__ Cout,
    int M, int N, int K, int ntx) {
  __shared__ unsigned short lds[2 * 32768];   // 128 KiB
  const int tid = threadIdx.x;
  const int w = tid >> 6, lane = tid & 63;
  const int fr = lane & 15, g = lane >> 4;
  const int wmi = w >> 2, wni = w & 3;
  const int nwg = gridDim.x;
  const int nty = nwg / ntx;
  const int l = (blockIdx.x & 7) * (nwg >> 3) + (blockIdx.x >> 3);
  const int S = ((ntx & 3) == 0) ? 4 : (((ntx & 1) == 0) ? 2 : 1);
  const int sw = S * nty;
  const int s_ = l / sw, r_ = l - s_ * sw;
  const int bx = s_ * S + (r_ % S);
  const int by = r_ / S;
  const int m0 = by << 8, n0 = bx << 8;

  f32x4 acc[8][4];
  #pragma unroll
  for (int i = 0; i < 8; ++i)
    #pragma unroll
    for (int j = 0; j < 4; ++j) acc[i][j] = (f32x4){0.f, 0.f, 0.f, 0.f};

  const int r0 = tid >> 3, pc = tid & 7;
  const int lc = pc ^ (r0 & 7);
  const unsigned short* Abase = A + (size_t)(m0 + r0) * K + (lc << 3);
  const unsigned short* Bbase = Bt + (size_t)(n0 + r0) * K + (lc << 3);
  const size_t aK64 = (size_t)64 * K, aK128 = (size_t)128 * K;

#define STG_A(h_, kt_, bb_) { \
    const unsigned short* s0_ = Abase + (size_t)(h_) * aK128 + ((size_t)(kt_) << 6); \
    unsigned short* d0_ = lds + (bb_) * 32768 + (h_) * 8192 + (w << 9); \
    GLD16(s0_, d0_); GLD16(s0_ + aK64, d0_ + 4096); }
#define STG_B(h_, kt_, bb_) { \
    const unsigned short* s0_ = Bbase + (size_t)(h_) * aK128 + ((size_t)(kt_) << 6); \
    unsigned short* d0_ = lds + (bb_) * 32768 + 16384 + (h_) * 8192 + (w << 9); \
    GLD16(s0_, d0_); GLD16(s0_ + aK64, d0_ + 4096); }

  bf16x8 Areg[4][2], Breg[4][2];
#define LDA(mh_, bb_) { \
    _Pragma("unroll") for (int mf = 0; mf < 4; ++mf) \
    _Pragma("unroll") for (int kk = 0; kk < 2; ++kk) { \
      int r = ((mh_) << 6) + (mf << 4) + fr; \
      Areg[mf][kk] = *(const bf16x8*)&lds[(bb_) * 32768 + wmi * 8192 + (r << 6) + ((((kk << 2) + g) ^ (r & 7)) << 3)]; } }
#define LDB(nh_, bb_) { \
    _Pragma("unroll") for (int nf2 = 0; nf2 < 2; ++nf2) \
    _Pragma("unroll") for (int kk = 0; kk < 2; ++kk) { \
      int nf = ((nh_) << 1) + nf2; \
      int r = ((wni & 1) << 6) + (nf << 4) + fr; \
      Breg[nf][kk] = *(const bf16x8*)&lds[(bb_) * 32768 + 16384 + (wni >> 1) * 8192 + (r << 6) + ((((kk << 2) + g) ^ (r & 7)) << 3)]; } }
#define MM(mh_, nh_) { \
    __builtin_amdgcn_s_setprio(1); \
    _Pragma("unroll") for (int mf = 0; mf < 4; ++mf) \
    _Pragma("unroll") for (int nf2 = 0; nf2 < 2; ++nf2) \
    _Pragma("unroll") for (int kk = 0; kk < 2; ++kk) \
      acc[((mh_) << 2) + mf][((nh_) << 1) + nf2] = __builtin_amdgcn_mfma_f32_16x16x32_bf16( \
          Areg[mf][kk], Breg[((nh_) << 1) + nf2][kk], acc[((mh_) << 2) + mf][((nh_) << 1) + nf2], 0, 0, 0); \
    __builtin_amdgcn_s_setprio(0); }
#define BAR_LG \
    __builtin_amdgcn_s_barrier(); \
    asm volatile("s_waitcnt lgkmcnt(0)" ::: "memory"); \
    __builtin_amdgcn_sched_barrier(0);
#define ENDBAR \
    __builtin_amdgcn_s_barrier(); \
    __builtin_amdgcn_sched_barrier(0);

  STG_B(0, 0, 0) STG_B(1, 0, 0) STG_A(0, 0, 0) STG_A(1, 0, 0) STG_B(0, 1, 1) STG_B(1, 1, 1)
  asm volatile("s_waitcnt vmcnt(4)" ::: "memory");
  __builtin_amdgcn_s_barrier();
  __builtin_amdgcn_sched_barrier(0);

  const int NITER = K >> 7;
  for (int it = 0; it < NITER; ++it) {
    const int t = it << 1;
    const bool lastI = (it == NITER - 1);
    LDA(0, 0) LDB(0, 0)
    STG_A(0, t + 1, 1)
    BAR_LG MM(0, 0) ENDBAR
    LDB(1, 0)
    STG_A(1, t + 1, 1)
    BAR_LG MM(0, 1) ENDBAR
    LDA(1, 0)
    if (!lastI) STG_B(0, t + 2, 0)
    BAR_LG MM(1, 0) ENDBAR
    if (!lastI) STG_B(1, t + 2, 0)
    BAR_LG MM(1, 1)
    if (!lastI) { asm volatile("s_waitcnt vmcnt(4)" ::: "memory"); }
    else        { asm volatile("s_waitcnt vmcnt(0)" ::: "memory"); }
    ENDBAR
    LDA(0, 1) LDB(0, 1)
    if (!lastI) STG_A(0, t + 2, 0)
    BAR_LG MM(0, 0) ENDBAR
    LDB(1, 1)
    if (!lastI) STG_A(1, t + 2, 0)
    BAR_LG MM(0, 1) ENDBAR
    LDA(1, 1)
    if (!lastI) STG_B(0, t + 3, 1)
    BAR_LG MM(1, 0) ENDBAR
    if (!lastI) STG_B(1, t + 3, 1)
    BAR_LG MM(1, 1)
    if (!lastI) { asm volatile("s_waitcnt vmcnt(4)" ::: "memory"); }
    else        { asm volatile("s_waitcnt vmcnt(0)" ::: "memory"); }
    ENDBAR
  }
#undef STG_A
#undef STG_B
#undef LDA
#undef LDB
#undef MM
#undef BAR_LG
#undef ENDBAR

  asm volatile("s_waitcnt vmcnt(0)" ::: "memory");
  __syncthreads();
  float (*eps)[260] = (float(*)[260])lds;
  const int er = tid >> 3, ec0 = (tid & 7) << 5;
  #pragma unroll
  for (int slab = 0; slab < 4; ++slab) {
    if (wmi == (slab >> 1)) {
      const int mhs = slab & 1;
      #pragma unroll
      for (int mf = 0; mf < 4; ++mf)
        #pragma unroll
        for (int nf = 0; nf < 4; ++nf)
          #pragma unroll
          for (int rr = 0; rr < 4; ++rr)
            eps[(mf << 4) + (g << 2) + rr][(wni << 6) + (nf << 4) + fr] = acc[(mhs << 2) + mf][nf][rr];
    }
    __syncthreads();
    const int grow = m0 + (slab << 6) + er;
    if (EPI == 0) {
      float* orow = (float*)Cout + (size_t)grow * N + n0 + ec0;
      #pragma unroll
      for (int u = 0; u < 8; ++u) {
        int col = n0 + ec0 + (u << 2);
        if (col < N) {
          float4 v; v.x = eps[er][ec0 + (u << 2)]; v.y = eps[er][ec0 + (u << 2) + 1];
          v.z = eps[er][ec0 + (u << 2) + 2]; v.w = eps[er][ec0 + (u << 2) + 3];
          *(float4*)(orow + (u << 2)) = v;
        }
      }
    } else {
      unsigned short* orow = (unsigned short*)Cout + (size_t)grow * N + n0 + ec0;
      #pragma unroll
      for (int u = 0; u < 4; ++u) {
        int col = n0 + ec0 + (u << 3);
        if (col < N) {
          u16x8 pk;
          #pragma unroll
          for (int e = 0; e < 8; ++e) {
            float v = eps[er][ec0 + (u << 3) + e];
            if (EPI == 2) v = 0.5f * (1.0f + erff((v - 0.70710678f) * 2.5066283f));
            pk[e] = f2bf(v);
          }
          *(u16x8*)(orow + (u << 3)) = pk;
        }
      }
    }
    __syncthreads();
  }
}

// ---------- bf16 MFMA GEMM (m97-class, 3 blk/CU) — R8 signature ----------
// EPI: 0 = f32 store, 1 = bf16 store, 2 = erf-activation -> bf16 store
template<int EPI>
__global__ __launch_bounds__(256, 3) void gemm4_k(const unsigned short* __restrict__ A,
    const unsigned short* __restrict__ Bt, void* __restrict__ Cout,
    int M, int N, int K, int ntx) {
  __shared__ char smem[49152];
  unsigned short* lds = (unsigned short*)smem;
  const int tid = threadIdx.x;
  const int w = tid >> 6, lane = tid & 63;
  const int fr = lane & 15, g = lane >> 4;
  const int nwg = gridDim.x;
  const int nty = nwg / ntx;
  const int l = (blockIdx.x & 7) * (nwg >> 3) + (blockIdx.x >> 3);
  const int S = ((ntx & 3) == 0) ? 4 : (((ntx & 1) == 0) ? 2 : 1);
  const int sw = S * nty;
  const int s = l / sw, r_ = l - s * sw;
  const int bx = s * S + (r_ % S);
  const int by = r_ / S;
  const int m0 = by << 7, n0 = bx << 7;
  const int wm = (w >> 1) << 6, wn = (w & 1) << 6;

  f32x4 acc[4][4];
  #pragma unroll
  for (int i = 0; i < 4; ++i)
    #pragma unroll
    for (int j = 0; j < 4; ++j) acc[i][j] = (f32x4){0.f, 0.f, 0.f, 0.f};

  const int r0s = tid >> 2, pc0 = tid & 3;
  const int lc0 = pc0 ^ ((r0s >> 1) & 3);
  const int r1s = r0s + 64;
  const int lc1 = pc0 ^ ((r1s >> 1) & 3);
  const unsigned short* a0 = A + (size_t)(m0 + r0s) * K + (lc0 << 3);
  const unsigned short* a1 = A + (size_t)(m0 + r1s) * K + (lc1 << 3);
  const unsigned short* b0 = Bt + (size_t)(n0 + r0s) * K + (lc0 << 3);
  const unsigned short* b1 = Bt + (size_t)(n0 + r1s) * K + (lc1 << 3);
  const int wofs = w << 9;

#define STAGE4(kt_, bb_) { \
    unsigned short* d_ = lds + (bb_) * 8192 + wofs; \
    GLD16(a0 + ((kt_) << 5), d_); \
    GLD16(a1 + ((kt_) << 5), d_ + 2048); \
    GLD16(b0 + ((kt_) << 5), d_ + 4096); \
    GLD16(b1 + ((kt_) << 5), d_ + 6144); }

  const int NT = K >> 5;
  STAGE4(0, 0)
  STAGE4(1, 1)
  asm volatile("s_waitcnt vmcnt(4)" ::: "memory");
  __builtin_amdgcn_s_barrier();
  __builtin_amdgcn_sched_barrier(0);

  int cb = 0;
  for (int t = 0; t < NT; ++t) {
    const unsigned short* bufp = lds + cb * 8192;
    int sb = cb + 2; if (sb >= 3) sb -= 3;
    const int have2 = (t + 2 < NT);
    if (have2) STAGE4(t + 2, sb)
    bf16x8 af[4], bv[4];
    #pragma unroll
    for (int i = 0; i < 4; ++i) {
      int r = wm + (i << 4) + fr;
      af[i] = *(const bf16x8*)&bufp[(r << 5) + (((g ^ (r >> 1)) & 3) << 3)];
    }
    #pragma unroll
    for (int j = 0; j < 4; ++j) {
      int r = wn + (j << 4) + fr;
      bv[j] = *(const bf16x8*)&bufp[4096 + (r << 5) + (((g ^ (r >> 1)) & 3) << 3)];
    }
    __builtin_amdgcn_s_setprio(1);
    #pragma unroll
    for (int i = 0; i < 4; ++i)
      #pragma unroll
      for (int j = 0; j < 4; ++j)
        acc[i][j] = __builtin_amdgcn_mfma_f32_16x16x32_bf16(af[i], bv[j], acc[i][j], 0, 0, 0);
    __builtin_amdgcn_s_setprio(0);
    if (t + 1 < NT) {
      if (have2) { asm volatile("s_waitcnt vmcnt(4)" ::: "memory"); }
      else       { asm volatile("s_waitcnt vmcnt(0)" ::: "memory"); }
      __builtin_amdgcn_s_barrier();
      __builtin_amdgcn_sched_barrier(0);
    }
    cb = cb + 1; if (cb >= 3) cb -= 3;
  }
#undef STAGE4

  float (*eps)[132] = (float(*)[132])smem;
  const int rin = g << 2;
  const int er = tid >> 2, ec0 = (tid & 3) << 5;
  #pragma unroll
  for (int rh = 0; rh < 2; ++rh) {
    __syncthreads();
    if ((wm >> 6) == rh) {
      #pragma unroll
      for (int i = 0; i < 4; ++i)
        #pragma unroll
        for (int j = 0; j < 4; ++j)
          #pragma unroll
          for (int rr = 0; rr < 4; ++rr)
            eps[(i << 4) + rin + rr][wn + (j << 4) + fr] = acc[i][j][rr];
    }
    __syncthreads();
    int grow = m0 + (rh << 6) + er;
    if (EPI == 0) {
      float* orow = (float*)Cout + (size_t)grow * N + n0 + ec0;
      #pragma unroll
      for (int u = 0; u < 8; ++u) {
        int col = n0 + ec0 + (u << 2);
        if (col < N) {
          float4 v; v.x = eps[er][ec0 + (u<<2)]; v.y = eps[er][ec0 + (u<<2) + 1];
          v.z = eps[er][ec0 + (u<<2) + 2]; v.w = eps[er][ec0 + (u<<2) + 3];
          *(float4*)(orow + (u << 2)) = v;
        }
      }
    } else {
      unsigned short* orow = (unsigned short*)Cout + (size_t)grow * N + n0 + ec0;
      #pragma unroll
      for (int u = 0; u < 4; ++u) {
        int col = n0 + ec0 + (u << 3);
        if (col < N) {
          u16x8 pk;
          #pragma unroll
          for (int e = 0; e < 8; ++e) {
            float v = eps[er][ec0 + (u << 3) + e];
            if (EPI == 2) v = 0.5f * (1.0f + erff((v - 0.70710678f) * 2.5066283f));
            pk[e] = f2bf(v);
          }
          *(u16x8*)(orow + (u << 3)) = pk;
        }
      }
    }
  }
}

// ---------- causal depthwise conv(4) + silu, with fused dt/softplus ----------
__global__ __launch_bounds__(256) void convk(const float* __restrict__ zxr,
    const float* __restrict__ conv_w, const float* __restrict__ conv_b,
    const float* __restrict__ dt_bias, float* __restrict__ xbc,
    float* __restrict__ dtb) {
  int i = blockIdx.x * 256 + threadIdx.x;     // 4*1024*2176
  if (i >= 4 * 1024 * 2176) return;
  int c = i % 2176; int bt = i / 2176; int t = bt & 1023;
  const float* col = zxr + (size_t)bt * 2208 + c;
  float acc = conv_b[c];
  float w0 = conv_w[c * 4 + 0], w1 = conv_w[c * 4 + 1], w2 = conv_w[c * 4 + 2], w3 = conv_w[c * 4 + 3];
  if (t >= 3) acc = fmaf(col[-3 * 2208], w0, acc);
  if (t >= 2) acc = fmaf(col[-2 * 2208], w1, acc);
  if (t >= 1) acc = fmaf(col[-1 * 2208], w2, acc);
  acc = fmaf(col[0], w3, acc);
  xbc[(size_t)bt * 2176 + c] = acc / (1.f + __expf(-acc));
  if (c < 32) {
    float v = zxr[(size_t)bt * 2208 + 2176 + c] + dt_bias[c];
    dtb[bt * 32 + c] = (v > 20.f) ? v : log1pf(__expf(v));
  }
}

// ---------- SSD chunked scan, stage 1 ----------
__global__ __launch_bounds__(256) void ssd1_k(const float* __restrict__ xbc,
    const float* __restrict__ dtb, const float* __restrict__ A_log,
    float* __restrict__ ydin, float* __restrict__ dhbuf, float* __restrict__ labuf) {
  __shared__ unsigned short Cs[64][68];
  __shared__ unsigned short Bsm[64][68];
  __shared__ unsigned short XT[64][68];
  __shared__ unsigned short BT[64][68];
  __shared__ unsigned short Ms[64][68];
  __shared__ float laS[64], dtS[64];
  const int id = blockIdx.x;
  const int h = id & 31, b = (id >> 5) & 3, c = id >> 7;
  const int tid = threadIdx.x, w = tid >> 6, lane = tid & 63;
  const int fr = lane & 15, g = lane >> 4;
  const size_t rowbase = (size_t)((b << 10) + (c << 6));

  {
    int r = tid >> 2, c0 = (tid & 3) << 4;
    const float* src = xbc + (rowbase + r) * 2176;
    #pragma unroll
    for (int i = 0; i < 4; ++i) {
      float4 v = *(const float4*)(src + 2112 + c0 + 4 * i);
      *(ushort4*)&Cs[r][c0 + 4 * i] = make_ushort4(f2bf(v.x), f2bf(v.y), f2bf(v.z), f2bf(v.w));
      float4 u = *(const float4*)(src + 2048 + c0 + 4 * i);
      *(ushort4*)&Bsm[r][c0 + 4 * i] = make_ushort4(f2bf(u.x), f2bf(u.y), f2bf(u.z), f2bf(u.w));
    }
  }
  {
    int r0 = (tid & 15) << 2, d0 = (tid >> 4) << 2;
    const float* src = xbc + (rowbase + r0) * 2176 + (h << 6) + d0;
    float4 v0 = *(const float4*)(src);
    float4 v1 = *(const float4*)(src + 2176);
    float4 v2 = *(const float4*)(src + 4352);
    float4 v3 = *(const float4*)(src + 6528);
    *(ushort4*)&XT[d0 + 0][r0] = make_ushort4(f2bf(v0.x), f2bf(v1.x), f2bf(v2.x), f2bf(v3.x));
    *(ushort4*)&XT[d0 + 1][r0] = make_ushort4(f2bf(v0.y), f2bf(v1.y), f2bf(v2.y), f2bf(v3.y));
    *(ushort4*)&XT[d0 + 2][r0] = make_ushort4(f2bf(v0.z), f2bf(v1.z), f2bf(v2.z), f2bf(v3.z));
    *(ushort4*)&XT[d0 + 3][r0] = make_ushort4(f2bf(v0.w), f2bf(v1.w), f2bf(v2.w), f2bf(v3.w));
  }
  if (w == 0) {
    float Ah = -__expf(A_log[h]);
    float dtv = dtb[(rowbase + lane) * 32 + h];
    float v = dtv * Ah;
    #pragma unroll
    for (int off = 1; off < 64; off <<= 1) {
      float u = __shfl_up(v, off);
      if (lane >= off) v += u;
    }
    laS[lane] = v; dtS[lane] = dtv;
    labuf[(size_t)((((b << 4) | c) << 5 | h) << 6) + lane] = v;
  }
  __syncthreads();

  const int wr = w >> 1, wc = w & 1;
  f32x4 gf[2][2];
  #pragma unroll
  for (int i = 0; i < 2; ++i)
    #pragma unroll
    for (int j = 0; j < 2; ++j) gf[i][j] = (f32x4){0.f, 0.f, 0.f, 0.f};
  {
    int r0 = (tid & 15) << 2, d0 = (tid >> 4) << 2;
    const float* src = xbc + (rowbase + r0) * 2176 + 2048 + d0;
    float la63 = laS[63];
    float4 v0 = *(const float4*)(src);
    float4 v1 = *(const float4*)(src + 2176);
    float4 v2 = *(const float4*)(src + 4352);
    float4 v3 = *(const float4*)(src + 6528);
    float w0 = __expf(la63 - laS[r0 + 0]) * dtS[r0 + 0];
    float w1 = __expf(la63 - laS[r0 + 1]) * dtS[r0 + 1];
    float w2 = __expf(la63 - laS[r0 + 2]) * dtS[r0 + 2];
    float w3 = __expf(la63 - laS[r0 + 3]) * dtS[r0 + 3];
    *(ushort4*)&BT[d0 + 0][r0] = make_ushort4(f2bf(v0.x*w0), f2bf(v1.x*w1), f2bf(v2.x*w2), f2bf(v3.x*w3));
    *(ushort4*)&BT[d0 + 1][r0] = make_ushort4(f2bf(v0.y*w0), f2bf(v1.y*w1), f2bf(v2.y*w2), f2bf(v3.y*w3));
    *(ushort4*)&BT[d0 + 2][r0] = make_ushort4(f2bf(v0.z*w0), f2bf(v1.z*w1), f2bf(v2.z*w2), f2bf(v3.z*w3));
    *(ushort4*)&BT[d0 + 3][r0] = make_ushort4(f2bf(v0.w*w0), f2bf(v1.w*w1), f2bf(v2.w*w2), f2bf(v3.w*w3));
  }
  #pragma unroll
  for (int ks = 0; ks < 2; ++ks) {
    bf16x8 ca[2], bb[2];
    #pragma unroll
    for (int i = 0; i < 2; ++i) ca[i] = *(const bf16x8*)&Cs[(wr << 5) + (i << 4) + fr][(ks << 5) + (g << 3)];
    #pragma unroll
    for (int j = 0; j < 2; ++j) bb[j] = *(const bf16x8*)&Bsm[(wc << 5) + (j << 4) + fr][(ks << 5) + (g << 3)];
    #pragma unroll
    for (int i = 0; i < 2; ++i)
      #pragma unroll
      for (int j = 0; j < 2; ++j)
        gf[i][j] = __builtin_amdgcn_mfma_f32_16x16x32_bf16(ca[i], bb[j], gf[i][j], 0, 0, 0);
  }
  #pragma unroll
  for (int i = 0; i < 2; ++i) {
    #pragma unroll
    for (int j = 0; j < 2; ++j) {
      int s = (wc << 5) + (j << 4) + fr;
      float la_s = laS[s], dt_s = dtS[s];
      #pragma unroll
      for (int rr = 0; rr < 4; ++rr) {
        int t = (wr << 5) + (i << 4) + (g << 2) + rr;
        float e = __expf(fminf(laS[t] - la_s, 0.f));
        float val = (s <= t) ? gf[i][j][rr] * e * dt_s : 0.f;
        Ms[t][s] = f2bf(val);
      }
    }
  }
  __syncthreads();

  f32x4 yf[2][2], hf[2][2];
  #pragma unroll
  for (int i = 0; i < 2; ++i)
    #pragma unroll
    for (int j = 0; j < 2; ++j) { yf[i][j] = (f32x4){0.f,0.f,0.f,0.f}; hf[i][j] = (f32x4){0.f,0.f,0.f,0.f}; }
  #pragma unroll
  for (int ks = 0; ks < 2; ++ks) {
    bf16x8 ma[2], ba[2], xb[2];
    #pragma unroll
    for (int i = 0; i < 2; ++i) {
      ma[i] = *(const bf16x8*)&Ms[(wr << 5) + (i << 4) + fr][(ks << 5) + (g << 3)];
      ba[i] = *(const bf16x8*)&BT[(wr << 5) + (i << 4) + fr][(ks << 5) + (g << 3)];
    }
    #pragma unroll
    for (int j = 0; j < 2; ++j) xb[j] = *(const bf16x8*)&XT[(wc << 5) + (j << 4) + fr][(ks << 5) + (g << 3)];
    #pragma unroll
    for (int i = 0; i < 2; ++i)
      #pragma unroll
      for (int j = 0; j < 2; ++j) {
        yf[i][j] = __builtin_amdgcn_mfma_f32_16x16x32_bf16(ma[i], xb[j], yf[i][j], 0, 0, 0);
        hf[i][j] = __builtin_amdgcn_mfma_f32_16x16x32_bf16(ba[i], xb[j], hf[i][j], 0, 0, 0);
      }
  }
  float* dhb = dhbuf + ((size_t)(((c << 2) + b) * 32 + h) << 12);
  #pragma unroll
  for (int i = 0; i < 2; ++i) {
    #pragma unroll
    for (int j = 0; j < 2; ++j) {
      int p = (wc << 5) + (j << 4) + fr;
      #pragma unroll
      for (int rr = 0; rr < 4; ++rr) {
        int t = (wr << 5) + (i << 4) + (g << 2) + rr;
        ydin[((rowbase + t) << 11) + (h << 6) + p] = yf[i][j][rr];
        dhb[(t << 6) + p] = hf[i][j][rr];
      }
    }
  }
}

// ---------- SSD stage 2 ----------
__global__ __launch_bounds__(256) void ssd2_k(const float* __restrict__ dhbuf,
    const float* __restrict__ labuf, float* __restrict__ hseq) {
  int idx = blockIdx.x * 256 + threadIdx.x;
  int np = idx & 4095;
  int h = (idx >> 12) & 31, b = idx >> 17;
  float carry = 0.f;
  #pragma unroll
  for (int c = 0; c < 16; ++c) {
    size_t o = ((size_t)(((c << 2) + b) * 32 + h) << 12) + np;
    hseq[o] = carry;
    float ec = __expf(labuf[(size_t)((((b << 4) | c) << 5 | h) << 6) + 63]);
    carry = fmaf(ec, carry, dhbuf[o]);
  }
}

// ---------- SSD stage 3 ----------
__global__ __launch_bounds__(256) void ssd3_k(const float* __restrict__ xbc,
    const float* __restrict__ hseq, const float* __restrict__ labuf,
    const float* __restrict__ Dv, float* __restrict__ ydin) {
  __shared__ unsigned short Cs[64][68];
  __shared__ unsigned short HT[64][68];
  __shared__ float laS[64];
  const int id = blockIdx.x;
  const int h = id & 31, b = (id >> 5) & 3, c = id >> 7;
  const int tid = threadIdx.x, w = tid >> 6, lane = tid & 63;
  const int fr = lane & 15, g = lane >> 4;
  const size_t rowbase = (size_t)((b << 10) + (c << 6));
  {
    int r = tid >> 2, c0 = (tid & 3) << 4;
    const float* src = xbc + (rowbase + r) * 2176 + 2112 + c0;
    #pragma unroll
    for (int i = 0; i < 4; ++i) {
      float4 v = *(const float4*)(src + 4 * i);
      *(ushort4*)&Cs[r][c0 + 4 * i] = make_ushort4(f2bf(v.x), f2bf(v.y), f2bf(v.z), f2bf(v.w));
    }
  }
  {
    const float* hb = hseq + ((size_t)(((c << 2) + b) * 32 + h) << 12);
    int n0 = (tid & 15) << 2, p0 = (tid >> 4) << 2;
    float4 v0 = *(const float4*)(hb + ((n0 + 0) << 6) + p0);
    float4 v1 = *(const float4*)(hb + ((n0 + 1) << 6) + p0);
    float4 v2 = *(const float4*)(hb + ((n0 + 2) << 6) + p0);
    float4 v3 = *(const float4*)(hb + ((n0 + 3) << 6) + p0);
    *(ushort4*)&HT[p0 + 0][n0] = make_ushort4(f2bf(v0.x), f2bf(v1.x), f2bf(v2.x), f2bf(v3.x));
    *(ushort4*)&HT[p0 + 1][n0] = make_ushort4(f2bf(v0.y), f2bf(v1.y), f2bf(v2.y), f2bf(v3.y));
    *(ushort4*)&HT[p0 + 2][n0] = make_ushort4(f2bf(v0.z), f2bf(v1.z), f2bf(v2.z), f2bf(v3.z));
    *(ushort4*)&HT[p0 + 3][n0] = make_ushort4(f2bf(v0.w), f2bf(v1.w), f2bf(v2.w), f2bf(v3.w));
  }
  if (tid < 64) laS[tid] = labuf[(size_t)((((b << 4) | c) << 5 | h) << 6) + tid];
  __syncthreads();
  const int wr = w >> 1, wc = w & 1;
  f32x4 yf[2][2];
  #pragma unroll
  for (int i = 0; i < 2; ++i)
    #pragma unroll
    for (int j = 0; j < 2; ++j) yf[i][j] = (f32x4){0.f, 0.f, 0.f, 0.f};
  #pragma unroll
  for (int ks = 0; ks < 2; ++ks) {
    bf16x8 ca[2], hv[2];
    #pragma unroll
    for (int i = 0; i < 2; ++i) ca[i] = *(const bf16x8*)&Cs[(wr << 5) + (i << 4) + fr][(ks << 5) + (g << 3)];
    #pragma unroll
    for (int j = 0; j < 2; ++j) hv[j] = *(const bf16x8*)&HT[(wc << 5) + (j << 4) + fr][(ks << 5) + (g << 3)];
    #pragma unroll
    for (int i = 0; i < 2; ++i)
      #pragma unroll
      for (int j = 0; j < 2; ++j)
        yf[i][j] = __builtin_amdgcn_mfma_f32_16x16x32_bf16(ca[i], hv[j], yf[i][j], 0, 0, 0);
  }
  float Dh = Dv[h];
  #pragma unroll
  for (int i = 0; i < 2; ++i) {
    #pragma unroll
    for (int j = 0; j < 2; ++j) {
      int p = (wc << 5) + (j << 4) + fr;
      #pragma unroll
      for (int rr = 0; rr < 4; ++rr) {
        int t = (wr << 5) + (i << 4) + (g << 2) + rr;
        size_t yo = ((rowbase + t) << 11) + (h << 6) + p;
        float xv = xbc[(rowbase + t) * 2176 + (h << 6) + p];
        ydin[yo] = ydin[yo] + __expf(laS[t]) * yf[i][j][rr] + Dh * xv;
      }
    }
  }
}

// ---------- g = ydin * silu(z); rmsnorm(2048) * mnorm_w -> bf16 ----------
__global__ __launch_bounds__(256) void gnormk(const float* __restrict__ ydin,
    const unsigned short* __restrict__ zbf, const float* __restrict__ mw,
    unsigned short* __restrict__ gbf) {
  int row = blockIdx.x, tid = threadIdx.x;
  size_t base = ((size_t)row << 11) + ((size_t)tid << 3);
  float4 y0 = *(const float4*)(ydin + base);
  float4 y1 = *(const float4*)(ydin + base + 4);
  ushort4 z0 = *(const ushort4*)(zbf + base);
  ushort4 z1 = *(const ushort4*)(zbf + base + 4);
  float g[8];
  {
    float z;
    z = bf2f(z0.x); g[0] = y0.x * (z / (1.f + __expf(-z)));
    z = bf2f(z0.y); g[1] = y0.y * (z / (1.f + __expf(-z)));
    z = bf2f(z0.z); g[2] = y0.z * (z / (1.f + __expf(-z)));
    z = bf2f(z0.w); g[3] = y0.w * (z / (1.f + __expf(-z)));
    z = bf2f(z1.x); g[4] = y1.x * (z / (1.f + __expf(-z)));
    z = bf2f(z1.y); g[5] = y1.y * (z / (1.f + __expf(-z)));
    z = bf2f(z1.z); g[6] = y1.z * (z / (1.f + __expf(-z)));
    z = bf2f(z1.w); g[7] = y1.w * (z / (1.f + __expf(-z)));
  }
  float ss = 0.f;
  #pragma unroll
  for (int k = 0; k < 8; ++k) ss += g[k] * g[k];
  #pragma unroll
  for (int off = 32; off; off >>= 1) ss += __shfl_xor(ss, off);
  __shared__ float ws4[4];
  if ((tid & 63) == 0) ws4[tid >> 6] = ss;
  __syncthreads();
  float tot = ws4[0] + ws4[1] + ws4[2] + ws4[3];
  float sc = rsqrtf(tot * (1.f / 2048.f) + 1e-5f);
  int c0 = tid << 3;
  float4 m0 = *(const float4*)(mw + c0);
  float4 m1 = *(const float4*)(mw + c0 + 4);
  *(ushort4*)(gbf + base)     = make_ushort4(f2bf(g[0]*sc*m0.x), f2bf(g[1]*sc*m0.y), f2bf(g[2]*sc*m0.z), f2bf(g[3]*sc*m0.w));
  *(ushort4*)(gbf + base + 4) = make_ushort4(f2bf(g[4]*sc*m1.x), f2bf(g[5]*sc*m1.y), f2bf(g[6]*sc*m1.z), f2bf(g[7]*sc*m1.w));
}

// ---------- MQA causal attention (MFMA flash), bf16 in/out ----------
__global__ __launch_bounds__(256) void attnk(const unsigned short* __restrict__ qkv,
                                             unsigned short* __restrict__ ybf) {
  __shared__ unsigned short Qs[64][72];
  __shared__ unsigned short Ks[64][72];
  __shared__ unsigned short VT[64][72];
  __shared__ unsigned short Ps[4][16][72];
  const int id = blockIdx.x;
  const int b = id & 3, h = (id >> 2) & 15, qt = id >> 6;
  const int t0 = qt << 6;
  const int tid = threadIdx.x, w = tid >> 6, lane = tid & 63;
  const int fr = lane & 15, g = lane >> 4;
  {
    int r = tid >> 2, d0 = (tid & 3) << 4;
    const unsigned short* src = qkv + ((size_t)((b << 10) | (t0 + r))) * 1152 + (h << 6) + d0;
    *(uint4*)&Qs[r][d0]     = *(const uint4*)(src);
    *(uint4*)&Qs[r][d0 + 8] = *(const uint4*)(src + 8);
  }
  __syncthreads();
  bf16x8 afQ0 = *(const bf16x8*)&Qs[(w << 4) + fr][g << 3];
  bf16x8 afQ1 = *(const bf16x8*)&Qs[(w << 4) + fr][32 + (g << 3)];
  f32x4 acc_o[4];
  #pragma unroll
  for (int i = 0; i < 4; ++i) acc_o[i] = (f32x4){0.f, 0.f, 0.f, 0.f};
  float m[4] = {-1e30f, -1e30f, -1e30f, -1e30f};
  float l[4] = {0.f, 0.f, 0.f, 0.f};
  const int qrow = t0 + (w << 4) + (g << 2);
  for (int kt = 0; kt <= qt; ++kt) {
    const int s0 = kt << 6;
    __syncthreads();
    {
      int r = tid >> 2, d0 = (tid & 3) << 4;
      const unsigned short* src = qkv + ((size_t)((b << 10) | (s0 + r))) * 1152 + 1024 + d0;
      *(uint4*)&Ks[r][d0]     = *(const uint4*)(src);
      *(uint4*)&Ks[r][d0 + 8] = *(const uint4*)(src + 8);
    }
    {
      int r0 = (tid & 15) << 2, d0 = (tid >> 4) << 2;
      const unsigned short* src = qkv + ((size_t)((b << 10) | (s0 + r0))) * 1152 + 1088 + d0;
      ushort4 v0 = *(const ushort4*)(src);
      ushort4 v1 = *(const ushort4*)(src + 1152);
      ushort4 v2 = *(const ushort4*)(src + 2304);
      ushort4 v3 = *(const ushort4*)(src + 3456);
      *(ushort4*)&VT[d0 + 0][r0] = make_ushort4(v0.x, v1.x, v2.x, v3.x);
      *(ushort4*)&VT[d0 + 1][r0] = make_ushort4(v0.y, v1.y, v2.y, v3.y);
      *(ushort4*)&VT[d0 + 2][r0] = make_ushort4(v0.z, v1.z, v2.z, v3.z);
      *(ushort4*)&VT[d0 + 3][r0] = make_ushort4(v0.w, v1.w, v2.w, v3.w);
    }
    __syncthreads();
    f32x4 s4[4];
    #pragma unroll
    for (int jt = 0; jt < 4; ++jt) {
      bf16x8 b0 = *(const bf16x8*)&Ks[(jt << 4) + fr][g << 3];
      bf16x8 b1 = *(const bf16x8*)&Ks[(jt << 4) + fr][32 + (g << 3)];
      f32x4 z4 = (f32x4){0.f, 0.f, 0.f, 0.f};
      z4 = __builtin_amdgcn_mfma_f32_16x16x32_bf16(afQ0, b0, z4, 0, 0, 0);
      z4 = __builtin_amdgcn_mfma_f32_16x16x32_bf16(afQ1, b1, z4, 0, 0, 0);
      s4[jt] = z4 * 0.125f;
    }
    if (kt == qt) {
      #pragma unroll
      for (int jt = 0; jt < 4; ++jt) {
        int key = s0 + (jt << 4) + fr;
        #pragma unroll
        for (int r = 0; r < 4; ++r)
          if (key > qrow + r) s4[jt][r] = -1e30f;
      }
    }
    #pragma unroll
    for (int r = 0; r < 4; ++r) {
      float mt = fmaxf(fmaxf(s4[0][r], s4[1][r]), fmaxf(s4[2][r], s4[3][r]));
      #pragma unroll
      for (int off = 8; off; off >>= 1) mt = fmaxf(mt, __shfl_xor(mt, off));
      float mn = fmaxf(m[r], mt);
      float scl = __expf(m[r] - mn);
      m[r] = mn;
      float ps = 0.f;
      #pragma unroll
      for (int jt = 0; jt < 4; ++jt) {
        float p = __expf(s4[jt][r] - mn);
        ps += p;
        Ps[w][(g << 2) + r][(jt << 4) + fr] = f2bf(p);
      }
      #pragma unroll
      for (int off = 8; off; off >>= 1) ps += __shfl_xor(ps, off);
      l[r] = l[r] * scl + ps;
      acc_o[0][r] *= scl; acc_o[1][r] *= scl; acc_o[2][r] *= scl; acc_o[3][r] *= scl;
    }
    #pragma unroll
    for (int ks = 0; ks < 2; ++ks) {
      bf16x8 ap = *(const bf16x8*)&Ps[w][fr][(ks << 5) + (g << 3)];
      #pragma unroll
      for (int dt = 0; dt < 4; ++dt) {
        bf16x8 bv = *(const bf16x8*)&VT[(dt << 4) + fr][(ks << 5) + (g << 3)];
        acc_o[dt] = __builtin_amdgcn_mfma_f32_16x16x32_bf16(ap, bv, acc_o[dt], 0, 0, 0);
      }
    }
  }
  #pragma unroll
  for (int dt = 0; dt < 4; ++dt) {
    #pragma unroll
    for (int r = 0; r < 4; ++r) {
      float o = acc_o[dt][r] / l[r];
      int t = t0 + (w << 4) + (g << 2) + r;
      ybf[(((size_t)((b << 10) | t)) << 10) + (h << 6) + (dt << 4) + fr] = f2bf(o);
    }
  }
}

// ---------- cmix token-shift mix -> xk, xr (bf16) ----------
__global__ __launch_bounds__(256) void mixk(const float* __restrict__ xn3,
    const float* __restrict__ tmk, const float* __restrict__ tmr,
    unsigned short* __restrict__ xkbf, unsigned short* __restrict__ xrbf) {
  int idx4 = blockIdx.x * 256 + threadIdx.x;
  int col = (idx4 & 255) << 2;
  int row = idx4 >> 8;
  int t = row & 1023;
  size_t off = ((size_t)idx4) << 2;
  float4 cur = *(const float4*)(xn3 + off);
  float4 prev = make_float4(0.f, 0.f, 0.f, 0.f);
  if (t > 0) prev = *(const float4*)(xn3 + off - 1024);
  float4 tk = *(const float4*)(tmk + col);
  float4 tr = *(const float4*)(tmr + col);
  float dx = prev.x - cur.x, dy = prev.y - cur.y, dz = prev.z - cur.z, dw = prev.w - cur.w;
  *(ushort4*)(xkbf + off) = make_ushort4(
      f2bf(cur.x + dx * tk.x), f2bf(cur.y + dy * tk.y), f2bf(cur.z + dz * tk.z), f2bf(cur.w + dw * tk.w));
  *(ushort4*)(xrbf + off) = make_ushort4(
      f2bf(cur.x + dx * tr.x), f2bf(cur.y + dy * tr.y), f2bf(cur.z + dz * tr.z), f2bf(cur.w + dw * tr.w));
}

// ---------- final: out = x2 + sigmoid(rraw) * vout ----------
__global__ __launch_bounds__(256) void finalk(const float* __restrict__ x2,
    const float* __restrict__ rraw, const float* __restrict__ vout,
    float* __restrict__ out) {
  int idx4 = blockIdx.x * 256 + threadIdx.x;
  size_t off = ((size_t)idx4) << 2;
  float4 xv = *(const float4*)(x2 + off);
  float4 rv = *(const float4*)(rraw + off);
  float4 vv = *(const float4*)(vout + off);
  float4 o;
  o.x = xv.x + vv.x / (1.f + __expf(-rv.x));
  o.y = xv.y + vv.y / (1.f + __expf(-rv.y));
  o.z = xv.z + vv.z / (1.f + __expf(-rv.z));
  o.w = xv.w + vv.w / (1.f + __expf(-rv.w));
  *(float4*)(out + off) = o;
}

// ---------- host launcher ----------
extern "C" void kernel_launch(void* const* d_in, const int* in_sizes, int n_in,
                              void* d_out, int out_size, void* d_ws, size_t ws_size,
                              hipStream_t stream) {
  (void)in_sizes; (void)n_in; (void)out_size;
  const float* x        = (const float*)d_in[0];
  const float* in_proj  = (const float*)d_in[1];
  const float* conv_w   = (const float*)d_in[2];
  const float* conv_b   = (const float*)d_in[3];
  const float* dt_bias  = (const float*)d_in[4];
  const float* A_log    = (const float*)d_in[5];
  const float* Dvec     = (const float*)d_in[6];
  const float* mnorm_w  = (const float*)d_in[7];
  const float* out_proj = (const float*)d_in[8];
  const float* attn_w   = (const float*)d_in[9];
  const float* proj_w   = (const float*)d_in[10];
  const float* tmk      = (const float*)d_in[11];
  const float* tmr      = (const float*)d_in[12];
  const float* key_w    = (const float*)d_in[13];
  const float* recept_w = (const float*)d_in[14];
  const float* value_w  = (const float*)d_in[15];
  float* out = (float*)d_out;

  if (ws_size < 199229440ull) return;

  char* ws = (char*)d_ws;
  unsigned short* Wt   = (unsigned short*)(ws + 0);
  unsigned short* Abf  = (unsigned short*)(ws + 8912896ull);
  unsigned short* Abf2 = (unsigned short*)(ws + 42467328ull);
  float* bigF = (float*)(ws + 59244544ull);
  float* big1 = (float*)(ws + 95420416ull);
  float* big2 = (float*)(ws + 131072000ull);
  float* x1   = (float*)(ws + 164626432ull);
  float* xn3  = (float*)(ws + 181403648ull);
  float* dtb  = (float*)(ws + 198180864ull);
  float* labuf= (float*)(ws + 198705152ull);
  unsigned short* zbf  = Abf2;
  unsigned short* xkbf = Abf2;
  unsigned short* xrbf = Abf2 + 4194304;
  float* dhbuf = bigF;
  float* hseq  = (float*)Abf;
  unsigned short* qkvbf = (unsigned short*)big1;

  dim3 b256(256);
  dim3 b512(512);
  dim3 tb(32, 8);

  // ===== Phase A: mamba2 =====
  resrms_k<0, 0, 0><<<4096, b256, 0, stream>>>(x, nullptr, nullptr, Abf, nullptr);
  transp_k<<<dim3(64, 32), tb, 0, stream>>>(in_proj, Wt, 1024, 2048, 2048, 0, 4256);
  gemm4_k<1><<<512, b256, 0, stream>>>(Abf, Wt, zbf, 4096, 2048, 1024, 16);              // z (bf16)
  transp_k<<<dim3(72, 32), tb, 0, stream>>>(in_proj, Wt, 1024, 2208, 2304, 2048, 4256);
  gemm4_k<0><<<576, b256, 0, stream>>>(Abf, Wt, bigF, 4096, 2208, 1024, 18);             // xBC+dt (f32)
  convk<<<34816, b256, 0, stream>>>(bigF, conv_w, conv_b, dt_bias, big1, dtb);           // xbc_act + dt
  ssd1_k<<<2048, b256, 0, stream>>>(big1, dtb, A_log, big2, dhbuf, labuf);               // Y_intra, dh, la
  ssd2_k<<<2048, b256, 0, stream>>>(dhbuf, labuf, hseq);                                 // chunk states
  ssd3_k<<<2048, b256, 0, stream>>>(big1, hseq, labuf, Dvec, big2);                      // ydin final
  gnormk<<<4096, b256, 0, stream>>>(big2, zbf, mnorm_w, Abf);                            // g (bf16)
  transp_k<<<dim3(32, 64), tb, 0, stream>>>(out_proj, Wt, 2048, 1024, 1024, 0, 1024);
  gemm4_k<0><<<256, b256, 0, stream>>>(Abf, Wt, big1, 4096, 1024, 2048, 8);              // mo
  resrms_k<1, 1, 0><<<4096, b256, 0, stream>>>(x, big1, x1, Abf, nullptr);               // x1, xn2

  // ===== Phase B: mqa =====
  transp_k<<<dim3(36, 32), tb, 0, stream>>>(attn_w, Wt, 1024, 1152, 1152, 0, 1152);
  gemm4_k<1><<<288, b256, 0, stream>>>(Abf, Wt, qkvbf, 4096, 1152, 1024, 9);             // qkv (bf16)
  attnk<<<1024, b256, 0, stream>>>(qkvbf, Abf);                                          // atty (bf16)
  transp_k<<<dim3(32, 32), tb, 0, stream>>>(proj_w, Wt, 1024, 1024, 1024, 0, 1024);
  gemm4_k<0><<<256, b256, 0, stream>>>(Abf, Wt, big2, 4096, 1024, 1024, 8);              // po
  resrms_k<1, 1, 1><<<4096, b256, 0, stream>>>(x1, big2, x1, Abf, xn3);                  // x2 (in x1), xn3

  // ===== Phase C: cmix =====
  mixk<<<4096, b256, 0, stream>>>(xn3, tmk, tmr, xkbf, xrbf);
  transp_k<<<dim3(128, 32), tb, 0, stream>>>(key_w, Wt, 1024, 4096, 4096, 0, 4096);
  gemm8_k<2><<<256, b512, 0, stream>>>(xkbf, Wt, Abf, 4096, 4096, 1024, 16);             // kact (bf16, 1 blk/CU)
  transp_k<<<dim3(32, 128), tb, 0, stream>>>(value_w, Wt, 4096, 1024, 1024, 0, 1024);
  gemm4_k<0><<<256, b256, 0, stream>>>(Abf, Wt, big2, 4096, 1024, 4096, 8);              // vout
  transp_k<<<dim3(32, 32), tb, 0, stream>>>(recept_w, Wt, 1024, 1024, 1024, 0, 1024);
  gemm4_k<0><<<256, b256, 0, stream>>>(xrbf, Wt, big1, 4096, 1024, 1024, 8);             // rraw
  finalk<<<4096, b256, 0, stream>>>(x1, big1, big2, out);
}

// Round 12
// 522.823 us; speedup vs baseline: 1.0581x; 1.0191x over previous
//
#include <hip/hip_runtime.h>

// ---------- helpers ----------
__device__ __forceinline__ unsigned short f2bf(float f) {
  unsigned u = __builtin_bit_cast(unsigned, f);
  u = u + 0x7fffu + ((u >> 16) & 1u);      // RNE
  return (unsigned short)(u >> 16);
}
__device__ __forceinline__ float bf2f(unsigned short u) {
  return __builtin_bit_cast(float, ((unsigned)u) << 16);
}

typedef __bf16 bf16x8 __attribute__((ext_vector_type(8)));
typedef float  f32x4  __attribute__((ext_vector_type(4)));
typedef unsigned short u16x8 __attribute__((ext_vector_type(8)));

#define GLD16(gp, lp) __builtin_amdgcn_global_load_lds( \
    (const __attribute__((address_space(1))) unsigned int*)(gp), \
    (__attribute__((address_space(3))) unsigned int*)(lp), 16, 0, 0)

// ---------- rmsnorm (+ optional residual) ----------
template<int HAS_DELTA, int WRITE_SUM, int WRITE_N32>
__global__ __launch_bounds__(256) void resrms_k(const float* __restrict__ xin,
    const float* __restrict__ delta, float* __restrict__ xsum,
    unsigned short* __restrict__ nbf, float* __restrict__ nf32) {
  int row = blockIdx.x, tid = threadIdx.x;
  size_t base = ((size_t)row << 10) + ((size_t)tid << 2);
  float4 v = *(const float4*)(xin + base);
  if (HAS_DELTA) {
    float4 d = *(const float4*)(delta + base);
    v.x += d.x; v.y += d.y; v.z += d.z; v.w += d.w;
  }
  if (WRITE_SUM) *(float4*)(xsum + base) = v;
  float ss = v.x*v.x + v.y*v.y + v.z*v.z + v.w*v.w;
  #pragma unroll
  for (int off = 32; off; off >>= 1) ss += __shfl_xor(ss, off);
  __shared__ float ws4[4];
  if ((tid & 63) == 0) ws4[tid >> 6] = ss;
  __syncthreads();
  float tot = ws4[0] + ws4[1] + ws4[2] + ws4[3];
  float sc = rsqrtf(tot * (1.0f / 1024.0f) + 1e-5f);
  *(ushort4*)(nbf + base) = make_ushort4(f2bf(v.x*sc), f2bf(v.y*sc), f2bf(v.z*sc), f2bf(v.w*sc));
  if (WRITE_N32) {
    float4 n; n.x = v.x*sc; n.y = v.y*sc; n.z = v.z*sc; n.w = v.w*sc;
    *(float4*)(nf32 + base) = n;
  }
}

// ---------- transpose+convert: W[K][ldw] f32 -> Wt[Npad][K] bf16 ----------
__device__ __forceinline__ void transp_body(const float* __restrict__ W,
    unsigned short* __restrict__ Wt, int K, int Ncols, int col_off, int ldw,
    int bx, int by, int tx, int ty) {
  __shared__ float t[32][33];
  int n0 = bx << 5, k0 = by << 5;
  #pragma unroll
  for (int rr = 0; rr < 32; rr += 8) {
    int k = k0 + rr + ty, n = n0 + tx;
    t[rr + ty][tx] = (n < Ncols) ? W[(size_t)k * ldw + col_off + n] : 0.f;
  }
  __syncthreads();
  #pragma unroll
  for (int rr = 0; rr < 32; rr += 8) {
    int nrow = n0 + rr + ty;
    Wt[(size_t)nrow * K + k0 + tx] = f2bf(t[tx][rr + ty]);
  }
}

__global__ void transp_k(const float* __restrict__ W, unsigned short* __restrict__ Wt,
                         int K, int Ncols, int Npad, int col_off, int ldw) {
  transp_body(W, Wt, K, Ncols, col_off, ldw, blockIdx.x, blockIdx.y, threadIdx.x, threadIdx.y);
}

// batched transpose: up to 3 jobs in one launch (flat 1D grid, tb=(32,8))
__global__ void transpN_k(
    const float* W0, unsigned short* T0, int K0, int N0c, int ld0, int nbx0, int nb0,
    const float* W1, unsigned short* T1, int K1, int N1c, int ld1, int nbx1, int nb1,
    const float* W2, unsigned short* T2, int K2, int N2c, int ld2, int nbx2) {
  int bid = blockIdx.x;
  if (bid < nb0) {
    transp_body(W0, T0, K0, N0c, 0, ld0, bid % nbx0, bid / nbx0, threadIdx.x, threadIdx.y);
  } else if (bid < nb0 + nb1) {
    int lb = bid - nb0;
    transp_body(W1, T1, K1, N1c, 0, ld1, lb % nbx1, lb / nbx1, threadIdx.x, threadIdx.y);
  } else {
    int lb = bid - nb0 - nb1;
    transp_body(W2, T2, K2, N2c, 0, ld2, lb % nbx2, lb / nbx2, threadIdx.x, threadIdx.y);
  }
}

// ---------- 8-phase 256x256 bf16 MFMA GEMM (used for kact only) ----------
template<int EPI>   // 0=f32, 1=bf16, 2=erf->bf16
__global__ __launch_bounds__(512, 2) void gemm8_k(const unsigned short* __restrict__ A,
    const unsigned short* __restrict__ Bt, void* __restrict__ Cout,
    int M, int N, int K, int ntx) {
  __shared__ unsigned short lds[2 * 32768];   // 128 KiB
  const int tid = threadIdx.x;
  const int w = tid >> 6, lane = tid & 63;
  const int fr = lane & 15, g = lane >> 4;
  const int wmi = w >> 2, wni = w & 3;
  const int nwg = gridDim.x;
  const int nty = nwg / ntx;
  const int l = (blockIdx.x & 7) * (nwg >> 3) + (blockIdx.x >> 3);
  const int S = ((ntx & 3) == 0) ? 4 : (((ntx & 1) == 0) ? 2 : 1);
  const int sw = S * nty;
  const int s_ = l / sw, r_ = l - s_ * sw;
  const int bx = s_ * S + (r_ % S);
  const int by = r_ / S;
  const int m0 = by << 8, n0 = bx << 8;

  f32x4 acc[8][4];
  #pragma unroll
  for (int i = 0; i < 8; ++i)
    #pragma unroll
    for (int j = 0; j < 4; ++j) acc[i][j] = (f32x4){0.f, 0.f, 0.f, 0.f};

  const int r0 = tid >> 3, pc = tid & 7;
  const int lc = pc ^ (r0 & 7);
  const unsigned short* Abase = A + (size_t)(m0 + r0) * K + (lc << 3);
  const unsigned short* Bbase = Bt + (size_t)(n0 + r0) * K + (lc << 3);
  const size_t aK64 = (size_t)64 * K, aK128 = (size_t)128 * K;

#define STG_A(h_, kt_, bb_) { \
    const unsigned short* s0_ = Abase + (size_t)(h_) * aK128 + ((size_t)(kt_) << 6); \
    unsigned short* d0_ = lds + (bb_) * 32768 + (h_) * 8192 + (w << 9); \
    GLD16(s0_, d0_); GLD16(s0_ + aK64, d0_ + 4096); }
#define STG_B(h_, kt_, bb_) { \
    const unsigned short* s0_ = Bbase + (size_t)(h_) * aK128 + ((size_t)(kt_) << 6); \
    unsigned short* d0_ = lds + (bb_) * 32768 + 16384 + (h_) * 8192 + (w << 9); \
    GLD16(s0_, d0_); GLD16(s0_ + aK64, d0_ + 4096); }

  bf16x8 Areg[4][2], Breg[4][2];
#define LDA(mh_, bb_) { \
    _Pragma("unroll") for (int mf = 0; mf < 4; ++mf) \
    _Pragma("unroll") for (int kk = 0; kk < 2; ++kk) { \
      int r = ((mh_) << 6) + (mf << 4) + fr; \
      Areg[mf][kk] = *(const bf16x8*)&lds[(bb_) * 32768 + wmi * 8192 + (r << 6) + ((((kk << 2) + g) ^ (r & 7)) << 3)]; } }
#define LDB(nh_, bb_) { \
    _Pragma("unroll") for (int nf2 = 0; nf2 < 2; ++nf2) \
    _Pragma("unroll") for (int kk = 0; kk < 2; ++kk) { \
      int nf = ((nh_) << 1) + nf2; \
      int r = ((wni & 1) << 6) + (nf << 4) + fr; \
      Breg[nf][kk] = *(const bf16x8*)&lds[(bb_) * 32768 + 16384 + (wni >> 1) * 8192 + (r << 6) + ((((kk << 2) + g) ^ (r & 7)) << 3)]; } }
#define MM(mh_, nh_) { \
    __builtin_amdgcn_s_setprio(1); \
    _Pragma("unroll") for (int mf = 0; mf < 4; ++mf) \
    _Pragma("unroll") for (int nf2 = 0; nf2 < 2; ++nf2) \
    _Pragma("unroll") for (int kk = 0; kk < 2; ++kk) \
      acc[((mh_) << 2) + mf][((nh_) << 1) + nf2] = __builtin_amdgcn_mfma_f32_16x16x32_bf16( \
          Areg[mf][kk], Breg[((nh_) << 1) + nf2][kk], acc[((mh_) << 2) + mf][((nh_) << 1) + nf2], 0, 0, 0); \
    __builtin_amdgcn_s_setprio(0); }
#define BAR_LG \
    __builtin_amdgcn_s_barrier(); \
    asm volatile("s_waitcnt lgkmcnt(0)" ::: "memory"); \
    __builtin_amdgcn_sched_barrier(0);
#define ENDBAR \
    __builtin_amdgcn_s_barrier(); \
    __builtin_amdgcn_sched_barrier(0);

  STG_B(0, 0, 0) STG_B(1, 0, 0) STG_A(0, 0, 0) STG_A(1, 0, 0) STG_B(0, 1, 1) STG_B(1, 1, 1)
  asm volatile("s_waitcnt vmcnt(4)" ::: "memory");
  __builtin_amdgcn_s_barrier();
  __builtin_amdgcn_sched_barrier(0);

  const int NITER = K >> 7;
  for (int it = 0; it < NITER; ++it) {
    const int t = it << 1;
    const bool lastI = (it == NITER - 1);
    LDA(0, 0) LDB(0, 0)
    STG_A(0, t + 1, 1)
    BAR_LG MM(0, 0) ENDBAR
    LDB(1, 0)
    STG_A(1, t + 1, 1)
    BAR_LG MM(0, 1) ENDBAR
    LDA(1, 0)
    if (!lastI) STG_B(0, t + 2, 0)
    BAR_LG MM(1, 0) ENDBAR
    if (!lastI) STG_B(1, t + 2, 0)
    BAR_LG MM(1, 1)
    if (!lastI) { asm volatile("s_waitcnt vmcnt(4)" ::: "memory"); }
    else        { asm volatile("s_waitcnt vmcnt(0)" ::: "memory"); }
    ENDBAR
    LDA(0, 1) LDB(0, 1)
    if (!lastI) STG_A(0, t + 2, 0)
    BAR_LG MM(0, 0) ENDBAR
    LDB(1, 1)
    if (!lastI) STG_A(1, t + 2, 0)
    BAR_LG MM(0, 1) ENDBAR
    LDA(1, 1)
    if (!lastI) STG_B(0, t + 3, 1)
    BAR_LG MM(1, 0) ENDBAR
    if (!lastI) STG_B(1, t + 3, 1)
    BAR_LG MM(1, 1)
    if (!lastI) { asm volatile("s_waitcnt vmcnt(4)" ::: "memory"); }
    else        { asm volatile("s_waitcnt vmcnt(0)" ::: "memory"); }
    ENDBAR
  }
#undef STG_A
#undef STG_B
#undef LDA
#undef LDB
#undef MM
#undef BAR_LG
#undef ENDBAR

  asm volatile("s_waitcnt vmcnt(0)" ::: "memory");
  __syncthreads();
  float (*eps)[260] = (float(*)[260])lds;
  const int er = tid >> 3, ec0 = (tid & 7) << 5;
  #pragma unroll
  for (int slab = 0; slab < 4; ++slab) {
    if (wmi == (slab >> 1)) {
      const int mhs = slab & 1;
      #pragma unroll
      for (int mf = 0; mf < 4; ++mf)
        #pragma unroll
        for (int nf = 0; nf < 4; ++nf)
          #pragma unroll
          for (int rr = 0; rr < 4; ++rr)
            eps[(mf << 4) + (g << 2) + rr][(wni << 6) + (nf << 4) + fr] = acc[(mhs << 2) + mf][nf][rr];
    }
    __syncthreads();
    const int grow = m0 + (slab << 6) + er;
    if (EPI == 0) {
      float* orow = (float*)Cout + (size_t)grow * N + n0 + ec0;
      #pragma unroll
      for (int u = 0; u < 8; ++u) {
        int col = n0 + ec0 + (u << 2);
        if (col < N) {
          float4 v; v.x = eps[er][ec0 + (u << 2)]; v.y = eps[er][ec0 + (u << 2) + 1];
          v.z = eps[er][ec0 + (u << 2) + 2]; v.w = eps[er][ec0 + (u << 2) + 3];
          *(float4*)(orow + (u << 2)) = v;
        }
      }
    } else {
      unsigned short* orow = (unsigned short*)Cout + (size_t)grow * N + n0 + ec0;
      #pragma unroll
      for (int u = 0; u < 4; ++u) {
        int col = n0 + ec0 + (u << 3);
        if (col < N) {
          u16x8 pk;
          #pragma unroll
          for (int e = 0; e < 8; ++e) {
            float v = eps[er][ec0 + (u << 3) + e];
            if (EPI == 2) v = 0.5f * (1.0f + erff((v - 0.70710678f) * 2.5066283f));
            pk[e] = f2bf(v);
          }
          *(u16x8*)(orow + (u << 3)) = pk;
        }
      }
    }
    __syncthreads();
  }
}

// ---------- bf16 MFMA GEMM (m97-class, 3 blk/CU) ----------
// EPI: 0 = f32 store, 1 = bf16 store, 2 = erf-activation -> bf16 store
template<int EPI>
__global__ __launch_bounds__(256, 3) void gemm4_k(const unsigned short* __restrict__ A,
    const unsigned short* __restrict__ Bt, void* __restrict__ Cout,
    int M, int N, int K, int ntx) {
  __shared__ char smem[49152];
  unsigned short* lds = (unsigned short*)smem;
  const int tid = threadIdx.x;
  const int w = tid >> 6, lane = tid & 63;
  const int fr = lane & 15, g = lane >> 4;
  const int nwg = gridDim.x;
  const int nty = nwg / ntx;
  const int l = (blockIdx.x & 7) * (nwg >> 3) + (blockIdx.x >> 3);
  const int S = ((ntx & 3) == 0) ? 4 : (((ntx & 1) == 0) ? 2 : 1);
  const int sw = S * nty;
  const int s = l / sw, r_ = l - s * sw;
  const int bx = s * S + (r_ % S);
  const int by = r_ / S;
  const int m0 = by << 7, n0 = bx << 7;
  const int wm = (w >> 1) << 6, wn = (w & 1) << 6;

  f32x4 acc[4][4];
  #pragma unroll
  for (int i = 0; i < 4; ++i)
    #pragma unroll
    for (int j = 0; j < 4; ++j) acc[i][j] = (f32x4){0.f, 0.f, 0.f, 0.f};

  const int r0s = tid >> 2, pc0 = tid & 3;
  const int lc0 = pc0 ^ ((r0s >> 1) & 3);
  const int r1s = r0s + 64;
  const int lc1 = pc0 ^ ((r1s >> 1) & 3);
  const unsigned short* a0 = A + (size_t)(m0 + r0s) * K + (lc0 << 3);
  const unsigned short* a1 = A + (size_t)(m0 + r1s) * K + (lc1 << 3);
  const unsigned short* b0 = Bt + (size_t)(n0 + r0s) * K + (lc0 << 3);
  const unsigned short* b1 = Bt + (size_t)(n0 + r1s) * K + (lc1 << 3);
  const int wofs = w << 9;

#define STAGE4(kt_, bb_) { \
    unsigned short* d_ = lds + (bb_) * 8192 + wofs; \
    GLD16(a0 + ((kt_) << 5), d_); \
    GLD16(a1 + ((kt_) << 5), d_ + 2048); \
    GLD16(b0 + ((kt_) << 5), d_ + 4096); \
    GLD16(b1 + ((kt_) << 5), d_ + 6144); }

  const int NT = K >> 5;
  STAGE4(0, 0)
  STAGE4(1, 1)
  asm volatile("s_waitcnt vmcnt(4)" ::: "memory");
  __builtin_amdgcn_s_barrier();
  __builtin_amdgcn_sched_barrier(0);

  int cb = 0;
  for (int t = 0; t < NT; ++t) {
    const unsigned short* bufp = lds + cb * 8192;
    int sb = cb + 2; if (sb >= 3) sb -= 3;
    const int have2 = (t + 2 < NT);
    if (have2) STAGE4(t + 2, sb)
    bf16x8 af[4], bv[4];
    #pragma unroll
    for (int i = 0; i < 4; ++i) {
      int r = wm + (i << 4) + fr;
      af[i] = *(const bf16x8*)&bufp[(r << 5) + (((g ^ (r >> 1)) & 3) << 3)];
    }
    #pragma unroll
    for (int j = 0; j < 4; ++j) {
      int r = wn + (j << 4) + fr;
      bv[j] = *(const bf16x8*)&bufp[4096 + (r << 5) + (((g ^ (r >> 1)) & 3) << 3)];
    }
    __builtin_amdgcn_s_setprio(1);
    #pragma unroll
    for (int i = 0; i < 4; ++i)
      #pragma unroll
      for (int j = 0; j < 4; ++j)
        acc[i][j] = __builtin_amdgcn_mfma_f32_16x16x32_bf16(af[i], bv[j], acc[i][j], 0, 0, 0);
    __builtin_amdgcn_s_setprio(0);
    if (t + 1 < NT) {
      if (have2) { asm volatile("s_waitcnt vmcnt(4)" ::: "memory"); }
      else       { asm volatile("s_waitcnt vmcnt(0)" ::: "memory"); }
      __builtin_amdgcn_s_barrier();
      __builtin_amdgcn_sched_barrier(0);
    }
    cb = cb + 1; if (cb >= 3) cb -= 3;
  }
#undef STAGE4

  float (*eps)[132] = (float(*)[132])smem;
  const int rin = g << 2;
  const int er = tid >> 2, ec0 = (tid & 3) << 5;
  #pragma unroll
  for (int rh = 0; rh < 2; ++rh) {
    __syncthreads();
    if ((wm >> 6) == rh) {
      #pragma unroll
      for (int i = 0; i < 4; ++i)
        #pragma unroll
        for (int j = 0; j < 4; ++j)
          #pragma unroll
          for (int rr = 0; rr < 4; ++rr)
            eps[(i << 4) + rin + rr][wn + (j << 4) + fr] = acc[i][j][rr];
    }
    __syncthreads();
    int grow = m0 + (rh << 6) + er;
    if (EPI == 0) {
      float* orow = (float*)Cout + (size_t)grow * N + n0 + ec0;
      #pragma unroll
      for (int u = 0; u < 8; ++u) {
        int col = n0 + ec0 + (u << 2);
        if (col < N) {
          float4 v; v.x = eps[er][ec0 + (u<<2)]; v.y = eps[er][ec0 + (u<<2) + 1];
          v.z = eps[er][ec0 + (u<<2) + 2]; v.w = eps[er][ec0 + (u<<2) + 3];
          *(float4*)(orow + (u << 2)) = v;
        }
      }
    } else {
      unsigned short* orow = (unsigned short*)Cout + (size_t)grow * N + n0 + ec0;
      #pragma unroll
      for (int u = 0; u < 4; ++u) {
        int col = n0 + ec0 + (u << 3);
        if (col < N) {
          u16x8 pk;
          #pragma unroll
          for (int e = 0; e < 8; ++e) {
            float v = eps[er][ec0 + (u << 3) + e];
            if (EPI == 2) v = 0.5f * (1.0f + erff((v - 0.70710678f) * 2.5066283f));
            pk[e] = f2bf(v);
          }
          *(u16x8*)(orow + (u << 3)) = pk;
        }
      }
    }
  }
}

// ---------- causal depthwise conv(4) + silu, float4 channels, fused dt/softplus ----------
__global__ __launch_bounds__(256) void convk(const float* __restrict__ zxr,
    const float* __restrict__ conv_w, const float* __restrict__ conv_b,
    const float* __restrict__ dt_bias, float* __restrict__ xbc,
    float* __restrict__ dtb) {
  int idx = blockIdx.x * 256 + threadIdx.x;   // 4*1024*544
  if (idx >= 4 * 1024 * 544) return;
  int c4 = idx % 544; int bt = idx / 544; int t = bt & 1023;
  int c = c4 << 2;
  const float* col = zxr + (size_t)bt * 2208 + c;
  float4 zz = make_float4(0.f, 0.f, 0.f, 0.f);
  float4 x0 = *(const float4*)col;
  float4 x1 = (t >= 1) ? *(const float4*)(col - 2208) : zz;
  float4 x2 = (t >= 2) ? *(const float4*)(col - 4416) : zz;
  float4 x3 = (t >= 3) ? *(const float4*)(col - 6624) : zz;
  const float4* wp = (const float4*)(conv_w + (c << 2));
  float4 wa = wp[0], wb = wp[1], wc_ = wp[2], wd = wp[3];   // taps for channels c..c+3
  float4 bb = *(const float4*)(conv_b + c);
  float4 a;
  a.x = bb.x; a.x = fmaf(x3.x, wa.x, a.x); a.x = fmaf(x2.x, wa.y, a.x); a.x = fmaf(x1.x, wa.z, a.x); a.x = fmaf(x0.x, wa.w, a.x);
  a.y = bb.y; a.y = fmaf(x3.y, wb.x, a.y); a.y = fmaf(x2.y, wb.y, a.y); a.y = fmaf(x1.y, wb.z, a.y); a.y = fmaf(x0.y, wb.w, a.y);
  a.z = bb.z; a.z = fmaf(x3.z, wc_.x, a.z); a.z = fmaf(x2.z, wc_.y, a.z); a.z = fmaf(x1.z, wc_.z, a.z); a.z = fmaf(x0.z, wc_.w, a.z);
  a.w = bb.w; a.w = fmaf(x3.w, wd.x, a.w); a.w = fmaf(x2.w, wd.y, a.w); a.w = fmaf(x1.w, wd.z, a.w); a.w = fmaf(x0.w, wd.w, a.w);
  float4 o;
  o.x = a.x / (1.f + __expf(-a.x));
  o.y = a.y / (1.f + __expf(-a.y));
  o.z = a.z / (1.f + __expf(-a.z));
  o.w = a.w / (1.f + __expf(-a.w));
  *(float4*)(xbc + (size_t)bt * 2176 + c) = o;
  if (c < 32) {
    float4 dv = *(const float4*)(zxr + (size_t)bt * 2208 + 2176 + c);
    float4 db = *(const float4*)(dt_bias + c);
    float4 r;
    float v;
    v = dv.x + db.x; r.x = (v > 20.f) ? v : log1pf(__expf(v));
    v = dv.y + db.y; r.y = (v > 20.f) ? v : log1pf(__expf(v));
    v = dv.z + db.z; r.z = (v > 20.f) ? v : log1pf(__expf(v));
    v = dv.w + db.w; r.w = (v > 20.f) ? v : log1pf(__expf(v));
    *(float4*)(dtb + bt * 32 + c) = r;
  }
}

// ---------- SSD chunked scan, stage 1 ----------
__global__ __launch_bounds__(256) void ssd1_k(const float* __restrict__ xbc,
    const float* __restrict__ dtb, const float* __restrict__ A_log,
    float* __restrict__ ydin, float* __restrict__ dhbuf, float* __restrict__ labuf) {
  __shared__ unsigned short Cs[64][68];
  __shared__ unsigned short Bsm[64][68];
  __shared__ unsigned short XT[64][68];
  __shared__ unsigned short BT[64][68];
  __shared__ unsigned short Ms[64][68];
  __shared__ float laS[64], dtS[64];
  const int id = blockIdx.x;
  const int h = id & 31, b = (id >> 5) & 3, c = id >> 7;
  const int tid = threadIdx.x, w = tid >> 6, lane = tid & 63;
  const int fr = lane & 15, g = lane >> 4;
  const size_t rowbase = (size_t)((b << 10) + (c << 6));

  {
    int r = tid >> 2, c0 = (tid & 3) << 4;
    const float* src = xbc + (rowbase + r) * 2176;
    #pragma unroll
    for (int i = 0; i < 4; ++i) {
      float4 v = *(const float4*)(src + 2112 + c0 + 4 * i);
      *(ushort4*)&Cs[r][c0 + 4 * i] = make_ushort4(f2bf(v.x), f2bf(v.y), f2bf(v.z), f2bf(v.w));
      float4 u = *(const float4*)(src + 2048 + c0 + 4 * i);
      *(ushort4*)&Bsm[r][c0 + 4 * i] = make_ushort4(f2bf(u.x), f2bf(u.y), f2bf(u.z), f2bf(u.w));
    }
  }
  {
    int r0 = (tid & 15) << 2, d0 = (tid >> 4) << 2;
    const float* src = xbc + (rowbase + r0) * 2176 + (h << 6) + d0;
    float4 v0 = *(const float4*)(src);
    float4 v1 = *(const float4*)(src + 2176);
    float4 v2 = *(const float4*)(src + 4352);
    float4 v3 = *(const float4*)(src + 6528);
    *(ushort4*)&XT[d0 + 0][r0] = make_ushort4(f2bf(v0.x), f2bf(v1.x), f2bf(v2.x), f2bf(v3.x));
    *(ushort4*)&XT[d0 + 1][r0] = make_ushort4(f2bf(v0.y), f2bf(v1.y), f2bf(v2.y), f2bf(v3.y));
    *(ushort4*)&XT[d0 + 2][r0] = make_ushort4(f2bf(v0.z), f2bf(v1.z), f2bf(v2.z), f2bf(v3.z));
    *(ushort4*)&XT[d0 + 3][r0] = make_ushort4(f2bf(v0.w), f2bf(v1.w), f2bf(v2.w), f2bf(v3.w));
  }
  if (w == 0) {
    float Ah = -__expf(A_log[h]);
    float dtv = dtb[(rowbase + lane) * 32 + h];
    float v = dtv * Ah;
    #pragma unroll
    for (int off = 1; off < 64; off <<= 1) {
      float u = __shfl_up(v, off);
      if (lane >= off) v += u;
    }
    laS[lane] = v; dtS[lane] = dtv;
    labuf[(size_t)((((b << 4) | c) << 5 | h) << 6) + lane] = v;
  }
  __syncthreads();

  const int wr = w >> 1, wc = w & 1;
  f32x4 gf[2][2];
  #pragma unroll
  for (int i = 0; i < 2; ++i)
    #pragma unroll
    for (int j = 0; j < 2; ++j) gf[i][j] = (f32x4){0.f, 0.f, 0.f, 0.f};
  {
    int r0 = (tid & 15) << 2, d0 = (tid >> 4) << 2;
    const float* src = xbc + (rowbase + r0) * 2176 + 2048 + d0;
    float la63 = laS[63];
    float4 v0 = *(const float4*)(src);
    float4 v1 = *(const float4*)(src + 2176);
    float4 v2 = *(const float4*)(src + 4352);
    float4 v3 = *(const float4*)(src + 6528);
    float w0 = __expf(la63 - laS[r0 + 0]) * dtS[r0 + 0];
    float w1 = __expf(la63 - laS[r0 + 1]) * dtS[r0 + 1];
    float w2 = __expf(la63 - laS[r0 + 2]) * dtS[r0 + 2];
    float w3 = __expf(la63 - laS[r0 + 3]) * dtS[r0 + 3];
    *(ushort4*)&BT[d0 + 0][r0] = make_ushort4(f2bf(v0.x*w0), f2bf(v1.x*w1), f2bf(v2.x*w2), f2bf(v3.x*w3));
    *(ushort4*)&BT[d0 + 1][r0] = make_ushort4(f2bf(v0.y*w0), f2bf(v1.y*w1), f2bf(v2.y*w2), f2bf(v3.y*w3));
    *(ushort4*)&BT[d0 + 2][r0] = make_ushort4(f2bf(v0.z*w0), f2bf(v1.z*w1), f2bf(v2.z*w2), f2bf(v3.z*w3));
    *(ushort4*)&BT[d0 + 3][r0] = make_ushort4(f2bf(v0.w*w0), f2bf(v1.w*w1), f2bf(v2.w*w2), f2bf(v3.w*w3));
  }
  #pragma unroll
  for (int ks = 0; ks < 2; ++ks) {
    bf16x8 ca[2], bb[2];
    #pragma unroll
    for (int i = 0; i < 2; ++i) ca[i] = *(const bf16x8*)&Cs[(wr << 5) + (i << 4) + fr][(ks << 5) + (g << 3)];
    #pragma unroll
    for (int j = 0; j < 2; ++j) bb[j] = *(const bf16x8*)&Bsm[(wc << 5) + (j << 4) + fr][(ks << 5) + (g << 3)];
    #pragma unroll
    for (int i = 0; i < 2; ++i)
      #pragma unroll
      for (int j = 0; j < 2; ++j)
        gf[i][j] = __builtin_amdgcn_mfma_f32_16x16x32_bf16(ca[i], bb[j], gf[i][j], 0, 0, 0);
  }
  #pragma unroll
  for (int i = 0; i < 2; ++i) {
    #pragma unroll
    for (int j = 0; j < 2; ++j) {
      int s = (wc << 5) + (j << 4) + fr;
      float la_s = laS[s], dt_s = dtS[s];
      #pragma unroll
      for (int rr = 0; rr < 4; ++rr) {
        int t = (wr << 5) + (i << 4) + (g << 2) + rr;
        float e = __expf(fminf(laS[t] - la_s, 0.f));
        float val = (s <= t) ? gf[i][j][rr] * e * dt_s : 0.f;
        Ms[t][s] = f2bf(val);
      }
    }
  }
  __syncthreads();

  f32x4 yf[2][2], hf[2][2];
  #pragma unroll
  for (int i = 0; i < 2; ++i)
    #pragma unroll
    for (int j = 0; j < 2; ++j) { yf[i][j] = (f32x4){0.f,0.f,0.f,0.f}; hf[i][j] = (f32x4){0.f,0.f,0.f,0.f}; }
  #pragma unroll
  for (int ks = 0; ks < 2; ++ks) {
    bf16x8 ma[2], ba[2], xb[2];
    #pragma unroll
    for (int i = 0; i < 2; ++i) {
      ma[i] = *(const bf16x8*)&Ms[(wr << 5) + (i << 4) + fr][(ks << 5) + (g << 3)];
      ba[i] = *(const bf16x8*)&BT[(wr << 5) + (i << 4) + fr][(ks << 5) + (g << 3)];
    }
    #pragma unroll
    for (int j = 0; j < 2; ++j) xb[j] = *(const bf16x8*)&XT[(wc << 5) + (j << 4) + fr][(ks << 5) + (g << 3)];
    #pragma unroll
    for (int i = 0; i < 2; ++i)
      #pragma unroll
      for (int j = 0; j < 2; ++j) {
        yf[i][j] = __builtin_amdgcn_mfma_f32_16x16x32_bf16(ma[i], xb[j], yf[i][j], 0, 0, 0);
        hf[i][j] = __builtin_amdgcn_mfma_f32_16x16x32_bf16(ba[i], xb[j], hf[i][j], 0, 0, 0);
      }
  }
  float* dhb = dhbuf + ((size_t)(((c << 2) + b) * 32 + h) << 12);
  #pragma unroll
  for (int i = 0; i < 2; ++i) {
    #pragma unroll
    for (int j = 0; j < 2; ++j) {
      int p = (wc << 5) + (j << 4) + fr;
      #pragma unroll
      for (int rr = 0; rr < 4; ++rr) {
        int t = (wr << 5) + (i << 4) + (g << 2) + rr;
        ydin[((rowbase + t) << 11) + (h << 6) + p] = yf[i][j][rr];
        dhb[(t << 6) + p] = hf[i][j][rr];
      }
    }
  }
}

// ---------- SSD stage 2 ----------
__global__ __launch_bounds__(256) void ssd2_k(const float* __restrict__ dhbuf,
    const float* __restrict__ labuf, float* __restrict__ hseq) {
  int idx = blockIdx.x * 256 + threadIdx.x;
  int np = idx & 4095;
  int h = (idx >> 12) & 31, b = idx >> 17;
  float carry = 0.f;
  #pragma unroll
  for (int c = 0; c < 16; ++c) {
    size_t o = ((size_t)(((c << 2) + b) * 32 + h) << 12) + np;
    hseq[o] = carry;
    float ec = __expf(labuf[(size_t)((((b << 4) | c) << 5 | h) << 6) + 63]);
    carry = fmaf(ec, carry, dhbuf[o]);
  }
}

// ---------- SSD stage 3 ----------
__global__ __launch_bounds__(256) void ssd3_k(const float* __restrict__ xbc,
    const float* __restrict__ hseq, const float* __restrict__ labuf,
    const float* __restrict__ Dv, float* __restrict__ ydin) {
  __shared__ unsigned short Cs[64][68];
  __shared__ unsigned short HT[64][68];
  __shared__ float laS[64];
  const int id = blockIdx.x;
  const int h = id & 31, b = (id >> 5) & 3, c = id >> 7;
  const int tid = threadIdx.x, w = tid >> 6, lane = tid & 63;
  const int fr = lane & 15, g = lane >> 4;
  const size_t rowbase = (size_t)((b << 10) + (c << 6));
  {
    int r = tid >> 2, c0 = (tid & 3) << 4;
    const float* src = xbc + (rowbase + r) * 2176 + 2112 + c0;
    #pragma unroll
    for (int i = 0; i < 4; ++i) {
      float4 v = *(const float4*)(src + 4 * i);
      *(ushort4*)&Cs[r][c0 + 4 * i] = make_ushort4(f2bf(v.x), f2bf(v.y), f2bf(v.z), f2bf(v.w));
    }
  }
  {
    const float* hb = hseq + ((size_t)(((c << 2) + b) * 32 + h) << 12);
    int n0 = (tid & 15) << 2, p0 = (tid >> 4) << 2;
    float4 v0 = *(const float4*)(hb + ((n0 + 0) << 6) + p0);
    float4 v1 = *(const float4*)(hb + ((n0 + 1) << 6) + p0);
    float4 v2 = *(const float4*)(hb + ((n0 + 2) << 6) + p0);
    float4 v3 = *(const float4*)(hb + ((n0 + 3) << 6) + p0);
    *(ushort4*)&HT[p0 + 0][n0] = make_ushort4(f2bf(v0.x), f2bf(v1.x), f2bf(v2.x), f2bf(v3.x));
    *(ushort4*)&HT[p0 + 1][n0] = make_ushort4(f2bf(v0.y), f2bf(v1.y), f2bf(v2.y), f2bf(v3.y));
    *(ushort4*)&HT[p0 + 2][n0] = make_ushort4(f2bf(v0.z), f2bf(v1.z), f2bf(v2.z), f2bf(v3.z));
    *(ushort4*)&HT[p0 + 3][n0] = make_ushort4(f2bf(v0.w), f2bf(v1.w), f2bf(v2.w), f2bf(v3.w));
  }
  if (tid < 64) laS[tid] = labuf[(size_t)((((b << 4) | c) << 5 | h) << 6) + tid];
  __syncthreads();
  const int wr = w >> 1, wc = w & 1;
  f32x4 yf[2][2];
  #pragma unroll
  for (int i = 0; i < 2; ++i)
    #pragma unroll
    for (int j = 0; j < 2; ++j) yf[i][j] = (f32x4){0.f, 0.f, 0.f, 0.f};
  #pragma unroll
  for (int ks = 0; ks < 2; ++ks) {
    bf16x8 ca[2], hv[2];
    #pragma unroll
    for (int i = 0; i < 2; ++i) ca[i] = *(const bf16x8*)&Cs[(wr << 5) + (i << 4) + fr][(ks << 5) + (g << 3)];
    #pragma unroll
    for (int j = 0; j < 2; ++j) hv[j] = *(const bf16x8*)&HT[(wc << 5) + (j << 4) + fr][(ks << 5) + (g << 3)];
    #pragma unroll
    for (int i = 0; i < 2; ++i)
      #pragma unroll
      for (int j = 0; j < 2; ++j)
        yf[i][j] = __builtin_amdgcn_mfma_f32_16x16x32_bf16(ca[i], hv[j], yf[i][j], 0, 0, 0);
  }
  float Dh = Dv[h];
  #pragma unroll
  for (int i = 0; i < 2; ++i) {
    #pragma unroll
    for (int j = 0; j < 2; ++j) {
      int p = (wc << 5) + (j << 4) + fr;
      #pragma unroll
      for (int rr = 0; rr < 4; ++rr) {
        int t = (wr << 5) + (i << 4) + (g << 2) + rr;
        size_t yo = ((rowbase + t) << 11) + (h << 6) + p;
        float xv = xbc[(rowbase + t) * 2176 + (h << 6) + p];
        ydin[yo] = ydin[yo] + __expf(laS[t]) * yf[i][j][rr] + Dh * xv;
      }
    }
  }
}

// ---------- g = ydin * silu(z); rmsnorm(2048) * mnorm_w -> bf16 ----------
__global__ __launch_bounds__(256) void gnormk(const float* __restrict__ ydin,
    const unsigned short* __restrict__ zbf, const float* __restrict__ mw,
    unsigned short* __restrict__ gbf) {
  int row = blockIdx.x, tid = threadIdx.x;
  size_t base = ((size_t)row << 11) + ((size_t)tid << 3);
  float4 y0 = *(const float4*)(ydin + base);
  float4 y1 = *(const float4*)(ydin + base + 4);
  ushort4 z0 = *(const ushort4*)(zbf + base);
  ushort4 z1 = *(const ushort4*)(zbf + base + 4);
  float g[8];
  {
    float z;
    z = bf2f(z0.x); g[0] = y0.x * (z / (1.f + __expf(-z)));
    z = bf2f(z0.y); g[1] = y0.y * (z / (1.f + __expf(-z)));
    z = bf2f(z0.z); g[2] = y0.z * (z / (1.f + __expf(-z)));
    z = bf2f(z0.w); g[3] = y0.w * (z / (1.f + __expf(-z)));
    z = bf2f(z1.x); g[4] = y1.x * (z / (1.f + __expf(-z)));
    z = bf2f(z1.y); g[5] = y1.y * (z / (1.f + __expf(-z)));
    z = bf2f(z1.z); g[6] = y1.z * (z / (1.f + __expf(-z)));
    z = bf2f(z1.w); g[7] = y1.w * (z / (1.f + __expf(-z)));
  }
  float ss = 0.f;
  #pragma unroll
  for (int k = 0; k < 8; ++k) ss += g[k] * g[k];
  #pragma unroll
  for (int off = 32; off; off >>= 1) ss += __shfl_xor(ss, off);
  __shared__ float ws4[4];
  if ((tid & 63) == 0) ws4[tid >> 6] = ss;
  __syncthreads();
  float tot = ws4[0] + ws4[1] + ws4[2] + ws4[3];
  float sc = rsqrtf(tot * (1.f / 2048.f) + 1e-5f);
  int c0 = tid << 3;
  float4 m0 = *(const float4*)(mw + c0);
  float4 m1 = *(const float4*)(mw + c0 + 4);
  *(ushort4*)(gbf + base)     = make_ushort4(f2bf(g[0]*sc*m0.x), f2bf(g[1]*sc*m0.y), f2bf(g[2]*sc*m0.z), f2bf(g[3]*sc*m0.w));
  *(ushort4*)(gbf + base + 4) = make_ushort4(f2bf(g[4]*sc*m1.x), f2bf(g[5]*sc*m1.y), f2bf(g[6]*sc*m1.z), f2bf(g[7]*sc*m1.w));
}

// ---------- MQA causal attention (MFMA flash), bf16 in/out ----------
__global__ __launch_bounds__(256) void attnk(const unsigned short* __restrict__ qkv,
                                             unsigned short* __restrict__ ybf) {
  __shared__ unsigned short Qs[64][72];
  __shared__ unsigned short Ks[64][72];
  __shared__ unsigned short VT[64][72];
  __shared__ unsigned short Ps[4][16][72];
  const int id = blockIdx.x;
  const int b = id & 3, h = (id >> 2) & 15, qt = id >> 6;
  const int t0 = qt << 6;
  const int tid = threadIdx.x, w = tid >> 6, lane = tid & 63;
  const int fr = lane & 15, g = lane >> 4;
  {
    int r = tid >> 2, d0 = (tid & 3) << 4;
    const unsigned short* src = qkv + ((size_t)((b << 10) | (t0 + r))) * 1152 + (h << 6) + d0;
    *(uint4*)&Qs[r][d0]     = *(const uint4*)(src);
    *(uint4*)&Qs[r][d0 + 8] = *(const uint4*)(src + 8);
  }
  __syncthreads();
  bf16x8 afQ0 = *(const bf16x8*)&Qs[(w << 4) + fr][g << 3];
  bf16x8 afQ1 = *(const bf16x8*)&Qs[(w << 4) + fr][32 + (g << 3)];
  f32x4 acc_o[4];
  #pragma unroll
  for (int i = 0; i < 4; ++i) acc_o[i] = (f32x4){0.f, 0.f, 0.f, 0.f};
  float m[4] = {-1e30f, -1e30f, -1e30f, -1e30f};
  float l[4] = {0.f, 0.f, 0.f, 0.f};
  const int qrow = t0 + (w << 4) + (g << 2);
  for (int kt = 0; kt <= qt; ++kt) {
    const int s0 = kt << 6;
    __syncthreads();
    {
      int r = tid >> 2, d0 = (tid & 3) << 4;
      const unsigned short* src = qkv + ((size_t)((b << 10) | (s0 + r))) * 1152 + 1024 + d0;
      *(uint4*)&Ks[r][d0]     = *(const uint4*)(src);
      *(uint4*)&Ks[r][d0 + 8] = *(const uint4*)(src + 8);
    }
    {
      int r0 = (tid & 15) << 2, d0 = (tid >> 4) << 2;
      const unsigned short* src = qkv + ((size_t)((b << 10) | (s0 + r0))) * 1152 + 1088 + d0;
      ushort4 v0 = *(const ushort4*)(src);
      ushort4 v1 = *(const ushort4*)(src + 1152);
      ushort4 v2 = *(const ushort4*)(src + 2304);
      ushort4 v3 = *(const ushort4*)(src + 3456);
      *(ushort4*)&VT[d0 + 0][r0] = make_ushort4(v0.x, v1.x, v2.x, v3.x);
      *(ushort4*)&VT[d0 + 1][r0] = make_ushort4(v0.y, v1.y, v2.y, v3.y);
      *(ushort4*)&VT[d0 + 2][r0] = make_ushort4(v0.z, v1.z, v2.z, v3.z);
      *(ushort4*)&VT[d0 + 3][r0] = make_ushort4(v0.w, v1.w, v2.w, v3.w);
    }
    __syncthreads();
    f32x4 s4[4];
    #pragma unroll
    for (int jt = 0; jt < 4; ++jt) {
      bf16x8 b0 = *(const bf16x8*)&Ks[(jt << 4) + fr][g << 3];
      bf16x8 b1 = *(const bf16x8*)&Ks[(jt << 4) + fr][32 + (g << 3)];
      f32x4 z4 = (f32x4){0.f, 0.f, 0.f, 0.f};
      z4 = __builtin_amdgcn_mfma_f32_16x16x32_bf16(afQ0, b0, z4, 0, 0, 0);
      z4 = __builtin_amdgcn_mfma_f32_16x16x32_bf16(afQ1, b1, z4, 0, 0, 0);
      s4[jt] = z4 * 0.125f;
    }
    if (kt == qt) {
      #pragma unroll
      for (int jt = 0; jt < 4; ++jt) {
        int key = s0 + (jt << 4) + fr;
        #pragma unroll
        for (int r = 0; r < 4; ++r)
          if (key > qrow + r) s4[jt][r] = -1e30f;
      }
    }
    #pragma unroll
    for (int r = 0; r < 4; ++r) {
      float mt = fmaxf(fmaxf(s4[0][r], s4[1][r]), fmaxf(s4[2][r], s4[3][r]));
      #pragma unroll
      for (int off = 8; off; off >>= 1) mt = fmaxf(mt, __shfl_xor(mt, off));
      float mn = fmaxf(m[r], mt);
      float scl = __expf(m[r] - mn);
      m[r] = mn;
      float ps = 0.f;
      #pragma unroll
      for (int jt = 0; jt < 4; ++jt) {
        float p = __expf(s4[jt][r] - mn);
        ps += p;
        Ps[w][(g << 2) + r][(jt << 4) + fr] = f2bf(p);
      }
      #pragma unroll
      for (int off = 8; off; off >>= 1) ps += __shfl_xor(ps, off);
      l[r] = l[r] * scl + ps;
      acc_o[0][r] *= scl; acc_o[1][r] *= scl; acc_o[2][r] *= scl; acc_o[3][r] *= scl;
    }
    #pragma unroll
    for (int ks = 0; ks < 2; ++ks) {
      bf16x8 ap = *(const bf16x8*)&Ps[w][fr][(ks << 5) + (g << 3)];
      #pragma unroll
      for (int dt = 0; dt < 4; ++dt) {
        bf16x8 bv = *(const bf16x8*)&VT[(dt << 4) + fr][(ks << 5) + (g << 3)];
        acc_o[dt] = __builtin_amdgcn_mfma_f32_16x16x32_bf16(ap, bv, acc_o[dt], 0, 0, 0);
      }
    }
  }
  #pragma unroll
  for (int dt = 0; dt < 4; ++dt) {
    #pragma unroll
    for (int r = 0; r < 4; ++r) {
      float o = acc_o[dt][r] / l[r];
      int t = t0 + (w << 4) + (g << 2) + r;
      ybf[(((size_t)((b << 10) | t)) << 10) + (h << 6) + (dt << 4) + fr] = f2bf(o);
    }
  }
}

// ---------- cmix token-shift mix -> xk, xr (bf16) ----------
__global__ __launch_bounds__(256) void mixk(const float* __restrict__ xn3,
    const float* __restrict__ tmk, const float* __restrict__ tmr,
    unsigned short* __restrict__ xkbf, unsigned short* __restrict__ xrbf) {
  int idx4 = blockIdx.x * 256 + threadIdx.x;
  int col = (idx4 & 255) << 2;
  int row = idx4 >> 8;
  int t = row & 1023;
  size_t off = ((size_t)idx4) << 2;
  float4 cur = *(const float4*)(xn3 + off);
  float4 prev = make_float4(0.f, 0.f, 0.f, 0.f);
  if (t > 0) prev = *(const float4*)(xn3 + off - 1024);
  float4 tk = *(const float4*)(tmk + col);
  float4 tr = *(const float4*)(tmr + col);
  float dx = prev.x - cur.x, dy = prev.y - cur.y, dz = prev.z - cur.z, dw = prev.w - cur.w;
  *(ushort4*)(xkbf + off) = make_ushort4(
      f2bf(cur.x + dx * tk.x), f2bf(cur.y + dy * tk.y), f2bf(cur.z + dz * tk.z), f2bf(cur.w + dw * tk.w));
  *(ushort4*)(xrbf + off) = make_ushort4(
      f2bf(cur.x + dx * tr.x), f2bf(cur.y + dy * tr.y), f2bf(cur.z + dz * tr.z), f2bf(cur.w + dw * tr.w));
}

// ---------- final: out = x2 + sigmoid(rraw) * vout ----------
__global__ __launch_bounds__(256) void finalk(const float* __restrict__ x2,
    const float* __restrict__ rraw, const float* __restrict__ vout,
    float* __restrict__ out) {
  int idx4 = blockIdx.x * 256 + threadIdx.x;
  size_t off = ((size_t)idx4) << 2;
  float4 xv = *(const float4*)(x2 + off);
  float4 rv = *(const float4*)(rraw + off);
  float4 vv = *(const float4*)(vout + off);
  float4 o;
  o.x = xv.x + vv.x / (1.f + __expf(-rv.x));
  o.y = xv.y + vv.y / (1.f + __expf(-rv.y));
  o.z = xv.z + vv.z / (1.f + __expf(-rv.z));
  o.w = xv.w + vv.w / (1.f + __expf(-rv.w));
  *(float4*)(out + off) = o;
}

// ---------- host launcher ----------
extern "C" void kernel_launch(void* const* d_in, const int* in_sizes, int n_in,
                              void* d_out, int out_size, void* d_ws, size_t ws_size,
                              hipStream_t stream) {
  (void)in_sizes; (void)n_in; (void)out_size;
  const float* x        = (const float*)d_in[0];
  const float* in_proj  = (const float*)d_in[1];
  const float* conv_w   = (const float*)d_in[2];
  const float* conv_b   = (const float*)d_in[3];
  const float* dt_bias  = (const float*)d_in[4];
  const float* A_log    = (const float*)d_in[5];
  const float* Dvec     = (const float*)d_in[6];
  const float* mnorm_w  = (const float*)d_in[7];
  const float* out_proj = (const float*)d_in[8];
  const float* attn_w   = (const float*)d_in[9];
  const float* proj_w   = (const float*)d_in[10];
  const float* tmk      = (const float*)d_in[11];
  const float* tmr      = (const float*)d_in[12];
  const float* key_w    = (const float*)d_in[13];
  const float* recept_w = (const float*)d_in[14];
  const float* value_w  = (const float*)d_in[15];
  float* out = (float*)d_out;

  if (ws_size < 199229440ull) return;

  char* ws = (char*)d_ws;
  unsigned short* Wt   = (unsigned short*)(ws + 0);              // 8.9 MB
  unsigned short* Abf  = (unsigned short*)(ws + 8912896ull);
  unsigned short* Abf2 = (unsigned short*)(ws + 42467328ull);
  float* bigF = (float*)(ws + 59244544ull);
  float* big1 = (float*)(ws + 95420416ull);
  float* big2 = (float*)(ws + 131072000ull);
  float* x1   = (float*)(ws + 164626432ull);
  float* xn3  = (float*)(ws + 181403648ull);
  float* dtb  = (float*)(ws + 198180864ull);
  float* labuf= (float*)(ws + 198705152ull);
  unsigned short* zbf  = Abf2;
  unsigned short* xkbf = Abf2;
  unsigned short* xrbf = Abf2 + 4194304;
  float* dhbuf = bigF;
  float* hseq  = (float*)Abf;
  unsigned short* qkvbf = (unsigned short*)big1;
  // phase C transposed weights: key^T -> Wt; value^T -> big1[0..8.4MB]; recept^T -> big1 @20MB
  unsigned short* valT = (unsigned short*)big1;
  unsigned short* recT = (unsigned short*)big1 + 10485760;   // byte offset 20,971,520 (> rraw's 16.8MB)

  dim3 b256(256);
  dim3 b512(512);
  dim3 tb(32, 8);

  // ===== Phase A: mamba2 =====
  resrms_k<0, 0, 0><<<4096, b256, 0, stream>>>(x, nullptr, nullptr, Abf, nullptr);
  transp_k<<<dim3(136, 32), tb, 0, stream>>>(in_proj, Wt, 1024, 4256, 4352, 0, 4256);    // full in_proj^T
  gemm4_k<1><<<512, b256, 0, stream>>>(Abf, Wt, zbf, 4096, 2048, 1024, 16);              // z (rows 0..2047)
  gemm4_k<0><<<576, b256, 0, stream>>>(Abf, Wt + 2097152, bigF, 4096, 2208, 1024, 18);   // xBC+dt (rows 2048..)
  convk<<<8704, b256, 0, stream>>>(bigF, conv_w, conv_b, dt_bias, big1, dtb);            // xbc_act + dt (f4)
  ssd1_k<<<2048, b256, 0, stream>>>(big1, dtb, A_log, big2, dhbuf, labuf);               // Y_intra, dh, la
  ssd2_k<<<2048, b256, 0, stream>>>(dhbuf, labuf, hseq);                                 // chunk states
  ssd3_k<<<2048, b256, 0, stream>>>(big1, hseq, labuf, Dvec, big2);                      // ydin final
  gnormk<<<4096, b256, 0, stream>>>(big2, zbf, mnorm_w, Abf);                            // g (bf16)
  transp_k<<<dim3(32, 64), tb, 0, stream>>>(out_proj, Wt, 2048, 1024, 1024, 0, 1024);
  gemm4_k<0><<<256, b256, 0, stream>>>(Abf, Wt, big1, 4096, 1024, 2048, 8);              // mo
  resrms_k<1, 1, 0><<<4096, b256, 0, stream>>>(x, big1, x1, Abf, nullptr);               // x1, xn2

  // ===== Phase B: mqa =====
  transpN_k<<<2176, tb, 0, stream>>>(                                                     // attn^T + proj^T
      attn_w, Wt, 1024, 1152, 1152, 36, 1152,
      proj_w, Wt + 1179648, 1024, 1024, 1024, 32, 1024,
      proj_w, Wt + 1179648, 1024, 1024, 1024, 32);
  gemm4_k<1><<<288, b256, 0, stream>>>(Abf, Wt, qkvbf, 4096, 1152, 1024, 9);             // qkv (bf16)
  attnk<<<1024, b256, 0, stream>>>(qkvbf, Abf);                                          // atty (bf16)
  gemm4_k<0><<<256, b256, 0, stream>>>(Abf, Wt + 1179648, big2, 4096, 1024, 1024, 8);    // po
  resrms_k<1, 1, 1><<<4096, b256, 0, stream>>>(x1, big2, x1, Abf, xn3);                  // x2 (in x1), xn3

  // ===== Phase C: cmix =====
  mixk<<<4096, b256, 0, stream>>>(xn3, tmk, tmr, xkbf, xrbf);
  transpN_k<<<9216, tb, 0, stream>>>(                                                     // key^T, value^T, recept^T
      key_w, Wt, 1024, 4096, 4096, 128, 4096,
      value_w, valT, 4096, 1024, 1024, 32, 4096,
      recept_w, recT, 1024, 1024, 1024, 32);
  gemm8_k<2><<<256, b512, 0, stream>>>(xkbf, Wt, Abf, 4096, 4096, 1024, 16);             // kact (bf16, 1 blk/CU)
  gemm4_k<0><<<256, b256, 0, stream>>>(Abf, valT, big2, 4096, 1024, 4096, 8);            // vout
  gemm4_k<0><<<256, b256, 0, stream>>>(xrbf, recT, big1, 4096, 1024, 1024, 8);           // rraw
  finalk<<<4096, b256, 0, stream>>>(x1, big1, big2, out);
}

// Round 13
// 500.804 us; speedup vs baseline: 1.1046x; 1.0440x over previous
//
#include <hip/hip_runtime.h>

// ---------- helpers ----------
__device__ __forceinline__ unsigned short f2bf(float f) {
  unsigned u = __builtin_bit_cast(unsigned, f);
  u = u + 0x7fffu + ((u >> 16) & 1u);      // RNE
  return (unsigned short)(u >> 16);
}
__device__ __forceinline__ float bf2f(unsigned short u) {
  return __builtin_bit_cast(float, ((unsigned)u) << 16);
}

typedef __bf16 bf16x8 __attribute__((ext_vector_type(8)));
typedef float  f32x4  __attribute__((ext_vector_type(4)));
typedef unsigned short u16x8 __attribute__((ext_vector_type(8)));

#define GLD16(gp, lp) __builtin_amdgcn_global_load_lds( \
    (const __attribute__((address_space(1))) unsigned int*)(gp), \
    (__attribute__((address_space(3))) unsigned int*)(lp), 16, 0, 0)

// ---------- rmsnorm (+ optional bf16 residual delta) ----------
template<int HAS_DELTA, int WRITE_SUM, int WRITE_N32>
__global__ __launch_bounds__(256) void resrms_k(const float* __restrict__ xin,
    const unsigned short* __restrict__ delta, float* __restrict__ xsum,
    unsigned short* __restrict__ nbf, float* __restrict__ nf32) {
  int row = blockIdx.x, tid = threadIdx.x;
  size_t base = ((size_t)row << 10) + ((size_t)tid << 2);
  float4 v = *(const float4*)(xin + base);
  if (HAS_DELTA) {
    ushort4 d = *(const ushort4*)(delta + base);
    v.x += bf2f(d.x); v.y += bf2f(d.y); v.z += bf2f(d.z); v.w += bf2f(d.w);
  }
  if (WRITE_SUM) *(float4*)(xsum + base) = v;
  float ss = v.x*v.x + v.y*v.y + v.z*v.z + v.w*v.w;
  #pragma unroll
  for (int off = 32; off; off >>= 1) ss += __shfl_xor(ss, off);
  __shared__ float ws4[4];
  if ((tid & 63) == 0) ws4[tid >> 6] = ss;
  __syncthreads();
  float tot = ws4[0] + ws4[1] + ws4[2] + ws4[3];
  float sc = rsqrtf(tot * (1.0f / 1024.0f) + 1e-5f);
  *(ushort4*)(nbf + base) = make_ushort4(f2bf(v.x*sc), f2bf(v.y*sc), f2bf(v.z*sc), f2bf(v.w*sc));
  if (WRITE_N32) {
    float4 n; n.x = v.x*sc; n.y = v.y*sc; n.z = v.z*sc; n.w = v.w*sc;
    *(float4*)(nf32 + base) = n;
  }
}

// ---------- transpose+convert: W[K][ldw] f32 -> Wt[Npad][K] bf16 ----------
__device__ __forceinline__ void transp_body(const float* __restrict__ W,
    unsigned short* __restrict__ Wt, int K, int Ncols, int col_off, int ldw,
    int bx, int by, int tx, int ty) {
  __shared__ float t[32][33];
  int n0 = bx << 5, k0 = by << 5;
  #pragma unroll
  for (int rr = 0; rr < 32; rr += 8) {
    int k = k0 + rr + ty, n = n0 + tx;
    t[rr + ty][tx] = (n < Ncols) ? W[(size_t)k * ldw + col_off + n] : 0.f;
  }
  __syncthreads();
  #pragma unroll
  for (int rr = 0; rr < 32; rr += 8) {
    int nrow = n0 + rr + ty;
    Wt[(size_t)nrow * K + k0 + tx] = f2bf(t[tx][rr + ty]);
  }
}

__global__ void transp_k(const float* __restrict__ W, unsigned short* __restrict__ Wt,
                         int K, int Ncols, int Npad, int col_off, int ldw) {
  transp_body(W, Wt, K, Ncols, col_off, ldw, blockIdx.x, blockIdx.y, threadIdx.x, threadIdx.y);
}

// batched transpose: up to 3 jobs in one launch (flat 1D grid, tb=(32,8))
__global__ void transpN_k(
    const float* W0, unsigned short* T0, int K0, int N0c, int ld0, int nbx0, int nb0,
    const float* W1, unsigned short* T1, int K1, int N1c, int ld1, int nbx1, int nb1,
    const float* W2, unsigned short* T2, int K2, int N2c, int ld2, int nbx2) {
  int bid = blockIdx.x;
  if (bid < nb0) {
    transp_body(W0, T0, K0, N0c, 0, ld0, bid % nbx0, bid / nbx0, threadIdx.x, threadIdx.y);
  } else if (bid < nb0 + nb1) {
    int lb = bid - nb0;
    transp_body(W1, T1, K1, N1c, 0, ld1, lb % nbx1, lb / nbx1, threadIdx.x, threadIdx.y);
  } else {
    int lb = bid - nb0 - nb1;
    transp_body(W2, T2, K2, N2c, 0, ld2, lb % nbx2, lb / nbx2, threadIdx.x, threadIdx.y);
  }
}

// ---------- 8-phase 256x256 bf16 MFMA GEMM (used for kact only) ----------
template<int EPI>   // 0=f32, 1=bf16, 2=erf->bf16
__global__ __launch_bounds__(512, 2) void gemm8_k(const unsigned short* __restrict__ A,
    const unsigned short* __restrict__ Bt, void* __restrict__ Cout,
    int M, int N, int K, int ntx) {
  __shared__ unsigned short lds[2 * 32768];   // 128 KiB
  const int tid = threadIdx.x;
  const int w = tid >> 6, lane = tid & 63;
  const int fr = lane & 15, g = lane >> 4;
  const int wmi = w >> 2, wni = w & 3;
  const int nwg = gridDim.x;
  const int nty = nwg / ntx;
  const int l = (blockIdx.x & 7) * (nwg >> 3) + (blockIdx.x >> 3);
  const int S = ((ntx & 3) == 0) ? 4 : (((ntx & 1) == 0) ? 2 : 1);
  const int sw = S * nty;
  const int s_ = l / sw, r_ = l - s_ * sw;
  const int bx = s_ * S + (r_ % S);
  const int by = r_ / S;
  const int m0 = by << 8, n0 = bx << 8;

  f32x4 acc[8][4];
  #pragma unroll
  for (int i = 0; i < 8; ++i)
    #pragma unroll
    for (int j = 0; j < 4; ++j) acc[i][j] = (f32x4){0.f, 0.f, 0.f, 0.f};

  const int r0 = tid >> 3, pc = tid & 7;
  const int lc = pc ^ (r0 & 7);
  const unsigned short* Abase = A + (size_t)(m0 + r0) * K + (lc << 3);
  const unsigned short* Bbase = Bt + (size_t)(n0 + r0) * K + (lc << 3);
  const size_t aK64 = (size_t)64 * K, aK128 = (size_t)128 * K;

#define STG_A(h_, kt_, bb_) { \
    const unsigned short* s0_ = Abase + (size_t)(h_) * aK128 + ((size_t)(kt_) << 6); \
    unsigned short* d0_ = lds + (bb_) * 32768 + (h_) * 8192 + (w << 9); \
    GLD16(s0_, d0_); GLD16(s0_ + aK64, d0_ + 4096); }
#define STG_B(h_, kt_, bb_) { \
    const unsigned short* s0_ = Bbase + (size_t)(h_) * aK128 + ((size_t)(kt_) << 6); \
    unsigned short* d0_ = lds + (bb_) * 32768 + 16384 + (h_) * 8192 + (w << 9); \
    GLD16(s0_, d0_); GLD16(s0_ + aK64, d0_ + 4096); }

  bf16x8 Areg[4][2], Breg[4][2];
#define LDA(mh_, bb_) { \
    _Pragma("unroll") for (int mf = 0; mf < 4; ++mf) \
    _Pragma("unroll") for (int kk = 0; kk < 2; ++kk) { \
      int r = ((mh_) << 6) + (mf << 4) + fr; \
      Areg[mf][kk] = *(const bf16x8*)&lds[(bb_) * 32768 + wmi * 8192 + (r << 6) + ((((kk << 2) + g) ^ (r & 7)) << 3)]; } }
#define LDB(nh_, bb_) { \
    _Pragma("unroll") for (int nf2 = 0; nf2 < 2; ++nf2) \
    _Pragma("unroll") for (int kk = 0; kk < 2; ++kk) { \
      int nf = ((nh_) << 1) + nf2; \
      int r = ((wni & 1) << 6) + (nf << 4) + fr; \
      Breg[nf][kk] = *(const bf16x8*)&lds[(bb_) * 32768 + 16384 + (wni >> 1) * 8192 + (r << 6) + ((((kk << 2) + g) ^ (r & 7)) << 3)]; } }
#define MM(mh_, nh_) { \
    __builtin_amdgcn_s_setprio(1); \
    _Pragma("unroll") for (int mf = 0; mf < 4; ++mf) \
    _Pragma("unroll") for (int nf2 = 0; nf2 < 2; ++nf2) \
    _Pragma("unroll") for (int kk = 0; kk < 2; ++kk) \
      acc[((mh_) << 2) + mf][((nh_) << 1) + nf2] = __builtin_amdgcn_mfma_f32_16x16x32_bf16( \
          Areg[mf][kk], Breg[((nh_) << 1) + nf2][kk], acc[((mh_) << 2) + mf][((nh_) << 1) + nf2], 0, 0, 0); \
    __builtin_amdgcn_s_setprio(0); }
#define BAR_LG \
    __builtin_amdgcn_s_barrier(); \
    asm volatile("s_waitcnt lgkmcnt(0)" ::: "memory"); \
    __builtin_amdgcn_sched_barrier(0);
#define ENDBAR \
    __builtin_amdgcn_s_barrier(); \
    __builtin_amdgcn_sched_barrier(0);

  STG_B(0, 0, 0) STG_B(1, 0, 0) STG_A(0, 0, 0) STG_A(1, 0, 0) STG_B(0, 1, 1) STG_B(1, 1, 1)
  asm volatile("s_waitcnt vmcnt(4)" ::: "memory");
  __builtin_amdgcn_s_barrier();
  __builtin_amdgcn_sched_barrier(0);

  const int NITER = K >> 7;
  for (int it = 0; it < NITER; ++it) {
    const int t = it << 1;
    const bool lastI = (it == NITER - 1);
    LDA(0, 0) LDB(0, 0)
    STG_A(0, t + 1, 1)
    BAR_LG MM(0, 0) ENDBAR
    LDB(1, 0)
    STG_A(1, t + 1, 1)
    BAR_LG MM(0, 1) ENDBAR
    LDA(1, 0)
    if (!lastI) STG_B(0, t + 2, 0)
    BAR_LG MM(1, 0) ENDBAR
    if (!lastI) STG_B(1, t + 2, 0)
    BAR_LG MM(1, 1)
    if (!lastI) { asm volatile("s_waitcnt vmcnt(4)" ::: "memory"); }
    else        { asm volatile("s_waitcnt vmcnt(0)" ::: "memory"); }
    ENDBAR
    LDA(0, 1) LDB(0, 1)
    if (!lastI) STG_A(0, t + 2, 0)
    BAR_LG MM(0, 0) ENDBAR
    LDB(1, 1)
    if (!lastI) STG_A(1, t + 2, 0)
    BAR_LG MM(0, 1) ENDBAR
    LDA(1, 1)
    if (!lastI) STG_B(0, t + 3, 1)
    BAR_LG MM(1, 0) ENDBAR
    if (!lastI) STG_B(1, t + 3, 1)
    BAR_LG MM(1, 1)
    if (!lastI) { asm volatile("s_waitcnt vmcnt(4)" ::: "memory"); }
    else        { asm volatile("s_waitcnt vmcnt(0)" ::: "memory"); }
    ENDBAR
  }
#undef STG_A
#undef STG_B
#undef LDA
#undef LDB
#undef MM
#undef BAR_LG
#undef ENDBAR

  asm volatile("s_waitcnt vmcnt(0)" ::: "memory");
  __syncthreads();
  float (*eps)[260] = (float(*)[260])lds;
  const int er = tid >> 3, ec0 = (tid & 7) << 5;
  #pragma unroll
  for (int slab = 0; slab < 4; ++slab) {
    if (wmi == (slab >> 1)) {
      const int mhs = slab & 1;
      #pragma unroll
      for (int mf = 0; mf < 4; ++mf)
        #pragma unroll
        for (int nf = 0; nf < 4; ++nf)
          #pragma unroll
          for (int rr = 0; rr < 4; ++rr)
            eps[(mf << 4) + (g << 2) + rr][(wni << 6) + (nf << 4) + fr] = acc[(mhs << 2) + mf][nf][rr];
    }
    __syncthreads();
    const int grow = m0 + (slab << 6) + er;
    if (EPI == 0) {
      float* orow = (float*)Cout + (size_t)grow * N + n0 + ec0;
      #pragma unroll
      for (int u = 0; u < 8; ++u) {
        int col = n0 + ec0 + (u << 2);
        if (col < N) {
          float4 v; v.x = eps[er][ec0 + (u << 2)]; v.y = eps[er][ec0 + (u << 2) + 1];
          v.z = eps[er][ec0 + (u << 2) + 2]; v.w = eps[er][ec0 + (u << 2) + 3];
          *(float4*)(orow + (u << 2)) = v;
        }
      }
    } else {
      unsigned short* orow = (unsigned short*)Cout + (size_t)grow * N + n0 + ec0;
      #pragma unroll
      for (int u = 0; u < 4; ++u) {
        int col = n0 + ec0 + (u << 3);
        if (col < N) {
          u16x8 pk;
          #pragma unroll
          for (int e = 0; e < 8; ++e) {
            float v = eps[er][ec0 + (u << 3) + e];
            if (EPI == 2) v = 0.5f * (1.0f + erff((v - 0.70710678f) * 2.5066283f));
            pk[e] = f2bf(v);
          }
          *(u16x8*)(orow + (u << 3)) = pk;
        }
      }
    }
    __syncthreads();
  }
}

// ---------- bf16 MFMA GEMM (m97-class, 3 blk/CU) ----------
// EPI: 0 = f32 store, 1 = bf16 store
template<int EPI>
__global__ __launch_bounds__(256, 3) void gemm4_k(const unsigned short* __restrict__ A,
    const unsigned short* __restrict__ Bt, void* __restrict__ Cout,
    int M, int N, int K, int ntx) {
  __shared__ char smem[49152];
  unsigned short* lds = (unsigned short*)smem;
  const int tid = threadIdx.x;
  const int w = tid >> 6, lane = tid & 63;
  const int fr = lane & 15, g = lane >> 4;
  const int nwg = gridDim.x;
  const int nty = nwg / ntx;
  const int l = (blockIdx.x & 7) * (nwg >> 3) + (blockIdx.x >> 3);
  const int S = ((ntx & 3) == 0) ? 4 : (((ntx & 1) == 0) ? 2 : 1);
  const int sw = S * nty;
  const int s = l / sw, r_ = l - s * sw;
  const int bx = s * S + (r_ % S);
  const int by = r_ / S;
  const int m0 = by << 7, n0 = bx << 7;
  const int wm = (w >> 1) << 6, wn = (w & 1) << 6;

  f32x4 acc[4][4];
  #pragma unroll
  for (int i = 0; i < 4; ++i)
    #pragma unroll
    for (int j = 0; j < 4; ++j) acc[i][j] = (f32x4){0.f, 0.f, 0.f, 0.f};

  const int r0s = tid >> 2, pc0 = tid & 3;
  const int lc0 = pc0 ^ ((r0s >> 1) & 3);
  const int r1s = r0s + 64;
  const int lc1 = pc0 ^ ((r1s >> 1) & 3);
  const unsigned short* a0 = A + (size_t)(m0 + r0s) * K + (lc0 << 3);
  const unsigned short* a1 = A + (size_t)(m0 + r1s) * K + (lc1 << 3);
  const unsigned short* b0 = Bt + (size_t)(n0 + r0s) * K + (lc0 << 3);
  const unsigned short* b1 = Bt + (size_t)(n0 + r1s) * K + (lc1 << 3);
  const int wofs = w << 9;

#define STAGE4(kt_, bb_) { \
    unsigned short* d_ = lds + (bb_) * 8192 + wofs; \
    GLD16(a0 + ((kt_) << 5), d_); \
    GLD16(a1 + ((kt_) << 5), d_ + 2048); \
    GLD16(b0 + ((kt_) << 5), d_ + 4096); \
    GLD16(b1 + ((kt_) << 5), d_ + 6144); }

  const int NT = K >> 5;
  STAGE4(0, 0)
  STAGE4(1, 1)
  asm volatile("s_waitcnt vmcnt(4)" ::: "memory");
  __builtin_amdgcn_s_barrier();
  __builtin_amdgcn_sched_barrier(0);

  int cb = 0;
  for (int t = 0; t < NT; ++t) {
    const unsigned short* bufp = lds + cb * 8192;
    int sb = cb + 2; if (sb >= 3) sb -= 3;
    const int have2 = (t + 2 < NT);
    if (have2) STAGE4(t + 2, sb)
    bf16x8 af[4], bv[4];
    #pragma unroll
    for (int i = 0; i < 4; ++i) {
      int r = wm + (i << 4) + fr;
      af[i] = *(const bf16x8*)&bufp[(r << 5) + (((g ^ (r >> 1)) & 3) << 3)];
    }
    #pragma unroll
    for (int j = 0; j < 4; ++j) {
      int r = wn + (j << 4) + fr;
      bv[j] = *(const bf16x8*)&bufp[4096 + (r << 5) + (((g ^ (r >> 1)) & 3) << 3)];
    }
    __builtin_amdgcn_s_setprio(1);
    #pragma unroll
    for (int i = 0; i < 4; ++i)
      #pragma unroll
      for (int j = 0; j < 4; ++j)
        acc[i][j] = __builtin_amdgcn_mfma_f32_16x16x32_bf16(af[i], bv[j], acc[i][j], 0, 0, 0);
    __builtin_amdgcn_s_setprio(0);
    if (t + 1 < NT) {
      if (have2) { asm volatile("s_waitcnt vmcnt(4)" ::: "memory"); }
      else       { asm volatile("s_waitcnt vmcnt(0)" ::: "memory"); }
      __builtin_amdgcn_s_barrier();
      __builtin_amdgcn_sched_barrier(0);
    }
    cb = cb + 1; if (cb >= 3) cb -= 3;
  }
#undef STAGE4

  float (*eps)[132] = (float(*)[132])smem;
  const int rin = g << 2;
  const int er = tid >> 2, ec0 = (tid & 3) << 5;
  #pragma unroll
  for (int rh = 0; rh < 2; ++rh) {
    __syncthreads();
    if ((wm >> 6) == rh) {
      #pragma unroll
      for (int i = 0; i < 4; ++i)
        #pragma unroll
        for (int j = 0; j < 4; ++j)
          #pragma unroll
          for (int rr = 0; rr < 4; ++rr)
            eps[(i << 4) + rin + rr][wn + (j << 4) + fr] = acc[i][j][rr];
    }
    __syncthreads();
    int grow = m0 + (rh << 6) + er;
    if (EPI == 0) {
      float* orow = (float*)Cout + (size_t)grow * N + n0 + ec0;
      #pragma unroll
      for (int u = 0; u < 8; ++u) {
        int col = n0 + ec0 + (u << 2);
        if (col < N) {
          float4 v; v.x = eps[er][ec0 + (u<<2)]; v.y = eps[er][ec0 + (u<<2) + 1];
          v.z = eps[er][ec0 + (u<<2) + 2]; v.w = eps[er][ec0 + (u<<2) + 3];
          *(float4*)(orow + (u << 2)) = v;
        }
      }
    } else {
      unsigned short* orow = (unsigned short*)Cout + (size_t)grow * N + n0 + ec0;
      #pragma unroll
      for (int u = 0; u < 4; ++u) {
        int col = n0 + ec0 + (u << 3);
        if (col < N) {
          u16x8 pk;
          #pragma unroll
          for (int e = 0; e < 8; ++e) pk[e] = f2bf(eps[er][ec0 + (u << 3) + e]);
          *(u16x8*)(orow + (u << 3)) = pk;
        }
      }
    }
  }
}

// ---------- causal depthwise conv(4) + silu, float4 channels, fused dt/softplus ----------
__global__ __launch_bounds__(256) void convk(const float* __restrict__ zxr,
    const float* __restrict__ conv_w, const float* __restrict__ conv_b,
    const float* __restrict__ dt_bias, float* __restrict__ xbc,
    float* __restrict__ dtb) {
  int idx = blockIdx.x * 256 + threadIdx.x;   // 4*1024*544
  if (idx >= 4 * 1024 * 544) return;
  int c4 = idx % 544; int bt = idx / 544; int t = bt & 1023;
  int c = c4 << 2;
  const float* col = zxr + (size_t)bt * 2208 + c;
  float4 zz = make_float4(0.f, 0.f, 0.f, 0.f);
  float4 x0 = *(const float4*)col;
  float4 x1 = (t >= 1) ? *(const float4*)(col - 2208) : zz;
  float4 x2 = (t >= 2) ? *(const float4*)(col - 4416) : zz;
  float4 x3 = (t >= 3) ? *(const float4*)(col - 6624) : zz;
  const float4* wp = (const float4*)(conv_w + (c << 2));
  float4 wa = wp[0], wb = wp[1], wc_ = wp[2], wd = wp[3];
  float4 bb = *(const float4*)(conv_b + c);
  float4 a;
  a.x = bb.x; a.x = fmaf(x3.x, wa.x, a.x); a.x = fmaf(x2.x, wa.y, a.x); a.x = fmaf(x1.x, wa.z, a.x); a.x = fmaf(x0.x, wa.w, a.x);
  a.y = bb.y; a.y = fmaf(x3.y, wb.x, a.y); a.y = fmaf(x2.y, wb.y, a.y); a.y = fmaf(x1.y, wb.z, a.y); a.y = fmaf(x0.y, wb.w, a.y);
  a.z = bb.z; a.z = fmaf(x3.z, wc_.x, a.z); a.z = fmaf(x2.z, wc_.y, a.z); a.z = fmaf(x1.z, wc_.z, a.z); a.z = fmaf(x0.z, wc_.w, a.z);
  a.w = bb.w; a.w = fmaf(x3.w, wd.x, a.w); a.w = fmaf(x2.w, wd.y, a.w); a.w = fmaf(x1.w, wd.z, a.w); a.w = fmaf(x0.w, wd.w, a.w);
  float4 o;
  o.x = a.x / (1.f + __expf(-a.x));
  o.y = a.y / (1.f + __expf(-a.y));
  o.z = a.z / (1.f + __expf(-a.z));
  o.w = a.w / (1.f + __expf(-a.w));
  *(float4*)(xbc + (size_t)bt * 2176 + c) = o;
  if (c < 32) {
    float4 dv = *(const float4*)(zxr + (size_t)bt * 2208 + 2176 + c);
    float4 db = *(const float4*)(dt_bias + c);
    float4 r;
    float v;
    v = dv.x + db.x; r.x = (v > 20.f) ? v : log1pf(__expf(v));
    v = dv.y + db.y; r.y = (v > 20.f) ? v : log1pf(__expf(v));
    v = dv.z + db.z; r.z = (v > 20.f) ? v : log1pf(__expf(v));
    v = dv.w + db.w; r.w = (v > 20.f) ? v : log1pf(__expf(v));
    *(float4*)(dtb + bt * 32 + c) = r;
  }
}

// ---------- SSD chunked scan, stage 1 ----------
__global__ __launch_bounds__(256) void ssd1_k(const float* __restrict__ xbc,
    const float* __restrict__ dtb, const float* __restrict__ A_log,
    float* __restrict__ ydin, float* __restrict__ dhbuf, float* __restrict__ labuf) {
  __shared__ unsigned short Cs[64][68];
  __shared__ unsigned short Bsm[64][68];
  __shared__ unsigned short XT[64][68];
  __shared__ unsigned short BT[64][68];
  __shared__ unsigned short Ms[64][68];
  __shared__ float laS[64], dtS[64];
  const int id = blockIdx.x;
  const int h = id & 31, b = (id >> 5) & 3, c = id >> 7;
  const int tid = threadIdx.x, w = tid >> 6, lane = tid & 63;
  const int fr = lane & 15, g = lane >> 4;
  const size_t rowbase = (size_t)((b << 10) + (c << 6));

  {
    int r = tid >> 2, c0 = (tid & 3) << 4;
    const float* src = xbc + (rowbase + r) * 2176;
    #pragma unroll
    for (int i = 0; i < 4; ++i) {
      float4 v = *(const float4*)(src + 2112 + c0 + 4 * i);
      *(ushort4*)&Cs[r][c0 + 4 * i] = make_ushort4(f2bf(v.x), f2bf(v.y), f2bf(v.z), f2bf(v.w));
      float4 u = *(const float4*)(src + 2048 + c0 + 4 * i);
      *(ushort4*)&Bsm[r][c0 + 4 * i] = make_ushort4(f2bf(u.x), f2bf(u.y), f2bf(u.z), f2bf(u.w));
    }
  }
  {
    int r0 = (tid & 15) << 2, d0 = (tid >> 4) << 2;
    const float* src = xbc + (rowbase + r0) * 2176 + (h << 6) + d0;
    float4 v0 = *(const float4*)(src);
    float4 v1 = *(const float4*)(src + 2176);
    float4 v2 = *(const float4*)(src + 4352);
    float4 v3 = *(const float4*)(src + 6528);
    *(ushort4*)&XT[d0 + 0][r0] = make_ushort4(f2bf(v0.x), f2bf(v1.x), f2bf(v2.x), f2bf(v3.x));
    *(ushort4*)&XT[d0 + 1][r0] = make_ushort4(f2bf(v0.y), f2bf(v1.y), f2bf(v2.y), f2bf(v3.y));
    *(ushort4*)&XT[d0 + 2][r0] = make_ushort4(f2bf(v0.z), f2bf(v1.z), f2bf(v2.z), f2bf(v3.z));
    *(ushort4*)&XT[d0 + 3][r0] = make_ushort4(f2bf(v0.w), f2bf(v1.w), f2bf(v2.w), f2bf(v3.w));
  }
  if (w == 0) {
    float Ah = -__expf(A_log[h]);
    float dtv = dtb[(rowbase + lane) * 32 + h];
    float v = dtv * Ah;
    #pragma unroll
    for (int off = 1; off < 64; off <<= 1) {
      float u = __shfl_up(v, off);
      if (lane >= off) v += u;
    }
    laS[lane] = v; dtS[lane] = dtv;
    labuf[(size_t)((((b << 4) | c) << 5 | h) << 6) + lane] = v;
  }
  __syncthreads();

  const int wr = w >> 1, wc = w & 1;
  f32x4 gf[2][2];
  #pragma unroll
  for (int i = 0; i < 2; ++i)
    #pragma unroll
    for (int j = 0; j < 2; ++j) gf[i][j] = (f32x4){0.f, 0.f, 0.f, 0.f};
  {
    int r0 = (tid & 15) << 2, d0 = (tid >> 4) << 2;
    const float* src = xbc + (rowbase + r0) * 2176 + 2048 + d0;
    float la63 = laS[63];
    float4 v0 = *(const float4*)(src);
    float4 v1 = *(const float4*)(src + 2176);
    float4 v2 = *(const float4*)(src + 4352);
    float4 v3 = *(const float4*)(src + 6528);
    float w0 = __expf(la63 - laS[r0 + 0]) * dtS[r0 + 0];
    float w1 = __expf(la63 - laS[r0 + 1]) * dtS[r0 + 1];
    float w2 = __expf(la63 - laS[r0 + 2]) * dtS[r0 + 2];
    float w3 = __expf(la63 - laS[r0 + 3]) * dtS[r0 + 3];
    *(ushort4*)&BT[d0 + 0][r0] = make_ushort4(f2bf(v0.x*w0), f2bf(v1.x*w1), f2bf(v2.x*w2), f2bf(v3.x*w3));
    *(ushort4*)&BT[d0 + 1][r0] = make_ushort4(f2bf(v0.y*w0), f2bf(v1.y*w1), f2bf(v2.y*w2), f2bf(v3.y*w3));
    *(ushort4*)&BT[d0 + 2][r0] = make_ushort4(f2bf(v0.z*w0), f2bf(v1.z*w1), f2bf(v2.z*w2), f2bf(v3.z*w3));
    *(ushort4*)&BT[d0 + 3][r0] = make_ushort4(f2bf(v0.w*w0), f2bf(v1.w*w1), f2bf(v2.w*w2), f2bf(v3.w*w3));
  }
  #pragma unroll
  for (int ks = 0; ks < 2; ++ks) {
    bf16x8 ca[2], bb[2];
    #pragma unroll
    for (int i = 0; i < 2; ++i) ca[i] = *(const bf16x8*)&Cs[(wr << 5) + (i << 4) + fr][(ks << 5) + (g << 3)];
    #pragma unroll
    for (int j = 0; j < 2; ++j) bb[j] = *(const bf16x8*)&Bsm[(wc << 5) + (j << 4) + fr][(ks << 5) + (g << 3)];
    #pragma unroll
    for (int i = 0; i < 2; ++i)
      #pragma unroll
      for (int j = 0; j < 2; ++j)
        gf[i][j] = __builtin_amdgcn_mfma_f32_16x16x32_bf16(ca[i], bb[j], gf[i][j], 0, 0, 0);
  }
  #pragma unroll
  for (int i = 0; i < 2; ++i) {
    #pragma unroll
    for (int j = 0; j < 2; ++j) {
      int s = (wc << 5) + (j << 4) + fr;
      float la_s = laS[s], dt_s = dtS[s];
      #pragma unroll
      for (int rr = 0; rr < 4; ++rr) {
        int t = (wr << 5) + (i << 4) + (g << 2) + rr;
        float e = __expf(fminf(laS[t] - la_s, 0.f));
        float val = (s <= t) ? gf[i][j][rr] * e * dt_s : 0.f;
        Ms[t][s] = f2bf(val);
      }
    }
  }
  __syncthreads();

  f32x4 yf[2][2], hf[2][2];
  #pragma unroll
  for (int i = 0; i < 2; ++i)
    #pragma unroll
    for (int j = 0; j < 2; ++j) { yf[i][j] = (f32x4){0.f,0.f,0.f,0.f}; hf[i][j] = (f32x4){0.f,0.f,0.f,0.f}; }
  #pragma unroll
  for (int ks = 0; ks < 2; ++ks) {
    bf16x8 ma[2], ba[2], xb[2];
    #pragma unroll
    for (int i = 0; i < 2; ++i) {
      ma[i] = *(const bf16x8*)&Ms[(wr << 5) + (i << 4) + fr][(ks << 5) + (g << 3)];
      ba[i] = *(const bf16x8*)&BT[(wr << 5) + (i << 4) + fr][(ks << 5) + (g << 3)];
    }
    #pragma unroll
    for (int j = 0; j < 2; ++j) xb[j] = *(const bf16x8*)&XT[(wc << 5) + (j << 4) + fr][(ks << 5) + (g << 3)];
    #pragma unroll
    for (int i = 0; i < 2; ++i)
      #pragma unroll
      for (int j = 0; j < 2; ++j) {
        yf[i][j] = __builtin_amdgcn_mfma_f32_16x16x32_bf16(ma[i], xb[j], yf[i][j], 0, 0, 0);
        hf[i][j] = __builtin_amdgcn_mfma_f32_16x16x32_bf16(ba[i], xb[j], hf[i][j], 0, 0, 0);
      }
  }
  float* dhb = dhbuf + ((size_t)(((c << 2) + b) * 32 + h) << 12);
  #pragma unroll
  for (int i = 0; i < 2; ++i) {
    #pragma unroll
    for (int j = 0; j < 2; ++j) {
      int p = (wc << 5) + (j << 4) + fr;
      #pragma unroll
      for (int rr = 0; rr < 4; ++rr) {
        int t = (wr << 5) + (i << 4) + (g << 2) + rr;
        ydin[((rowbase + t) << 11) + (h << 6) + p] = yf[i][j][rr];
        dhb[(t << 6) + p] = hf[i][j][rr];
      }
    }
  }
}

// ---------- SSD stage 2 ----------
__global__ __launch_bounds__(256) void ssd2_k(const float* __restrict__ dhbuf,
    const float* __restrict__ labuf, float* __restrict__ hseq) {
  int idx = blockIdx.x * 256 + threadIdx.x;
  int np = idx & 4095;
  int h = (idx >> 12) & 31, b = idx >> 17;
  float carry = 0.f;
  #pragma unroll
  for (int c = 0; c < 16; ++c) {
    size_t o = ((size_t)(((c << 2) + b) * 32 + h) << 12) + np;
    hseq[o] = carry;
    float ec = __expf(labuf[(size_t)((((b << 4) | c) << 5 | h) << 6) + 63]);
    carry = fmaf(ec, carry, dhbuf[o]);
  }
}

// ---------- SSD stage 3 ----------
__global__ __launch_bounds__(256) void ssd3_k(const float* __restrict__ xbc,
    const float* __restrict__ hseq, const float* __restrict__ labuf,
    const float* __restrict__ Dv, float* __restrict__ ydin) {
  __shared__ unsigned short Cs[64][68];
  __shared__ unsigned short HT[64][68];
  __shared__ float laS[64];
  const int id = blockIdx.x;
  const int h = id & 31, b = (id >> 5) & 3, c = id >> 7;
  const int tid = threadIdx.x, w = tid >> 6, lane = tid & 63;
  const int fr = lane & 15, g = lane >> 4;
  const size_t rowbase = (size_t)((b << 10) + (c << 6));
  {
    int r = tid >> 2, c0 = (tid & 3) << 4;
    const float* src = xbc + (rowbase + r) * 2176 + 2112 + c0;
    #pragma unroll
    for (int i = 0; i < 4; ++i) {
      float4 v = *(const float4*)(src + 4 * i);
      *(ushort4*)&Cs[r][c0 + 4 * i] = make_ushort4(f2bf(v.x), f2bf(v.y), f2bf(v.z), f2bf(v.w));
    }
  }
  {
    const float* hb = hseq + ((size_t)(((c << 2) + b) * 32 + h) << 12);
    int n0 = (tid & 15) << 2, p0 = (tid >> 4) << 2;
    float4 v0 = *(const float4*)(hb + ((n0 + 0) << 6) + p0);
    float4 v1 = *(const float4*)(hb + ((n0 + 1) << 6) + p0);
    float4 v2 = *(const float4*)(hb + ((n0 + 2) << 6) + p0);
    float4 v3 = *(const float4*)(hb + ((n0 + 3) << 6) + p0);
    *(ushort4*)&HT[p0 + 0][n0] = make_ushort4(f2bf(v0.x), f2bf(v1.x), f2bf(v2.x), f2bf(v3.x));
    *(ushort4*)&HT[p0 + 1][n0] = make_ushort4(f2bf(v0.y), f2bf(v1.y), f2bf(v2.y), f2bf(v3.y));
    *(ushort4*)&HT[p0 + 2][n0] = make_ushort4(f2bf(v0.z), f2bf(v1.z), f2bf(v2.z), f2bf(v3.z));
    *(ushort4*)&HT[p0 + 3][n0] = make_ushort4(f2bf(v0.w), f2bf(v1.w), f2bf(v2.w), f2bf(v3.w));
  }
  if (tid < 64) laS[tid] = labuf[(size_t)((((b << 4) | c) << 5 | h) << 6) + tid];
  __syncthreads();
  const int wr = w >> 1, wc = w & 1;
  f32x4 yf[2][2];
  #pragma unroll
  for (int i = 0; i < 2; ++i)
    #pragma unroll
    for (int j = 0; j < 2; ++j) yf[i][j] = (f32x4){0.f, 0.f, 0.f, 0.f};
  #pragma unroll
  for (int ks = 0; ks < 2; ++ks) {
    bf16x8 ca[2], hv[2];
    #pragma unroll
    for (int i = 0; i < 2; ++i) ca[i] = *(const bf16x8*)&Cs[(wr << 5) + (i << 4) + fr][(ks << 5) + (g << 3)];
    #pragma unroll
    for (int j = 0; j < 2; ++j) hv[j] = *(const bf16x8*)&HT[(wc << 5) + (j << 4) + fr][(ks << 5) + (g << 3)];
    #pragma unroll
    for (int i = 0; i < 2; ++i)
      #pragma unroll
      for (int j = 0; j < 2; ++j)
        yf[i][j] = __builtin_amdgcn_mfma_f32_16x16x32_bf16(ca[i], hv[j], yf[i][j], 0, 0, 0);
  }
  float Dh = Dv[h];
  #pragma unroll
  for (int i = 0; i < 2; ++i) {
    #pragma unroll
    for (int j = 0; j < 2; ++j) {
      int p = (wc << 5) + (j << 4) + fr;
      #pragma unroll
      for (int rr = 0; rr < 4; ++rr) {
        int t = (wr << 5) + (i << 4) + (g << 2) + rr;
        size_t yo = ((rowbase + t) << 11) + (h << 6) + p;
        float xv = xbc[(rowbase + t) * 2176 + (h << 6) + p];
        ydin[yo] = ydin[yo] + __expf(laS[t]) * yf[i][j][rr] + Dh * xv;
      }
    }
  }
}

// ---------- g = ydin * silu(z); rmsnorm(2048) * mnorm_w -> bf16 ----------
__global__ __launch_bounds__(256) void gnormk(const float* __restrict__ ydin,
    const unsigned short* __restrict__ zbf, const float* __restrict__ mw,
    unsigned short* __restrict__ gbf) {
  int row = blockIdx.x, tid = threadIdx.x;
  size_t base = ((size_t)row << 11) + ((size_t)tid << 3);
  float4 y0 = *(const float4*)(ydin + base);
  float4 y1 = *(const float4*)(ydin + base + 4);
  ushort4 z0 = *(const ushort4*)(zbf + base);
  ushort4 z1 = *(const ushort4*)(zbf + base + 4);
  float g[8];
  {
    float z;
    z = bf2f(z0.x); g[0] = y0.x * (z / (1.f + __expf(-z)));
    z = bf2f(z0.y); g[1] = y0.y * (z / (1.f + __expf(-z)));
    z = bf2f(z0.z); g[2] = y0.z * (z / (1.f + __expf(-z)));
    z = bf2f(z0.w); g[3] = y0.w * (z / (1.f + __expf(-z)));
    z = bf2f(z1.x); g[4] = y1.x * (z / (1.f + __expf(-z)));
    z = bf2f(z1.y); g[5] = y1.y * (z / (1.f + __expf(-z)));
    z = bf2f(z1.z); g[6] = y1.z * (z / (1.f + __expf(-z)));
    z = bf2f(z1.w); g[7] = y1.w * (z / (1.f + __expf(-z)));
  }
  float ss = 0.f;
  #pragma unroll
  for (int k = 0; k < 8; ++k) ss += g[k] * g[k];
  #pragma unroll
  for (int off = 32; off; off >>= 1) ss += __shfl_xor(ss, off);
  __shared__ float ws4[4];
  if ((tid & 63) == 0) ws4[tid >> 6] = ss;
  __syncthreads();
  float tot = ws4[0] + ws4[1] + ws4[2] + ws4[3];
  float sc = rsqrtf(tot * (1.f / 2048.f) + 1e-5f);
  int c0 = tid << 3;
  float4 m0 = *(const float4*)(mw + c0);
  float4 m1 = *(const float4*)(mw + c0 + 4);
  *(ushort4*)(gbf + base)     = make_ushort4(f2bf(g[0]*sc*m0.x), f2bf(g[1]*sc*m0.y), f2bf(g[2]*sc*m0.z), f2bf(g[3]*sc*m0.w));
  *(ushort4*)(gbf + base + 4) = make_ushort4(f2bf(g[4]*sc*m1.x), f2bf(g[5]*sc*m1.y), f2bf(g[6]*sc*m1.z), f2bf(g[7]*sc*m1.w));
}

// ---------- MQA causal attention (MFMA flash), bf16 in/out ----------
__global__ __launch_bounds__(256) void attnk(const unsigned short* __restrict__ qkv,
                                             unsigned short* __restrict__ ybf) {
  __shared__ unsigned short Qs[64][72];
  __shared__ unsigned short Ks[64][72];
  __shared__ unsigned short VT[64][72];
  __shared__ unsigned short Ps[4][16][72];
  const int id = blockIdx.x;
  const int b = id & 3, h = (id >> 2) & 15, qt = id >> 6;
  const int t0 = qt << 6;
  const int tid = threadIdx.x, w = tid >> 6, lane = tid & 63;
  const int fr = lane & 15, g = lane >> 4;
  {
    int r = tid >> 2, d0 = (tid & 3) << 4;
    const unsigned short* src = qkv + ((size_t)((b << 10) | (t0 + r))) * 1152 + (h << 6) + d0;
    *(uint4*)&Qs[r][d0]     = *(const uint4*)(src);
    *(uint4*)&Qs[r][d0 + 8] = *(const uint4*)(src + 8);
  }
  __syncthreads();
  bf16x8 afQ0 = *(const bf16x8*)&Qs[(w << 4) + fr][g << 3];
  bf16x8 afQ1 = *(const bf16x8*)&Qs[(w << 4) + fr][32 + (g << 3)];
  f32x4 acc_o[4];
  #pragma unroll
  for (int i = 0; i < 4; ++i) acc_o[i] = (f32x4){0.f, 0.f, 0.f, 0.f};
  float m[4] = {-1e30f, -1e30f, -1e30f, -1e30f};
  float l[4] = {0.f, 0.f, 0.f, 0.f};
  const int qrow = t0 + (w << 4) + (g << 2);
  for (int kt = 0; kt <= qt; ++kt) {
    const int s0 = kt << 6;
    __syncthreads();
    {
      int r = tid >> 2, d0 = (tid & 3) << 4;
      const unsigned short* src = qkv + ((size_t)((b << 10) | (s0 + r))) * 1152 + 1024 + d0;
      *(uint4*)&Ks[r][d0]     = *(const uint4*)(src);
      *(uint4*)&Ks[r][d0 + 8] = *(const uint4*)(src + 8);
    }
    {
      int r0 = (tid & 15) << 2, d0 = (tid >> 4) << 2;
      const unsigned short* src = qkv + ((size_t)((b << 10) | (s0 + r0))) * 1152 + 1088 + d0;
      ushort4 v0 = *(const ushort4*)(src);
      ushort4 v1 = *(const ushort4*)(src + 1152);
      ushort4 v2 = *(const ushort4*)(src + 2304);
      ushort4 v3 = *(const ushort4*)(src + 3456);
      *(ushort4*)&VT[d0 + 0][r0] = make_ushort4(v0.x, v1.x, v2.x, v3.x);
      *(ushort4*)&VT[d0 + 1][r0] = make_ushort4(v0.y, v1.y, v2.y, v3.y);
      *(ushort4*)&VT[d0 + 2][r0] = make_ushort4(v0.z, v1.z, v2.z, v3.z);
      *(ushort4*)&VT[d0 + 3][r0] = make_ushort4(v0.w, v1.w, v2.w, v3.w);
    }
    __syncthreads();
    f32x4 s4[4];
    #pragma unroll
    for (int jt = 0; jt < 4; ++jt) {
      bf16x8 b0 = *(const bf16x8*)&Ks[(jt << 4) + fr][g << 3];
      bf16x8 b1 = *(const bf16x8*)&Ks[(jt << 4) + fr][32 + (g << 3)];
      f32x4 z4 = (f32x4){0.f, 0.f, 0.f, 0.f};
      z4 = __builtin_amdgcn_mfma_f32_16x16x32_bf16(afQ0, b0, z4, 0, 0, 0);
      z4 = __builtin_amdgcn_mfma_f32_16x16x32_bf16(afQ1, b1, z4, 0, 0, 0);
      s4[jt] = z4 * 0.125f;
    }
    if (kt == qt) {
      #pragma unroll
      for (int jt = 0; jt < 4; ++jt) {
        int key = s0 + (jt << 4) + fr;
        #pragma unroll
        for (int r = 0; r < 4; ++r)
          if (key > qrow + r) s4[jt][r] = -1e30f;
      }
    }
    #pragma unroll
    for (int r = 0; r < 4; ++r) {
      float mt = fmaxf(fmaxf(s4[0][r], s4[1][r]), fmaxf(s4[2][r], s4[3][r]));
      #pragma unroll
      for (int off = 8; off; off >>= 1) mt = fmaxf(mt, __shfl_xor(mt, off));
      float mn = fmaxf(m[r], mt);
      float scl = __expf(m[r] - mn);
      m[r] = mn;
      float ps = 0.f;
      #pragma unroll
      for (int jt = 0; jt < 4; ++jt) {
        float p = __expf(s4[jt][r] - mn);
        ps += p;
        Ps[w][(g << 2) + r][(jt << 4) + fr] = f2bf(p);
      }
      #pragma unroll
      for (int off = 8; off; off >>= 1) ps += __shfl_xor(ps, off);
      l[r] = l[r] * scl + ps;
      acc_o[0][r] *= scl; acc_o[1][r] *= scl; acc_o[2][r] *= scl; acc_o[3][r] *= scl;
    }
    #pragma unroll
    for (int ks = 0; ks < 2; ++ks) {
      bf16x8 ap = *(const bf16x8*)&Ps[w][fr][(ks << 5) + (g << 3)];
      #pragma unroll
      for (int dt = 0; dt < 4; ++dt) {
        bf16x8 bv = *(const bf16x8*)&VT[(dt << 4) + fr][(ks << 5) + (g << 3)];
        acc_o[dt] = __builtin_amdgcn_mfma_f32_16x16x32_bf16(ap, bv, acc_o[dt], 0, 0, 0);
      }
    }
  }
  #pragma unroll
  for (int dt = 0; dt < 4; ++dt) {
    #pragma unroll
    for (int r = 0; r < 4; ++r) {
      float o = acc_o[dt][r] / l[r];
      int t = t0 + (w << 4) + (g << 2) + r;
      ybf[(((size_t)((b << 10) | t)) << 10) + (h << 6) + (dt << 4) + fr] = f2bf(o);
    }
  }
}

// ---------- cmix token-shift mix -> xk, xr (bf16) ----------
__global__ __launch_bounds__(256) void mixk(const float* __restrict__ xn3,
    const float* __restrict__ tmk, const float* __restrict__ tmr,
    unsigned short* __restrict__ xkbf, unsigned short* __restrict__ xrbf) {
  int idx4 = blockIdx.x * 256 + threadIdx.x;
  int col = (idx4 & 255) << 2;
  int row = idx4 >> 8;
  int t = row & 1023;
  size_t off = ((size_t)idx4) << 2;
  float4 cur = *(const float4*)(xn3 + off);
  float4 prev = make_float4(0.f, 0.f, 0.f, 0.f);
  if (t > 0) prev = *(const float4*)(xn3 + off - 1024);
  float4 tk = *(const float4*)(tmk + col);
  float4 tr = *(const float4*)(tmr + col);
  float dx = prev.x - cur.x, dy = prev.y - cur.y, dz = prev.z - cur.z, dw = prev.w - cur.w;
  *(ushort4*)(xkbf + off) = make_ushort4(
      f2bf(cur.x + dx * tk.x), f2bf(cur.y + dy * tk.y), f2bf(cur.z + dz * tk.z), f2bf(cur.w + dw * tk.w));
  *(ushort4*)(xrbf + off) = make_ushort4(
      f2bf(cur.x + dx * tr.x), f2bf(cur.y + dy * tr.y), f2bf(cur.z + dz * tr.z), f2bf(cur.w + dw * tr.w));
}

// ---------- final: out = x2 + sigmoid(rraw) * vout  (rraw, vout bf16) ----------
__global__ __launch_bounds__(256) void finalk(const float* __restrict__ x2,
    const unsigned short* __restrict__ rraw, const unsigned short* __restrict__ vout,
    float* __restrict__ out) {
  int idx4 = blockIdx.x * 256 + threadIdx.x;
  size_t off = ((size_t)idx4) << 2;
  float4 xv = *(const float4*)(x2 + off);
  ushort4 rv = *(const ushort4*)(rraw + off);
  ushort4 vv = *(const ushort4*)(vout + off);
  float4 o;
  o.x = xv.x + bf2f(vv.x) / (1.f + __expf(-bf2f(rv.x)));
  o.y = xv.y + bf2f(vv.y) / (1.f + __expf(-bf2f(rv.y)));
  o.z = xv.z + bf2f(vv.z) / (1.f + __expf(-bf2f(rv.z)));
  o.w = xv.w + bf2f(vv.w) / (1.f + __expf(-bf2f(rv.w)));
  *(float4*)(out + off) = o;
}

// ---------- host launcher ----------
extern "C" void kernel_launch(void* const* d_in, const int* in_sizes, int n_in,
                              void* d_out, int out_size, void* d_ws, size_t ws_size,
                              hipStream_t stream) {
  (void)in_sizes; (void)n_in; (void)out_size;
  const float* x        = (const float*)d_in[0];
  const float* in_proj  = (const float*)d_in[1];
  const float* conv_w   = (const float*)d_in[2];
  const float* conv_b   = (const float*)d_in[3];
  const float* dt_bias  = (const float*)d_in[4];
  const float* A_log    = (const float*)d_in[5];
  const float* Dvec     = (const float*)d_in[6];
  const float* mnorm_w  = (const float*)d_in[7];
  const float* out_proj = (const float*)d_in[8];
  const float* attn_w   = (const float*)d_in[9];
  const float* proj_w   = (const float*)d_in[10];
  const float* tmk      = (const float*)d_in[11];
  const float* tmr      = (const float*)d_in[12];
  const float* key_w    = (const float*)d_in[13];
  const float* recept_w = (const float*)d_in[14];
  const float* value_w  = (const float*)d_in[15];
  float* out = (float*)d_out;

  if (ws_size < 199229440ull) return;

  char* ws = (char*)d_ws;
  unsigned short* Wt   = (unsigned short*)(ws + 0);              // 8.9 MB
  unsigned short* Abf  = (unsigned short*)(ws + 8912896ull);
  unsigned short* Abf2 = (unsigned short*)(ws + 42467328ull);
  float* bigF = (float*)(ws + 59244544ull);
  float* big1 = (float*)(ws + 95420416ull);
  float* big2 = (float*)(ws + 131072000ull);
  float* x1   = (float*)(ws + 164626432ull);
  float* xn3  = (float*)(ws + 181403648ull);
  float* dtb  = (float*)(ws + 198180864ull);
  float* labuf= (float*)(ws + 198705152ull);
  unsigned short* zbf  = Abf2;
  unsigned short* xkbf = Abf2;
  unsigned short* xrbf = Abf2 + 4194304;
  float* dhbuf = bigF;
  float* hseq  = (float*)Abf;
  unsigned short* qkvbf = (unsigned short*)big1;
  unsigned short* mobf  = (unsigned short*)big1;      // mo as bf16
  unsigned short* pobf  = (unsigned short*)big2;      // po as bf16
  unsigned short* voutbf = (unsigned short*)big2;     // vout as bf16
  unsigned short* rrawbf = (unsigned short*)big1;     // rraw as bf16 (after valT dead)
  unsigned short* valT = (unsigned short*)big1;
  unsigned short* recT = (unsigned short*)big1 + 10485760;   // @20MB (> rraw's 8.4MB)

  dim3 b256(256);
  dim3 b512(512);
  dim3 tb(32, 8);

  // ===== Phase A: mamba2 =====
  resrms_k<0, 0, 0><<<4096, b256, 0, stream>>>(x, nullptr, nullptr, Abf, nullptr);
  transp_k<<<dim3(136, 32), tb, 0, stream>>>(in_proj, Wt, 1024, 4256, 4352, 0, 4256);    // full in_proj^T
  gemm4_k<1><<<512, b256, 0, stream>>>(Abf, Wt, zbf, 4096, 2048, 1024, 16);              // z (rows 0..2047)
  gemm4_k<0><<<576, b256, 0, stream>>>(Abf, Wt + 2097152, bigF, 4096, 2208, 1024, 18);   // xBC+dt (rows 2048..)
  convk<<<8704, b256, 0, stream>>>(bigF, conv_w, conv_b, dt_bias, big1, dtb);            // xbc_act + dt (f4)
  ssd1_k<<<2048, b256, 0, stream>>>(big1, dtb, A_log, big2, dhbuf, labuf);               // Y_intra, dh, la
  ssd2_k<<<2048, b256, 0, stream>>>(dhbuf, labuf, hseq);                                 // chunk states
  ssd3_k<<<2048, b256, 0, stream>>>(big1, hseq, labuf, Dvec, big2);                      // ydin final
  gnormk<<<4096, b256, 0, stream>>>(big2, zbf, mnorm_w, Abf);                            // g (bf16)
  transp_k<<<dim3(32, 64), tb, 0, stream>>>(out_proj, Wt, 2048, 1024, 1024, 0, 1024);
  gemm4_k<1><<<256, b256, 0, stream>>>(Abf, Wt, mobf, 4096, 1024, 2048, 8);              // mo (bf16)
  resrms_k<1, 1, 0><<<4096, b256, 0, stream>>>(x, mobf, x1, Abf, nullptr);               // x1, xn2

  // ===== Phase B: mqa =====
  transpN_k<<<2176, tb, 0, stream>>>(                                                     // attn^T + proj^T
      attn_w, Wt, 1024, 1152, 1152, 36, 1152,
      proj_w, Wt + 1179648, 1024, 1024, 1024, 32, 1024,
      proj_w, Wt + 1179648, 1024, 1024, 1024, 32);
  gemm4_k<1><<<288, b256, 0, stream>>>(Abf, Wt, qkvbf, 4096, 1152, 1024, 9);             // qkv (bf16)
  attnk<<<1024, b256, 0, stream>>>(qkvbf, Abf);                                          // atty (bf16)
  gemm4_k<1><<<256, b256, 0, stream>>>(Abf, Wt + 1179648, pobf, 4096, 1024, 1024, 8);    // po (bf16)
  resrms_k<1, 1, 1><<<4096, b256, 0, stream>>>(x1, pobf, x1, Abf, xn3);                  // x2 (in x1), xn3

  // ===== Phase C: cmix =====
  mixk<<<4096, b256, 0, stream>>>(xn3, tmk, tmr, xkbf, xrbf);
  transpN_k<<<9216, tb, 0, stream>>>(                                                     // key^T, value^T, recept^T
      key_w, Wt, 1024, 4096, 4096, 128, 4096,
      value_w, valT, 4096, 1024, 1024, 32, 4096,
      recept_w, recT, 1024, 1024, 1024, 32);
  gemm8_k<2><<<256, b512, 0, stream>>>(xkbf, Wt, Abf, 4096, 4096, 1024, 16);             // kact (bf16, 1 blk/CU)
  gemm4_k<1><<<256, b256, 0, stream>>>(Abf, valT, voutbf, 4096, 1024, 4096, 8);          // vout (bf16)
  gemm4_k<1><<<256, b256, 0, stream>>>(xrbf, recT, rrawbf, 4096, 1024, 1024, 8);         // rraw (bf16)
  finalk<<<4096, b256, 0, stream>>>(x1, rrawbf, voutbf, out);
}

// Round 14
// 477.812 us; speedup vs baseline: 1.1578x; 1.0481x over previous
//
#include <hip/hip_runtime.h>

// ---------- helpers ----------
__device__ __forceinline__ unsigned short f2bf(float f) {
  unsigned u = __builtin_bit_cast(unsigned, f);
  u = u + 0x7fffu + ((u >> 16) & 1u);      // RNE
  return (unsigned short)(u >> 16);
}
__device__ __forceinline__ float bf2f(unsigned short u) {
  return __builtin_bit_cast(float, ((unsigned)u) << 16);
}

typedef __bf16 bf16x8 __attribute__((ext_vector_type(8)));
typedef float  f32x4  __attribute__((ext_vector_type(4)));
typedef unsigned short u16x8 __attribute__((ext_vector_type(8)));

#define GLD16(gp, lp) __builtin_amdgcn_global_load_lds( \
    (const __attribute__((address_space(1))) unsigned int*)(gp), \
    (__attribute__((address_space(3))) unsigned int*)(lp), 16, 0, 0)

// ---------- rmsnorm (+ optional bf16 residual delta) ----------
template<int HAS_DELTA, int WRITE_SUM, int WRITE_N32>
__global__ __launch_bounds__(256) void resrms_k(const float* __restrict__ xin,
    const unsigned short* __restrict__ delta, float* __restrict__ xsum,
    unsigned short* __restrict__ nbf, float* __restrict__ nf32) {
  int row = blockIdx.x, tid = threadIdx.x;
  size_t base = ((size_t)row << 10) + ((size_t)tid << 2);
  float4 v = *(const float4*)(xin + base);
  if (HAS_DELTA) {
    ushort4 d = *(const ushort4*)(delta + base);
    v.x += bf2f(d.x); v.y += bf2f(d.y); v.z += bf2f(d.z); v.w += bf2f(d.w);
  }
  if (WRITE_SUM) *(float4*)(xsum + base) = v;
  float ss = v.x*v.x + v.y*v.y + v.z*v.z + v.w*v.w;
  #pragma unroll
  for (int off = 32; off; off >>= 1) ss += __shfl_xor(ss, off);
  __shared__ float ws4[4];
  if ((tid & 63) == 0) ws4[tid >> 6] = ss;
  __syncthreads();
  float tot = ws4[0] + ws4[1] + ws4[2] + ws4[3];
  float sc = rsqrtf(tot * (1.0f / 1024.0f) + 1e-5f);
  *(ushort4*)(nbf + base) = make_ushort4(f2bf(v.x*sc), f2bf(v.y*sc), f2bf(v.z*sc), f2bf(v.w*sc));
  if (WRITE_N32) {
    float4 n; n.x = v.x*sc; n.y = v.y*sc; n.z = v.z*sc; n.w = v.w*sc;
    *(float4*)(nf32 + base) = n;
  }
}

// ---------- transpose+convert: W[K][ldw] f32 -> Wt[Npad][K] bf16 ----------
__device__ __forceinline__ void transp_body(const float* __restrict__ W,
    unsigned short* __restrict__ Wt, int K, int Ncols, int col_off, int ldw,
    int bx, int by, int tx, int ty) {
  __shared__ float t[32][33];
  int n0 = bx << 5, k0 = by << 5;
  #pragma unroll
  for (int rr = 0; rr < 32; rr += 8) {
    int k = k0 + rr + ty, n = n0 + tx;
    t[rr + ty][tx] = (n < Ncols) ? W[(size_t)k * ldw + col_off + n] : 0.f;
  }
  __syncthreads();
  #pragma unroll
  for (int rr = 0; rr < 32; rr += 8) {
    int nrow = n0 + rr + ty;
    Wt[(size_t)nrow * K + k0 + tx] = f2bf(t[tx][rr + ty]);
  }
}

__global__ void transp_k(const float* __restrict__ W, unsigned short* __restrict__ Wt,
                         int K, int Ncols, int Npad, int col_off, int ldw) {
  transp_body(W, Wt, K, Ncols, col_off, ldw, blockIdx.x, blockIdx.y, threadIdx.x, threadIdx.y);
}

// batched transpose: up to 3 jobs in one launch (flat 1D grid, tb=(32,8))
__global__ void transpN_k(
    const float* W0, unsigned short* T0, int K0, int N0c, int ld0, int nbx0, int nb0,
    const float* W1, unsigned short* T1, int K1, int N1c, int ld1, int nbx1, int nb1,
    const float* W2, unsigned short* T2, int K2, int N2c, int ld2, int nbx2) {
  int bid = blockIdx.x;
  if (bid < nb0) {
    transp_body(W0, T0, K0, N0c, 0, ld0, bid % nbx0, bid / nbx0, threadIdx.x, threadIdx.y);
  } else if (bid < nb0 + nb1) {
    int lb = bid - nb0;
    transp_body(W1, T1, K1, N1c, 0, ld1, lb % nbx1, lb / nbx1, threadIdx.x, threadIdx.y);
  } else {
    int lb = bid - nb0 - nb1;
    transp_body(W2, T2, K2, N2c, 0, ld2, lb % nbx2, lb / nbx2, threadIdx.x, threadIdx.y);
  }
}

// ---------- 8-phase 256x256 bf16 MFMA GEMM (used for kact only) ----------
template<int EPI>   // 0=f32, 1=bf16, 2=erf->bf16
__global__ __launch_bounds__(512, 2) void gemm8_k(const unsigned short* __restrict__ A,
    const unsigned short* __restrict__ Bt, void* __restrict__ Cout,
    int M, int N, int K, int ntx) {
  __shared__ unsigned short lds[2 * 32768];   // 128 KiB
  const int tid = threadIdx.x;
  const int w = tid >> 6, lane = tid & 63;
  const int fr = lane & 15, g = lane >> 4;
  const int wmi = w >> 2, wni = w & 3;
  const int nwg = gridDim.x;
  const int nty = nwg / ntx;
  const int l = (blockIdx.x & 7) * (nwg >> 3) + (blockIdx.x >> 3);
  const int S = ((ntx & 3) == 0) ? 4 : (((ntx & 1) == 0) ? 2 : 1);
  const int sw = S * nty;
  const int s_ = l / sw, r_ = l - s_ * sw;
  const int bx = s_ * S + (r_ % S);
  const int by = r_ / S;
  const int m0 = by << 8, n0 = bx << 8;

  f32x4 acc[8][4];
  #pragma unroll
  for (int i = 0; i < 8; ++i)
    #pragma unroll
    for (int j = 0; j < 4; ++j) acc[i][j] = (f32x4){0.f, 0.f, 0.f, 0.f};

  const int r0 = tid >> 3, pc = tid & 7;
  const int lc = pc ^ (r0 & 7);
  const unsigned short* Abase = A + (size_t)(m0 + r0) * K + (lc << 3);
  const unsigned short* Bbase = Bt + (size_t)(n0 + r0) * K + (lc << 3);
  const size_t aK64 = (size_t)64 * K, aK128 = (size_t)128 * K;

#define STG_A(h_, kt_, bb_) { \
    const unsigned short* s0_ = Abase + (size_t)(h_) * aK128 + ((size_t)(kt_) << 6); \
    unsigned short* d0_ = lds + (bb_) * 32768 + (h_) * 8192 + (w << 9); \
    GLD16(s0_, d0_); GLD16(s0_ + aK64, d0_ + 4096); }
#define STG_B(h_, kt_, bb_) { \
    const unsigned short* s0_ = Bbase + (size_t)(h_) * aK128 + ((size_t)(kt_) << 6); \
    unsigned short* d0_ = lds + (bb_) * 32768 + 16384 + (h_) * 8192 + (w << 9); \
    GLD16(s0_, d0_); GLD16(s0_ + aK64, d0_ + 4096); }

  bf16x8 Areg[4][2], Breg[4][2];
#define LDA(mh_, bb_) { \
    _Pragma("unroll") for (int mf = 0; mf < 4; ++mf) \
    _Pragma("unroll") for (int kk = 0; kk < 2; ++kk) { \
      int r = ((mh_) << 6) + (mf << 4) + fr; \
      Areg[mf][kk] = *(const bf16x8*)&lds[(bb_) * 32768 + wmi * 8192 + (r << 6) + ((((kk << 2) + g) ^ (r & 7)) << 3)]; } }
#define LDB(nh_, bb_) { \
    _Pragma("unroll") for (int nf2 = 0; nf2 < 2; ++nf2) \
    _Pragma("unroll") for (int kk = 0; kk < 2; ++kk) { \
      int nf = ((nh_) << 1) + nf2; \
      int r = ((wni & 1) << 6) + (nf << 4) + fr; \
      Breg[nf][kk] = *(const bf16x8*)&lds[(bb_) * 32768 + 16384 + (wni >> 1) * 8192 + (r << 6) + ((((kk << 2) + g) ^ (r & 7)) << 3)]; } }
#define MM(mh_, nh_) { \
    __builtin_amdgcn_s_setprio(1); \
    _Pragma("unroll") for (int mf = 0; mf < 4; ++mf) \
    _Pragma("unroll") for (int nf2 = 0; nf2 < 2; ++nf2) \
    _Pragma("unroll") for (int kk = 0; kk < 2; ++kk) \
      acc[((mh_) << 2) + mf][((nh_) << 1) + nf2] = __builtin_amdgcn_mfma_f32_16x16x32_bf16( \
          Areg[mf][kk], Breg[((nh_) << 1) + nf2][kk], acc[((mh_) << 2) + mf][((nh_) << 1) + nf2], 0, 0, 0); \
    __builtin_amdgcn_s_setprio(0); }
#define BAR_LG \
    __builtin_amdgcn_s_barrier(); \
    asm volatile("s_waitcnt lgkmcnt(0)" ::: "memory"); \
    __builtin_amdgcn_sched_barrier(0);
#define ENDBAR \
    __builtin_amdgcn_s_barrier(); \
    __builtin_amdgcn_sched_barrier(0);

  STG_B(0, 0, 0) STG_B(1, 0, 0) STG_A(0, 0, 0) STG_A(1, 0, 0) STG_B(0, 1, 1) STG_B(1, 1, 1)
  asm volatile("s_waitcnt vmcnt(4)" ::: "memory");
  __builtin_amdgcn_s_barrier();
  __builtin_amdgcn_sched_barrier(0);

  const int NITER = K >> 7;
  for (int it = 0; it < NITER; ++it) {
    const int t = it << 1;
    const bool lastI = (it == NITER - 1);
    LDA(0, 0) LDB(0, 0)
    STG_A(0, t + 1, 1)
    BAR_LG MM(0, 0) ENDBAR
    LDB(1, 0)
    STG_A(1, t + 1, 1)
    BAR_LG MM(0, 1) ENDBAR
    LDA(1, 0)
    if (!lastI) STG_B(0, t + 2, 0)
    BAR_LG MM(1, 0) ENDBAR
    if (!lastI) STG_B(1, t + 2, 0)
    BAR_LG MM(1, 1)
    if (!lastI) { asm volatile("s_waitcnt vmcnt(4)" ::: "memory"); }
    else        { asm volatile("s_waitcnt vmcnt(0)" ::: "memory"); }
    ENDBAR
    LDA(0, 1) LDB(0, 1)
    if (!lastI) STG_A(0, t + 2, 0)
    BAR_LG MM(0, 0) ENDBAR
    LDB(1, 1)
    if (!lastI) STG_A(1, t + 2, 0)
    BAR_LG MM(0, 1) ENDBAR
    LDA(1, 1)
    if (!lastI) STG_B(0, t + 3, 1)
    BAR_LG MM(1, 0) ENDBAR
    if (!lastI) STG_B(1, t + 3, 1)
    BAR_LG MM(1, 1)
    if (!lastI) { asm volatile("s_waitcnt vmcnt(4)" ::: "memory"); }
    else        { asm volatile("s_waitcnt vmcnt(0)" ::: "memory"); }
    ENDBAR
  }
#undef STG_A
#undef STG_B
#undef LDA
#undef LDB
#undef MM
#undef BAR_LG
#undef ENDBAR

  asm volatile("s_waitcnt vmcnt(0)" ::: "memory");
  __syncthreads();
  float (*eps)[260] = (float(*)[260])lds;
  const int er = tid >> 3, ec0 = (tid & 7) << 5;
  #pragma unroll
  for (int slab = 0; slab < 4; ++slab) {
    if (wmi == (slab >> 1)) {
      const int mhs = slab & 1;
      #pragma unroll
      for (int mf = 0; mf < 4; ++mf)
        #pragma unroll
        for (int nf = 0; nf < 4; ++nf)
          #pragma unroll
          for (int rr = 0; rr < 4; ++rr)
            eps[(mf << 4) + (g << 2) + rr][(wni << 6) + (nf << 4) + fr] = acc[(mhs << 2) + mf][nf][rr];
    }
    __syncthreads();
    const int grow = m0 + (slab << 6) + er;
    if (EPI == 0) {
      float* orow = (float*)Cout + (size_t)grow * N + n0 + ec0;
      #pragma unroll
      for (int u = 0; u < 8; ++u) {
        int col = n0 + ec0 + (u << 2);
        if (col < N) {
          float4 v; v.x = eps[er][ec0 + (u << 2)]; v.y = eps[er][ec0 + (u << 2) + 1];
          v.z = eps[er][ec0 + (u << 2) + 2]; v.w = eps[er][ec0 + (u << 2) + 3];
          *(float4*)(orow + (u << 2)) = v;
        }
      }
    } else {
      unsigned short* orow = (unsigned short*)Cout + (size_t)grow * N + n0 + ec0;
      #pragma unroll
      for (int u = 0; u < 4; ++u) {
        int col = n0 + ec0 + (u << 3);
        if (col < N) {
          u16x8 pk;
          #pragma unroll
          for (int e = 0; e < 8; ++e) {
            float v = eps[er][ec0 + (u << 3) + e];
            if (EPI == 2) v = 0.5f * (1.0f + erff((v - 0.70710678f) * 2.5066283f));
            pk[e] = f2bf(v);
          }
          *(u16x8*)(orow + (u << 3)) = pk;
        }
      }
    }
    __syncthreads();
  }
}

// ---------- bf16 MFMA GEMM (m97-class, 3 blk/CU) ----------
// EPI: 0 = f32 store, 1 = bf16 store
template<int EPI>
__global__ __launch_bounds__(256, 3) void gemm4_k(const unsigned short* __restrict__ A,
    const unsigned short* __restrict__ Bt, void* __restrict__ Cout,
    int M, int N, int K, int ntx) {
  __shared__ char smem[49152];
  unsigned short* lds = (unsigned short*)smem;
  const int tid = threadIdx.x;
  const int w = tid >> 6, lane = tid & 63;
  const int fr = lane & 15, g = lane >> 4;
  const int nwg = gridDim.x;
  const int nty = nwg / ntx;
  const int l = (blockIdx.x & 7) * (nwg >> 3) + (blockIdx.x >> 3);
  const int S = ((ntx & 3) == 0) ? 4 : (((ntx & 1) == 0) ? 2 : 1);
  const int sw = S * nty;
  const int s = l / sw, r_ = l - s * sw;
  const int bx = s * S + (r_ % S);
  const int by = r_ / S;
  const int m0 = by << 7, n0 = bx << 7;
  const int wm = (w >> 1) << 6, wn = (w & 1) << 6;

  f32x4 acc[4][4];
  #pragma unroll
  for (int i = 0; i < 4; ++i)
    #pragma unroll
    for (int j = 0; j < 4; ++j) acc[i][j] = (f32x4){0.f, 0.f, 0.f, 0.f};

  const int r0s = tid >> 2, pc0 = tid & 3;
  const int lc0 = pc0 ^ ((r0s >> 1) & 3);
  const int r1s = r0s + 64;
  const int lc1 = pc0 ^ ((r1s >> 1) & 3);
  const unsigned short* a0 = A + (size_t)(m0 + r0s) * K + (lc0 << 3);
  const unsigned short* a1 = A + (size_t)(m0 + r1s) * K + (lc1 << 3);
  const unsigned short* b0 = Bt + (size_t)(n0 + r0s) * K + (lc0 << 3);
  const unsigned short* b1 = Bt + (size_t)(n0 + r1s) * K + (lc1 << 3);
  const int wofs = w << 9;

#define STAGE4(kt_, bb_) { \
    unsigned short* d_ = lds + (bb_) * 8192 + wofs; \
    GLD16(a0 + ((kt_) << 5), d_); \
    GLD16(a1 + ((kt_) << 5), d_ + 2048); \
    GLD16(b0 + ((kt_) << 5), d_ + 4096); \
    GLD16(b1 + ((kt_) << 5), d_ + 6144); }

  const int NT = K >> 5;
  STAGE4(0, 0)
  STAGE4(1, 1)
  asm volatile("s_waitcnt vmcnt(4)" ::: "memory");
  __builtin_amdgcn_s_barrier();
  __builtin_amdgcn_sched_barrier(0);

  int cb = 0;
  for (int t = 0; t < NT; ++t) {
    const unsigned short* bufp = lds + cb * 8192;
    int sb = cb + 2; if (sb >= 3) sb -= 3;
    const int have2 = (t + 2 < NT);
    if (have2) STAGE4(t + 2, sb)
    bf16x8 af[4], bv[4];
    #pragma unroll
    for (int i = 0; i < 4; ++i) {
      int r = wm + (i << 4) + fr;
      af[i] = *(const bf16x8*)&bufp[(r << 5) + (((g ^ (r >> 1)) & 3) << 3)];
    }
    #pragma unroll
    for (int j = 0; j < 4; ++j) {
      int r = wn + (j << 4) + fr;
      bv[j] = *(const bf16x8*)&bufp[4096 + (r << 5) + (((g ^ (r >> 1)) & 3) << 3)];
    }
    __builtin_amdgcn_s_setprio(1);
    #pragma unroll
    for (int i = 0; i < 4; ++i)
      #pragma unroll
      for (int j = 0; j < 4; ++j)
        acc[i][j] = __builtin_amdgcn_mfma_f32_16x16x32_bf16(af[i], bv[j], acc[i][j], 0, 0, 0);
    __builtin_amdgcn_s_setprio(0);
    if (t + 1 < NT) {
      if (have2) { asm volatile("s_waitcnt vmcnt(4)" ::: "memory"); }
      else       { asm volatile("s_waitcnt vmcnt(0)" ::: "memory"); }
      __builtin_amdgcn_s_barrier();
      __builtin_amdgcn_sched_barrier(0);
    }
    cb = cb + 1; if (cb >= 3) cb -= 3;
  }
#undef STAGE4

  float (*eps)[132] = (float(*)[132])smem;
  const int rin = g << 2;
  const int er = tid >> 2, ec0 = (tid & 3) << 5;
  #pragma unroll
  for (int rh = 0; rh < 2; ++rh) {
    __syncthreads();
    if ((wm >> 6) == rh) {
      #pragma unroll
      for (int i = 0; i < 4; ++i)
        #pragma unroll
        for (int j = 0; j < 4; ++j)
          #pragma unroll
          for (int rr = 0; rr < 4; ++rr)
            eps[(i << 4) + rin + rr][wn + (j << 4) + fr] = acc[i][j][rr];
    }
    __syncthreads();
    int grow = m0 + (rh << 6) + er;
    if (EPI == 0) {
      float* orow = (float*)Cout + (size_t)grow * N + n0 + ec0;
      #pragma unroll
      for (int u = 0; u < 8; ++u) {
        int col = n0 + ec0 + (u << 2);
        if (col < N) {
          float4 v; v.x = eps[er][ec0 + (u<<2)]; v.y = eps[er][ec0 + (u<<2) + 1];
          v.z = eps[er][ec0 + (u<<2) + 2]; v.w = eps[er][ec0 + (u<<2) + 3];
          *(float4*)(orow + (u << 2)) = v;
        }
      }
    } else {
      unsigned short* orow = (unsigned short*)Cout + (size_t)grow * N + n0 + ec0;
      #pragma unroll
      for (int u = 0; u < 4; ++u) {
        int col = n0 + ec0 + (u << 3);
        if (col < N) {
          u16x8 pk;
          #pragma unroll
          for (int e = 0; e < 8; ++e) pk[e] = f2bf(eps[er][ec0 + (u << 3) + e]);
          *(u16x8*)(orow + (u << 3)) = pk;
        }
      }
    }
  }
}

// ---------- causal depthwise conv(4) + silu, bf16 in/out, fused dt/softplus ----------
__global__ __launch_bounds__(256) void convk(const unsigned short* __restrict__ zxr,
    const float* __restrict__ conv_w, const float* __restrict__ conv_b,
    const float* __restrict__ dt_bias, unsigned short* __restrict__ xbc,
    float* __restrict__ dtb) {
  int idx = blockIdx.x * 256 + threadIdx.x;   // 4*1024*544
  if (idx >= 4 * 1024 * 544) return;
  int c4 = idx % 544; int bt = idx / 544; int t = bt & 1023;
  int c = c4 << 2;
  const unsigned short* col = zxr + (size_t)bt * 2208 + c;
  ushort4 zu = make_ushort4(0, 0, 0, 0);
  ushort4 u0 = *(const ushort4*)col;
  ushort4 u1 = (t >= 1) ? *(const ushort4*)(col - 2208) : zu;
  ushort4 u2 = (t >= 2) ? *(const ushort4*)(col - 4416) : zu;
  ushort4 u3 = (t >= 3) ? *(const ushort4*)(col - 6624) : zu;
  float4 x0 = make_float4(bf2f(u0.x), bf2f(u0.y), bf2f(u0.z), bf2f(u0.w));
  float4 x1 = make_float4(bf2f(u1.x), bf2f(u1.y), bf2f(u1.z), bf2f(u1.w));
  float4 x2 = make_float4(bf2f(u2.x), bf2f(u2.y), bf2f(u2.z), bf2f(u2.w));
  float4 x3 = make_float4(bf2f(u3.x), bf2f(u3.y), bf2f(u3.z), bf2f(u3.w));
  const float4* wp = (const float4*)(conv_w + (c << 2));
  float4 wa = wp[0], wb = wp[1], wc_ = wp[2], wd = wp[3];
  float4 bb = *(const float4*)(conv_b + c);
  float4 a;
  a.x = bb.x; a.x = fmaf(x3.x, wa.x, a.x); a.x = fmaf(x2.x, wa.y, a.x); a.x = fmaf(x1.x, wa.z, a.x); a.x = fmaf(x0.x, wa.w, a.x);
  a.y = bb.y; a.y = fmaf(x3.y, wb.x, a.y); a.y = fmaf(x2.y, wb.y, a.y); a.y = fmaf(x1.y, wb.z, a.y); a.y = fmaf(x0.y, wb.w, a.y);
  a.z = bb.z; a.z = fmaf(x3.z, wc_.x, a.z); a.z = fmaf(x2.z, wc_.y, a.z); a.z = fmaf(x1.z, wc_.z, a.z); a.z = fmaf(x0.z, wc_.w, a.z);
  a.w = bb.w; a.w = fmaf(x3.w, wd.x, a.w); a.w = fmaf(x2.w, wd.y, a.w); a.w = fmaf(x1.w, wd.z, a.w); a.w = fmaf(x0.w, wd.w, a.w);
  ushort4 o;
  o.x = f2bf(a.x / (1.f + __expf(-a.x)));
  o.y = f2bf(a.y / (1.f + __expf(-a.y)));
  o.z = f2bf(a.z / (1.f + __expf(-a.z)));
  o.w = f2bf(a.w / (1.f + __expf(-a.w)));
  *(ushort4*)(xbc + (size_t)bt * 2176 + c) = o;
  if (c < 32) {
    ushort4 du = *(const ushort4*)(zxr + (size_t)bt * 2208 + 2176 + c);
    float4 db = *(const float4*)(dt_bias + c);
    float4 r;
    float v;
    v = bf2f(du.x) + db.x; r.x = (v > 20.f) ? v : log1pf(__expf(v));
    v = bf2f(du.y) + db.y; r.y = (v > 20.f) ? v : log1pf(__expf(v));
    v = bf2f(du.z) + db.z; r.z = (v > 20.f) ? v : log1pf(__expf(v));
    v = bf2f(du.w) + db.w; r.w = (v > 20.f) ? v : log1pf(__expf(v));
    *(float4*)(dtb + bt * 32 + c) = r;
  }
}

// ---------- SSD chunked scan, stage 1 (xbc is bf16) ----------
__global__ __launch_bounds__(256) void ssd1_k(const unsigned short* __restrict__ xbc,
    const float* __restrict__ dtb, const float* __restrict__ A_log,
    float* __restrict__ ydin, float* __restrict__ dhbuf, float* __restrict__ labuf) {
  __shared__ unsigned short Cs[64][68];
  __shared__ unsigned short Bsm[64][68];
  __shared__ unsigned short XT[64][68];
  __shared__ unsigned short BT[64][68];
  __shared__ unsigned short Ms[64][68];
  __shared__ float laS[64], dtS[64];
  const int id = blockIdx.x;
  const int h = id & 31, b = (id >> 5) & 3, c = id >> 7;
  const int tid = threadIdx.x, w = tid >> 6, lane = tid & 63;
  const int fr = lane & 15, g = lane >> 4;
  const size_t rowbase = (size_t)((b << 10) + (c << 6));

  {
    int r = tid >> 2, c0 = (tid & 3) << 4;
    const unsigned short* src = xbc + (rowbase + r) * 2176;
    #pragma unroll
    for (int i = 0; i < 4; ++i) {
      *(ushort4*)&Cs[r][c0 + 4 * i]  = *(const ushort4*)(src + 2112 + c0 + 4 * i);
      *(ushort4*)&Bsm[r][c0 + 4 * i] = *(const ushort4*)(src + 2048 + c0 + 4 * i);
    }
  }
  {
    int r0 = (tid & 15) << 2, d0 = (tid >> 4) << 2;
    const unsigned short* src = xbc + (rowbase + r0) * 2176 + (h << 6) + d0;
    ushort4 v0 = *(const ushort4*)(src);
    ushort4 v1 = *(const ushort4*)(src + 2176);
    ushort4 v2 = *(const ushort4*)(src + 4352);
    ushort4 v3 = *(const ushort4*)(src + 6528);
    *(ushort4*)&XT[d0 + 0][r0] = make_ushort4(v0.x, v1.x, v2.x, v3.x);
    *(ushort4*)&XT[d0 + 1][r0] = make_ushort4(v0.y, v1.y, v2.y, v3.y);
    *(ushort4*)&XT[d0 + 2][r0] = make_ushort4(v0.z, v1.z, v2.z, v3.z);
    *(ushort4*)&XT[d0 + 3][r0] = make_ushort4(v0.w, v1.w, v2.w, v3.w);
  }
  if (w == 0) {
    float Ah = -__expf(A_log[h]);
    float dtv = dtb[(rowbase + lane) * 32 + h];
    float v = dtv * Ah;
    #pragma unroll
    for (int off = 1; off < 64; off <<= 1) {
      float u = __shfl_up(v, off);
      if (lane >= off) v += u;
    }
    laS[lane] = v; dtS[lane] = dtv;
    labuf[(size_t)((((b << 4) | c) << 5 | h) << 6) + lane] = v;
  }
  __syncthreads();

  const int wr = w >> 1, wc = w & 1;
  f32x4 gf[2][2];
  #pragma unroll
  for (int i = 0; i < 2; ++i)
    #pragma unroll
    for (int j = 0; j < 2; ++j) gf[i][j] = (f32x4){0.f, 0.f, 0.f, 0.f};
  {
    int r0 = (tid & 15) << 2, d0 = (tid >> 4) << 2;
    const unsigned short* src = xbc + (rowbase + r0) * 2176 + 2048 + d0;
    float la63 = laS[63];
    ushort4 v0 = *(const ushort4*)(src);
    ushort4 v1 = *(const ushort4*)(src + 2176);
    ushort4 v2 = *(const ushort4*)(src + 4352);
    ushort4 v3 = *(const ushort4*)(src + 6528);
    float w0 = __expf(la63 - laS[r0 + 0]) * dtS[r0 + 0];
    float w1 = __expf(la63 - laS[r0 + 1]) * dtS[r0 + 1];
    float w2 = __expf(la63 - laS[r0 + 2]) * dtS[r0 + 2];
    float w3 = __expf(la63 - laS[r0 + 3]) * dtS[r0 + 3];
    *(ushort4*)&BT[d0 + 0][r0] = make_ushort4(f2bf(bf2f(v0.x)*w0), f2bf(bf2f(v1.x)*w1), f2bf(bf2f(v2.x)*w2), f2bf(bf2f(v3.x)*w3));
    *(ushort4*)&BT[d0 + 1][r0] = make_ushort4(f2bf(bf2f(v0.y)*w0), f2bf(bf2f(v1.y)*w1), f2bf(bf2f(v2.y)*w2), f2bf(bf2f(v3.y)*w3));
    *(ushort4*)&BT[d0 + 2][r0] = make_ushort4(f2bf(bf2f(v0.z)*w0), f2bf(bf2f(v1.z)*w1), f2bf(bf2f(v2.z)*w2), f2bf(bf2f(v3.z)*w3));
    *(ushort4*)&BT[d0 + 3][r0] = make_ushort4(f2bf(bf2f(v0.w)*w0), f2bf(bf2f(v1.w)*w1), f2bf(bf2f(v2.w)*w2), f2bf(bf2f(v3.w)*w3));
  }
  #pragma unroll
  for (int ks = 0; ks < 2; ++ks) {
    bf16x8 ca[2], bb[2];
    #pragma unroll
    for (int i = 0; i < 2; ++i) ca[i] = *(const bf16x8*)&Cs[(wr << 5) + (i << 4) + fr][(ks << 5) + (g << 3)];
    #pragma unroll
    for (int j = 0; j < 2; ++j) bb[j] = *(const bf16x8*)&Bsm[(wc << 5) + (j << 4) + fr][(ks << 5) + (g << 3)];
    #pragma unroll
    for (int i = 0; i < 2; ++i)
      #pragma unroll
      for (int j = 0; j < 2; ++j)
        gf[i][j] = __builtin_amdgcn_mfma_f32_16x16x32_bf16(ca[i], bb[j], gf[i][j], 0, 0, 0);
  }
  #pragma unroll
  for (int i = 0; i < 2; ++i) {
    #pragma unroll
    for (int j = 0; j < 2; ++j) {
      int s = (wc << 5) + (j << 4) + fr;
      float la_s = laS[s], dt_s = dtS[s];
      #pragma unroll
      for (int rr = 0; rr < 4; ++rr) {
        int t = (wr << 5) + (i << 4) + (g << 2) + rr;
        float e = __expf(fminf(laS[t] - la_s, 0.f));
        float val = (s <= t) ? gf[i][j][rr] * e * dt_s : 0.f;
        Ms[t][s] = f2bf(val);
      }
    }
  }
  __syncthreads();

  f32x4 yf[2][2], hf[2][2];
  #pragma unroll
  for (int i = 0; i < 2; ++i)
    #pragma unroll
    for (int j = 0; j < 2; ++j) { yf[i][j] = (f32x4){0.f,0.f,0.f,0.f}; hf[i][j] = (f32x4){0.f,0.f,0.f,0.f}; }
  #pragma unroll
  for (int ks = 0; ks < 2; ++ks) {
    bf16x8 ma[2], ba[2], xb[2];
    #pragma unroll
    for (int i = 0; i < 2; ++i) {
      ma[i] = *(const bf16x8*)&Ms[(wr << 5) + (i << 4) + fr][(ks << 5) + (g << 3)];
      ba[i] = *(const bf16x8*)&BT[(wr << 5) + (i << 4) + fr][(ks << 5) + (g << 3)];
    }
    #pragma unroll
    for (int j = 0; j < 2; ++j) xb[j] = *(const bf16x8*)&XT[(wc << 5) + (j << 4) + fr][(ks << 5) + (g << 3)];
    #pragma unroll
    for (int i = 0; i < 2; ++i)
      #pragma unroll
      for (int j = 0; j < 2; ++j) {
        yf[i][j] = __builtin_amdgcn_mfma_f32_16x16x32_bf16(ma[i], xb[j], yf[i][j], 0, 0, 0);
        hf[i][j] = __builtin_amdgcn_mfma_f32_16x16x32_bf16(ba[i], xb[j], hf[i][j], 0, 0, 0);
      }
  }
  float* dhb = dhbuf + ((size_t)(((c << 2) + b) * 32 + h) << 12);
  #pragma unroll
  for (int i = 0; i < 2; ++i) {
    #pragma unroll
    for (int j = 0; j < 2; ++j) {
      int p = (wc << 5) + (j << 4) + fr;
      #pragma unroll
      for (int rr = 0; rr < 4; ++rr) {
        int t = (wr << 5) + (i << 4) + (g << 2) + rr;
        ydin[((rowbase + t) << 11) + (h << 6) + p] = yf[i][j][rr];
        dhb[(t << 6) + p] = hf[i][j][rr];
      }
    }
  }
}

// ---------- SSD stage 2 ----------
__global__ __launch_bounds__(256) void ssd2_k(const float* __restrict__ dhbuf,
    const float* __restrict__ labuf, float* __restrict__ hseq) {
  int idx = blockIdx.x * 256 + threadIdx.x;
  int np = idx & 4095;
  int h = (idx >> 12) & 31, b = idx >> 17;
  float carry = 0.f;
  #pragma unroll
  for (int c = 0; c < 16; ++c) {
    size_t o = ((size_t)(((c << 2) + b) * 32 + h) << 12) + np;
    hseq[o] = carry;
    float ec = __expf(labuf[(size_t)((((b << 4) | c) << 5 | h) << 6) + 63]);
    carry = fmaf(ec, carry, dhbuf[o]);
  }
}

// ---------- SSD stage 3 (xbc is bf16) ----------
__global__ __launch_bounds__(256) void ssd3_k(const unsigned short* __restrict__ xbc,
    const float* __restrict__ hseq, const float* __restrict__ labuf,
    const float* __restrict__ Dv, float* __restrict__ ydin) {
  __shared__ unsigned short Cs[64][68];
  __shared__ unsigned short HT[64][68];
  __shared__ float laS[64];
  const int id = blockIdx.x;
  const int h = id & 31, b = (id >> 5) & 3, c = id >> 7;
  const int tid = threadIdx.x, w = tid >> 6, lane = tid & 63;
  const int fr = lane & 15, g = lane >> 4;
  const size_t rowbase = (size_t)((b << 10) + (c << 6));
  {
    int r = tid >> 2, c0 = (tid & 3) << 4;
    const unsigned short* src = xbc + (rowbase + r) * 2176 + 2112;
    #pragma unroll
    for (int i = 0; i < 4; ++i)
      *(ushort4*)&Cs[r][c0 + 4 * i] = *(const ushort4*)(src + c0 + 4 * i);
  }
  {
    const float* hb = hseq + ((size_t)(((c << 2) + b) * 32 + h) << 12);
    int n0 = (tid & 15) << 2, p0 = (tid >> 4) << 2;
    float4 v0 = *(const float4*)(hb + ((n0 + 0) << 6) + p0);
    float4 v1 = *(const float4*)(hb + ((n0 + 1) << 6) + p0);
    float4 v2 = *(const float4*)(hb + ((n0 + 2) << 6) + p0);
    float4 v3 = *(const float4*)(hb + ((n0 + 3) << 6) + p0);
    *(ushort4*)&HT[p0 + 0][n0] = make_ushort4(f2bf(v0.x), f2bf(v1.x), f2bf(v2.x), f2bf(v3.x));
    *(ushort4*)&HT[p0 + 1][n0] = make_ushort4(f2bf(v0.y), f2bf(v1.y), f2bf(v2.y), f2bf(v3.y));
    *(ushort4*)&HT[p0 + 2][n0] = make_ushort4(f2bf(v0.z), f2bf(v1.z), f2bf(v2.z), f2bf(v3.z));
    *(ushort4*)&HT[p0 + 3][n0] = make_ushort4(f2bf(v0.w), f2bf(v1.w), f2bf(v2.w), f2bf(v3.w));
  }
  if (tid < 64) laS[tid] = labuf[(size_t)((((b << 4) | c) << 5 | h) << 6) + tid];
  __syncthreads();
  const int wr = w >> 1, wc = w & 1;
  f32x4 yf[2][2];
  #pragma unroll
  for (int i = 0; i < 2; ++i)
    #pragma unroll
    for (int j = 0; j < 2; ++j) yf[i][j] = (f32x4){0.f, 0.f, 0.f, 0.f};
  #pragma unroll
  for (int ks = 0; ks < 2; ++ks) {
    bf16x8 ca[2], hv[2];
    #pragma unroll
    for (int i = 0; i < 2; ++i) ca[i] = *(const bf16x8*)&Cs[(wr << 5) + (i << 4) + fr][(ks << 5) + (g << 3)];
    #pragma unroll
    for (int j = 0; j < 2; ++j) hv[j] = *(const bf16x8*)&HT[(wc << 5) + (j << 4) + fr][(ks << 5) + (g << 3)];
    #pragma unroll
    for (int i = 0; i < 2; ++i)
      #pragma unroll
      for (int j = 0; j < 2; ++j)
        yf[i][j] = __builtin_amdgcn_mfma_f32_16x16x32_bf16(ca[i], hv[j], yf[i][j], 0, 0, 0);
  }
  float Dh = Dv[h];
  #pragma unroll
  for (int i = 0; i < 2; ++i) {
    #pragma unroll
    for (int j = 0; j < 2; ++j) {
      int p = (wc << 5) + (j << 4) + fr;
      #pragma unroll
      for (int rr = 0; rr < 4; ++rr) {
        int t = (wr << 5) + (i << 4) + (g << 2) + rr;
        size_t yo = ((rowbase + t) << 11) + (h << 6) + p;
        float xv = bf2f(xbc[(rowbase + t) * 2176 + (h << 6) + p]);
        ydin[yo] = ydin[yo] + __expf(laS[t]) * yf[i][j][rr] + Dh * xv;
      }
    }
  }
}

// ---------- g = ydin * silu(z); rmsnorm(2048) * mnorm_w -> bf16 ----------
__global__ __launch_bounds__(256) void gnormk(const float* __restrict__ ydin,
    const unsigned short* __restrict__ zbf, const float* __restrict__ mw,
    unsigned short* __restrict__ gbf) {
  int row = blockIdx.x, tid = threadIdx.x;
  size_t base = ((size_t)row << 11) + ((size_t)tid << 3);
  float4 y0 = *(const float4*)(ydin + base);
  float4 y1 = *(const float4*)(ydin + base + 4);
  ushort4 z0 = *(const ushort4*)(zbf + base);
  ushort4 z1 = *(const ushort4*)(zbf + base + 4);
  float g[8];
  {
    float z;
    z = bf2f(z0.x); g[0] = y0.x * (z / (1.f + __expf(-z)));
    z = bf2f(z0.y); g[1] = y0.y * (z / (1.f + __expf(-z)));
    z = bf2f(z0.z); g[2] = y0.z * (z / (1.f + __expf(-z)));
    z = bf2f(z0.w); g[3] = y0.w * (z / (1.f + __expf(-z)));
    z = bf2f(z1.x); g[4] = y1.x * (z / (1.f + __expf(-z)));
    z = bf2f(z1.y); g[5] = y1.y * (z / (1.f + __expf(-z)));
    z = bf2f(z1.z); g[6] = y1.z * (z / (1.f + __expf(-z)));
    z = bf2f(z1.w); g[7] = y1.w * (z / (1.f + __expf(-z)));
  }
  float ss = 0.f;
  #pragma unroll
  for (int k = 0; k < 8; ++k) ss += g[k] * g[k];
  #pragma unroll
  for (int off = 32; off; off >>= 1) ss += __shfl_xor(ss, off);
  __shared__ float ws4[4];
  if ((tid & 63) == 0) ws4[tid >> 6] = ss;
  __syncthreads();
  float tot = ws4[0] + ws4[1] + ws4[2] + ws4[3];
  float sc = rsqrtf(tot * (1.f / 2048.f) + 1e-5f);
  int c0 = tid << 3;
  float4 m0 = *(const float4*)(mw + c0);
  float4 m1 = *(const float4*)(mw + c0 + 4);
  *(ushort4*)(gbf + base)     = make_ushort4(f2bf(g[0]*sc*m0.x), f2bf(g[1]*sc*m0.y), f2bf(g[2]*sc*m0.z), f2bf(g[3]*sc*m0.w));
  *(ushort4*)(gbf + base + 4) = make_ushort4(f2bf(g[4]*sc*m1.x), f2bf(g[5]*sc*m1.y), f2bf(g[6]*sc*m1.z), f2bf(g[7]*sc*m1.w));
}

// ---------- MQA causal attention (MFMA flash), bf16 in/out ----------
__global__ __launch_bounds__(256) void attnk(const unsigned short* __restrict__ qkv,
                                             unsigned short* __restrict__ ybf) {
  __shared__ unsigned short Qs[64][72];
  __shared__ unsigned short Ks[64][72];
  __shared__ unsigned short VT[64][72];
  __shared__ unsigned short Ps[4][16][72];
  const int id = blockIdx.x;
  const int b = id & 3, h = (id >> 2) & 15, qt = id >> 6;
  const int t0 = qt << 6;
  const int tid = threadIdx.x, w = tid >> 6, lane = tid & 63;
  const int fr = lane & 15, g = lane >> 4;
  {
    int r = tid >> 2, d0 = (tid & 3) << 4;
    const unsigned short* src = qkv + ((size_t)((b << 10) | (t0 + r))) * 1152 + (h << 6) + d0;
    *(uint4*)&Qs[r][d0]     = *(const uint4*)(src);
    *(uint4*)&Qs[r][d0 + 8] = *(const uint4*)(src + 8);
  }
  __syncthreads();
  bf16x8 afQ0 = *(const bf16x8*)&Qs[(w << 4) + fr][g << 3];
  bf16x8 afQ1 = *(const bf16x8*)&Qs[(w << 4) + fr][32 + (g << 3)];
  f32x4 acc_o[4];
  #pragma unroll
  for (int i = 0; i < 4; ++i) acc_o[i] = (f32x4){0.f, 0.f, 0.f, 0.f};
  float m[4] = {-1e30f, -1e30f, -1e30f, -1e30f};
  float l[4] = {0.f, 0.f, 0.f, 0.f};
  const int qrow = t0 + (w << 4) + (g << 2);
  for (int kt = 0; kt <= qt; ++kt) {
    const int s0 = kt << 6;
    __syncthreads();
    {
      int r = tid >> 2, d0 = (tid & 3) << 4;
      const unsigned short* src = qkv + ((size_t)((b << 10) | (s0 + r))) * 1152 + 1024 + d0;
      *(uint4*)&Ks[r][d0]     = *(const uint4*)(src);
      *(uint4*)&Ks[r][d0 + 8] = *(const uint4*)(src + 8);
    }
    {
      int r0 = (tid & 15) << 2, d0 = (tid >> 4) << 2;
      const unsigned short* src = qkv + ((size_t)((b << 10) | (s0 + r0))) * 1152 + 1088 + d0;
      ushort4 v0 = *(const ushort4*)(src);
      ushort4 v1 = *(const ushort4*)(src + 1152);
      ushort4 v2 = *(const ushort4*)(src + 2304);
      ushort4 v3 = *(const ushort4*)(src + 3456);
      *(ushort4*)&VT[d0 + 0][r0] = make_ushort4(v0.x, v1.x, v2.x, v3.x);
      *(ushort4*)&VT[d0 + 1][r0] = make_ushort4(v0.y, v1.y, v2.y, v3.y);
      *(ushort4*)&VT[d0 + 2][r0] = make_ushort4(v0.z, v1.z, v2.z, v3.z);
      *(ushort4*)&VT[d0 + 3][r0] = make_ushort4(v0.w, v1.w, v2.w, v3.w);
    }
    __syncthreads();
    f32x4 s4[4];
    #pragma unroll
    for (int jt = 0; jt < 4; ++jt) {
      bf16x8 b0 = *(const bf16x8*)&Ks[(jt << 4) + fr][g << 3];
      bf16x8 b1 = *(const bf16x8*)&Ks[(jt << 4) + fr][32 + (g << 3)];
      f32x4 z4 = (f32x4){0.f, 0.f, 0.f, 0.f};
      z4 = __builtin_amdgcn_mfma_f32_16x16x32_bf16(afQ0, b0, z4, 0, 0, 0);
      z4 = __builtin_amdgcn_mfma_f32_16x16x32_bf16(afQ1, b1, z4, 0, 0, 0);
      s4[jt] = z4 * 0.125f;
    }
    if (kt == qt) {
      #pragma unroll
      for (int jt = 0; jt < 4; ++jt) {
        int key = s0 + (jt << 4) + fr;
        #pragma unroll
        for (int r = 0; r < 4; ++r)
          if (key > qrow + r) s4[jt][r] = -1e30f;
      }
    }
    #pragma unroll
    for (int r = 0; r < 4; ++r) {
      float mt = fmaxf(fmaxf(s4[0][r], s4[1][r]), fmaxf(s4[2][r], s4[3][r]));
      #pragma unroll
      for (int off = 8; off; off >>= 1) mt = fmaxf(mt, __shfl_xor(mt, off));
      float mn = fmaxf(m[r], mt);
      float scl = __expf(m[r] - mn);
      m[r] = mn;
      float ps = 0.f;
      #pragma unroll
      for (int jt = 0; jt < 4; ++jt) {
        float p = __expf(s4[jt][r] - mn);
        ps += p;
        Ps[w][(g << 2) + r][(jt << 4) + fr] = f2bf(p);
      }
      #pragma unroll
      for (int off = 8; off; off >>= 1) ps += __shfl_xor(ps, off);
      l[r] = l[r] * scl + ps;
      acc_o[0][r] *= scl; acc_o[1][r] *= scl; acc_o[2][r] *= scl; acc_o[3][r] *= scl;
    }
    #pragma unroll
    for (int ks = 0; ks < 2; ++ks) {
      bf16x8 ap = *(const bf16x8*)&Ps[w][fr][(ks << 5) + (g << 3)];
      #pragma unroll
      for (int dt = 0; dt < 4; ++dt) {
        bf16x8 bv = *(const bf16x8*)&VT[(dt << 4) + fr][(ks << 5) + (g << 3)];
        acc_o[dt] = __builtin_amdgcn_mfma_f32_16x16x32_bf16(ap, bv, acc_o[dt], 0, 0, 0);
      }
    }
  }
  #pragma unroll
  for (int dt = 0; dt < 4; ++dt) {
    #pragma unroll
    for (int r = 0; r < 4; ++r) {
      float o = acc_o[dt][r] / l[r];
      int t = t0 + (w << 4) + (g << 2) + r;
      ybf[(((size_t)((b << 10) | t)) << 10) + (h << 6) + (dt << 4) + fr] = f2bf(o);
    }
  }
}

// ---------- cmix token-shift mix -> xk, xr (bf16) ----------
__global__ __launch_bounds__(256) void mixk(const float* __restrict__ xn3,
    const float* __restrict__ tmk, const float* __restrict__ tmr,
    unsigned short* __restrict__ xkbf, unsigned short* __restrict__ xrbf) {
  int idx4 = blockIdx.x * 256 + threadIdx.x;
  int col = (idx4 & 255) << 2;
  int row = idx4 >> 8;
  int t = row & 1023;
  size_t off = ((size_t)idx4) << 2;
  float4 cur = *(const float4*)(xn3 + off);
  float4 prev = make_float4(0.f, 0.f, 0.f, 0.f);
  if (t > 0) prev = *(const float4*)(xn3 + off - 1024);
  float4 tk = *(const float4*)(tmk + col);
  float4 tr = *(const float4*)(tmr + col);
  float dx = prev.x - cur.x, dy = prev.y - cur.y, dz = prev.z - cur.z, dw = prev.w - cur.w;
  *(ushort4*)(xkbf + off) = make_ushort4(
      f2bf(cur.x + dx * tk.x), f2bf(cur.y + dy * tk.y), f2bf(cur.z + dz * tk.z), f2bf(cur.w + dw * tk.w));
  *(ushort4*)(xrbf + off) = make_ushort4(
      f2bf(cur.x + dx * tr.x), f2bf(cur.y + dy * tr.y), f2bf(cur.z + dz * tr.z), f2bf(cur.w + dw * tr.w));
}

// ---------- final: out = x2 + sigmoid(rraw) * vout  (rraw, vout bf16) ----------
__global__ __launch_bounds__(256) void finalk(const float* __restrict__ x2,
    const unsigned short* __restrict__ rraw, const unsigned short* __restrict__ vout,
    float* __restrict__ out) {
  int idx4 = blockIdx.x * 256 + threadIdx.x;
  size_t off = ((size_t)idx4) << 2;
  float4 xv = *(const float4*)(x2 + off);
  ushort4 rv = *(const ushort4*)(rraw + off);
  ushort4 vv = *(const ushort4*)(vout + off);
  float4 o;
  o.x = xv.x + bf2f(vv.x) / (1.f + __expf(-bf2f(rv.x)));
  o.y = xv.y + bf2f(vv.y) / (1.f + __expf(-bf2f(rv.y)));
  o.z = xv.z + bf2f(vv.z) / (1.f + __expf(-bf2f(rv.z)));
  o.w = xv.w + bf2f(vv.w) / (1.f + __expf(-bf2f(rv.w)));
  *(float4*)(out + off) = o;
}

// ---------- host launcher ----------
extern "C" void kernel_launch(void* const* d_in, const int* in_sizes, int n_in,
                              void* d_out, int out_size, void* d_ws, size_t ws_size,
                              hipStream_t stream) {
  (void)in_sizes; (void)n_in; (void)out_size;
  const float* x        = (const float*)d_in[0];
  const float* in_proj  = (const float*)d_in[1];
  const float* conv_w   = (const float*)d_in[2];
  const float* conv_b   = (const float*)d_in[3];
  const float* dt_bias  = (const float*)d_in[4];
  const float* A_log    = (const float*)d_in[5];
  const float* Dvec     = (const float*)d_in[6];
  const float* mnorm_w  = (const float*)d_in[7];
  const float* out_proj = (const float*)d_in[8];
  const float* attn_w   = (const float*)d_in[9];
  const float* proj_w   = (const float*)d_in[10];
  const float* tmk      = (const float*)d_in[11];
  const float* tmr      = (const float*)d_in[12];
  const float* key_w    = (const float*)d_in[13];
  const float* recept_w = (const float*)d_in[14];
  const float* value_w  = (const float*)d_in[15];
  float* out = (float*)d_out;

  if (ws_size < 199229440ull) return;

  char* ws = (char*)d_ws;
  unsigned short* Wt   = (unsigned short*)(ws + 0);              // 8.9 MB
  unsigned short* Abf  = (unsigned short*)(ws + 8912896ull);
  unsigned short* Abf2 = (unsigned short*)(ws + 42467328ull);
  float* bigF = (float*)(ws + 59244544ull);
  float* big1 = (float*)(ws + 95420416ull);
  float* big2 = (float*)(ws + 131072000ull);
  float* x1   = (float*)(ws + 164626432ull);
  float* xn3  = (float*)(ws + 181403648ull);
  float* dtb  = (float*)(ws + 198180864ull);
  float* labuf= (float*)(ws + 198705152ull);
  unsigned short* zbf  = Abf2;
  unsigned short* xkbf = Abf2;
  unsigned short* xrbf = Abf2 + 4194304;
  float* dhbuf = bigF;
  float* hseq  = (float*)Abf;
  unsigned short* zxrb = (unsigned short*)bigF;       // xBC+dt as bf16 [4096][2208]
  unsigned short* xbcb = (unsigned short*)big1;       // xbc_act as bf16 [4096][2176]
  unsigned short* qkvbf = (unsigned short*)big1;
  unsigned short* mobf  = (unsigned short*)big1;      // mo as bf16
  unsigned short* pobf  = (unsigned short*)big2;      // po as bf16
  unsigned short* voutbf = (unsigned short*)big2;     // vout as bf16
  unsigned short* rrawbf = (unsigned short*)big1;     // rraw as bf16 (after valT dead)
  unsigned short* valT = (unsigned short*)big1;
  unsigned short* recT = (unsigned short*)big1 + 10485760;   // @20MB (> rraw's 8.4MB)

  dim3 b256(256);
  dim3 b512(512);
  dim3 tb(32, 8);

  // ===== Phase A: mamba2 =====
  resrms_k<0, 0, 0><<<4096, b256, 0, stream>>>(x, nullptr, nullptr, Abf, nullptr);
  transp_k<<<dim3(136, 32), tb, 0, stream>>>(in_proj, Wt, 1024, 4256, 4352, 0, 4256);    // full in_proj^T
  gemm4_k<1><<<512, b256, 0, stream>>>(Abf, Wt, zbf, 4096, 2048, 1024, 16);              // z (rows 0..2047)
  gemm4_k<1><<<576, b256, 0, stream>>>(Abf, Wt + 2097152, zxrb, 4096, 2208, 1024, 18);   // xBC+dt (bf16)
  convk<<<8704, b256, 0, stream>>>(zxrb, conv_w, conv_b, dt_bias, xbcb, dtb);            // xbc_act (bf16) + dt
  ssd1_k<<<2048, b256, 0, stream>>>(xbcb, dtb, A_log, big2, dhbuf, labuf);               // Y_intra, dh, la
  ssd2_k<<<2048, b256, 0, stream>>>(dhbuf, labuf, hseq);                                 // chunk states
  ssd3_k<<<2048, b256, 0, stream>>>(xbcb, hseq, labuf, Dvec, big2);                      // ydin final
  gnormk<<<4096, b256, 0, stream>>>(big2, zbf, mnorm_w, Abf);                            // g (bf16)
  transp_k<<<dim3(32, 64), tb, 0, stream>>>(out_proj, Wt, 2048, 1024, 1024, 0, 1024);
  gemm4_k<1><<<256, b256, 0, stream>>>(Abf, Wt, mobf, 4096, 1024, 2048, 8);              // mo (bf16)
  resrms_k<1, 1, 0><<<4096, b256, 0, stream>>>(x, mobf, x1, Abf, nullptr);               // x1, xn2

  // ===== Phase B: mqa =====
  transpN_k<<<2176, tb, 0, stream>>>(                                                     // attn^T + proj^T
      attn_w, Wt, 1024, 1152, 1152, 36, 1152,
      proj_w, Wt + 1179648, 1024, 1024, 1024, 32, 1024,
      proj_w, Wt + 1179648, 1024, 1024, 1024, 32);
  gemm4_k<1><<<288, b256, 0, stream>>>(Abf, Wt, qkvbf, 4096, 1152, 1024, 9);             // qkv (bf16)
  attnk<<<1024, b256, 0, stream>>>(qkvbf, Abf);                                          // atty (bf16)
  gemm4_k<1><<<256, b256, 0, stream>>>(Abf, Wt + 1179648, pobf, 4096, 1024, 1024, 8);    // po (bf16)
  resrms_k<1, 1, 1><<<4096, b256, 0, stream>>>(x1, pobf, x1, Abf, xn3);                  // x2 (in x1), xn3

  // ===== Phase C: cmix =====
  mixk<<<4096, b256, 0, stream>>>(xn3, tmk, tmr, xkbf, xrbf);
  transpN_k<<<9216, tb, 0, stream>>>(                                                     // key^T, value^T, recept^T
      key_w, Wt, 1024, 4096, 4096, 128, 4096,
      value_w, valT, 4096, 1024, 1024, 32, 4096,
      recept_w, recT, 1024, 1024, 1024, 32);
  gemm8_k<2><<<256, b512, 0, stream>>>(xkbf, Wt, Abf, 4096, 4096, 1024, 16);             // kact (bf16, 1 blk/CU)
  gemm4_k<1><<<256, b256, 0, stream>>>(Abf, valT, voutbf, 4096, 1024, 4096, 8);          // vout (bf16)
  gemm4_k<1><<<256, b256, 0, stream>>>(xrbf, recT, rrawbf, 4096, 1024, 1024, 8);         // rraw (bf16)
  finalk<<<4096, b256, 0, stream>>>(x1, rrawbf, voutbf, out);
}

// Round 15
// 452.608 us; speedup vs baseline: 1.2222x; 1.0557x over previous
//
#include <hip/hip_runtime.h>

// ---------- helpers ----------
__device__ __forceinline__ unsigned short f2bf(float f) {
  unsigned u = __builtin_bit_cast(unsigned, f);
  u = u + 0x7fffu + ((u >> 16) & 1u);      // RNE
  return (unsigned short)(u >> 16);
}
__device__ __forceinline__ float bf2f(unsigned short u) {
  return __builtin_bit_cast(float, ((unsigned)u) << 16);
}

typedef __bf16 bf16x8 __attribute__((ext_vector_type(8)));
typedef float  f32x4  __attribute__((ext_vector_type(4)));
typedef unsigned short u16x8 __attribute__((ext_vector_type(8)));

#define GLD16(gp, lp) __builtin_amdgcn_global_load_lds( \
    (const __attribute__((address_space(1))) unsigned int*)(gp), \
    (__attribute__((address_space(3))) unsigned int*)(lp), 16, 0, 0)

// ---------- rmsnorm (+ optional bf16 residual delta) ----------
template<int HAS_DELTA, int WRITE_SUM>
__global__ __launch_bounds__(256) void resrms_k(const float* __restrict__ xin,
    const unsigned short* __restrict__ delta, float* __restrict__ xsum,
    unsigned short* __restrict__ nbf) {
  int row = blockIdx.x, tid = threadIdx.x;
  size_t base = ((size_t)row << 10) + ((size_t)tid << 2);
  float4 v = *(const float4*)(xin + base);
  if (HAS_DELTA) {
    ushort4 d = *(const ushort4*)(delta + base);
    v.x += bf2f(d.x); v.y += bf2f(d.y); v.z += bf2f(d.z); v.w += bf2f(d.w);
  }
  if (WRITE_SUM) *(float4*)(xsum + base) = v;
  float ss = v.x*v.x + v.y*v.y + v.z*v.z + v.w*v.w;
  #pragma unroll
  for (int off = 32; off; off >>= 1) ss += __shfl_xor(ss, off);
  __shared__ float ws4[4];
  if ((tid & 63) == 0) ws4[tid >> 6] = ss;
  __syncthreads();
  float tot = ws4[0] + ws4[1] + ws4[2] + ws4[3];
  float sc = rsqrtf(tot * (1.0f / 1024.0f) + 1e-5f);
  *(ushort4*)(nbf + base) = make_ushort4(f2bf(v.x*sc), f2bf(v.y*sc), f2bf(v.z*sc), f2bf(v.w*sc));
}

// ---------- transpose+convert: W[K][ldw] f32 -> Wt[Npad][K] bf16 ----------
__device__ __forceinline__ void transp_body(const float* __restrict__ W,
    unsigned short* __restrict__ Wt, int K, int Ncols, int col_off, int ldw,
    int bx, int by, int tx, int ty) {
  __shared__ float t[32][33];
  int n0 = bx << 5, k0 = by << 5;
  #pragma unroll
  for (int rr = 0; rr < 32; rr += 8) {
    int k = k0 + rr + ty, n = n0 + tx;
    t[rr + ty][tx] = (n < Ncols) ? W[(size_t)k * ldw + col_off + n] : 0.f;
  }
  __syncthreads();
  #pragma unroll
  for (int rr = 0; rr < 32; rr += 8) {
    int nrow = n0 + rr + ty;
    Wt[(size_t)nrow * K + k0 + tx] = f2bf(t[tx][rr + ty]);
  }
}

__global__ void transp_k(const float* __restrict__ W, unsigned short* __restrict__ Wt,
                         int K, int Ncols, int Npad, int col_off, int ldw) {
  transp_body(W, Wt, K, Ncols, col_off, ldw, blockIdx.x, blockIdx.y, threadIdx.x, threadIdx.y);
}

// batched transpose: up to 3 jobs in one launch (flat 1D grid, tb=(32,8))
__global__ void transpN_k(
    const float* W0, unsigned short* T0, int K0, int N0c, int ld0, int nbx0, int nb0,
    const float* W1, unsigned short* T1, int K1, int N1c, int ld1, int nbx1, int nb1,
    const float* W2, unsigned short* T2, int K2, int N2c, int ld2, int nbx2) {
  int bid = blockIdx.x;
  if (bid < nb0) {
    transp_body(W0, T0, K0, N0c, 0, ld0, bid % nbx0, bid / nbx0, threadIdx.x, threadIdx.y);
  } else if (bid < nb0 + nb1) {
    int lb = bid - nb0;
    transp_body(W1, T1, K1, N1c, 0, ld1, lb % nbx1, lb / nbx1, threadIdx.x, threadIdx.y);
  } else {
    int lb = bid - nb0 - nb1;
    transp_body(W2, T2, K2, N2c, 0, ld2, lb % nbx2, lb / nbx2, threadIdx.x, threadIdx.y);
  }
}

// ---------- 8-phase 256x256 bf16 MFMA GEMM (used for kact only) ----------
template<int EPI>   // 0=f32, 1=bf16, 2=erf->bf16
__global__ __launch_bounds__(512, 2) void gemm8_k(const unsigned short* __restrict__ A,
    const unsigned short* __restrict__ Bt, void* __restrict__ Cout,
    int M, int N, int K, int ntx) {
  __shared__ unsigned short lds[2 * 32768];   // 128 KiB
  const int tid = threadIdx.x;
  const int w = tid >> 6, lane = tid & 63;
  const int fr = lane & 15, g = lane >> 4;
  const int wmi = w >> 2, wni = w & 3;
  const int nwg = gridDim.x;
  const int nty = nwg / ntx;
  const int l = (blockIdx.x & 7) * (nwg >> 3) + (blockIdx.x >> 3);
  const int S = ((ntx & 3) == 0) ? 4 : (((ntx & 1) == 0) ? 2 : 1);
  const int sw = S * nty;
  const int s_ = l / sw, r_ = l - s_ * sw;
  const int bx = s_ * S + (r_ % S);
  const int by = r_ / S;
  const int m0 = by << 8, n0 = bx << 8;

  f32x4 acc[8][4];
  #pragma unroll
  for (int i = 0; i < 8; ++i)
    #pragma unroll
    for (int j = 0; j < 4; ++j) acc[i][j] = (f32x4){0.f, 0.f, 0.f, 0.f};

  const int r0 = tid >> 3, pc = tid & 7;
  const int lc = pc ^ (r0 & 7);
  const unsigned short* Abase = A + (size_t)(m0 + r0) * K + (lc << 3);
  const unsigned short* Bbase = Bt + (size_t)(n0 + r0) * K + (lc << 3);
  const size_t aK64 = (size_t)64 * K, aK128 = (size_t)128 * K;

#define STG_A(h_, kt_, bb_) { \
    const unsigned short* s0_ = Abase + (size_t)(h_) * aK128 + ((size_t)(kt_) << 6); \
    unsigned short* d0_ = lds + (bb_) * 32768 + (h_) * 8192 + (w << 9); \
    GLD16(s0_, d0_); GLD16(s0_ + aK64, d0_ + 4096); }
#define STG_B(h_, kt_, bb_) { \
    const unsigned short* s0_ = Bbase + (size_t)(h_) * aK128 + ((size_t)(kt_) << 6); \
    unsigned short* d0_ = lds + (bb_) * 32768 + 16384 + (h_) * 8192 + (w << 9); \
    GLD16(s0_, d0_); GLD16(s0_ + aK64, d0_ + 4096); }

  bf16x8 Areg[4][2], Breg[4][2];
#define LDA(mh_, bb_) { \
    _Pragma("unroll") for (int mf = 0; mf < 4; ++mf) \
    _Pragma("unroll") for (int kk = 0; kk < 2; ++kk) { \
      int r = ((mh_) << 6) + (mf << 4) + fr; \
      Areg[mf][kk] = *(const bf16x8*)&lds[(bb_) * 32768 + wmi * 8192 + (r << 6) + ((((kk << 2) + g) ^ (r & 7)) << 3)]; } }
#define LDB(nh_, bb_) { \
    _Pragma("unroll") for (int nf2 = 0; nf2 < 2; ++nf2) \
    _Pragma("unroll") for (int kk = 0; kk < 2; ++kk) { \
      int nf = ((nh_) << 1) + nf2; \
      int r = ((wni & 1) << 6) + (nf << 4) + fr; \
      Breg[nf][kk] = *(const bf16x8*)&lds[(bb_) * 32768 + 16384 + (wni >> 1) * 8192 + (r << 6) + ((((kk << 2) + g) ^ (r & 7)) << 3)]; } }
#define MM(mh_, nh_) { \
    __builtin_amdgcn_s_setprio(1); \
    _Pragma("unroll") for (int mf = 0; mf < 4; ++mf) \
    _Pragma("unroll") for (int nf2 = 0; nf2 < 2; ++nf2) \
    _Pragma("unroll") for (int kk = 0; kk < 2; ++kk) \
      acc[((mh_) << 2) + mf][((nh_) << 1) + nf2] = __builtin_amdgcn_mfma_f32_16x16x32_bf16( \
          Areg[mf][kk], Breg[((nh_) << 1) + nf2][kk], acc[((mh_) << 2) + mf][((nh_) << 1) + nf2], 0, 0, 0); \
    __builtin_amdgcn_s_setprio(0); }
#define BAR_LG \
    __builtin_amdgcn_s_barrier(); \
    asm volatile("s_waitcnt lgkmcnt(0)" ::: "memory"); \
    __builtin_amdgcn_sched_barrier(0);
#define ENDBAR \
    __builtin_amdgcn_s_barrier(); \
    __builtin_amdgcn_sched_barrier(0);

  STG_B(0, 0, 0) STG_B(1, 0, 0) STG_A(0, 0, 0) STG_A(1, 0, 0) STG_B(0, 1, 1) STG_B(1, 1, 1)
  asm volatile("s_waitcnt vmcnt(4)" ::: "memory");
  __builtin_amdgcn_s_barrier();
  __builtin_amdgcn_sched_barrier(0);

  const int NITER = K >> 7;
  for (int it = 0; it < NITER; ++it) {
    const int t = it << 1;
    const bool lastI = (it == NITER - 1);
    LDA(0, 0) LDB(0, 0)
    STG_A(0, t + 1, 1)
    BAR_LG MM(0, 0) ENDBAR
    LDB(1, 0)
    STG_A(1, t + 1, 1)
    BAR_LG MM(0, 1) ENDBAR
    LDA(1, 0)
    if (!lastI) STG_B(0, t + 2, 0)
    BAR_LG MM(1, 0) ENDBAR
    if (!lastI) STG_B(1, t + 2, 0)
    BAR_LG MM(1, 1)
    if (!lastI) { asm volatile("s_waitcnt vmcnt(4)" ::: "memory"); }
    else        { asm volatile("s_waitcnt vmcnt(0)" ::: "memory"); }
    ENDBAR
    LDA(0, 1) LDB(0, 1)
    if (!lastI) STG_A(0, t + 2, 0)
    BAR_LG MM(0, 0) ENDBAR
    LDB(1, 1)
    if (!lastI) STG_A(1, t + 2, 0)
    BAR_LG MM(0, 1) ENDBAR
    LDA(1, 1)
    if (!lastI) STG_B(0, t + 3, 1)
    BAR_LG MM(1, 0) ENDBAR
    if (!lastI) STG_B(1, t + 3, 1)
    BAR_LG MM(1, 1)
    if (!lastI) { asm volatile("s_waitcnt vmcnt(4)" ::: "memory"); }
    else        { asm volatile("s_waitcnt vmcnt(0)" ::: "memory"); }
    ENDBAR
  }
#undef STG_A
#undef STG_B
#undef LDA
#undef LDB
#undef MM
#undef BAR_LG
#undef ENDBAR

  asm volatile("s_waitcnt vmcnt(0)" ::: "memory");
  __syncthreads();
  float (*eps)[260] = (float(*)[260])lds;
  const int er = tid >> 3, ec0 = (tid & 7) << 5;
  #pragma unroll
  for (int slab = 0; slab < 4; ++slab) {
    if (wmi == (slab >> 1)) {
      const int mhs = slab & 1;
      #pragma unroll
      for (int mf = 0; mf < 4; ++mf)
        #pragma unroll
        for (int nf = 0; nf < 4; ++nf)
          #pragma unroll
          for (int rr = 0; rr < 4; ++rr)
            eps[(mf << 4) + (g << 2) + rr][(wni << 6) + (nf << 4) + fr] = acc[(mhs << 2) + mf][nf][rr];
    }
    __syncthreads();
    const int grow = m0 + (slab << 6) + er;
    if (EPI == 0) {
      float* orow = (float*)Cout + (size_t)grow * N + n0 + ec0;
      #pragma unroll
      for (int u = 0; u < 8; ++u) {
        int col = n0 + ec0 + (u << 2);
        if (col < N) {
          float4 v; v.x = eps[er][ec0 + (u << 2)]; v.y = eps[er][ec0 + (u << 2) + 1];
          v.z = eps[er][ec0 + (u << 2) + 2]; v.w = eps[er][ec0 + (u << 2) + 3];
          *(float4*)(orow + (u << 2)) = v;
        }
      }
    } else {
      unsigned short* orow = (unsigned short*)Cout + (size_t)grow * N + n0 + ec0;
      #pragma unroll
      for (int u = 0; u < 4; ++u) {
        int col = n0 + ec0 + (u << 3);
        if (col < N) {
          u16x8 pk;
          #pragma unroll
          for (int e = 0; e < 8; ++e) {
            float v = eps[er][ec0 + (u << 3) + e];
            if (EPI == 2) v = 0.5f * (1.0f + erff((v - 0.70710678f) * 2.5066283f));
            pk[e] = f2bf(v);
          }
          *(u16x8*)(orow + (u << 3)) = pk;
        }
      }
    }
    __syncthreads();
  }
}

// ---------- bf16 MFMA GEMM (m97-class, 3 blk/CU) ----------
// EPI: 0 = f32 store, 1 = bf16 store
template<int EPI>
__global__ __launch_bounds__(256, 3) void gemm4_k(const unsigned short* __restrict__ A,
    const unsigned short* __restrict__ Bt, void* __restrict__ Cout,
    int M, int N, int K, int ntx) {
  __shared__ char smem[49152];
  unsigned short* lds = (unsigned short*)smem;
  const int tid = threadIdx.x;
  const int w = tid >> 6, lane = tid & 63;
  const int fr = lane & 15, g = lane >> 4;
  const int nwg = gridDim.x;
  const int nty = nwg / ntx;
  const int l = (blockIdx.x & 7) * (nwg >> 3) + (blockIdx.x >> 3);
  const int S = ((ntx & 3) == 0) ? 4 : (((ntx & 1) == 0) ? 2 : 1);
  const int sw = S * nty;
  const int s = l / sw, r_ = l - s * sw;
  const int bx = s * S + (r_ % S);
  const int by = r_ / S;
  const int m0 = by << 7, n0 = bx << 7;
  const int wm = (w >> 1) << 6, wn = (w & 1) << 6;

  f32x4 acc[4][4];
  #pragma unroll
  for (int i = 0; i < 4; ++i)
    #pragma unroll
    for (int j = 0; j < 4; ++j) acc[i][j] = (f32x4){0.f, 0.f, 0.f, 0.f};

  const int r0s = tid >> 2, pc0 = tid & 3;
  const int lc0 = pc0 ^ ((r0s >> 1) & 3);
  const int r1s = r0s + 64;
  const int lc1 = pc0 ^ ((r1s >> 1) & 3);
  const unsigned short* a0 = A + (size_t)(m0 + r0s) * K + (lc0 << 3);
  const unsigned short* a1 = A + (size_t)(m0 + r1s) * K + (lc1 << 3);
  const unsigned short* b0 = Bt + (size_t)(n0 + r0s) * K + (lc0 << 3);
  const unsigned short* b1 = Bt + (size_t)(n0 + r1s) * K + (lc1 << 3);
  const int wofs = w << 9;

#define STAGE4(kt_, bb_) { \
    unsigned short* d_ = lds + (bb_) * 8192 + wofs; \
    GLD16(a0 + ((kt_) << 5), d_); \
    GLD16(a1 + ((kt_) << 5), d_ + 2048); \
    GLD16(b0 + ((kt_) << 5), d_ + 4096); \
    GLD16(b1 + ((kt_) << 5), d_ + 6144); }

  const int NT = K >> 5;
  STAGE4(0, 0)
  STAGE4(1, 1)
  asm volatile("s_waitcnt vmcnt(4)" ::: "memory");
  __builtin_amdgcn_s_barrier();
  __builtin_amdgcn_sched_barrier(0);

  int cb = 0;
  for (int t = 0; t < NT; ++t) {
    const unsigned short* bufp = lds + cb * 8192;
    int sb = cb + 2; if (sb >= 3) sb -= 3;
    const int have2 = (t + 2 < NT);
    if (have2) STAGE4(t + 2, sb)
    bf16x8 af[4], bv[4];
    #pragma unroll
    for (int i = 0; i < 4; ++i) {
      int r = wm + (i << 4) + fr;
      af[i] = *(const bf16x8*)&bufp[(r << 5) + (((g ^ (r >> 1)) & 3) << 3)];
    }
    #pragma unroll
    for (int j = 0; j < 4; ++j) {
      int r = wn + (j << 4) + fr;
      bv[j] = *(const bf16x8*)&bufp[4096 + (r << 5) + (((g ^ (r >> 1)) & 3) << 3)];
    }
    __builtin_amdgcn_s_setprio(1);
    #pragma unroll
    for (int i = 0; i < 4; ++i)
      #pragma unroll
      for (int j = 0; j < 4; ++j)
        acc[i][j] = __builtin_amdgcn_mfma_f32_16x16x32_bf16(af[i], bv[j], acc[i][j], 0, 0, 0);
    __builtin_amdgcn_s_setprio(0);
    if (t + 1 < NT) {
      if (have2) { asm volatile("s_waitcnt vmcnt(4)" ::: "memory"); }
      else       { asm volatile("s_waitcnt vmcnt(0)" ::: "memory"); }
      __builtin_amdgcn_s_barrier();
      __builtin_amdgcn_sched_barrier(0);
    }
    cb = cb + 1; if (cb >= 3) cb -= 3;
  }
#undef STAGE4

  float (*eps)[132] = (float(*)[132])smem;
  const int rin = g << 2;
  const int er = tid >> 2, ec0 = (tid & 3) << 5;
  #pragma unroll
  for (int rh = 0; rh < 2; ++rh) {
    __syncthreads();
    if ((wm >> 6) == rh) {
      #pragma unroll
      for (int i = 0; i < 4; ++i)
        #pragma unroll
        for (int j = 0; j < 4; ++j)
          #pragma unroll
          for (int rr = 0; rr < 4; ++rr)
            eps[(i << 4) + rin + rr][wn + (j << 4) + fr] = acc[i][j][rr];
    }
    __syncthreads();
    int grow = m0 + (rh << 6) + er;
    if (EPI == 0) {
      float* orow = (float*)Cout + (size_t)grow * N + n0 + ec0;
      #pragma unroll
      for (int u = 0; u < 8; ++u) {
        int col = n0 + ec0 + (u << 2);
        if (col < N) {
          float4 v; v.x = eps[er][ec0 + (u<<2)]; v.y = eps[er][ec0 + (u<<2) + 1];
          v.z = eps[er][ec0 + (u<<2) + 2]; v.w = eps[er][ec0 + (u<<2) + 3];
          *(float4*)(orow + (u << 2)) = v;
        }
      }
    } else {
      unsigned short* orow = (unsigned short*)Cout + (size_t)grow * N + n0 + ec0;
      #pragma unroll
      for (int u = 0; u < 4; ++u) {
        int col = n0 + ec0 + (u << 3);
        if (col < N) {
          u16x8 pk;
          #pragma unroll
          for (int e = 0; e < 8; ++e) pk[e] = f2bf(eps[er][ec0 + (u << 3) + e]);
          *(u16x8*)(orow + (u << 3)) = pk;
        }
      }
    }
  }
}

// ---------- causal depthwise conv(4) + silu, bf16 in/out, fused dt/softplus ----------
__global__ __launch_bounds__(256) void convk(const unsigned short* __restrict__ zxr,
    const float* __restrict__ conv_w, const float* __restrict__ conv_b,
    const float* __restrict__ dt_bias, unsigned short* __restrict__ xbc,
    float* __restrict__ dtb) {
  int idx = blockIdx.x * 256 + threadIdx.x;   // 4*1024*544
  if (idx >= 4 * 1024 * 544) return;
  int c4 = idx % 544; int bt = idx / 544; int t = bt & 1023;
  int c = c4 << 2;
  const unsigned short* col = zxr + (size_t)bt * 2208 + c;
  ushort4 zu = make_ushort4(0, 0, 0, 0);
  ushort4 u0 = *(const ushort4*)col;
  ushort4 u1 = (t >= 1) ? *(const ushort4*)(col - 2208) : zu;
  ushort4 u2 = (t >= 2) ? *(const ushort4*)(col - 4416) : zu;
  ushort4 u3 = (t >= 3) ? *(const ushort4*)(col - 6624) : zu;
  float4 x0 = make_float4(bf2f(u0.x), bf2f(u0.y), bf2f(u0.z), bf2f(u0.w));
  float4 x1 = make_float4(bf2f(u1.x), bf2f(u1.y), bf2f(u1.z), bf2f(u1.w));
  float4 x2 = make_float4(bf2f(u2.x), bf2f(u2.y), bf2f(u2.z), bf2f(u2.w));
  float4 x3 = make_float4(bf2f(u3.x), bf2f(u3.y), bf2f(u3.z), bf2f(u3.w));
  const float4* wp = (const float4*)(conv_w + (c << 2));
  float4 wa = wp[0], wb = wp[1], wc_ = wp[2], wd = wp[3];
  float4 bb = *(const float4*)(conv_b + c);
  float4 a;
  a.x = bb.x; a.x = fmaf(x3.x, wa.x, a.x); a.x = fmaf(x2.x, wa.y, a.x); a.x = fmaf(x1.x, wa.z, a.x); a.x = fmaf(x0.x, wa.w, a.x);
  a.y = bb.y; a.y = fmaf(x3.y, wb.x, a.y); a.y = fmaf(x2.y, wb.y, a.y); a.y = fmaf(x1.y, wb.z, a.y); a.y = fmaf(x0.y, wb.w, a.y);
  a.z = bb.z; a.z = fmaf(x3.z, wc_.x, a.z); a.z = fmaf(x2.z, wc_.y, a.z); a.z = fmaf(x1.z, wc_.z, a.z); a.z = fmaf(x0.z, wc_.w, a.z);
  a.w = bb.w; a.w = fmaf(x3.w, wd.x, a.w); a.w = fmaf(x2.w, wd.y, a.w); a.w = fmaf(x1.w, wd.z, a.w); a.w = fmaf(x0.w, wd.w, a.w);
  ushort4 o;
  o.x = f2bf(a.x / (1.f + __expf(-a.x)));
  o.y = f2bf(a.y / (1.f + __expf(-a.y)));
  o.z = f2bf(a.z / (1.f + __expf(-a.z)));
  o.w = f2bf(a.w / (1.f + __expf(-a.w)));
  *(ushort4*)(xbc + (size_t)bt * 2176 + c) = o;
  if (c < 32) {
    ushort4 du = *(const ushort4*)(zxr + (size_t)bt * 2208 + 2176 + c);
    float4 db = *(const float4*)(dt_bias + c);
    float4 r;
    float v;
    v = bf2f(du.x) + db.x; r.x = (v > 20.f) ? v : log1pf(__expf(v));
    v = bf2f(du.y) + db.y; r.y = (v > 20.f) ? v : log1pf(__expf(v));
    v = bf2f(du.z) + db.z; r.z = (v > 20.f) ? v : log1pf(__expf(v));
    v = bf2f(du.w) + db.w; r.w = (v > 20.f) ? v : log1pf(__expf(v));
    *(float4*)(dtb + bt * 32 + c) = r;
  }
}

// ---------- SSD chunked scan, stage 1 (xbc bf16; ydin/dhbuf bf16 out) ----------
__global__ __launch_bounds__(256) void ssd1_k(const unsigned short* __restrict__ xbc,
    const float* __restrict__ dtb, const float* __restrict__ A_log,
    unsigned short* __restrict__ ydin, unsigned short* __restrict__ dhbuf,
    float* __restrict__ labuf) {
  __shared__ unsigned short Cs[64][68];
  __shared__ unsigned short Bsm[64][68];
  __shared__ unsigned short XT[64][68];
  __shared__ unsigned short BT[64][68];
  __shared__ unsigned short Ms[64][68];
  __shared__ float laS[64], dtS[64];
  const int id = blockIdx.x;
  const int h = id & 31, b = (id >> 5) & 3, c = id >> 7;
  const int tid = threadIdx.x, w = tid >> 6, lane = tid & 63;
  const int fr = lane & 15, g = lane >> 4;
  const size_t rowbase = (size_t)((b << 10) + (c << 6));

  {
    int r = tid >> 2, c0 = (tid & 3) << 4;
    const unsigned short* src = xbc + (rowbase + r) * 2176;
    #pragma unroll
    for (int i = 0; i < 4; ++i) {
      *(ushort4*)&Cs[r][c0 + 4 * i]  = *(const ushort4*)(src + 2112 + c0 + 4 * i);
      *(ushort4*)&Bsm[r][c0 + 4 * i] = *(const ushort4*)(src + 2048 + c0 + 4 * i);
    }
  }
  {
    int r0 = (tid & 15) << 2, d0 = (tid >> 4) << 2;
    const unsigned short* src = xbc + (rowbase + r0) * 2176 + (h << 6) + d0;
    ushort4 v0 = *(const ushort4*)(src);
    ushort4 v1 = *(const ushort4*)(src + 2176);
    ushort4 v2 = *(const ushort4*)(src + 4352);
    ushort4 v3 = *(const ushort4*)(src + 6528);
    *(ushort4*)&XT[d0 + 0][r0] = make_ushort4(v0.x, v1.x, v2.x, v3.x);
    *(ushort4*)&XT[d0 + 1][r0] = make_ushort4(v0.y, v1.y, v2.y, v3.y);
    *(ushort4*)&XT[d0 + 2][r0] = make_ushort4(v0.z, v1.z, v2.z, v3.z);
    *(ushort4*)&XT[d0 + 3][r0] = make_ushort4(v0.w, v1.w, v2.w, v3.w);
  }
  if (w == 0) {
    float Ah = -__expf(A_log[h]);
    float dtv = dtb[(rowbase + lane) * 32 + h];
    float v = dtv * Ah;
    #pragma unroll
    for (int off = 1; off < 64; off <<= 1) {
      float u = __shfl_up(v, off);
      if (lane >= off) v += u;
    }
    laS[lane] = v; dtS[lane] = dtv;
    labuf[(size_t)((((b << 4) | c) << 5 | h) << 6) + lane] = v;
  }
  __syncthreads();

  const int wr = w >> 1, wc = w & 1;
  f32x4 gf[2][2];
  #pragma unroll
  for (int i = 0; i < 2; ++i)
    #pragma unroll
    for (int j = 0; j < 2; ++j) gf[i][j] = (f32x4){0.f, 0.f, 0.f, 0.f};
  {
    int r0 = (tid & 15) << 2, d0 = (tid >> 4) << 2;
    const unsigned short* src = xbc + (rowbase + r0) * 2176 + 2048 + d0;
    float la63 = laS[63];
    ushort4 v0 = *(const ushort4*)(src);
    ushort4 v1 = *(const ushort4*)(src + 2176);
    ushort4 v2 = *(const ushort4*)(src + 4352);
    ushort4 v3 = *(const ushort4*)(src + 6528);
    float w0 = __expf(la63 - laS[r0 + 0]) * dtS[r0 + 0];
    float w1 = __expf(la63 - laS[r0 + 1]) * dtS[r0 + 1];
    float w2 = __expf(la63 - laS[r0 + 2]) * dtS[r0 + 2];
    float w3 = __expf(la63 - laS[r0 + 3]) * dtS[r0 + 3];
    *(ushort4*)&BT[d0 + 0][r0] = make_ushort4(f2bf(bf2f(v0.x)*w0), f2bf(bf2f(v1.x)*w1), f2bf(bf2f(v2.x)*w2), f2bf(bf2f(v3.x)*w3));
    *(ushort4*)&BT[d0 + 1][r0] = make_ushort4(f2bf(bf2f(v0.y)*w0), f2bf(bf2f(v1.y)*w1), f2bf(bf2f(v2.y)*w2), f2bf(bf2f(v3.y)*w3));
    *(ushort4*)&BT[d0 + 2][r0] = make_ushort4(f2bf(bf2f(v0.z)*w0), f2bf(bf2f(v1.z)*w1), f2bf(bf2f(v2.z)*w2), f2bf(bf2f(v3.z)*w3));
    *(ushort4*)&BT[d0 + 3][r0] = make_ushort4(f2bf(bf2f(v0.w)*w0), f2bf(bf2f(v1.w)*w1), f2bf(bf2f(v2.w)*w2), f2bf(bf2f(v3.w)*w3));
  }
  #pragma unroll
  for (int ks = 0; ks < 2; ++ks) {
    bf16x8 ca[2], bb[2];
    #pragma unroll
    for (int i = 0; i < 2; ++i) ca[i] = *(const bf16x8*)&Cs[(wr << 5) + (i << 4) + fr][(ks << 5) + (g << 3)];
    #pragma unroll
    for (int j = 0; j < 2; ++j) bb[j] = *(const bf16x8*)&Bsm[(wc << 5) + (j << 4) + fr][(ks << 5) + (g << 3)];
    #pragma unroll
    for (int i = 0; i < 2; ++i)
      #pragma unroll
      for (int j = 0; j < 2; ++j)
        gf[i][j] = __builtin_amdgcn_mfma_f32_16x16x32_bf16(ca[i], bb[j], gf[i][j], 0, 0, 0);
  }
  #pragma unroll
  for (int i = 0; i < 2; ++i) {
    #pragma unroll
    for (int j = 0; j < 2; ++j) {
      int s = (wc << 5) + (j << 4) + fr;
      float la_s = laS[s], dt_s = dtS[s];
      #pragma unroll
      for (int rr = 0; rr < 4; ++rr) {
        int t = (wr << 5) + (i << 4) + (g << 2) + rr;
        float e = __expf(fminf(laS[t] - la_s, 0.f));
        float val = (s <= t) ? gf[i][j][rr] * e * dt_s : 0.f;
        Ms[t][s] = f2bf(val);
      }
    }
  }
  __syncthreads();

  f32x4 yf[2][2], hf[2][2];
  #pragma unroll
  for (int i = 0; i < 2; ++i)
    #pragma unroll
    for (int j = 0; j < 2; ++j) { yf[i][j] = (f32x4){0.f,0.f,0.f,0.f}; hf[i][j] = (f32x4){0.f,0.f,0.f,0.f}; }
  #pragma unroll
  for (int ks = 0; ks < 2; ++ks) {
    bf16x8 ma[2], ba[2], xb[2];
    #pragma unroll
    for (int i = 0; i < 2; ++i) {
      ma[i] = *(const bf16x8*)&Ms[(wr << 5) + (i << 4) + fr][(ks << 5) + (g << 3)];
      ba[i] = *(const bf16x8*)&BT[(wr << 5) + (i << 4) + fr][(ks << 5) + (g << 3)];
    }
    #pragma unroll
    for (int j = 0; j < 2; ++j) xb[j] = *(const bf16x8*)&XT[(wc << 5) + (j << 4) + fr][(ks << 5) + (g << 3)];
    #pragma unroll
    for (int i = 0; i < 2; ++i)
      #pragma unroll
      for (int j = 0; j < 2; ++j) {
        yf[i][j] = __builtin_amdgcn_mfma_f32_16x16x32_bf16(ma[i], xb[j], yf[i][j], 0, 0, 0);
        hf[i][j] = __builtin_amdgcn_mfma_f32_16x16x32_bf16(ba[i], xb[j], hf[i][j], 0, 0, 0);
      }
  }
  unsigned short* dhb = dhbuf + ((size_t)(((c << 2) + b) * 32 + h) << 12);
  #pragma unroll
  for (int i = 0; i < 2; ++i) {
    #pragma unroll
    for (int j = 0; j < 2; ++j) {
      int p = (wc << 5) + (j << 4) + fr;
      #pragma unroll
      for (int rr = 0; rr < 4; ++rr) {
        int t = (wr << 5) + (i << 4) + (g << 2) + rr;
        ydin[((rowbase + t) << 11) + (h << 6) + p] = f2bf(yf[i][j][rr]);
        dhb[(t << 6) + p] = f2bf(hf[i][j][rr]);
      }
    }
  }
}

// ---------- SSD stage 2 (bf16 storage, f32 carry) ----------
__global__ __launch_bounds__(256) void ssd2_k(const unsigned short* __restrict__ dhbuf,
    const float* __restrict__ labuf, unsigned short* __restrict__ hseq) {
  int idx = blockIdx.x * 256 + threadIdx.x;
  int np = idx & 4095;
  int h = (idx >> 12) & 31, b = idx >> 17;
  float carry = 0.f;
  #pragma unroll
  for (int c = 0; c < 16; ++c) {
    size_t o = ((size_t)(((c << 2) + b) * 32 + h) << 12) + np;
    hseq[o] = f2bf(carry);
    float ec = __expf(labuf[(size_t)((((b << 4) | c) << 5 | h) << 6) + 63]);
    carry = fmaf(ec, carry, bf2f(dhbuf[o]));
  }
}

// ---------- SSD stage 3 (xbc, hseq, ydin all bf16) ----------
__global__ __launch_bounds__(256) void ssd3_k(const unsigned short* __restrict__ xbc,
    const unsigned short* __restrict__ hseq, const float* __restrict__ labuf,
    const float* __restrict__ Dv, unsigned short* __restrict__ ydin) {
  __shared__ unsigned short Cs[64][68];
  __shared__ unsigned short HT[64][68];
  __shared__ float laS[64];
  const int id = blockIdx.x;
  const int h = id & 31, b = (id >> 5) & 3, c = id >> 7;
  const int tid = threadIdx.x, w = tid >> 6, lane = tid & 63;
  const int fr = lane & 15, g = lane >> 4;
  const size_t rowbase = (size_t)((b << 10) + (c << 6));
  {
    int r = tid >> 2, c0 = (tid & 3) << 4;
    const unsigned short* src = xbc + (rowbase + r) * 2176 + 2112;
    #pragma unroll
    for (int i = 0; i < 4; ++i)
      *(ushort4*)&Cs[r][c0 + 4 * i] = *(const ushort4*)(src + c0 + 4 * i);
  }
  {
    const unsigned short* hb = hseq + ((size_t)(((c << 2) + b) * 32 + h) << 12);
    int n0 = (tid & 15) << 2, p0 = (tid >> 4) << 2;
    ushort4 v0 = *(const ushort4*)(hb + ((n0 + 0) << 6) + p0);
    ushort4 v1 = *(const ushort4*)(hb + ((n0 + 1) << 6) + p0);
    ushort4 v2 = *(const ushort4*)(hb + ((n0 + 2) << 6) + p0);
    ushort4 v3 = *(const ushort4*)(hb + ((n0 + 3) << 6) + p0);
    *(ushort4*)&HT[p0 + 0][n0] = make_ushort4(v0.x, v1.x, v2.x, v3.x);
    *(ushort4*)&HT[p0 + 1][n0] = make_ushort4(v0.y, v1.y, v2.y, v3.y);
    *(ushort4*)&HT[p0 + 2][n0] = make_ushort4(v0.z, v1.z, v2.z, v3.z);
    *(ushort4*)&HT[p0 + 3][n0] = make_ushort4(v0.w, v1.w, v2.w, v3.w);
  }
  if (tid < 64) laS[tid] = labuf[(size_t)((((b << 4) | c) << 5 | h) << 6) + tid];
  __syncthreads();
  const int wr = w >> 1, wc = w & 1;
  f32x4 yf[2][2];
  #pragma unroll
  for (int i = 0; i < 2; ++i)
    #pragma unroll
    for (int j = 0; j < 2; ++j) yf[i][j] = (f32x4){0.f, 0.f, 0.f, 0.f};
  #pragma unroll
  for (int ks = 0; ks < 2; ++ks) {
    bf16x8 ca[2], hv[2];
    #pragma unroll
    for (int i = 0; i < 2; ++i) ca[i] = *(const bf16x8*)&Cs[(wr << 5) + (i << 4) + fr][(ks << 5) + (g << 3)];
    #pragma unroll
    for (int j = 0; j < 2; ++j) hv[j] = *(const bf16x8*)&HT[(wc << 5) + (j << 4) + fr][(ks << 5) + (g << 3)];
    #pragma unroll
    for (int i = 0; i < 2; ++i)
      #pragma unroll
      for (int j = 0; j < 2; ++j)
        yf[i][j] = __builtin_amdgcn_mfma_f32_16x16x32_bf16(ca[i], hv[j], yf[i][j], 0, 0, 0);
  }
  float Dh = Dv[h];
  #pragma unroll
  for (int i = 0; i < 2; ++i) {
    #pragma unroll
    for (int j = 0; j < 2; ++j) {
      int p = (wc << 5) + (j << 4) + fr;
      #pragma unroll
      for (int rr = 0; rr < 4; ++rr) {
        int t = (wr << 5) + (i << 4) + (g << 2) + rr;
        size_t yo = ((rowbase + t) << 11) + (h << 6) + p;
        float xv = bf2f(xbc[(rowbase + t) * 2176 + (h << 6) + p]);
        float prev = bf2f(ydin[yo]);
        ydin[yo] = f2bf(prev + __expf(laS[t]) * yf[i][j][rr] + Dh * xv);
      }
    }
  }
}

// ---------- g = ydin * silu(z); rmsnorm(2048) * mnorm_w -> bf16 (ydin bf16) ----------
__global__ __launch_bounds__(256) void gnormk(const unsigned short* __restrict__ ydin,
    const unsigned short* __restrict__ zbf, const float* __restrict__ mw,
    unsigned short* __restrict__ gbf) {
  int row = blockIdx.x, tid = threadIdx.x;
  size_t base = ((size_t)row << 11) + ((size_t)tid << 3);
  u16x8 yu = *(const u16x8*)(ydin + base);
  u16x8 zu = *(const u16x8*)(zbf + base);
  float g[8];
  #pragma unroll
  for (int k = 0; k < 8; ++k) {
    float z = bf2f(zu[k]);
    g[k] = bf2f(yu[k]) * (z / (1.f + __expf(-z)));
  }
  float ss = 0.f;
  #pragma unroll
  for (int k = 0; k < 8; ++k) ss += g[k] * g[k];
  #pragma unroll
  for (int off = 32; off; off >>= 1) ss += __shfl_xor(ss, off);
  __shared__ float ws4[4];
  if ((tid & 63) == 0) ws4[tid >> 6] = ss;
  __syncthreads();
  float tot = ws4[0] + ws4[1] + ws4[2] + ws4[3];
  float sc = rsqrtf(tot * (1.f / 2048.f) + 1e-5f);
  int c0 = tid << 3;
  float4 m0 = *(const float4*)(mw + c0);
  float4 m1 = *(const float4*)(mw + c0 + 4);
  float mwv[8] = {m0.x, m0.y, m0.z, m0.w, m1.x, m1.y, m1.z, m1.w};
  u16x8 pk;
  #pragma unroll
  for (int k = 0; k < 8; ++k) pk[k] = f2bf(g[k] * sc * mwv[k]);
  *(u16x8*)(gbf + base) = pk;
}

// ---------- MQA causal attention (MFMA flash), bf16 in/out ----------
__global__ __launch_bounds__(256) void attnk(const unsigned short* __restrict__ qkv,
                                             unsigned short* __restrict__ ybf) {
  __shared__ unsigned short Qs[64][72];
  __shared__ unsigned short Ks[64][72];
  __shared__ unsigned short VT[64][72];
  __shared__ unsigned short Ps[4][16][72];
  const int id = blockIdx.x;
  const int b = id & 3, h = (id >> 2) & 15, qt = id >> 6;
  const int t0 = qt << 6;
  const int tid = threadIdx.x, w = tid >> 6, lane = tid & 63;
  const int fr = lane & 15, g = lane >> 4;
  {
    int r = tid >> 2, d0 = (tid & 3) << 4;
    const unsigned short* src = qkv + ((size_t)((b << 10) | (t0 + r))) * 1152 + (h << 6) + d0;
    *(uint4*)&Qs[r][d0]     = *(const uint4*)(src);
    *(uint4*)&Qs[r][d0 + 8] = *(const uint4*)(src + 8);
  }
  __syncthreads();
  bf16x8 afQ0 = *(const bf16x8*)&Qs[(w << 4) + fr][g << 3];
  bf16x8 afQ1 = *(const bf16x8*)&Qs[(w << 4) + fr][32 + (g << 3)];
  f32x4 acc_o[4];
  #pragma unroll
  for (int i = 0; i < 4; ++i) acc_o[i] = (f32x4){0.f, 0.f, 0.f, 0.f};
  float m[4] = {-1e30f, -1e30f, -1e30f, -1e30f};
  float l[4] = {0.f, 0.f, 0.f, 0.f};
  const int qrow = t0 + (w << 4) + (g << 2);
  for (int kt = 0; kt <= qt; ++kt) {
    const int s0 = kt << 6;
    __syncthreads();
    {
      int r = tid >> 2, d0 = (tid & 3) << 4;
      const unsigned short* src = qkv + ((size_t)((b << 10) | (s0 + r))) * 1152 + 1024 + d0;
      *(uint4*)&Ks[r][d0]     = *(const uint4*)(src);
      *(uint4*)&Ks[r][d0 + 8] = *(const uint4*)(src + 8);
    }
    {
      int r0 = (tid & 15) << 2, d0 = (tid >> 4) << 2;
      const unsigned short* src = qkv + ((size_t)((b << 10) | (s0 + r0))) * 1152 + 1088 + d0;
      ushort4 v0 = *(const ushort4*)(src);
      ushort4 v1 = *(const ushort4*)(src + 1152);
      ushort4 v2 = *(const ushort4*)(src + 2304);
      ushort4 v3 = *(const ushort4*)(src + 3456);
      *(ushort4*)&VT[d0 + 0][r0] = make_ushort4(v0.x, v1.x, v2.x, v3.x);
      *(ushort4*)&VT[d0 + 1][r0] = make_ushort4(v0.y, v1.y, v2.y, v3.y);
      *(ushort4*)&VT[d0 + 2][r0] = make_ushort4(v0.z, v1.z, v2.z, v3.z);
      *(ushort4*)&VT[d0 + 3][r0] = make_ushort4(v0.w, v1.w, v2.w, v3.w);
    }
    __syncthreads();
    f32x4 s4[4];
    #pragma unroll
    for (int jt = 0; jt < 4; ++jt) {
      bf16x8 b0 = *(const bf16x8*)&Ks[(jt << 4) + fr][g << 3];
      bf16x8 b1 = *(const bf16x8*)&Ks[(jt << 4) + fr][32 + (g << 3)];
      f32x4 z4 = (f32x4){0.f, 0.f, 0.f, 0.f};
      z4 = __builtin_amdgcn_mfma_f32_16x16x32_bf16(afQ0, b0, z4, 0, 0, 0);
      z4 = __builtin_amdgcn_mfma_f32_16x16x32_bf16(afQ1, b1, z4, 0, 0, 0);
      s4[jt] = z4 * 0.125f;
    }
    if (kt == qt) {
      #pragma unroll
      for (int jt = 0; jt < 4; ++jt) {
        int key = s0 + (jt << 4) + fr;
        #pragma unroll
        for (int r = 0; r < 4; ++r)
          if (key > qrow + r) s4[jt][r] = -1e30f;
      }
    }
    #pragma unroll
    for (int r = 0; r < 4; ++r) {
      float mt = fmaxf(fmaxf(s4[0][r], s4[1][r]), fmaxf(s4[2][r], s4[3][r]));
      #pragma unroll
      for (int off = 8; off; off >>= 1) mt = fmaxf(mt, __shfl_xor(mt, off));
      float mn = fmaxf(m[r], mt);
      float scl = __expf(m[r] - mn);
      m[r] = mn;
      float ps = 0.f;
      #pragma unroll
      for (int jt = 0; jt < 4; ++jt) {
        float p = __expf(s4[jt][r] - mn);
        ps += p;
        Ps[w][(g << 2) + r][(jt << 4) + fr] = f2bf(p);
      }
      #pragma unroll
      for (int off = 8; off; off >>= 1) ps += __shfl_xor(ps, off);
      l[r] = l[r] * scl + ps;
      acc_o[0][r] *= scl; acc_o[1][r] *= scl; acc_o[2][r] *= scl; acc_o[3][r] *= scl;
    }
    #pragma unroll
    for (int ks = 0; ks < 2; ++ks) {
      bf16x8 ap = *(const bf16x8*)&Ps[w][fr][(ks << 5) + (g << 3)];
      #pragma unroll
      for (int dt = 0; dt < 4; ++dt) {
        bf16x8 bv = *(const bf16x8*)&VT[(dt << 4) + fr][(ks << 5) + (g << 3)];
        acc_o[dt] = __builtin_amdgcn_mfma_f32_16x16x32_bf16(ap, bv, acc_o[dt], 0, 0, 0);
      }
    }
  }
  #pragma unroll
  for (int dt = 0; dt < 4; ++dt) {
    #pragma unroll
    for (int r = 0; r < 4; ++r) {
      float o = acc_o[dt][r] / l[r];
      int t = t0 + (w << 4) + (g << 2) + r;
      ybf[(((size_t)((b << 10) | t)) << 10) + (h << 6) + (dt << 4) + fr] = f2bf(o);
    }
  }
}

// ---------- cmix token-shift mix (bf16 in) -> xk, xr (bf16) ----------
__global__ __launch_bounds__(256) void mixk(const unsigned short* __restrict__ xnb,
    const float* __restrict__ tmk, const float* __restrict__ tmr,
    unsigned short* __restrict__ xkbf, unsigned short* __restrict__ xrbf) {
  int idx4 = blockIdx.x * 256 + threadIdx.x;
  int col = (idx4 & 255) << 2;
  int row = idx4 >> 8;
  int t = row & 1023;
  size_t off = ((size_t)idx4) << 2;
  ushort4 cu = *(const ushort4*)(xnb + off);
  ushort4 pu = make_ushort4(0, 0, 0, 0);
  if (t > 0) pu = *(const ushort4*)(xnb + off - 1024);
  float4 cur = make_float4(bf2f(cu.x), bf2f(cu.y), bf2f(cu.z), bf2f(cu.w));
  float4 prev = make_float4(bf2f(pu.x), bf2f(pu.y), bf2f(pu.z), bf2f(pu.w));
  float4 tk = *(const float4*)(tmk + col);
  float4 tr = *(const float4*)(tmr + col);
  float dx = prev.x - cur.x, dy = prev.y - cur.y, dz = prev.z - cur.z, dw = prev.w - cur.w;
  *(ushort4*)(xkbf + off) = make_ushort4(
      f2bf(cur.x + dx * tk.x), f2bf(cur.y + dy * tk.y), f2bf(cur.z + dz * tk.z), f2bf(cur.w + dw * tk.w));
  *(ushort4*)(xrbf + off) = make_ushort4(
      f2bf(cur.x + dx * tr.x), f2bf(cur.y + dy * tr.y), f2bf(cur.z + dz * tr.z), f2bf(cur.w + dw * tr.w));
}

// ---------- final: out = x2 + sigmoid(rraw) * vout  (rraw, vout bf16) ----------
__global__ __launch_bounds__(256) void finalk(const float* __restrict__ x2,
    const unsigned short* __restrict__ rraw, const unsigned short* __restrict__ vout,
    float* __restrict__ out) {
  int idx4 = blockIdx.x * 256 + threadIdx.x;
  size_t off = ((size_t)idx4) << 2;
  float4 xv = *(const float4*)(x2 + off);
  ushort4 rv = *(const ushort4*)(rraw + off);
  ushort4 vv = *(const ushort4*)(vout + off);
  float4 o;
  o.x = xv.x + bf2f(vv.x) / (1.f + __expf(-bf2f(rv.x)));
  o.y = xv.y + bf2f(vv.y) / (1.f + __expf(-bf2f(rv.y)));
  o.z = xv.z + bf2f(vv.z) / (1.f + __expf(-bf2f(rv.z)));
  o.w = xv.w + bf2f(vv.w) / (1.f + __expf(-bf2f(rv.w)));
  *(float4*)(out + off) = o;
}

// ---------- host launcher ----------
extern "C" void kernel_launch(void* const* d_in, const int* in_sizes, int n_in,
                              void* d_out, int out_size, void* d_ws, size_t ws_size,
                              hipStream_t stream) {
  (void)in_sizes; (void)n_in; (void)out_size;
  const float* x        = (const float*)d_in[0];
  const float* in_proj  = (const float*)d_in[1];
  const float* conv_w   = (const float*)d_in[2];
  const float* conv_b   = (const float*)d_in[3];
  const float* dt_bias  = (const float*)d_in[4];
  const float* A_log    = (const float*)d_in[5];
  const float* Dvec     = (const float*)d_in[6];
  const float* mnorm_w  = (const float*)d_in[7];
  const float* out_proj = (const float*)d_in[8];
  const float* attn_w   = (const float*)d_in[9];
  const float* proj_w   = (const float*)d_in[10];
  const float* tmk      = (const float*)d_in[11];
  const float* tmr      = (const float*)d_in[12];
  const float* key_w    = (const float*)d_in[13];
  const float* recept_w = (const float*)d_in[14];
  const float* value_w  = (const float*)d_in[15];
  float* out = (float*)d_out;

  if (ws_size < 199229440ull) return;

  char* ws = (char*)d_ws;
  unsigned short* Wt   = (unsigned short*)(ws + 0);              // 8.9 MB
  unsigned short* Abf  = (unsigned short*)(ws + 8912896ull);
  unsigned short* Abf2 = (unsigned short*)(ws + 42467328ull);
  float* bigF = (float*)(ws + 59244544ull);
  float* big1 = (float*)(ws + 95420416ull);
  float* big2 = (float*)(ws + 131072000ull);
  float* x1   = (float*)(ws + 164626432ull);
  float* dtb  = (float*)(ws + 198180864ull);
  float* labuf= (float*)(ws + 198705152ull);
  unsigned short* zbf  = Abf2;
  unsigned short* xkbf = Abf2;
  unsigned short* xrbf = Abf2 + 4194304;
  unsigned short* dhbufb = (unsigned short*)bigF;
  unsigned short* hseqb  = (unsigned short*)Abf;
  unsigned short* zxrb = (unsigned short*)bigF;       // xBC+dt bf16 [4096][2208]
  unsigned short* xbcb = (unsigned short*)big1;       // xbc_act bf16 [4096][2176]
  unsigned short* ydinb = (unsigned short*)big2;      // ydin bf16 [4096][2048]
  unsigned short* qkvbf = (unsigned short*)big1;
  unsigned short* mobf  = (unsigned short*)big1;      // mo bf16
  unsigned short* pobf  = (unsigned short*)big2;      // po bf16
  unsigned short* voutbf = (unsigned short*)big2;     // vout bf16
  unsigned short* rrawbf = (unsigned short*)big1;     // rraw bf16 (after valT dead)
  unsigned short* valT = (unsigned short*)big1;
  unsigned short* recT = (unsigned short*)big1 + 10485760;   // @20MB (> rraw's 8.4MB)

  dim3 b256(256);
  dim3 b512(512);
  dim3 tb(32, 8);

  // ===== Phase A: mamba2 =====
  resrms_k<0, 0><<<4096, b256, 0, stream>>>(x, nullptr, nullptr, Abf);
  transp_k<<<dim3(136, 32), tb, 0, stream>>>(in_proj, Wt, 1024, 4256, 4352, 0, 4256);    // full in_proj^T
  gemm4_k<1><<<512, b256, 0, stream>>>(Abf, Wt, zbf, 4096, 2048, 1024, 16);              // z (rows 0..2047)
  gemm4_k<1><<<576, b256, 0, stream>>>(Abf, Wt + 2097152, zxrb, 4096, 2208, 1024, 18);   // xBC+dt (bf16)
  convk<<<8704, b256, 0, stream>>>(zxrb, conv_w, conv_b, dt_bias, xbcb, dtb);            // xbc_act (bf16) + dt
  ssd1_k<<<2048, b256, 0, stream>>>(xbcb, dtb, A_log, ydinb, dhbufb, labuf);             // Y_intra, dh, la
  ssd2_k<<<2048, b256, 0, stream>>>(dhbufb, labuf, hseqb);                               // chunk states
  ssd3_k<<<2048, b256, 0, stream>>>(xbcb, hseqb, labuf, Dvec, ydinb);                    // ydin final
  gnormk<<<4096, b256, 0, stream>>>(ydinb, zbf, mnorm_w, Abf);                           // g (bf16)
  transp_k<<<dim3(32, 64), tb, 0, stream>>>(out_proj, Wt, 2048, 1024, 1024, 0, 1024);
  gemm4_k<1><<<256, b256, 0, stream>>>(Abf, Wt, mobf, 4096, 1024, 2048, 8);              // mo (bf16)
  resrms_k<1, 1><<<4096, b256, 0, stream>>>(x, mobf, x1, Abf);                           // x1, xn2

  // ===== Phase B: mqa =====
  transpN_k<<<2176, tb, 0, stream>>>(                                                     // attn^T + proj^T
      attn_w, Wt, 1024, 1152, 1152, 36, 1152,
      proj_w, Wt + 1179648, 1024, 1024, 1024, 32, 1024,
      proj_w, Wt + 1179648, 1024, 1024, 1024, 32);
  gemm4_k<1><<<288, b256, 0, stream>>>(Abf, Wt, qkvbf, 4096, 1152, 1024, 9);             // qkv (bf16)
  attnk<<<1024, b256, 0, stream>>>(qkvbf, Abf);                                          // atty (bf16)
  gemm4_k<1><<<256, b256, 0, stream>>>(Abf, Wt + 1179648, pobf, 4096, 1024, 1024, 8);    // po (bf16)
  resrms_k<1, 1><<<4096, b256, 0, stream>>>(x1, pobf, x1, Abf);                          // x2 (in x1), xn3 (bf16 in Abf)

  // ===== Phase C: cmix =====
  mixk<<<4096, b256, 0, stream>>>(Abf, tmk, tmr, xkbf, xrbf);                            // reads xn3 bf16
  transpN_k<<<9216, tb, 0, stream>>>(                                                     // key^T, value^T, recept^T
      key_w, Wt, 1024, 4096, 4096, 128, 4096,
      value_w, valT, 4096, 1024, 1024, 32, 4096,
      recept_w, recT, 1024, 1024, 1024, 32);
  gemm8_k<2><<<256, b512, 0, stream>>>(xkbf, Wt, Abf, 4096, 4096, 1024, 16);             // kact (bf16, 1 blk/CU)
  gemm4_k<1><<<256, b256, 0, stream>>>(Abf, valT, voutbf, 4096, 1024, 4096, 8);          // vout (bf16)
  gemm4_k<1><<<256, b256, 0, stream>>>(xrbf, recT, rrawbf, 4096, 1024, 1024, 8);         // rraw (bf16)
  finalk<<<4096, b256, 0, stream>>>(x1, rrawbf, voutbf, out);
}

// Round 16
// 441.184 us; speedup vs baseline: 1.2539x; 1.0259x over previous
//
#include <hip/hip_runtime.h>

// ---------- helpers ----------
__device__ __forceinline__ unsigned short f2bf(float f) {
  unsigned u = __builtin_bit_cast(unsigned, f);
  u = u + 0x7fffu + ((u >> 16) & 1u);      // RNE
  return (unsigned short)(u >> 16);
}
__device__ __forceinline__ float bf2f(unsigned short u) {
  return __builtin_bit_cast(float, ((unsigned)u) << 16);
}

typedef __bf16 bf16x8 __attribute__((ext_vector_type(8)));
typedef float  f32x4  __attribute__((ext_vector_type(4)));
typedef unsigned short u16x8 __attribute__((ext_vector_type(8)));

#define GLD16(gp, lp) __builtin_amdgcn_global_load_lds( \
    (const __attribute__((address_space(1))) unsigned int*)(gp), \
    (__attribute__((address_space(3))) unsigned int*)(lp), 16, 0, 0)

// ---------- rmsnorm (+ optional bf16 residual delta); XIN_BF16: xin is bf16 ----------
template<int HAS_DELTA, int WRITE_SUM, int XIN_BF16>
__global__ __launch_bounds__(256) void resrms_k(const void* __restrict__ xin_,
    const unsigned short* __restrict__ delta, unsigned short* __restrict__ xsum,
    unsigned short* __restrict__ nbf) {
  int row = blockIdx.x, tid = threadIdx.x;
  size_t base = ((size_t)row << 10) + ((size_t)tid << 2);
  float4 v;
  if (XIN_BF16) {
    ushort4 u = *(const ushort4*)((const unsigned short*)xin_ + base);
    v = make_float4(bf2f(u.x), bf2f(u.y), bf2f(u.z), bf2f(u.w));
  } else {
    v = *(const float4*)((const float*)xin_ + base);
  }
  if (HAS_DELTA) {
    ushort4 d = *(const ushort4*)(delta + base);
    v.x += bf2f(d.x); v.y += bf2f(d.y); v.z += bf2f(d.z); v.w += bf2f(d.w);
  }
  if (WRITE_SUM)
    *(ushort4*)(xsum + base) = make_ushort4(f2bf(v.x), f2bf(v.y), f2bf(v.z), f2bf(v.w));
  float ss = v.x*v.x + v.y*v.y + v.z*v.z + v.w*v.w;
  #pragma unroll
  for (int off = 32; off; off >>= 1) ss += __shfl_xor(ss, off);
  __shared__ float ws4[4];
  if ((tid & 63) == 0) ws4[tid >> 6] = ss;
  __syncthreads();
  float tot = ws4[0] + ws4[1] + ws4[2] + ws4[3];
  float sc = rsqrtf(tot * (1.0f / 1024.0f) + 1e-5f);
  *(ushort4*)(nbf + base) = make_ushort4(f2bf(v.x*sc), f2bf(v.y*sc), f2bf(v.z*sc), f2bf(v.w*sc));
}

// ---------- transpose+convert: W[K][ldw] f32 -> Wt[Npad][K] bf16 ----------
__device__ __forceinline__ void transp_body(const float* __restrict__ W,
    unsigned short* __restrict__ Wt, int K, int Ncols, int col_off, int ldw,
    int bx, int by, int tx, int ty) {
  __shared__ float t[32][33];
  int n0 = bx << 5, k0 = by << 5;
  #pragma unroll
  for (int rr = 0; rr < 32; rr += 8) {
    int k = k0 + rr + ty, n = n0 + tx;
    t[rr + ty][tx] = (n < Ncols) ? W[(size_t)k * ldw + col_off + n] : 0.f;
  }
  __syncthreads();
  #pragma unroll
  for (int rr = 0; rr < 32; rr += 8) {
    int nrow = n0 + rr + ty;
    Wt[(size_t)nrow * K + k0 + tx] = f2bf(t[tx][rr + ty]);
  }
}

__global__ void transp_k(const float* __restrict__ W, unsigned short* __restrict__ Wt,
                         int K, int Ncols, int Npad, int col_off, int ldw) {
  transp_body(W, Wt, K, Ncols, col_off, ldw, blockIdx.x, blockIdx.y, threadIdx.x, threadIdx.y);
}

// batched transpose: up to 3 jobs in one launch (flat 1D grid, tb=(32,8))
__global__ void transpN_k(
    const float* W0, unsigned short* T0, int K0, int N0c, int ld0, int nbx0, int nb0,
    const float* W1, unsigned short* T1, int K1, int N1c, int ld1, int nbx1, int nb1,
    const float* W2, unsigned short* T2, int K2, int N2c, int ld2, int nbx2) {
  int bid = blockIdx.x;
  if (bid < nb0) {
    transp_body(W0, T0, K0, N0c, 0, ld0, bid % nbx0, bid / nbx0, threadIdx.x, threadIdx.y);
  } else if (bid < nb0 + nb1) {
    int lb = bid - nb0;
    transp_body(W1, T1, K1, N1c, 0, ld1, lb % nbx1, lb / nbx1, threadIdx.x, threadIdx.y);
  } else {
    int lb = bid - nb0 - nb1;
    transp_body(W2, T2, K2, N2c, 0, ld2, lb % nbx2, lb / nbx2, threadIdx.x, threadIdx.y);
  }
}

// ---------- 8-phase 256x256 bf16 MFMA GEMM (used for kact only) ----------
template<int EPI>   // 0=f32, 1=bf16, 2=erf->bf16
__global__ __launch_bounds__(512, 2) void gemm8_k(const unsigned short* __restrict__ A,
    const unsigned short* __restrict__ Bt, void* __restrict__ Cout,
    int M, int N, int K, int ntx) {
  __shared__ unsigned short lds[2 * 32768];   // 128 KiB
  const int tid = threadIdx.x;
  const int w = tid >> 6, lane = tid & 63;
  const int fr = lane & 15, g = lane >> 4;
  const int wmi = w >> 2, wni = w & 3;
  const int nwg = gridDim.x;
  const int nty = nwg / ntx;
  const int l = (blockIdx.x & 7) * (nwg >> 3) + (blockIdx.x >> 3);
  const int S = ((ntx & 3) == 0) ? 4 : (((ntx & 1) == 0) ? 2 : 1);
  const int sw = S * nty;
  const int s_ = l / sw, r_ = l - s_ * sw;
  const int bx = s_ * S + (r_ % S);
  const int by = r_ / S;
  const int m0 = by << 8, n0 = bx << 8;

  f32x4 acc[8][4];
  #pragma unroll
  for (int i = 0; i < 8; ++i)
    #pragma unroll
    for (int j = 0; j < 4; ++j) acc[i][j] = (f32x4){0.f, 0.f, 0.f, 0.f};

  const int r0 = tid >> 3, pc = tid & 7;
  const int lc = pc ^ (r0 & 7);
  const unsigned short* Abase = A + (size_t)(m0 + r0) * K + (lc << 3);
  const unsigned short* Bbase = Bt + (size_t)(n0 + r0) * K + (lc << 3);
  const size_t aK64 = (size_t)64 * K, aK128 = (size_t)128 * K;

#define STG_A(h_, kt_, bb_) { \
    const unsigned short* s0_ = Abase + (size_t)(h_) * aK128 + ((size_t)(kt_) << 6); \
    unsigned short* d0_ = lds + (bb_) * 32768 + (h_) * 8192 + (w << 9); \
    GLD16(s0_, d0_); GLD16(s0_ + aK64, d0_ + 4096); }
#define STG_B(h_, kt_, bb_) { \
    const unsigned short* s0_ = Bbase + (size_t)(h_) * aK128 + ((size_t)(kt_) << 6); \
    unsigned short* d0_ = lds + (bb_) * 32768 + 16384 + (h_) * 8192 + (w << 9); \
    GLD16(s0_, d0_); GLD16(s0_ + aK64, d0_ + 4096); }

  bf16x8 Areg[4][2], Breg[4][2];
#define LDA(mh_, bb_) { \
    _Pragma("unroll") for (int mf = 0; mf < 4; ++mf) \
    _Pragma("unroll") for (int kk = 0; kk < 2; ++kk) { \
      int r = ((mh_) << 6) + (mf << 4) + fr; \
      Areg[mf][kk] = *(const bf16x8*)&lds[(bb_) * 32768 + wmi * 8192 + (r << 6) + ((((kk << 2) + g) ^ (r & 7)) << 3)]; } }
#define LDB(nh_, bb_) { \
    _Pragma("unroll") for (int nf2 = 0; nf2 < 2; ++nf2) \
    _Pragma("unroll") for (int kk = 0; kk < 2; ++kk) { \
      int nf = ((nh_) << 1) + nf2; \
      int r = ((wni & 1) << 6) + (nf << 4) + fr; \
      Breg[nf][kk] = *(const bf16x8*)&lds[(bb_) * 32768 + 16384 + (wni >> 1) * 8192 + (r << 6) + ((((kk << 2) + g) ^ (r & 7)) << 3)]; } }
#define MM(mh_, nh_) { \
    __builtin_amdgcn_s_setprio(1); \
    _Pragma("unroll") for (int mf = 0; mf < 4; ++mf) \
    _Pragma("unroll") for (int nf2 = 0; nf2 < 2; ++nf2) \
    _Pragma("unroll") for (int kk = 0; kk < 2; ++kk) \
      acc[((mh_) << 2) + mf][((nh_) << 1) + nf2] = __builtin_amdgcn_mfma_f32_16x16x32_bf16( \
          Areg[mf][kk], Breg[((nh_) << 1) + nf2][kk], acc[((mh_) << 2) + mf][((nh_) << 1) + nf2], 0, 0, 0); \
    __builtin_amdgcn_s_setprio(0); }
#define BAR_LG \
    __builtin_amdgcn_s_barrier(); \
    asm volatile("s_waitcnt lgkmcnt(0)" ::: "memory"); \
    __builtin_amdgcn_sched_barrier(0);
#define ENDBAR \
    __builtin_amdgcn_s_barrier(); \
    __builtin_amdgcn_sched_barrier(0);

  STG_B(0, 0, 0) STG_B(1, 0, 0) STG_A(0, 0, 0) STG_A(1, 0, 0) STG_B(0, 1, 1) STG_B(1, 1, 1)
  asm volatile("s_waitcnt vmcnt(4)" ::: "memory");
  __builtin_amdgcn_s_barrier();
  __builtin_amdgcn_sched_barrier(0);

  const int NITER = K >> 7;
  for (int it = 0; it < NITER; ++it) {
    const int t = it << 1;
    const bool lastI = (it == NITER - 1);
    LDA(0, 0) LDB(0, 0)
    STG_A(0, t + 1, 1)
    BAR_LG MM(0, 0) ENDBAR
    LDB(1, 0)
    STG_A(1, t + 1, 1)
    BAR_LG MM(0, 1) ENDBAR
    LDA(1, 0)
    if (!lastI) STG_B(0, t + 2, 0)
    BAR_LG MM(1, 0) ENDBAR
    if (!lastI) STG_B(1, t + 2, 0)
    BAR_LG MM(1, 1)
    if (!lastI) { asm volatile("s_waitcnt vmcnt(4)" ::: "memory"); }
    else        { asm volatile("s_waitcnt vmcnt(0)" ::: "memory"); }
    ENDBAR
    LDA(0, 1) LDB(0, 1)
    if (!lastI) STG_A(0, t + 2, 0)
    BAR_LG MM(0, 0) ENDBAR
    LDB(1, 1)
    if (!lastI) STG_A(1, t + 2, 0)
    BAR_LG MM(0, 1) ENDBAR
    LDA(1, 1)
    if (!lastI) STG_B(0, t + 3, 1)
    BAR_LG MM(1, 0) ENDBAR
    if (!lastI) STG_B(1, t + 3, 1)
    BAR_LG MM(1, 1)
    if (!lastI) { asm volatile("s_waitcnt vmcnt(4)" ::: "memory"); }
    else        { asm volatile("s_waitcnt vmcnt(0)" ::: "memory"); }
    ENDBAR
  }
#undef STG_A
#undef STG_B
#undef LDA
#undef LDB
#undef MM
#undef BAR_LG
#undef ENDBAR

  asm volatile("s_waitcnt vmcnt(0)" ::: "memory");
  __syncthreads();
  float (*eps)[260] = (float(*)[260])lds;
  const int er = tid >> 3, ec0 = (tid & 7) << 5;
  #pragma unroll
  for (int slab = 0; slab < 4; ++slab) {
    if (wmi == (slab >> 1)) {
      const int mhs = slab & 1;
      #pragma unroll
      for (int mf = 0; mf < 4; ++mf)
        #pragma unroll
        for (int nf = 0; nf < 4; ++nf)
          #pragma unroll
          for (int rr = 0; rr < 4; ++rr)
            eps[(mf << 4) + (g << 2) + rr][(wni << 6) + (nf << 4) + fr] = acc[(mhs << 2) + mf][nf][rr];
    }
    __syncthreads();
    const int grow = m0 + (slab << 6) + er;
    if (EPI == 0) {
      float* orow = (float*)Cout + (size_t)grow * N + n0 + ec0;
      #pragma unroll
      for (int u = 0; u < 8; ++u) {
        int col = n0 + ec0 + (u << 2);
        if (col < N) {
          float4 v; v.x = eps[er][ec0 + (u << 2)]; v.y = eps[er][ec0 + (u << 2) + 1];
          v.z = eps[er][ec0 + (u << 2) + 2]; v.w = eps[er][ec0 + (u << 2) + 3];
          *(float4*)(orow + (u << 2)) = v;
        }
      }
    } else {
      unsigned short* orow = (unsigned short*)Cout + (size_t)grow * N + n0 + ec0;
      #pragma unroll
      for (int u = 0; u < 4; ++u) {
        int col = n0 + ec0 + (u << 3);
        if (col < N) {
          u16x8 pk;
          #pragma unroll
          for (int e = 0; e < 8; ++e) {
            float v = eps[er][ec0 + (u << 3) + e];
            if (EPI == 2) v = 0.5f * (1.0f + erff((v - 0.70710678f) * 2.5066283f));
            pk[e] = f2bf(v);
          }
          *(u16x8*)(orow + (u << 3)) = pk;
        }
      }
    }
    __syncthreads();
  }
}

// ---------- bf16 MFMA GEMM (m97-class, 3 blk/CU) ----------
// EPI: 0 = f32 store, 1 = bf16 store
template<int EPI>
__global__ __launch_bounds__(256, 3) void gemm4_k(const unsigned short* __restrict__ A,
    const unsigned short* __restrict__ Bt, void* __restrict__ Cout,
    int M, int N, int K, int ntx) {
  __shared__ char smem[49152];
  unsigned short* lds = (unsigned short*)smem;
  const int tid = threadIdx.x;
  const int w = tid >> 6, lane = tid & 63;
  const int fr = lane & 15, g = lane >> 4;
  const int nwg = gridDim.x;
  const int nty = nwg / ntx;
  const int l = (blockIdx.x & 7) * (nwg >> 3) + (blockIdx.x >> 3);
  const int S = ((ntx & 3) == 0) ? 4 : (((ntx & 1) == 0) ? 2 : 1);
  const int sw = S * nty;
  const int s = l / sw, r_ = l - s * sw;
  const int bx = s * S + (r_ % S);
  const int by = r_ / S;
  const int m0 = by << 7, n0 = bx << 7;
  const int wm = (w >> 1) << 6, wn = (w & 1) << 6;

  f32x4 acc[4][4];
  #pragma unroll
  for (int i = 0; i < 4; ++i)
    #pragma unroll
    for (int j = 0; j < 4; ++j) acc[i][j] = (f32x4){0.f, 0.f, 0.f, 0.f};

  const int r0s = tid >> 2, pc0 = tid & 3;
  const int lc0 = pc0 ^ ((r0s >> 1) & 3);
  const int r1s = r0s + 64;
  const int lc1 = pc0 ^ ((r1s >> 1) & 3);
  const unsigned short* a0 = A + (size_t)(m0 + r0s) * K + (lc0 << 3);
  const unsigned short* a1 = A + (size_t)(m0 + r1s) * K + (lc1 << 3);
  const unsigned short* b0 = Bt + (size_t)(n0 + r0s) * K + (lc0 << 3);
  const unsigned short* b1 = Bt + (size_t)(n0 + r1s) * K + (lc1 << 3);
  const int wofs = w << 9;

#define STAGE4(kt_, bb_) { \
    unsigned short* d_ = lds + (bb_) * 8192 + wofs; \
    GLD16(a0 + ((kt_) << 5), d_); \
    GLD16(a1 + ((kt_) << 5), d_ + 2048); \
    GLD16(b0 + ((kt_) << 5), d_ + 4096); \
    GLD16(b1 + ((kt_) << 5), d_ + 6144); }

  const int NT = K >> 5;
  STAGE4(0, 0)
  STAGE4(1, 1)
  asm volatile("s_waitcnt vmcnt(4)" ::: "memory");
  __builtin_amdgcn_s_barrier();
  __builtin_amdgcn_sched_barrier(0);

  int cb = 0;
  for (int t = 0; t < NT; ++t) {
    const unsigned short* bufp = lds + cb * 8192;
    int sb = cb + 2; if (sb >= 3) sb -= 3;
    const int have2 = (t + 2 < NT);
    if (have2) STAGE4(t + 2, sb)
    bf16x8 af[4], bv[4];
    #pragma unroll
    for (int i = 0; i < 4; ++i) {
      int r = wm + (i << 4) + fr;
      af[i] = *(const bf16x8*)&bufp[(r << 5) + (((g ^ (r >> 1)) & 3) << 3)];
    }
    #pragma unroll
    for (int j = 0; j < 4; ++j) {
      int r = wn + (j << 4) + fr;
      bv[j] = *(const bf16x8*)&bufp[4096 + (r << 5) + (((g ^ (r >> 1)) & 3) << 3)];
    }
    __builtin_amdgcn_s_setprio(1);
    #pragma unroll
    for (int i = 0; i < 4; ++i)
      #pragma unroll
      for (int j = 0; j < 4; ++j)
        acc[i][j] = __builtin_amdgcn_mfma_f32_16x16x32_bf16(af[i], bv[j], acc[i][j], 0, 0, 0);
    __builtin_amdgcn_s_setprio(0);
    if (t + 1 < NT) {
      if (have2) { asm volatile("s_waitcnt vmcnt(4)" ::: "memory"); }
      else       { asm volatile("s_waitcnt vmcnt(0)" ::: "memory"); }
      __builtin_amdgcn_s_barrier();
      __builtin_amdgcn_sched_barrier(0);
    }
    cb = cb + 1; if (cb >= 3) cb -= 3;
  }
#undef STAGE4

  float (*eps)[132] = (float(*)[132])smem;
  const int rin = g << 2;
  const int er = tid >> 2, ec0 = (tid & 3) << 5;
  #pragma unroll
  for (int rh = 0; rh < 2; ++rh) {
    __syncthreads();
    if ((wm >> 6) == rh) {
      #pragma unroll
      for (int i = 0; i < 4; ++i)
        #pragma unroll
        for (int j = 0; j < 4; ++j)
          #pragma unroll
          for (int rr = 0; rr < 4; ++rr)
            eps[(i << 4) + rin + rr][wn + (j << 4) + fr] = acc[i][j][rr];
    }
    __syncthreads();
    int grow = m0 + (rh << 6) + er;
    if (EPI == 0) {
      float* orow = (float*)Cout + (size_t)grow * N + n0 + ec0;
      #pragma unroll
      for (int u = 0; u < 8; ++u) {
        int col = n0 + ec0 + (u << 2);
        if (col < N) {
          float4 v; v.x = eps[er][ec0 + (u<<2)]; v.y = eps[er][ec0 + (u<<2) + 1];
          v.z = eps[er][ec0 + (u<<2) + 2]; v.w = eps[er][ec0 + (u<<2) + 3];
          *(float4*)(orow + (u << 2)) = v;
        }
      }
    } else {
      unsigned short* orow = (unsigned short*)Cout + (size_t)grow * N + n0 + ec0;
      #pragma unroll
      for (int u = 0; u < 4; ++u) {
        int col = n0 + ec0 + (u << 3);
        if (col < N) {
          u16x8 pk;
          #pragma unroll
          for (int e = 0; e < 8; ++e) pk[e] = f2bf(eps[er][ec0 + (u << 3) + e]);
          *(u16x8*)(orow + (u << 3)) = pk;
        }
      }
    }
  }
}

// ---------- causal depthwise conv(4) + silu, bf16 in/out (combined zxr stride 4256) ----------
__global__ __launch_bounds__(256) void convk(const unsigned short* __restrict__ zxr,
    const float* __restrict__ conv_w, const float* __restrict__ conv_b,
    const float* __restrict__ dt_bias, unsigned short* __restrict__ xbc,
    float* __restrict__ dtb) {
  int idx = blockIdx.x * 256 + threadIdx.x;   // 4*1024*544
  if (idx >= 4 * 1024 * 544) return;
  int c4 = idx % 544; int bt = idx / 544; int t = bt & 1023;
  int c = c4 << 2;
  const unsigned short* col = zxr + (size_t)bt * 4256 + 2048 + c;
  ushort4 zu = make_ushort4(0, 0, 0, 0);
  ushort4 u0 = *(const ushort4*)col;
  ushort4 u1 = (t >= 1) ? *(const ushort4*)(col - 4256) : zu;
  ushort4 u2 = (t >= 2) ? *(const ushort4*)(col - 8512) : zu;
  ushort4 u3 = (t >= 3) ? *(const ushort4*)(col - 12768) : zu;
  float4 x0 = make_float4(bf2f(u0.x), bf2f(u0.y), bf2f(u0.z), bf2f(u0.w));
  float4 x1 = make_float4(bf2f(u1.x), bf2f(u1.y), bf2f(u1.z), bf2f(u1.w));
  float4 x2 = make_float4(bf2f(u2.x), bf2f(u2.y), bf2f(u2.z), bf2f(u2.w));
  float4 x3 = make_float4(bf2f(u3.x), bf2f(u3.y), bf2f(u3.z), bf2f(u3.w));
  const float4* wp = (const float4*)(conv_w + (c << 2));
  float4 wa = wp[0], wb = wp[1], wc_ = wp[2], wd = wp[3];
  float4 bb = *(const float4*)(conv_b + c);
  float4 a;
  a.x = bb.x; a.x = fmaf(x3.x, wa.x, a.x); a.x = fmaf(x2.x, wa.y, a.x); a.x = fmaf(x1.x, wa.z, a.x); a.x = fmaf(x0.x, wa.w, a.x);
  a.y = bb.y; a.y = fmaf(x3.y, wb.x, a.y); a.y = fmaf(x2.y, wb.y, a.y); a.y = fmaf(x1.y, wb.z, a.y); a.y = fmaf(x0.y, wb.w, a.y);
  a.z = bb.z; a.z = fmaf(x3.z, wc_.x, a.z); a.z = fmaf(x2.z, wc_.y, a.z); a.z = fmaf(x1.z, wc_.z, a.z); a.z = fmaf(x0.z, wc_.w, a.z);
  a.w = bb.w; a.w = fmaf(x3.w, wd.x, a.w); a.w = fmaf(x2.w, wd.y, a.w); a.w = fmaf(x1.w, wd.z, a.w); a.w = fmaf(x0.w, wd.w, a.w);
  ushort4 o;
  o.x = f2bf(a.x / (1.f + __expf(-a.x)));
  o.y = f2bf(a.y / (1.f + __expf(-a.y)));
  o.z = f2bf(a.z / (1.f + __expf(-a.z)));
  o.w = f2bf(a.w / (1.f + __expf(-a.w)));
  *(ushort4*)(xbc + (size_t)bt * 2176 + c) = o;
  if (c < 32) {
    ushort4 du = *(const ushort4*)(zxr + (size_t)bt * 4256 + 4224 + c);
    float4 db = *(const float4*)(dt_bias + c);
    float4 r;
    float v;
    v = bf2f(du.x) + db.x; r.x = (v > 20.f) ? v : log1pf(__expf(v));
    v = bf2f(du.y) + db.y; r.y = (v > 20.f) ? v : log1pf(__expf(v));
    v = bf2f(du.z) + db.z; r.z = (v > 20.f) ? v : log1pf(__expf(v));
    v = bf2f(du.w) + db.w; r.w = (v > 20.f) ? v : log1pf(__expf(v));
    *(float4*)(dtb + bt * 32 + c) = r;
  }
}

// ---------- SSD chunked scan, stage 1 (xbc bf16; ydin/dhbuf bf16 out) ----------
__global__ __launch_bounds__(256) void ssd1_k(const unsigned short* __restrict__ xbc,
    const float* __restrict__ dtb, const float* __restrict__ A_log,
    unsigned short* __restrict__ ydin, unsigned short* __restrict__ dhbuf,
    float* __restrict__ labuf) {
  __shared__ unsigned short Cs[64][68];
  __shared__ unsigned short Bsm[64][68];
  __shared__ unsigned short XT[64][68];
  __shared__ unsigned short BT[64][68];
  __shared__ unsigned short Ms[64][68];
  __shared__ float laS[64], dtS[64];
  const int id = blockIdx.x;
  const int h = id & 31, b = (id >> 5) & 3, c = id >> 7;
  const int tid = threadIdx.x, w = tid >> 6, lane = tid & 63;
  const int fr = lane & 15, g = lane >> 4;
  const size_t rowbase = (size_t)((b << 10) + (c << 6));

  {
    int r = tid >> 2, c0 = (tid & 3) << 4;
    const unsigned short* src = xbc + (rowbase + r) * 2176;
    #pragma unroll
    for (int i = 0; i < 4; ++i) {
      *(ushort4*)&Cs[r][c0 + 4 * i]  = *(const ushort4*)(src + 2112 + c0 + 4 * i);
      *(ushort4*)&Bsm[r][c0 + 4 * i] = *(const ushort4*)(src + 2048 + c0 + 4 * i);
    }
  }
  {
    int r0 = (tid & 15) << 2, d0 = (tid >> 4) << 2;
    const unsigned short* src = xbc + (rowbase + r0) * 2176 + (h << 6) + d0;
    ushort4 v0 = *(const ushort4*)(src);
    ushort4 v1 = *(const ushort4*)(src + 2176);
    ushort4 v2 = *(const ushort4*)(src + 4352);
    ushort4 v3 = *(const ushort4*)(src + 6528);
    *(ushort4*)&XT[d0 + 0][r0] = make_ushort4(v0.x, v1.x, v2.x, v3.x);
    *(ushort4*)&XT[d0 + 1][r0] = make_ushort4(v0.y, v1.y, v2.y, v3.y);
    *(ushort4*)&XT[d0 + 2][r0] = make_ushort4(v0.z, v1.z, v2.z, v3.z);
    *(ushort4*)&XT[d0 + 3][r0] = make_ushort4(v0.w, v1.w, v2.w, v3.w);
  }
  if (w == 0) {
    float Ah = -__expf(A_log[h]);
    float dtv = dtb[(rowbase + lane) * 32 + h];
    float v = dtv * Ah;
    #pragma unroll
    for (int off = 1; off < 64; off <<= 1) {
      float u = __shfl_up(v, off);
      if (lane >= off) v += u;
    }
    laS[lane] = v; dtS[lane] = dtv;
    labuf[(size_t)((((b << 4) | c) << 5 | h) << 6) + lane] = v;
  }
  __syncthreads();

  const int wr = w >> 1, wc = w & 1;
  f32x4 gf[2][2];
  #pragma unroll
  for (int i = 0; i < 2; ++i)
    #pragma unroll
    for (int j = 0; j < 2; ++j) gf[i][j] = (f32x4){0.f, 0.f, 0.f, 0.f};
  {
    int r0 = (tid & 15) << 2, d0 = (tid >> 4) << 2;
    const unsigned short* src = xbc + (rowbase + r0) * 2176 + 2048 + d0;
    float la63 = laS[63];
    ushort4 v0 = *(const ushort4*)(src);
    ushort4 v1 = *(const ushort4*)(src + 2176);
    ushort4 v2 = *(const ushort4*)(src + 4352);
    ushort4 v3 = *(const ushort4*)(src + 6528);
    float w0 = __expf(la63 - laS[r0 + 0]) * dtS[r0 + 0];
    float w1 = __expf(la63 - laS[r0 + 1]) * dtS[r0 + 1];
    float w2 = __expf(la63 - laS[r0 + 2]) * dtS[r0 + 2];
    float w3 = __expf(la63 - laS[r0 + 3]) * dtS[r0 + 3];
    *(ushort4*)&BT[d0 + 0][r0] = make_ushort4(f2bf(bf2f(v0.x)*w0), f2bf(bf2f(v1.x)*w1), f2bf(bf2f(v2.x)*w2), f2bf(bf2f(v3.x)*w3));
    *(ushort4*)&BT[d0 + 1][r0] = make_ushort4(f2bf(bf2f(v0.y)*w0), f2bf(bf2f(v1.y)*w1), f2bf(bf2f(v2.y)*w2), f2bf(bf2f(v3.y)*w3));
    *(ushort4*)&BT[d0 + 2][r0] = make_ushort4(f2bf(bf2f(v0.z)*w0), f2bf(bf2f(v1.z)*w1), f2bf(bf2f(v2.z)*w2), f2bf(bf2f(v3.z)*w3));
    *(ushort4*)&BT[d0 + 3][r0] = make_ushort4(f2bf(bf2f(v0.w)*w0), f2bf(bf2f(v1.w)*w1), f2bf(bf2f(v2.w)*w2), f2bf(bf2f(v3.w)*w3));
  }
  #pragma unroll
  for (int ks = 0; ks < 2; ++ks) {
    bf16x8 ca[2], bb[2];
    #pragma unroll
    for (int i = 0; i < 2; ++i) ca[i] = *(const bf16x8*)&Cs[(wr << 5) + (i << 4) + fr][(ks << 5) + (g << 3)];
    #pragma unroll
    for (int j = 0; j < 2; ++j) bb[j] = *(const bf16x8*)&Bsm[(wc << 5) + (j << 4) + fr][(ks << 5) + (g << 3)];
    #pragma unroll
    for (int i = 0; i < 2; ++i)
      #pragma unroll
      for (int j = 0; j < 2; ++j)
        gf[i][j] = __builtin_amdgcn_mfma_f32_16x16x32_bf16(ca[i], bb[j], gf[i][j], 0, 0, 0);
  }
  #pragma unroll
  for (int i = 0; i < 2; ++i) {
    #pragma unroll
    for (int j = 0; j < 2; ++j) {
      int s = (wc << 5) + (j << 4) + fr;
      float la_s = laS[s], dt_s = dtS[s];
      #pragma unroll
      for (int rr = 0; rr < 4; ++rr) {
        int t = (wr << 5) + (i << 4) + (g << 2) + rr;
        float e = __expf(fminf(laS[t] - la_s, 0.f));
        float val = (s <= t) ? gf[i][j][rr] * e * dt_s : 0.f;
        Ms[t][s] = f2bf(val);
      }
    }
  }
  __syncthreads();

  f32x4 yf[2][2], hf[2][2];
  #pragma unroll
  for (int i = 0; i < 2; ++i)
    #pragma unroll
    for (int j = 0; j < 2; ++j) { yf[i][j] = (f32x4){0.f,0.f,0.f,0.f}; hf[i][j] = (f32x4){0.f,0.f,0.f,0.f}; }
  #pragma unroll
  for (int ks = 0; ks < 2; ++ks) {
    bf16x8 ma[2], ba[2], xb[2];
    #pragma unroll
    for (int i = 0; i < 2; ++i) {
      ma[i] = *(const bf16x8*)&Ms[(wr << 5) + (i << 4) + fr][(ks << 5) + (g << 3)];
      ba[i] = *(const bf16x8*)&BT[(wr << 5) + (i << 4) + fr][(ks << 5) + (g << 3)];
    }
    #pragma unroll
    for (int j = 0; j < 2; ++j) xb[j] = *(const bf16x8*)&XT[(wc << 5) + (j << 4) + fr][(ks << 5) + (g << 3)];
    #pragma unroll
    for (int i = 0; i < 2; ++i)
      #pragma unroll
      for (int j = 0; j < 2; ++j) {
        yf[i][j] = __builtin_amdgcn_mfma_f32_16x16x32_bf16(ma[i], xb[j], yf[i][j], 0, 0, 0);
        hf[i][j] = __builtin_amdgcn_mfma_f32_16x16x32_bf16(ba[i], xb[j], hf[i][j], 0, 0, 0);
      }
  }
  unsigned short* dhb = dhbuf + ((size_t)(((c << 2) + b) * 32 + h) << 12);
  #pragma unroll
  for (int i = 0; i < 2; ++i) {
    #pragma unroll
    for (int j = 0; j < 2; ++j) {
      int p = (wc << 5) + (j << 4) + fr;
      #pragma unroll
      for (int rr = 0; rr < 4; ++rr) {
        int t = (wr << 5) + (i << 4) + (g << 2) + rr;
        ydin[((rowbase + t) << 11) + (h << 6) + p] = f2bf(yf[i][j][rr]);
        dhb[(t << 6) + p] = f2bf(hf[i][j][rr]);
      }
    }
  }
}

// ---------- SSD stage 2 (bf16 storage, f32 carry) ----------
__global__ __launch_bounds__(256) void ssd2_k(const unsigned short* __restrict__ dhbuf,
    const float* __restrict__ labuf, unsigned short* __restrict__ hseq) {
  int idx = blockIdx.x * 256 + threadIdx.x;
  int np = idx & 4095;
  int h = (idx >> 12) & 31, b = idx >> 17;
  float carry = 0.f;
  #pragma unroll
  for (int c = 0; c < 16; ++c) {
    size_t o = ((size_t)(((c << 2) + b) * 32 + h) << 12) + np;
    hseq[o] = f2bf(carry);
    float ec = __expf(labuf[(size_t)((((b << 4) | c) << 5 | h) << 6) + 63]);
    carry = fmaf(ec, carry, bf2f(dhbuf[o]));
  }
}

// ---------- SSD stage 3 (xbc, hseq, ydin all bf16) ----------
__global__ __launch_bounds__(256) void ssd3_k(const unsigned short* __restrict__ xbc,
    const unsigned short* __restrict__ hseq, const float* __restrict__ labuf,
    const float* __restrict__ Dv, unsigned short* __restrict__ ydin) {
  __shared__ unsigned short Cs[64][68];
  __shared__ unsigned short HT[64][68];
  __shared__ float laS[64];
  const int id = blockIdx.x;
  const int h = id & 31, b = (id >> 5) & 3, c = id >> 7;
  const int tid = threadIdx.x, w = tid >> 6, lane = tid & 63;
  const int fr = lane & 15, g = lane >> 4;
  const size_t rowbase = (size_t)((b << 10) + (c << 6));
  {
    int r = tid >> 2, c0 = (tid & 3) << 4;
    const unsigned short* src = xbc + (rowbase + r) * 2176 + 2112;
    #pragma unroll
    for (int i = 0; i < 4; ++i)
      *(ushort4*)&Cs[r][c0 + 4 * i] = *(const ushort4*)(src + c0 + 4 * i);
  }
  {
    const unsigned short* hb = hseq + ((size_t)(((c << 2) + b) * 32 + h) << 12);
    int n0 = (tid & 15) << 2, p0 = (tid >> 4) << 2;
    ushort4 v0 = *(const ushort4*)(hb + ((n0 + 0) << 6) + p0);
    ushort4 v1 = *(const ushort4*)(hb + ((n0 + 1) << 6) + p0);
    ushort4 v2 = *(const ushort4*)(hb + ((n0 + 2) << 6) + p0);
    ushort4 v3 = *(const ushort4*)(hb + ((n0 + 3) << 6) + p0);
    *(ushort4*)&HT[p0 + 0][n0] = make_ushort4(v0.x, v1.x, v2.x, v3.x);
    *(ushort4*)&HT[p0 + 1][n0] = make_ushort4(v0.y, v1.y, v2.y, v3.y);
    *(ushort4*)&HT[p0 + 2][n0] = make_ushort4(v0.z, v1.z, v2.z, v3.z);
    *(ushort4*)&HT[p0 + 3][n0] = make_ushort4(v0.w, v1.w, v2.w, v3.w);
  }
  if (tid < 64) laS[tid] = labuf[(size_t)((((b << 4) | c) << 5 | h) << 6) + tid];
  __syncthreads();
  const int wr = w >> 1, wc = w & 1;
  f32x4 yf[2][2];
  #pragma unroll
  for (int i = 0; i < 2; ++i)
    #pragma unroll
    for (int j = 0; j < 2; ++j) yf[i][j] = (f32x4){0.f, 0.f, 0.f, 0.f};
  #pragma unroll
  for (int ks = 0; ks < 2; ++ks) {
    bf16x8 ca[2], hv[2];
    #pragma unroll
    for (int i = 0; i < 2; ++i) ca[i] = *(const bf16x8*)&Cs[(wr << 5) + (i << 4) + fr][(ks << 5) + (g << 3)];
    #pragma unroll
    for (int j = 0; j < 2; ++j) hv[j] = *(const bf16x8*)&HT[(wc << 5) + (j << 4) + fr][(ks << 5) + (g << 3)];
    #pragma unroll
    for (int i = 0; i < 2; ++i)
      #pragma unroll
      for (int j = 0; j < 2; ++j)
        yf[i][j] = __builtin_amdgcn_mfma_f32_16x16x32_bf16(ca[i], hv[j], yf[i][j], 0, 0, 0);
  }
  float Dh = Dv[h];
  #pragma unroll
  for (int i = 0; i < 2; ++i) {
    #pragma unroll
    for (int j = 0; j < 2; ++j) {
      int p = (wc << 5) + (j << 4) + fr;
      #pragma unroll
      for (int rr = 0; rr < 4; ++rr) {
        int t = (wr << 5) + (i << 4) + (g << 2) + rr;
        size_t yo = ((rowbase + t) << 11) + (h << 6) + p;
        float xv = bf2f(xbc[(rowbase + t) * 2176 + (h << 6) + p]);
        float prev = bf2f(ydin[yo]);
        ydin[yo] = f2bf(prev + __expf(laS[t]) * yf[i][j][rr] + Dh * xv);
      }
    }
  }
}

// ---------- g = ydin * silu(z); rmsnorm(2048) * mnorm_w -> bf16 (z from combined, stride 4256) ----------
__global__ __launch_bounds__(256) void gnormk(const unsigned short* __restrict__ ydin,
    const unsigned short* __restrict__ zcomb, const float* __restrict__ mw,
    unsigned short* __restrict__ gbf) {
  int row = blockIdx.x, tid = threadIdx.x;
  size_t base = ((size_t)row << 11) + ((size_t)tid << 3);
  u16x8 yu = *(const u16x8*)(ydin + base);
  u16x8 zu = *(const u16x8*)(zcomb + (size_t)row * 4256 + (tid << 3));
  float g[8];
  #pragma unroll
  for (int k = 0; k < 8; ++k) {
    float z = bf2f(zu[k]);
    g[k] = bf2f(yu[k]) * (z / (1.f + __expf(-z)));
  }
  float ss = 0.f;
  #pragma unroll
  for (int k = 0; k < 8; ++k) ss += g[k] * g[k];
  #pragma unroll
  for (int off = 32; off; off >>= 1) ss += __shfl_xor(ss, off);
  __shared__ float ws4[4];
  if ((tid & 63) == 0) ws4[tid >> 6] = ss;
  __syncthreads();
  float tot = ws4[0] + ws4[1] + ws4[2] + ws4[3];
  float sc = rsqrtf(tot * (1.f / 2048.f) + 1e-5f);
  int c0 = tid << 3;
  float4 m0 = *(const float4*)(mw + c0);
  float4 m1 = *(const float4*)(mw + c0 + 4);
  float mwv[8] = {m0.x, m0.y, m0.z, m0.w, m1.x, m1.y, m1.z, m1.w};
  u16x8 pk;
  #pragma unroll
  for (int k = 0; k < 8; ++k) pk[k] = f2bf(g[k] * sc * mwv[k]);
  *(u16x8*)(gbf + base) = pk;
}

// ---------- MQA causal attention (MFMA flash), bf16 in/out ----------
__global__ __launch_bounds__(256) void attnk(const unsigned short* __restrict__ qkv,
                                             unsigned short* __restrict__ ybf) {
  __shared__ unsigned short Qs[64][72];
  __shared__ unsigned short Ks[64][72];
  __shared__ unsigned short VT[64][72];
  __shared__ unsigned short Ps[4][16][72];
  const int id = blockIdx.x;
  const int b = id & 3, h = (id >> 2) & 15, qt = id >> 6;
  const int t0 = qt << 6;
  const int tid = threadIdx.x, w = tid >> 6, lane = tid & 63;
  const int fr = lane & 15, g = lane >> 4;
  {
    int r = tid >> 2, d0 = (tid & 3) << 4;
    const unsigned short* src = qkv + ((size_t)((b << 10) | (t0 + r))) * 1152 + (h << 6) + d0;
    *(uint4*)&Qs[r][d0]     = *(const uint4*)(src);
    *(uint4*)&Qs[r][d0 + 8] = *(const uint4*)(src + 8);
  }
  __syncthreads();
  bf16x8 afQ0 = *(const bf16x8*)&Qs[(w << 4) + fr][g << 3];
  bf16x8 afQ1 = *(const bf16x8*)&Qs[(w << 4) + fr][32 + (g << 3)];
  f32x4 acc_o[4];
  #pragma unroll
  for (int i = 0; i < 4; ++i) acc_o[i] = (f32x4){0.f, 0.f, 0.f, 0.f};
  float m[4] = {-1e30f, -1e30f, -1e30f, -1e30f};
  float l[4] = {0.f, 0.f, 0.f, 0.f};
  const int qrow = t0 + (w << 4) + (g << 2);
  for (int kt = 0; kt <= qt; ++kt) {
    const int s0 = kt << 6;
    __syncthreads();
    {
      int r = tid >> 2, d0 = (tid & 3) << 4;
      const unsigned short* src = qkv + ((size_t)((b << 10) | (s0 + r))) * 1152 + 1024 + d0;
      *(uint4*)&Ks[r][d0]     = *(const uint4*)(src);
      *(uint4*)&Ks[r][d0 + 8] = *(const uint4*)(src + 8);
    }
    {
      int r0 = (tid & 15) << 2, d0 = (tid >> 4) << 2;
      const unsigned short* src = qkv + ((size_t)((b << 10) | (s0 + r0))) * 1152 + 1088 + d0;
      ushort4 v0 = *(const ushort4*)(src);
      ushort4 v1 = *(const ushort4*)(src + 1152);
      ushort4 v2 = *(const ushort4*)(src + 2304);
      ushort4 v3 = *(const ushort4*)(src + 3456);
      *(ushort4*)&VT[d0 + 0][r0] = make_ushort4(v0.x, v1.x, v2.x, v3.x);
      *(ushort4*)&VT[d0 + 1][r0] = make_ushort4(v0.y, v1.y, v2.y, v3.y);
      *(ushort4*)&VT[d0 + 2][r0] = make_ushort4(v0.z, v1.z, v2.z, v3.z);
      *(ushort4*)&VT[d0 + 3][r0] = make_ushort4(v0.w, v1.w, v2.w, v3.w);
    }
    __syncthreads();
    f32x4 s4[4];
    #pragma unroll
    for (int jt = 0; jt < 4; ++jt) {
      bf16x8 b0 = *(const bf16x8*)&Ks[(jt << 4) + fr][g << 3];
      bf16x8 b1 = *(const bf16x8*)&Ks[(jt << 4) + fr][32 + (g << 3)];
      f32x4 z4 = (f32x4){0.f, 0.f, 0.f, 0.f};
      z4 = __builtin_amdgcn_mfma_f32_16x16x32_bf16(afQ0, b0, z4, 0, 0, 0);
      z4 = __builtin_amdgcn_mfma_f32_16x16x32_bf16(afQ1, b1, z4, 0, 0, 0);
      s4[jt] = z4 * 0.125f;
    }
    if (kt == qt) {
      #pragma unroll
      for (int jt = 0; jt < 4; ++jt) {
        int key = s0 + (jt << 4) + fr;
        #pragma unroll
        for (int r = 0; r < 4; ++r)
          if (key > qrow + r) s4[jt][r] = -1e30f;
      }
    }
    #pragma unroll
    for (int r = 0; r < 4; ++r) {
      float mt = fmaxf(fmaxf(s4[0][r], s4[1][r]), fmaxf(s4[2][r], s4[3][r]));
      #pragma unroll
      for (int off = 8; off; off >>= 1) mt = fmaxf(mt, __shfl_xor(mt, off));
      float mn = fmaxf(m[r], mt);
      float scl = __expf(m[r] - mn);
      m[r] = mn;
      float ps = 0.f;
      #pragma unroll
      for (int jt = 0; jt < 4; ++jt) {
        float p = __expf(s4[jt][r] - mn);
        ps += p;
        Ps[w][(g << 2) + r][(jt << 4) + fr] = f2bf(p);
      }
      #pragma unroll
      for (int off = 8; off; off >>= 1) ps += __shfl_xor(ps, off);
      l[r] = l[r] * scl + ps;
      acc_o[0][r] *= scl; acc_o[1][r] *= scl; acc_o[2][r] *= scl; acc_o[3][r] *= scl;
    }
    #pragma unroll
    for (int ks = 0; ks < 2; ++ks) {
      bf16x8 ap = *(const bf16x8*)&Ps[w][fr][(ks << 5) + (g << 3)];
      #pragma unroll
      for (int dt = 0; dt < 4; ++dt) {
        bf16x8 bv = *(const bf16x8*)&VT[(dt << 4) + fr][(ks << 5) + (g << 3)];
        acc_o[dt] = __builtin_amdgcn_mfma_f32_16x16x32_bf16(ap, bv, acc_o[dt], 0, 0, 0);
      }
    }
  }
  #pragma unroll
  for (int dt = 0; dt < 4; ++dt) {
    #pragma unroll
    for (int r = 0; r < 4; ++r) {
      float o = acc_o[dt][r] / l[r];
      int t = t0 + (w << 4) + (g << 2) + r;
      ybf[(((size_t)((b << 10) | t)) << 10) + (h << 6) + (dt << 4) + fr] = f2bf(o);
    }
  }
}

// ---------- cmix token-shift mix (bf16 in) -> xk, xr (bf16) ----------
__global__ __launch_bounds__(256) void mixk(const unsigned short* __restrict__ xnb,
    const float* __restrict__ tmk, const float* __restrict__ tmr,
    unsigned short* __restrict__ xkbf, unsigned short* __restrict__ xrbf) {
  int idx4 = blockIdx.x * 256 + threadIdx.x;
  int col = (idx4 & 255) << 2;
  int row = idx4 >> 8;
  int t = row & 1023;
  size_t off = ((size_t)idx4) << 2;
  ushort4 cu = *(const ushort4*)(xnb + off);
  ushort4 pu = make_ushort4(0, 0, 0, 0);
  if (t > 0) pu = *(const ushort4*)(xnb + off - 1024);
  float4 cur = make_float4(bf2f(cu.x), bf2f(cu.y), bf2f(cu.z), bf2f(cu.w));
  float4 prev = make_float4(bf2f(pu.x), bf2f(pu.y), bf2f(pu.z), bf2f(pu.w));
  float4 tk = *(const float4*)(tmk + col);
  float4 tr = *(const float4*)(tmr + col);
  float dx = prev.x - cur.x, dy = prev.y - cur.y, dz = prev.z - cur.z, dw = prev.w - cur.w;
  *(ushort4*)(xkbf + off) = make_ushort4(
      f2bf(cur.x + dx * tk.x), f2bf(cur.y + dy * tk.y), f2bf(cur.z + dz * tk.z), f2bf(cur.w + dw * tk.w));
  *(ushort4*)(xrbf + off) = make_ushort4(
      f2bf(cur.x + dx * tr.x), f2bf(cur.y + dy * tr.y), f2bf(cur.z + dz * tr.z), f2bf(cur.w + dw * tr.w));
}

// ---------- final: out = x2 + sigmoid(rraw) * vout  (x2, rraw, vout bf16) ----------
__global__ __launch_bounds__(256) void finalk(const unsigned short* __restrict__ x2,
    const unsigned short* __restrict__ rraw, const unsigned short* __restrict__ vout,
    float* __restrict__ out) {
  int idx4 = blockIdx.x * 256 + threadIdx.x;
  size_t off = ((size_t)idx4) << 2;
  ushort4 xu = *(const ushort4*)(x2 + off);
  ushort4 rv = *(const ushort4*)(rraw + off);
  ushort4 vv = *(const ushort4*)(vout + off);
  float4 o;
  o.x = bf2f(xu.x) + bf2f(vv.x) / (1.f + __expf(-bf2f(rv.x)));
  o.y = bf2f(xu.y) + bf2f(vv.y) / (1.f + __expf(-bf2f(rv.y)));
  o.z = bf2f(xu.z) + bf2f(vv.z) / (1.f + __expf(-bf2f(rv.z)));
  o.w = bf2f(xu.w) + bf2f(vv.w) / (1.f + __expf(-bf2f(rv.w)));
  *(float4*)(out + off) = o;
}

// ---------- host launcher ----------
extern "C" void kernel_launch(void* const* d_in, const int* in_sizes, int n_in,
                              void* d_out, int out_size, void* d_ws, size_t ws_size,
                              hipStream_t stream) {
  (void)in_sizes; (void)n_in; (void)out_size;
  const float* x        = (const float*)d_in[0];
  const float* in_proj  = (const float*)d_in[1];
  const float* conv_w   = (const float*)d_in[2];
  const float* conv_b   = (const float*)d_in[3];
  const float* dt_bias  = (const float*)d_in[4];
  const float* A_log    = (const float*)d_in[5];
  const float* Dvec     = (const float*)d_in[6];
  const float* mnorm_w  = (const float*)d_in[7];
  const float* out_proj = (const float*)d_in[8];
  const float* attn_w   = (const float*)d_in[9];
  const float* proj_w   = (const float*)d_in[10];
  const float* tmk      = (const float*)d_in[11];
  const float* tmr      = (const float*)d_in[12];
  const float* key_w    = (const float*)d_in[13];
  const float* recept_w = (const float*)d_in[14];
  const float* value_w  = (const float*)d_in[15];
  float* out = (float*)d_out;

  if (ws_size < 199229440ull) return;

  char* ws = (char*)d_ws;
  unsigned short* Wt   = (unsigned short*)(ws + 0);              // 8.9 MB
  unsigned short* Abf  = (unsigned short*)(ws + 8912896ull);     // 33.5 MB region
  unsigned short* Abf2 = (unsigned short*)(ws + 42467328ull);
  float* bigF = (float*)(ws + 59244544ull);                      // 36.2 MB region
  float* big1 = (float*)(ws + 95420416ull);
  float* big2 = (float*)(ws + 131072000ull);
  unsigned short* x1b = (unsigned short*)(ws + 164626432ull);    // x1 bf16 8.4MB
  float* dtb  = (float*)(ws + 198180864ull);
  float* labuf= (float*)(ws + 198705152ull);
  unsigned short* xkbf = Abf2;
  unsigned short* xrbf = Abf2 + 4194304;
  unsigned short* zcomb = (unsigned short*)bigF;      // combined z+xBC bf16 [4096][4256] (34.9MB)
  unsigned short* hseqb  = (unsigned short*)Abf;                       // 16.8MB
  unsigned short* dhbufb = (unsigned short*)Abf + 8388608;             // +16.8MB (Abf region upper half)
  unsigned short* xbcb = (unsigned short*)big1;       // xbc_act bf16 [4096][2176]
  unsigned short* ydinb = (unsigned short*)big2;      // ydin bf16 [4096][2048]
  unsigned short* qkvbf = (unsigned short*)big1;
  unsigned short* mobf  = (unsigned short*)big1;      // mo bf16
  unsigned short* pobf  = (unsigned short*)big2;      // po bf16
  unsigned short* voutbf = (unsigned short*)big2;     // vout bf16
  unsigned short* rrawbf = (unsigned short*)big1;     // rraw bf16 (after valT dead)
  unsigned short* valT = (unsigned short*)big1;
  unsigned short* recT = (unsigned short*)big1 + 10485760;   // @20MB (> rraw's 8.4MB)

  dim3 b256(256);
  dim3 b512(512);
  dim3 tb(32, 8);

  // ===== Phase A: mamba2 =====
  resrms_k<0, 0, 0><<<4096, b256, 0, stream>>>(x, nullptr, nullptr, Abf);                // xn1 (Abf lower)
  transp_k<<<dim3(136, 32), tb, 0, stream>>>(in_proj, Wt, 1024, 4256, 4352, 0, 4256);    // full in_proj^T
  gemm4_k<1><<<1088, b256, 0, stream>>>(Abf, Wt, zcomb, 4096, 4256, 1024, 34);           // z+xBC+dt combined (bf16)
  convk<<<8704, b256, 0, stream>>>(zcomb, conv_w, conv_b, dt_bias, xbcb, dtb);           // xbc_act (bf16) + dt
  ssd1_k<<<2048, b256, 0, stream>>>(xbcb, dtb, A_log, ydinb, dhbufb, labuf);             // Y_intra, dh, la
  ssd2_k<<<2048, b256, 0, stream>>>(dhbufb, labuf, hseqb);                               // chunk states (xn1 dead)
  ssd3_k<<<2048, b256, 0, stream>>>(xbcb, hseqb, labuf, Dvec, ydinb);                    // ydin final
  gnormk<<<4096, b256, 0, stream>>>(ydinb, zcomb, mnorm_w, Abf);                         // g (bf16, hseq dead)
  transp_k<<<dim3(32, 64), tb, 0, stream>>>(out_proj, Wt, 2048, 1024, 1024, 0, 1024);
  gemm4_k<1><<<256, b256, 0, stream>>>(Abf, Wt, mobf, 4096, 1024, 2048, 8);              // mo (bf16)
  resrms_k<1, 1, 0><<<4096, b256, 0, stream>>>(x, mobf, x1b, Abf);                       // x1(bf16), xn2

  // ===== Phase B: mqa =====
  transpN_k<<<2176, tb, 0, stream>>>(                                                     // attn^T + proj^T
      attn_w, Wt, 1024, 1152, 1152, 36, 1152,
      proj_w, Wt + 1179648, 1024, 1024, 1024, 32, 1024,
      proj_w, Wt + 1179648, 1024, 1024, 1024, 32);
  gemm4_k<1><<<288, b256, 0, stream>>>(Abf, Wt, qkvbf, 4096, 1152, 1024, 9);             // qkv (bf16)
  attnk<<<1024, b256, 0, stream>>>(qkvbf, Abf);                                          // atty (bf16)
  gemm4_k<1><<<256, b256, 0, stream>>>(Abf, Wt + 1179648, pobf, 4096, 1024, 1024, 8);    // po (bf16)
  resrms_k<1, 1, 1><<<4096, b256, 0, stream>>>(x1b, pobf, x1b, Abf);                     // x2 (bf16, in-place), xn3

  // ===== Phase C: cmix =====
  mixk<<<4096, b256, 0, stream>>>(Abf, tmk, tmr, xkbf, xrbf);                            // reads xn3 bf16
  transpN_k<<<9216, tb, 0, stream>>>(                                                     // key^T, value^T, recept^T
      key_w, Wt, 1024, 4096, 4096, 128, 4096,
      value_w, valT, 4096, 1024, 1024, 32, 4096,
      recept_w, recT, 1024, 1024, 1024, 32);
  gemm8_k<2><<<256, b512, 0, stream>>>(xkbf, Wt, Abf, 4096, 4096, 1024, 16);             // kact (bf16, 1 blk/CU)
  gemm4_k<1><<<256, b256, 0, stream>>>(Abf, valT, voutbf, 4096, 1024, 4096, 8);          // vout (bf16)
  gemm4_k<1><<<256, b256, 0, stream>>>(xrbf, recT, rrawbf, 4096, 1024, 1024, 8);         // rraw (bf16)
  finalk<<<4096, b256, 0, stream>>>(x1b, rrawbf, voutbf, out);
}